// Round 1
// 1942.150 us; speedup vs baseline: 1.1804x; 1.1804x over previous
//
#include <hip/hip_runtime.h>
#include <cstdint>

#define NB 4
#define NPTS 4096
#define KNN 20
#define BN (NB*NPTS)   // 16384

typedef _Float16 f16x8 __attribute__((ext_vector_type(8)));
typedef float    f32x4 __attribute__((ext_vector_type(4)));

__device__ __forceinline__ float lrelu_f(float x) { return x > 0.f ? x : 0.2f * x; }

__device__ __forceinline__ float med3f(float c, float lo, float hi) {
#if defined(__has_builtin)
#if __has_builtin(__builtin_amdgcn_fmed3f)
  return __builtin_amdgcn_fmed3f(c, lo, hi);
#else
  return fminf(fmaxf(c, lo), hi);
#endif
#else
  return fminf(fmaxf(c, lo), hi);
#endif
}

// async global->LDS, 16B per lane (lane-linear LDS dest required)
__device__ __forceinline__ void gld16(const void* g, void* l) {
  __builtin_amdgcn_global_load_lds(
      (const __attribute__((address_space(1))) void*)g,
      (__attribute__((address_space(3))) void*)l,
      16, 0, 0);
}

__device__ __forceinline__ void split_store(_Float16* __restrict__ H, _Float16* __restrict__ L,
                                            size_t idx, float v) {
  _Float16 h = (_Float16)v;
  H[idx] = h;
  L[idx] = (_Float16)(v - (float)h);
}

// ---------------------------------------------------------------- prep weights
// Produces: WT2 (fp32, dg2), BUV1/BUV2 (fp32 bias), and f16 hi/lo splits of the
// effective weights in [M][K] layout for the MFMA gemms.
__global__ __launch_bounds__(256) void prep_weights(
    const float* __restrict__ wdg1, const float* __restrict__ bdg1,
    const float* __restrict__ wdg2,
    const float* __restrict__ wsn1, const float* __restrict__ bsn1,
    const float* __restrict__ w3,
    float* __restrict__ WT2, float* __restrict__ BUV1, float* __restrict__ BUV2,
    _Float16* __restrict__ W3H, _Float16* __restrict__ W3L,
    _Float16* __restrict__ WH1, _Float16* __restrict__ WL1,
    _Float16* __restrict__ WH2, _Float16* __restrict__ WL2)
{
  int i = blockIdx.x * 256 + threadIdx.x;
  if (i < 512*1024) {           // w3 is already [M=1024][K=512]
    float v = w3[i];
    split_store(W3H, W3L, i, v);
  }
  if (i < 256*64) {             // WEFF1: [M=256][K=64]
    int r = i >> 6, c = i & 63;
    float v = (r < 128) ? wdg1[r*128 + c]
                        : (wdg1[(r-128)*128 + 64 + c] - wdg1[(r-128)*128 + c]);
    split_store(WH1, WL1, i, v);
  }
  if (i < 512*128) {            // WEFF2: [M=512][K=128]
    int r = i >> 7, c = i & 127;
    float v = (r < 256) ? wsn1[r*256 + c]
                        : (wsn1[(r-256)*256 + 128 + c] - wsn1[(r-256)*256 + c]);
    split_store(WH2, WL2, i, v);
  }
  if (i < 128*128) { int c = i >> 7, o = i & 127; WT2[i] = wdg2[o*128 + c]; }
  if (i < 256) BUV1[i] = (i < 128) ? 0.f : bdg1[i-128];
  if (i < 512) BUV2[i] = (i < 256) ? 0.f : bsn1[i-256];
}

// ---------------------------------------------------------------- pack xyz -> float4 (x,y,z,xx)
__global__ __launch_bounds__(256) void pack_xyz(
    const float* __restrict__ xyz, float4* __restrict__ XTP4)
{
  int i = blockIdx.x * 256 + threadIdx.x;
  if (i >= BN) return;
  int b = i >> 12, n = i & (NPTS-1);
  const float* p = xyz + (size_t)b*3*NPTS;
  float x = p[n], y = p[NPTS+n], z = p[2*NPTS+n];
  float4 v; v.x = x; v.y = y; v.z = z; v.w = x*x + y*y + z*z;
  XTP4[i] = v;
}

// ---------------------------------------------------------------- conv1 + conv2 fused (3->64->64), point-major out + sqnorm + f16 split
__global__ __launch_bounds__(256) void conv12(
    const float* __restrict__ xyz,
    const float* __restrict__ w1, const float* __restrict__ b1,
    const float* __restrict__ w2, const float* __restrict__ b2,
    float* __restrict__ XT2, float* __restrict__ XX2,
    _Float16* __restrict__ XT2H, _Float16* __restrict__ XT2L)
{
  __shared__ float w2t[64*65];
  __shared__ float h1s[4][64];
  int tid = threadIdx.x;
  for (int i = tid; i < 4096; i += 256) {
    int o = i >> 6, c = i & 63;
    w2t[c*65 + o] = w2[i];
  }
  int g = tid >> 6, o = tid & 63;
  int pt = blockIdx.x*4 + g;
  int b = pt >> 12, n = pt & (NPTS-1);
  const float* p = xyz + (size_t)b*3*NPTS;
  float x = p[n], y = p[NPTS+n], z = p[2*NPTS+n];
  float h1 = b1[o] + w1[o*3]*x + w1[o*3+1]*y + w1[o*3+2]*z;
  h1 = lrelu_f(h1);
  __syncthreads();
  h1s[g][o] = h1;
  __syncthreads();
  float acc = b2[o];
  #pragma unroll
  for (int c = 0; c < 64; ++c) acc = fmaf(w2t[c*65+o], h1s[g][c], acc);
  acc = lrelu_f(acc);
  XT2[(size_t)pt*64 + o] = acc;
  split_store(XT2H, XT2L, (size_t)pt*64 + o, acc);
  float v = acc*acc;
  #pragma unroll
  for (int s = 32; s > 0; s >>= 1) v += __shfl_down(v, s, 64);
  if (o == 0) XX2[pt] = v;
}

// ---------------------------------------------------------------- distance GEMM (per batch): D[q][j] = xx_j - 2*dot(q,j)
__global__ __launch_bounds__(256) void dist_gemm(
    const float* __restrict__ XQ,   // batch slice of XT2, [4096][64]
    const float* __restrict__ XXb,  // batch slice of XX2, [4096]
    float* __restrict__ D)          // [4096][4096]
{
  __shared__ float Qs[16][132];
  __shared__ float Xs[16][132];
  int tid = threadIdx.x;
  int rg = tid & 15, cg = tid >> 4;
  int q0 = blockIdx.y * 128, j0 = blockIdx.x * 128;
  float acc[8][8];
  #pragma unroll
  for (int u = 0; u < 8; ++u)
    #pragma unroll
    for (int v = 0; v < 8; ++v) acc[u][v] = 0.f;

  for (int c0 = 0; c0 < 64; c0 += 16) {
    #pragma unroll
    for (int i = 0; i < 8; ++i) {
      int idx = tid + i*256;
      int kk = idx & 15, p = idx >> 4;
      Qs[kk][p] = XQ[(size_t)(q0+p)*64 + c0 + kk];
      Xs[kk][p] = XQ[(size_t)(j0+p)*64 + c0 + kk];
    }
    __syncthreads();
    #pragma unroll
    for (int kk = 0; kk < 16; ++kk) {
      float a[8], bb[8];
      #pragma unroll
      for (int u = 0; u < 8; ++u) a[u] = Qs[kk][rg*8+u];
      #pragma unroll
      for (int v = 0; v < 8; ++v) bb[v] = Xs[kk][cg*8+v];
      #pragma unroll
      for (int u = 0; u < 8; ++u)
        #pragma unroll
        for (int v = 0; v < 8; ++v) acc[u][v] = fmaf(a[u], bb[v], acc[u][v]);
    }
    __syncthreads();
  }
  float xxv[8];
  #pragma unroll
  for (int v = 0; v < 8; ++v) xxv[v] = XXb[j0 + cg*8 + v];
  #pragma unroll
  for (int u = 0; u < 8; ++u) {
    float* po = D + (size_t)(q0 + rg*8 + u)*NPTS + j0 + cg*8;
    #pragma unroll
    for (int v = 0; v < 8; ++v) po[v] = fmaf(-2.f, acc[u][v], xxv[v]);
  }
}

// ---------------------------------------------------------------- knn select: one wave per query, exact top-20 indices
template<bool FEAT_MODE>
__global__ __launch_bounds__(256) void knn_select(
    const float* __restrict__ D, const float4* __restrict__ XTP4,
    int batch, int* __restrict__ IDX)
{
  int lane = threadIdx.x & 63;
  int ql = blockIdx.x*4 + (threadIdx.x >> 6);   // query local to batch
  int qg = batch*NPTS + ql;                     // global point id
  const float4* drow4 = FEAT_MODE ? (const float4*)(D + (size_t)ql*NPTS) : nullptr;
  const float4* Xb4 = XTP4 + (size_t)batch*NPTS;
  float qx = 0.f, qy = 0.f, qz = 0.f;
  if (!FEAT_MODE) { float4 qp = XTP4[qg]; qx = qp.x; qy = qp.y; qz = qp.z; }

  auto key3 = [&](float4 p) -> float {
    float dot = qx*p.x;
    dot = fmaf(qy, p.y, dot);
    dot = fmaf(qz, p.z, dot);
    return fmaf(-2.f, dot, p.w);
  };
  auto getd4 = [&](int t) -> float4 {
    if (FEAT_MODE) {
      return drow4[t*64 + lane];
    } else {
      int jb = t*256 + lane*4;
      float4 r;
      r.x = key3(Xb4[jb+0]);
      r.y = key3(Xb4[jb+1]);
      r.z = key3(Xb4[jb+2]);
      r.w = key3(Xb4[jb+3]);
      return r;
    }
  };

  // ---- phase 1: per-lane top-20 distances (values only) over 64 candidates
  float bd[KNN];
  #pragma unroll
  for (int t = 0; t < KNN; ++t) bd[t] = 1e30f;
  for (int t = 0; t < 16; ++t) {
    float4 dv = getd4(t);
    float ds[4] = {dv.x, dv.y, dv.z, dv.w};
    #pragma unroll
    for (int e = 0; e < 4; ++e) {
      float cd = ds[e];
      #pragma unroll
      for (int s = KNN-1; s >= 1; --s) bd[s] = med3f(cd, bd[s-1], bd[s]);
      bd[0] = fminf(bd[0], cd);
    }
  }

  // ---- phase 2: wave-level 20th-smallest value (thr)
  float thr = 1e30f;
  {
    int total = 0;
    #pragma unroll 1
    for (int r = 0; r < KNN; ++r) {
      float m = bd[0];
      #pragma unroll
      for (int k = 1; k < 64; k <<= 1) m = fminf(m, __shfl_xor(m, k, 64));
      unsigned long long bal = __ballot(bd[0] == m);
      total += __popcll(bal);
      if (total >= KNN) { thr = m; break; }
      if (bd[0] == m) {
        #pragma unroll
        for (int s = 0; s < KNN-1; ++s) bd[s] = bd[s+1];
        bd[KNN-1] = 1e30f;
      }
    }
  }

  // ---- phase 3: rescan, emit strict (d<thr) via ballot-compaction; ties by smallest j
  unsigned long long lml = (1ull << lane) - 1ull;
  int S = 0;
  int myj = 0x7fffffff;
  for (int t = 0; t < 16; ++t) {
    float4 dv = getd4(t);
    float ds[4] = {dv.x, dv.y, dv.z, dv.w};
    int jb = t*256 + lane*4;
    #pragma unroll
    for (int e = 0; e < 4; ++e) {
      float d = ds[e];
      int j = jb + e;
      bool ps = d < thr;
      unsigned long long mk = __ballot(ps);
      int pos = S + __popcll(mk & lml);
      if (ps && pos < KNN) IDX[(size_t)qg*KNN + pos] = j;
      S += __popcll(mk);
      if (d == thr && j < myj) myj = j;
    }
  }
  int need = KNN - S;
  if (need == 1) {
    int mn = myj;
    #pragma unroll
    for (int k = 1; k < 64; k <<= 1) mn = min(mn, __shfl_xor(mn, k, 64));
    if (lane == 0) IDX[(size_t)qg*KNN + S] = mn;
  } else if (need > 1) {
    if (lane == 0) {
      int taken = 0;
      for (int j = 0; j < NPTS && taken < need; ++j) {
        float d;
        if (FEAT_MODE) d = D[(size_t)ql*NPTS + j];
        else           d = key3(Xb4[j]);
        if (d == thr) { IDX[(size_t)qg*KNN + S + taken] = j; ++taken; }
      }
    }
  }
}

// ---------------------------------------------------------------- f16x3 split MFMA GEMM
// Out[M x N] = act( W[M][K] * F^T[K][pt] + bias ), W/F given as f16 hi/lo pairs.
// 128x128 tile, BK=32, 4 waves (2x2, each 64x64 = 4x4 frags of 16x16).
// 3 MFMAs per frag-pair per K-step: Ah*Bh + Ah*Bl + Al*Bh  (lo*lo dropped, ~2^-22 rel).
template<bool LRELU_, bool CM>
__global__ __launch_bounds__(256) void mfma_gemm(
    const _Float16* __restrict__ WH, const _Float16* __restrict__ WL,  // [Mtot][KT]
    int Mtot, int KT,
    const _Float16* __restrict__ FH, const _Float16* __restrict__ FL,  // [pt][fstride], cols foff..foff+KT
    int fstride, int foff,
    const float* __restrict__ bias,
    float* __restrict__ Out, int ostride)
{
  __shared__ _Float16 As[2][128*32];   // [hi/lo][row][k]  row stride 32 halves = 64B
  __shared__ _Float16 Bs[2][128*32];
  int tid = threadIdx.x;
  int lane = tid & 63, wave = tid >> 6;
  int wr = wave >> 1, wc = wave & 1;
  int rt = blockIdx.y * 128, ct = blockIdx.x * 128;

  // staging: thread t loads 16B chunks; LDS half-offset = t*8 + i*2048
  // -> row = t/4 + i*64, k-offset = (t&3)*8  (lane-linear dest, as gld requires)
  int srow = tid >> 2;
  int skh  = (tid & 3) * 8;
  const _Float16* gA0 = WH + (size_t)(rt + srow)*KT + skh;
  const _Float16* gA1 = WL + (size_t)(rt + srow)*KT + skh;
  const _Float16* gB0 = FH + (size_t)(ct + srow)*fstride + foff + skh;
  const _Float16* gB1 = FL + (size_t)(ct + srow)*fstride + foff + skh;
  const size_t a2 = (size_t)64*KT;
  const size_t b2 = (size_t)64*fstride;
  _Float16* lA0 = &As[0][tid*8];
  _Float16* lA1 = &As[1][tid*8];
  _Float16* lB0 = &Bs[0][tid*8];
  _Float16* lB1 = &Bs[1][tid*8];

  f32x4 acc[4][4];
  #pragma unroll
  for (int m = 0; m < 4; ++m)
    #pragma unroll
    for (int n = 0; n < 4; ++n) acc[m][n] = (f32x4){0.f, 0.f, 0.f, 0.f};

  int fr = lane & 15;          // own-matrix index within 16-tile (A: M-row, B: N-col)
  int kg = (lane >> 4) * 8;    // k-chunk (8 contiguous halves)

  for (int k0 = 0; k0 < KT; k0 += 32) {
    gld16(gA0 + k0,      lA0);
    gld16(gA0 + k0 + a2, lA0 + 2048);
    gld16(gA1 + k0,      lA1);
    gld16(gA1 + k0 + a2, lA1 + 2048);
    gld16(gB0 + k0,      lB0);
    gld16(gB0 + k0 + b2, lB0 + 2048);
    gld16(gB1 + k0,      lB1);
    gld16(gB1 + k0 + b2, lB1 + 2048);
    __syncthreads();           // drains vmcnt (loads) before reads

    f16x8 ah[4], al[4], bh[4], bl[4];
    #pragma unroll
    for (int m = 0; m < 4; ++m) {
      int ro = (wr*64 + m*16 + fr)*32 + kg;
      ah[m] = *(const f16x8*)&As[0][ro];
      al[m] = *(const f16x8*)&As[1][ro];
    }
    #pragma unroll
    for (int n = 0; n < 4; ++n) {
      int co = (wc*64 + n*16 + fr)*32 + kg;
      bh[n] = *(const f16x8*)&Bs[0][co];
      bl[n] = *(const f16x8*)&Bs[1][co];
    }
    #pragma unroll
    for (int m = 0; m < 4; ++m)
      #pragma unroll
      for (int n = 0; n < 4; ++n) {
        acc[m][n] = __builtin_amdgcn_mfma_f32_16x16x32_f16(ah[m], bh[n], acc[m][n], 0, 0, 0);
        acc[m][n] = __builtin_amdgcn_mfma_f32_16x16x32_f16(ah[m], bl[n], acc[m][n], 0, 0, 0);
        acc[m][n] = __builtin_amdgcn_mfma_f32_16x16x32_f16(al[m], bh[n], acc[m][n], 0, 0, 0);
      }
    __syncthreads();           // protect LDS from next iteration's loads
  }

  // epilogue: C/D map (m89-verified): col = lane&15 (N/pt), row = (lane>>4)*4 + reg (M)
  int rowg = (lane >> 4) * 4;
  if (CM) {
    int b = ct >> 12, n0 = ct & (NPTS-1);
    #pragma unroll
    for (int m = 0; m < 4; ++m) {
      int rbase = rt + wr*64 + m*16 + rowg;
      #pragma unroll
      for (int r4 = 0; r4 < 4; ++r4) {
        int r = rbase + r4;
        float bv = bias[r];
        float* po = Out + ((size_t)b*Mtot + r)*NPTS + n0 + wc*64 + fr;
        #pragma unroll
        for (int n = 0; n < 4; ++n) {
          float v = acc[m][n][r4] + bv;
          if (LRELU_) v = lrelu_f(v);
          po[n*16] = v;
        }
      }
    }
  } else {
    #pragma unroll
    for (int n = 0; n < 4; ++n) {
      int pt = ct + wc*64 + n*16 + fr;
      #pragma unroll
      for (int m = 0; m < 4; ++m) {
        int r0 = rt + wr*64 + m*16 + rowg;
        float4 v;
        v.x = acc[m][n][0] + bias[r0];
        v.y = acc[m][n][1] + bias[r0+1];
        v.z = acc[m][n][2] + bias[r0+2];
        v.w = acc[m][n][3] + bias[r0+3];
        if (LRELU_) { v.x = lrelu_f(v.x); v.y = lrelu_f(v.y); v.z = lrelu_f(v.z); v.w = lrelu_f(v.w); }
        *(float4*)&Out[(size_t)pt*ostride + r0] = v;
      }
    }
  }
}

// ---------------------------------------------------------------- gather H1 = lrelu(U1[j] + V1[n]) (per batch), also x1 = max_k (f16 split out)
__global__ __launch_bounds__(256) void gather_h1(
    const float* __restrict__ UV1, const int* __restrict__ IDXF,
    float* __restrict__ H1,
    _Float16* __restrict__ FFH, _Float16* __restrict__ FFL, int batch)
{
  int n = blockIdx.x;
  int tid = threadIdx.x;
  size_t ptg = (size_t)batch*NPTS + n;
  __shared__ int js[KNN];
  if (tid < KNN) js[tid] = IDXF[ptg*KNN + tid];
  __syncthreads();
  int c = tid & 127, k0 = tid >> 7;
  float vv = UV1[ptg*256 + 128 + c];
  const float* Ub = UV1 + ((size_t)batch*NPTS)*256;
  float* Hb = H1 + (size_t)n*KNN*128;
  float mx = -1e30f;
  for (int kk = k0; kk < KNN; kk += 2) {
    int j = js[kk];
    float h = lrelu_f(Ub[(size_t)j*256 + c] + vv);
    Hb[kk*128 + c] = h;
    mx = fmaxf(mx, h);
  }
  __shared__ float m2[2][128];
  m2[k0][c] = mx;
  __syncthreads();
  if (tid < 128) {
    float m = fmaxf(m2[0][tid], m2[1][tid]);
    split_store(FFH, FFL, ptg*512 + tid, m);
  }
}

// ---------------------------------------------------------------- dg2 GEMM with lrelu + 20-group max epilogue -> x2 (f16 split out)
__global__ __launch_bounds__(256) void dg2_gemm(
    const float* __restrict__ Wt2, const float* __restrict__ H1,
    const float* __restrict__ bias,
    _Float16* __restrict__ FFH, _Float16* __restrict__ FFL, int batch)
{
  __shared__ float Ws[16][128];
  __shared__ float Fs[16][84];
  __shared__ float mb[16][132];
  int tid = threadIdx.x;
  int rg = tid & 15, cg = tid >> 4;
  int ct = blockIdx.x * 80;
  float acc[8][5];
  #pragma unroll
  for (int u = 0; u < 8; ++u)
    #pragma unroll
    for (int v = 0; v < 5; ++v) acc[u][v] = 0.f;

  for (int c0 = 0; c0 < 128; c0 += 16) {
    #pragma unroll
    for (int i = 0; i < 8; ++i) {
      int idx = tid + i*256;
      int kk = idx >> 7, r = idx & 127;
      Ws[kk][r] = Wt2[(c0+kk)*128 + r];
    }
    #pragma unroll
    for (int i = 0; i < 5; ++i) {
      int idx = tid + i*256;
      int kk = idx & 15, p = idx >> 4;
      Fs[kk][p] = H1[(size_t)(ct+p)*128 + c0 + kk];
    }
    __syncthreads();
    #pragma unroll
    for (int kk = 0; kk < 16; ++kk) {
      float a[8], bb[5];
      #pragma unroll
      for (int u = 0; u < 8; ++u) a[u] = Ws[kk][rg*8+u];
      #pragma unroll
      for (int v = 0; v < 5; ++v) bb[v] = Fs[kk][cg*5+v];
      #pragma unroll
      for (int u = 0; u < 8; ++u)
        #pragma unroll
        for (int v = 0; v < 5; ++v) acc[u][v] = fmaf(a[u], bb[v], acc[u][v]);
    }
    __syncthreads();
  }
  #pragma unroll
  for (int u = 0; u < 8; ++u) {
    int r = rg*8+u;
    float bv = bias[r];
    float m = -1e30f;
    #pragma unroll
    for (int v = 0; v < 5; ++v) m = fmaxf(m, lrelu_f(acc[u][v] + bv));
    mb[cg][r] = m;
  }
  __syncthreads();
  if ((cg & 3) == 0) {
    int g = cg >> 2;
    size_t pt = (size_t)batch*NPTS + blockIdx.x*4 + g;
    #pragma unroll
    for (int u = 0; u < 8; ++u) {
      int r = rg*8+u;
      float m = fmaxf(fmaxf(mb[cg][r], mb[cg+1][r]), fmaxf(mb[cg+2][r], mb[cg+3][r]));
      split_store(FFH, FFL, pt*512 + 128 + r, m);
    }
  }
}

// ---------------------------------------------------------------- sn block: x3 = max_k lrelu(U2[j] + V2[n])  (f16 split out)
__global__ __launch_bounds__(256) void sn_gather(
    const float* __restrict__ UV2, const int* __restrict__ IDXX,
    _Float16* __restrict__ FFH, _Float16* __restrict__ FFL)
{
  int tid = threadIdx.x;   // channel 0..255
  int p0 = blockIdx.x * 4;
  for (int pp = 0; pp < 4; ++pp) {
    size_t pt = (size_t)(p0 + pp);
    size_t bb = (size_t)((p0+pp) >> 12) << 12;
    float v = UV2[pt*512 + 256 + tid];
    float m = -1e30f;
    for (int k = 0; k < KNN; ++k) {
      int j = IDXX[pt*KNN + k];
      float h = lrelu_f(UV2[(bb + j)*512 + tid] + v);
      m = fmaxf(m, h);
    }
    split_store(FFH, FFL, pt*512 + 256 + tid, m);
  }
}

// ---------------------------------------------------------------- farthest point sampling (per batch)
__global__ __launch_bounds__(256) void fps_kernel(
    const float* __restrict__ xyz, int* __restrict__ SIDX)
{
  int b = blockIdx.x, tid = threadIdx.x;
  const float* p = xyz + (size_t)b*3*NPTS;
  __shared__ float dist[NPTS];
  __shared__ float rmax[256];
  __shared__ int   ridx[256];
  __shared__ int   curf;
  for (int i = tid; i < NPTS; i += 256) dist[i] = 1e10f;
  if (tid == 0) curf = 0;
  __syncthreads();
  for (int it = 0; it < 32; ++it) {
    int far = curf;
    if (tid == 0) SIDX[b*32 + it] = far;
    float cx = p[far], cy = p[NPTS+far], cz = p[2*NPTS+far];
    float lm = -1e30f; int li = 0;
    for (int i = tid; i < NPTS; i += 256) {
      float dx = p[i]-cx, dy = p[NPTS+i]-cy, dz = p[2*NPTS+i]-cz;
      float d = dx*dx + dy*dy + dz*dz;
      float dm = fminf(dist[i], d);
      dist[i] = dm;
      if (dm > lm) { lm = dm; li = i; }
    }
    rmax[tid] = lm; ridx[tid] = li;
    __syncthreads();
    for (int s = 128; s > 0; s >>= 1) {
      if (tid < s) {
        float a = rmax[tid], bv = rmax[tid+s];
        int ia = ridx[tid], ib = ridx[tid+s];
        if (bv > a || (bv == a && ib < ia)) { rmax[tid] = bv; ridx[tid] = ib; }
      }
      __syncthreads();
    }
    if (tid == 0) curf = ridx[0];
    __syncthreads();
  }
}

// ---------------------------------------------------------------- k-farthest (8) among 32 samples
__global__ __launch_bounds__(128) void kfn_kernel(
    const float* __restrict__ xyz, const int* __restrict__ SIDX,
    int* __restrict__ NIDX)
{
  int tid = threadIdx.x;     // 0..127
  int b = tid >> 5, i = tid & 31;
  const float* p = xyz + (size_t)b*3*NPTS;
  __shared__ float sx[4][32], sy[4][32], sz[4][32];
  {
    int si = SIDX[b*32 + i];
    sx[b][i] = p[si]; sy[b][i] = p[NPTS+si]; sz[b][i] = p[2*NPTS+si];
  }
  __syncthreads();
  float xi = sx[b][i], yi = sy[b][i], zi = sz[b][i];
  float xxi = xi*xi + yi*yi + zi*zi;
  float bd[8]; int bi_[8];
  #pragma unroll
  for (int t = 0; t < 8; ++t) { bd[t] = -1e30f; bi_[t] = 0; }
  for (int j = 0; j < 32; ++j) {
    float xj = sx[b][j], yj = sy[b][j], zj = sz[b][j];
    float xxj = xj*xj + yj*yj + zj*zj;
    float d = xxi - 2.f*(xi*xj + yi*yj + zi*zj) + xxj;
    if (d > bd[7]) {
      float cd = d; int ci = j;
      #pragma unroll
      for (int t = 0; t < 8; ++t) {
        bool sw = bd[t] < cd;       // descending
        float nv = sw ? cd : bd[t];
        int   ni = sw ? ci : bi_[t];
        float ov = sw ? bd[t] : cd;
        int   oi = sw ? bi_[t] : ci;
        bd[t] = nv; bi_[t] = ni; cd = ov; ci = oi;
      }
    }
  }
  size_t o = (size_t)(b*32 + i)*8;
  #pragma unroll
  for (int t = 0; t < 8; ++t) NIDX[o+t] = bi_[t];
}

// ---------------------------------------------------------------- triplet terms
__global__ __launch_bounds__(256) void trip_kernel(
    const float* __restrict__ es0, const float* __restrict__ et0,
    const int* __restrict__ SIDX, const int* __restrict__ NIDX,
    float* __restrict__ ACC)
{
  int bi_ = blockIdx.x; int b = bi_ >> 5;
  int tid = threadIdx.x;
  __shared__ int js[8];
  __shared__ int ssi;
  if (tid == 0) ssi = SIDX[bi_];
  if (tid < 8) js[tid] = SIDX[b*32 + NIDX[bi_*8 + tid]];
  __syncthreads();
  int si = ssi;
  const float* es = es0 + (size_t)b*1024*NPTS;
  const float* et = et0 + (size_t)b*1024*NPTS;
  float sp = 0.f, sn = 0.f;
  for (int c = tid; c < 1024; c += 256) {
    const float* erow = et + (size_t)c*NPTS;
    float s = es[(size_t)c*NPTS + si];
    float d0 = s - erow[si]; sp += d0*d0;
    #pragma unroll
    for (int t = 0; t < 8; ++t) { float d1 = s - erow[js[t]]; sn += d1*d1; }
  }
  __shared__ float r1[256], r2[256];
  r1[tid] = sp; r2[tid] = sn; __syncthreads();
  for (int s2 = 128; s2 > 0; s2 >>= 1) {
    if (tid < s2) { r1[tid] += r1[tid+s2]; r2[tid] += r2[tid+s2]; }
    __syncthreads();
  }
  if (tid == 0) {
    float dp = r1[0] * (1.f/1024.f);
    float dn = r2[0] * (1.f/8192.f);
    float tr = fmaxf(0.f, 1.f - dn/(1.f + dp));
    atomicAdd(&ACC[0], tr);
  }
}

// ---------------------------------------------------------------- norms + mse + mae
__global__ __launch_bounds__(256) void stats_kernel(
    const float* __restrict__ es0, const float* __restrict__ et0,
    float* __restrict__ ACC)
{
  int tid = threadIdx.x;
  int p = tid & 63, g = tid >> 6;
  int pt0 = blockIdx.x * 64;
  int b = pt0 >> 12, n0 = pt0 & (NPTS-1);
  const float* es = es0 + (size_t)b*1024*NPTS + n0;
  const float* et = et0 + (size_t)b*1024*NPTS + n0;
  float ss = 0.f, tt = 0.f, sq = 0.f, ab = 0.f;
  for (int c = g; c < 1024; c += 4) {
    float s = es[(size_t)c*NPTS + p];
    float t = et[(size_t)c*NPTS + p];
    ss += s*s; tt += t*t;
    float d = s - t;
    sq += d*d; ab += fabsf(d);
  }
  __shared__ float rs[4][64], rt[4][64];
  __shared__ float red[256];
  rs[g][p] = ss; rt[g][p] = tt;
  red[tid] = sq;
  __syncthreads();
  for (int s2 = 128; s2 > 0; s2 >>= 1) {
    if (tid < s2) red[tid] += red[tid+s2];
    __syncthreads();
  }
  if (tid == 0) atomicAdd(&ACC[3], red[0]);
  __syncthreads();
  red[tid] = ab; __syncthreads();
  for (int s2 = 128; s2 > 0; s2 >>= 1) {
    if (tid < s2) red[tid] += red[tid+s2];
    __syncthreads();
  }
  if (tid == 0) atomicAdd(&ACC[4], red[0]);
  if (tid < 64) {
    float a = sqrtf(rs[0][tid]+rs[1][tid]+rs[2][tid]+rs[3][tid]) - 1.f;
    float c = sqrtf(rt[0][tid]+rt[1][tid]+rt[2][tid]+rt[3][tid]) - 1.f;
    float av = a*a, cv = c*c;
    #pragma unroll
    for (int s2 = 32; s2 > 0; s2 >>= 1) {
      av += __shfl_down(av, s2, 64);
      cv += __shfl_down(cv, s2, 64);
    }
    if (tid == 0) { atomicAdd(&ACC[1], av); atomicAdd(&ACC[2], cv); }
  }
}

// ---------------------------------------------------------------- finalize scalars
__global__ void finalize_kernel(const float* __restrict__ ACC, float* __restrict__ o3) {
  if (threadIdx.x == 0 && blockIdx.x == 0) {
    float ln1 = sqrtf(ACC[1] * (1.f/16384.f));
    float ln2 = sqrtf(ACC[2] * (1.f/16384.f));
    o3[0] = ACC[0]*(1.f/128.f) + (ln1 + ln2)*0.5f*0.03f;
    o3[1] = ACC[3] * (1.f/4194304.f);   // mean((s-t)^2)*B
    o3[2] = ACC[4] * (1.f/4194304.f);   // mean(|s-t|)*B
  }
}

// ================================================================ host
extern "C" void kernel_launch(void* const* d_in, const int* in_sizes, int n_in,
                              void* d_out, int out_size, void* d_ws, size_t ws_size,
                              hipStream_t stream) {
  (void)in_sizes; (void)n_in; (void)out_size; (void)ws_size;
  const float* src  = (const float*)d_in[0];
  const float* tgt  = (const float*)d_in[1];
  const float* w1   = (const float*)d_in[2];
  const float* b1   = (const float*)d_in[3];
  const float* w2   = (const float*)d_in[4];
  const float* b2   = (const float*)d_in[5];
  const float* wdg1 = (const float*)d_in[6];
  const float* bdg1 = (const float*)d_in[7];
  const float* wdg2 = (const float*)d_in[8];
  const float* bdg2 = (const float*)d_in[9];
  const float* wsn1 = (const float*)d_in[10];
  const float* bsn1 = (const float*)d_in[11];
  const float* w3   = (const float*)d_in[12];
  const float* b3   = (const float*)d_in[13];
  float* out = (float*)d_out;

  float* ws = (float*)d_ws;
  float*  XTP  = ws;                                   // BN*4 (float4 x,y,z,xx)
  float*  XT2  = XTP + (size_t)BN*4;                   // BN*64
  float*  XX2  = XT2 + (size_t)BN*64;                  // BN
  float*  UV1  = XX2 + BN;                             // BN*256
  _Float16* FFH = (_Float16*)(UV1 + (size_t)BN*256);   // BN*512 halves (x1|x2|x3 hi)
  _Float16* FFL = FFH + (size_t)BN*512;                // BN*512 halves (lo)
  float*  UV2  = (float*)(FFL + (size_t)BN*512);       // BN*512
  float*  Dbuf = (float*)FFH;                          // NPTS*NPTS fp32 aliases FFH|FFL|UV2 (dead at gather time)
  float*  H1   = UV2 + (size_t)BN*512;                 // NPTS*KNN*128
  _Float16* XT2H = (_Float16*)H1;                      // BN*64 halves — aliases H1 head (dead once gather starts)
  _Float16* XT2L = XT2H + (size_t)BN*64;               // BN*64 halves
  int*    IDXF = (int*)(H1 + (size_t)NPTS*KNN*128);    // BN*KNN
  int*    IDXX = IDXF + (size_t)BN*KNN;                // BN*KNN
  float*  WT2  = (float*)(IDXX + (size_t)BN*KNN);      // 128*128
  float*  BUV1 = WT2 + 128*128;                        // 256
  float*  BUV2 = BUV1 + 256;                           // 512
  _Float16* W3H = (_Float16*)(BUV2 + 512);             // 1024*512 halves
  _Float16* W3L = W3H + 1024*512;
  _Float16* WH1 = W3L + 1024*512;                      // 256*64 halves
  _Float16* WL1 = WH1 + 256*64;
  _Float16* WH2 = WL1 + 256*64;                        // 512*128 halves
  _Float16* WL2 = WH2 + 512*128;
  int*    SIDX = (int*)(WL2 + 512*128);                // NB*32
  int*    NIDX = SIDX + NB*32;                         // NB*32*8
  float*  ACC  = (float*)(NIDX + NB*32*8);             // 8

  prep_weights<<<2048, 256, 0, stream>>>(wdg1, bdg1, wdg2, wsn1, bsn1, w3,
                                         WT2, BUV1, BUV2,
                                         W3H, W3L, WH1, WL1, WH2, WL2);

  auto run_cloud = [&](const float* xyz, float* emb) {
    pack_xyz<<<BN/256, 256, 0, stream>>>(xyz, (float4*)XTP);
    conv12<<<BN/4, 256, 0, stream>>>(xyz, w1, b1, w2, b2, XT2, XX2, XT2H, XT2L);
    // KNN: per batch, distance GEMM (feat) + wave-per-query selection (feat & xyz)
    for (int bb = 0; bb < NB; ++bb) {
      dist_gemm<<<dim3(32,32), 256, 0, stream>>>(
          XT2 + (size_t)bb*NPTS*64, XX2 + (size_t)bb*NPTS, Dbuf);
      knn_select<true><<<NPTS/4, 256, 0, stream>>>(Dbuf, (const float4*)XTP, bb, IDXF);
      knn_select<false><<<NPTS/4, 256, 0, stream>>>(nullptr, (const float4*)XTP, bb, IDXX);
    }
    // UV1 = WEFF1 * XT2 (f16x3 MFMA)
    mfma_gemm<false,false><<<dim3(BN/128, 2), 256, 0, stream>>>(
        WH1, WL1, 256, 64, XT2H, XT2L, 64, 0, BUV1, UV1, 256);
    for (int bb = 0; bb < NB; ++bb) {
      gather_h1<<<NPTS, 256, 0, stream>>>(UV1, IDXF, H1, FFH, FFL, bb);
      dg2_gemm<<<NPTS*KNN/80, 256, 0, stream>>>(WT2, H1, bdg2, FFH, FFL, bb);
    }
    // UV2 = WEFF2 * x2 (f16x3 MFMA, FEAT cols 128..255)
    mfma_gemm<false,false><<<dim3(BN/128, 4), 256, 0, stream>>>(
        WH2, WL2, 512, 128, FFH, FFL, 512, 128, BUV2, UV2, 512);
    sn_gather<<<BN/4, 256, 0, stream>>>(UV2, IDXX, FFH, FFL);
    // emb = lrelu(W3 * feat + b3), channel-major (f16x3 MFMA)
    mfma_gemm<true,true><<<dim3(BN/128, 8), 256, 0, stream>>>(
        W3H, W3L, 1024, 512, FFH, FFL, 512, 0, b3, emb, 0);
  };

  float* emb_s = out;
  float* emb_t = out + (size_t)BN*1024;
  run_cloud(src, emb_s);
  run_cloud(tgt, emb_t);

  hipMemsetAsync(ACC, 0, 8*sizeof(float), stream);
  fps_kernel<<<NB, 256, 0, stream>>>(src, SIDX);
  kfn_kernel<<<1, 128, 0, stream>>>(src, SIDX, NIDX);
  trip_kernel<<<NB*32, 256, 0, stream>>>(emb_s, emb_t, SIDX, NIDX, ACC);
  stats_kernel<<<BN/64, 256, 0, stream>>>(emb_s, emb_t, ACC);
  finalize_kernel<<<1, 64, 0, stream>>>(ACC, out + (size_t)2*BN*1024);
}

// Round 2
// 1512.710 us; speedup vs baseline: 1.5155x; 1.2839x over previous
//
#include <hip/hip_runtime.h>
#include <cstdint>

#define NB 4
#define NPTS 4096
#define KNN 20
#define BN (NB*NPTS)   // 16384

typedef _Float16 f16x8 __attribute__((ext_vector_type(8)));
typedef _Float16 f16x4 __attribute__((ext_vector_type(4)));
typedef float    f32x4 __attribute__((ext_vector_type(4)));

__device__ __forceinline__ float lrelu_f(float x) { return x > 0.f ? x : 0.2f * x; }

__device__ __forceinline__ float med3f(float c, float lo, float hi) {
#if defined(__has_builtin)
#if __has_builtin(__builtin_amdgcn_fmed3f)
  return __builtin_amdgcn_fmed3f(c, lo, hi);
#else
  return fminf(fmaxf(c, lo), hi);
#endif
#else
  return fminf(fmaxf(c, lo), hi);
#endif
}

// async global->LDS, 16B per lane (lane-linear LDS dest required)
__device__ __forceinline__ void gld16(const void* g, void* l) {
  __builtin_amdgcn_global_load_lds(
      (const __attribute__((address_space(1))) void*)g,
      (__attribute__((address_space(3))) void*)l,
      16, 0, 0);
}

__device__ __forceinline__ void split_store(_Float16* __restrict__ H, _Float16* __restrict__ L,
                                            size_t idx, float v) {
  _Float16 h = (_Float16)v;
  H[idx] = h;
  L[idx] = (_Float16)(v - (float)h);
}

// ---------------------------------------------------------------- prep weights
__global__ __launch_bounds__(256) void prep_weights(
    const float* __restrict__ wdg1, const float* __restrict__ bdg1,
    const float* __restrict__ wdg2,
    const float* __restrict__ wsn1, const float* __restrict__ bsn1,
    const float* __restrict__ w3,
    _Float16* __restrict__ W2H, _Float16* __restrict__ W2L,
    float* __restrict__ BUV1, float* __restrict__ BUV2,
    _Float16* __restrict__ W3H, _Float16* __restrict__ W3L,
    _Float16* __restrict__ WH1, _Float16* __restrict__ WL1,
    _Float16* __restrict__ WH2, _Float16* __restrict__ WL2)
{
  int i = blockIdx.x * 256 + threadIdx.x;
  if (i < 512*1024) {           // w3 is already [M=1024][K=512]
    float v = w3[i];
    split_store(W3H, W3L, i, v);
  }
  if (i < 256*64) {             // WEFF1: [M=256][K=64]
    int r = i >> 6, c = i & 63;
    float v = (r < 128) ? wdg1[r*128 + c]
                        : (wdg1[(r-128)*128 + 64 + c] - wdg1[(r-128)*128 + c]);
    split_store(WH1, WL1, i, v);
  }
  if (i < 512*128) {            // WEFF2: [M=512][K=128]
    int r = i >> 7, c = i & 127;
    float v = (r < 256) ? wsn1[r*256 + c]
                        : (wsn1[(r-256)*256 + 128 + c] - wsn1[(r-256)*256 + c]);
    split_store(WH2, WL2, i, v);
  }
  if (i < 128*128) split_store(W2H, W2L, i, wdg2[i]);  // [M=o][K=c] identity layout
  if (i < 256) BUV1[i] = (i < 128) ? 0.f : bdg1[i-128];
  if (i < 512) BUV2[i] = (i < 256) ? 0.f : bsn1[i-256];
}

// ---------------------------------------------------------------- pack xyz -> float4 (x,y,z,xx)
__global__ __launch_bounds__(256) void pack_xyz(
    const float* __restrict__ xyz, float4* __restrict__ XTP4)
{
  int i = blockIdx.x * 256 + threadIdx.x;
  if (i >= BN) return;
  int b = i >> 12, n = i & (NPTS-1);
  const float* p = xyz + (size_t)b*3*NPTS;
  float x = p[n], y = p[NPTS+n], z = p[2*NPTS+n];
  float4 v; v.x = x; v.y = y; v.z = z; v.w = x*x + y*y + z*z;
  XTP4[i] = v;
}

// ---------------------------------------------------------------- conv1 + conv2 fused (3->64->64)
__global__ __launch_bounds__(256) void conv12(
    const float* __restrict__ xyz,
    const float* __restrict__ w1, const float* __restrict__ b1,
    const float* __restrict__ w2, const float* __restrict__ b2,
    float* __restrict__ XT2, float* __restrict__ XX2,
    _Float16* __restrict__ XT2H, _Float16* __restrict__ XT2L)
{
  __shared__ float w2t[64*65];
  __shared__ float h1s[4][64];
  int tid = threadIdx.x;
  for (int i = tid; i < 4096; i += 256) {
    int o = i >> 6, c = i & 63;
    w2t[c*65 + o] = w2[i];
  }
  int g = tid >> 6, o = tid & 63;
  int pt = blockIdx.x*4 + g;
  int b = pt >> 12, n = pt & (NPTS-1);
  const float* p = xyz + (size_t)b*3*NPTS;
  float x = p[n], y = p[NPTS+n], z = p[2*NPTS+n];
  float h1 = b1[o] + w1[o*3]*x + w1[o*3+1]*y + w1[o*3+2]*z;
  h1 = lrelu_f(h1);
  __syncthreads();
  h1s[g][o] = h1;
  __syncthreads();
  float acc = b2[o];
  #pragma unroll
  for (int c = 0; c < 64; ++c) acc = fmaf(w2t[c*65+o], h1s[g][c], acc);
  acc = lrelu_f(acc);
  XT2[(size_t)pt*64 + o] = acc;
  split_store(XT2H, XT2L, (size_t)pt*64 + o, acc);
  float v = acc*acc;
  #pragma unroll
  for (int s = 32; s > 0; s >>= 1) v += __shfl_down(v, s, 64);
  if (o == 0) XX2[pt] = v;
}

// ---------------------------------------------------------------- distance GEMM (per batch)
__global__ __launch_bounds__(256) void dist_gemm(
    const float* __restrict__ XQ,   // batch slice of XT2, [4096][64]
    const float* __restrict__ XXb,  // batch slice of XX2, [4096]
    float* __restrict__ D)          // [4096][4096]
{
  __shared__ float Qs[16][132];
  __shared__ float Xs[16][132];
  int tid = threadIdx.x;
  int rg = tid & 15, cg = tid >> 4;
  int q0 = blockIdx.y * 128, j0 = blockIdx.x * 128;
  float acc[8][8];
  #pragma unroll
  for (int u = 0; u < 8; ++u)
    #pragma unroll
    for (int v = 0; v < 8; ++v) acc[u][v] = 0.f;

  for (int c0 = 0; c0 < 64; c0 += 16) {
    #pragma unroll
    for (int i = 0; i < 8; ++i) {
      int idx = tid + i*256;
      int kk = idx & 15, p = idx >> 4;
      Qs[kk][p] = XQ[(size_t)(q0+p)*64 + c0 + kk];
      Xs[kk][p] = XQ[(size_t)(j0+p)*64 + c0 + kk];
    }
    __syncthreads();
    #pragma unroll
    for (int kk = 0; kk < 16; ++kk) {
      float a[8], bb[8];
      #pragma unroll
      for (int u = 0; u < 8; ++u) a[u] = Qs[kk][rg*8+u];
      #pragma unroll
      for (int v = 0; v < 8; ++v) bb[v] = Xs[kk][cg*8+v];
      #pragma unroll
      for (int u = 0; u < 8; ++u)
        #pragma unroll
        for (int v = 0; v < 8; ++v) acc[u][v] = fmaf(a[u], bb[v], acc[u][v]);
    }
    __syncthreads();
  }
  float xxv[8];
  #pragma unroll
  for (int v = 0; v < 8; ++v) xxv[v] = XXb[j0 + cg*8 + v];
  #pragma unroll
  for (int u = 0; u < 8; ++u) {
    float* po = D + (size_t)(q0 + rg*8 + u)*NPTS + j0 + cg*8;
    #pragma unroll
    for (int v = 0; v < 8; ++v) po[v] = fmaf(-2.f, acc[u][v], xxv[v]);
  }
}

// ---------------------------------------------------------------- knn select
template<bool FEAT_MODE>
__global__ __launch_bounds__(256) void knn_select(
    const float* __restrict__ D, const float4* __restrict__ XTP4,
    int batch, int* __restrict__ IDX)
{
  int lane = threadIdx.x & 63;
  int ql = blockIdx.x*4 + (threadIdx.x >> 6);   // query local to batch
  int qg = batch*NPTS + ql;                     // global point id
  const float4* drow4 = FEAT_MODE ? (const float4*)(D + (size_t)ql*NPTS) : nullptr;
  const float4* Xb4 = XTP4 + (size_t)batch*NPTS;
  float qx = 0.f, qy = 0.f, qz = 0.f;
  if (!FEAT_MODE) { float4 qp = XTP4[qg]; qx = qp.x; qy = qp.y; qz = qp.z; }

  auto key3 = [&](float4 p) -> float {
    float dot = qx*p.x;
    dot = fmaf(qy, p.y, dot);
    dot = fmaf(qz, p.z, dot);
    return fmaf(-2.f, dot, p.w);
  };
  auto getd4 = [&](int t) -> float4 {
    if (FEAT_MODE) {
      return drow4[t*64 + lane];
    } else {
      int jb = t*256 + lane*4;
      float4 r;
      r.x = key3(Xb4[jb+0]);
      r.y = key3(Xb4[jb+1]);
      r.z = key3(Xb4[jb+2]);
      r.w = key3(Xb4[jb+3]);
      return r;
    }
  };

  float bd[KNN];
  #pragma unroll
  for (int t = 0; t < KNN; ++t) bd[t] = 1e30f;
  for (int t = 0; t < 16; ++t) {
    float4 dv = getd4(t);
    float ds[4] = {dv.x, dv.y, dv.z, dv.w};
    #pragma unroll
    for (int e = 0; e < 4; ++e) {
      float cd = ds[e];
      #pragma unroll
      for (int s = KNN-1; s >= 1; --s) bd[s] = med3f(cd, bd[s-1], bd[s]);
      bd[0] = fminf(bd[0], cd);
    }
  }

  float thr = 1e30f;
  {
    int total = 0;
    #pragma unroll 1
    for (int r = 0; r < KNN; ++r) {
      float m = bd[0];
      #pragma unroll
      for (int k = 1; k < 64; k <<= 1) m = fminf(m, __shfl_xor(m, k, 64));
      unsigned long long bal = __ballot(bd[0] == m);
      total += __popcll(bal);
      if (total >= KNN) { thr = m; break; }
      if (bd[0] == m) {
        #pragma unroll
        for (int s = 0; s < KNN-1; ++s) bd[s] = bd[s+1];
        bd[KNN-1] = 1e30f;
      }
    }
  }

  unsigned long long lml = (1ull << lane) - 1ull;
  int S = 0;
  int myj = 0x7fffffff;
  for (int t = 0; t < 16; ++t) {
    float4 dv = getd4(t);
    float ds[4] = {dv.x, dv.y, dv.z, dv.w};
    int jb = t*256 + lane*4;
    #pragma unroll
    for (int e = 0; e < 4; ++e) {
      float d = ds[e];
      int j = jb + e;
      bool ps = d < thr;
      unsigned long long mk = __ballot(ps);
      int pos = S + __popcll(mk & lml);
      if (ps && pos < KNN) IDX[(size_t)qg*KNN + pos] = j;
      S += __popcll(mk);
      if (d == thr && j < myj) myj = j;
    }
  }
  int need = KNN - S;
  if (need == 1) {
    int mn = myj;
    #pragma unroll
    for (int k = 1; k < 64; k <<= 1) mn = min(mn, __shfl_xor(mn, k, 64));
    if (lane == 0) IDX[(size_t)qg*KNN + S] = mn;
  } else if (need > 1) {
    if (lane == 0) {
      int taken = 0;
      for (int j = 0; j < NPTS && taken < need; ++j) {
        float d;
        if (FEAT_MODE) d = D[(size_t)ql*NPTS + j];
        else           d = key3(Xb4[j]);
        if (d == thr) { IDX[(size_t)qg*KNN + S + taken] = j; ++taken; }
      }
    }
  }
}

// ---------------------------------------------------------------- f16x3 split MFMA GEMM (generic)
template<bool LRELU_, bool CM>
__global__ __launch_bounds__(256) void mfma_gemm(
    const _Float16* __restrict__ WH, const _Float16* __restrict__ WL,  // [Mtot][KT]
    int Mtot, int KT,
    const _Float16* __restrict__ FH, const _Float16* __restrict__ FL,  // [pt][fstride]
    int fstride, int foff,
    const float* __restrict__ bias,
    float* __restrict__ Out, int ostride)
{
  __shared__ _Float16 As[2][128*32];
  __shared__ _Float16 Bs[2][128*32];
  int tid = threadIdx.x;
  int lane = tid & 63, wave = tid >> 6;
  int wr = wave >> 1, wc = wave & 1;
  int rt = blockIdx.y * 128, ct = blockIdx.x * 128;

  int srow = tid >> 2;
  int skh  = (tid & 3) * 8;
  const _Float16* gA0 = WH + (size_t)(rt + srow)*KT + skh;
  const _Float16* gA1 = WL + (size_t)(rt + srow)*KT + skh;
  const _Float16* gB0 = FH + (size_t)(ct + srow)*fstride + foff + skh;
  const _Float16* gB1 = FL + (size_t)(ct + srow)*fstride + foff + skh;
  const size_t a2 = (size_t)64*KT;
  const size_t b2 = (size_t)64*fstride;
  _Float16* lA0 = &As[0][tid*8];
  _Float16* lA1 = &As[1][tid*8];
  _Float16* lB0 = &Bs[0][tid*8];
  _Float16* lB1 = &Bs[1][tid*8];

  f32x4 acc[4][4];
  #pragma unroll
  for (int m = 0; m < 4; ++m)
    #pragma unroll
    for (int n = 0; n < 4; ++n) acc[m][n] = (f32x4){0.f, 0.f, 0.f, 0.f};

  int fr = lane & 15;
  int kg = (lane >> 4) * 8;

  for (int k0 = 0; k0 < KT; k0 += 32) {
    gld16(gA0 + k0,      lA0);
    gld16(gA0 + k0 + a2, lA0 + 2048);
    gld16(gA1 + k0,      lA1);
    gld16(gA1 + k0 + a2, lA1 + 2048);
    gld16(gB0 + k0,      lB0);
    gld16(gB0 + k0 + b2, lB0 + 2048);
    gld16(gB1 + k0,      lB1);
    gld16(gB1 + k0 + b2, lB1 + 2048);
    __syncthreads();

    f16x8 ah[4], al[4], bh[4], bl[4];
    #pragma unroll
    for (int m = 0; m < 4; ++m) {
      int ro = (wr*64 + m*16 + fr)*32 + kg;
      ah[m] = *(const f16x8*)&As[0][ro];
      al[m] = *(const f16x8*)&As[1][ro];
    }
    #pragma unroll
    for (int n = 0; n < 4; ++n) {
      int co = (wc*64 + n*16 + fr)*32 + kg;
      bh[n] = *(const f16x8*)&Bs[0][co];
      bl[n] = *(const f16x8*)&Bs[1][co];
    }
    #pragma unroll
    for (int m = 0; m < 4; ++m)
      #pragma unroll
      for (int n = 0; n < 4; ++n) {
        acc[m][n] = __builtin_amdgcn_mfma_f32_16x16x32_f16(ah[m], bh[n], acc[m][n], 0, 0, 0);
        acc[m][n] = __builtin_amdgcn_mfma_f32_16x16x32_f16(ah[m], bl[n], acc[m][n], 0, 0, 0);
        acc[m][n] = __builtin_amdgcn_mfma_f32_16x16x32_f16(al[m], bh[n], acc[m][n], 0, 0, 0);
      }
    __syncthreads();
  }

  int rowg = (lane >> 4) * 4;
  if (CM) {
    int b = ct >> 12, n0 = ct & (NPTS-1);
    #pragma unroll
    for (int m = 0; m < 4; ++m) {
      int rbase = rt + wr*64 + m*16 + rowg;
      #pragma unroll
      for (int r4 = 0; r4 < 4; ++r4) {
        int r = rbase + r4;
        float bv = bias[r];
        float* po = Out + ((size_t)b*Mtot + r)*NPTS + n0 + wc*64 + fr;
        #pragma unroll
        for (int n = 0; n < 4; ++n) {
          float v = acc[m][n][r4] + bv;
          if (LRELU_) v = lrelu_f(v);
          po[n*16] = v;
        }
      }
    }
  } else {
    #pragma unroll
    for (int n = 0; n < 4; ++n) {
      int pt = ct + wc*64 + n*16 + fr;
      #pragma unroll
      for (int m = 0; m < 4; ++m) {
        int r0 = rt + wr*64 + m*16 + rowg;
        float4 v;
        v.x = acc[m][n][0] + bias[r0];
        v.y = acc[m][n][1] + bias[r0+1];
        v.z = acc[m][n][2] + bias[r0+2];
        v.w = acc[m][n][3] + bias[r0+3];
        if (LRELU_) { v.x = lrelu_f(v.x); v.y = lrelu_f(v.y); v.z = lrelu_f(v.z); v.w = lrelu_f(v.w); }
        *(float4*)&Out[(size_t)pt*ostride + r0] = v;
      }
    }
  }
}

// ---------------------------------------------------------------- fused gather + dg2 MFMA + x1/x2 group-max
// Block = 4 center points (80 = 4x20 neighbor rows), M=128 channels, K=128, f16x3 MFMA.
// x1 = max_k lrelu(U+V) computed during staging; x2 = max_k lrelu(W2*h1 + b) in epilogue
// (lrelu monotone => max before bias+lrelu).
__global__ __launch_bounds__(256) void dg2_fused(
    const _Float16* __restrict__ W2H, const _Float16* __restrict__ W2L, // [128][128]
    const float* __restrict__ UV1,      // [BN][256] (U|V)
    const int* __restrict__ IDXF,       // [BN][KNN]
    const float* __restrict__ bias,     // bdg2 [128]
    _Float16* __restrict__ FFH, _Float16* __restrict__ FFL)
{
  constexpr int RS = 136;  // Hs row stride in halves (272B: 16B-aligned, 2-way-bank free)
  __shared__ __align__(16) unsigned char smem[43520];
  _Float16* HsH = (_Float16*)smem;            // [80][RS]
  _Float16* HsL = (_Float16*)(smem + 21760);  // [80][RS]
  float*    Cs  = (float*)smem;               // [128][84] epilogue reuse
  __shared__ int js[80];
  __shared__ float4 mxs[128];

  int tid = threadIdx.x;
  int lane = tid & 63, wave = tid >> 6;
  size_t pt0 = (size_t)blockIdx.x * 4;        // global point id of group 0
  size_t bbase = (pt0 >> 12) << 12;           // batch base point

  if (tid < 80) js[tid] = IDXF[pt0*KNN + tid];

  // preload A fragments (weights hi/lo, all 4 k-steps) — L2-hot, reused by 4096 blocks
  int fr = lane & 15, kg = (lane >> 4) * 8;
  f16x8 ah[2][4], al[2][4];
  #pragma unroll
  for (int m = 0; m < 2; ++m) {
    int row = wave*32 + m*16 + fr;
    #pragma unroll
    for (int ks = 0; ks < 4; ++ks) {
      ah[m][ks] = *(const f16x8*)&W2H[row*128 + ks*32 + kg];
      al[m][ks] = *(const f16x8*)&W2L[row*128 + ks*32 + kg];
    }
  }
  __syncthreads();   // js visible

  // stage B rows (h1) as hi/lo halves + x1 partial max
  {
    int g = (tid >> 5) & 3, half = tid >> 7, c4 = tid & 31;
    size_t ptg = pt0 + g;
    float4 vv = *(const float4*)&UV1[ptg*256 + 128 + c4*4];
    float4 mx = make_float4(-1e30f, -1e30f, -1e30f, -1e30f);
    #pragma unroll
    for (int k = 0; k < 10; ++k) {
      int row = g*20 + half*10 + k;
      int j = js[row];
      float4 u = *(const float4*)&UV1[(bbase + (size_t)j)*256 + c4*4];
      float h0 = lrelu_f(u.x + vv.x);
      float h1 = lrelu_f(u.y + vv.y);
      float h2 = lrelu_f(u.z + vv.z);
      float h3 = lrelu_f(u.w + vv.w);
      f16x4 hh, hl;
      hh[0] = (_Float16)h0; hl[0] = (_Float16)(h0 - (float)hh[0]);
      hh[1] = (_Float16)h1; hl[1] = (_Float16)(h1 - (float)hh[1]);
      hh[2] = (_Float16)h2; hl[2] = (_Float16)(h2 - (float)hh[2]);
      hh[3] = (_Float16)h3; hl[3] = (_Float16)(h3 - (float)hh[3]);
      *(f16x4*)&HsH[row*RS + c4*4] = hh;
      *(f16x4*)&HsL[row*RS + c4*4] = hl;
      mx.x = fmaxf(mx.x, h0); mx.y = fmaxf(mx.y, h1);
      mx.z = fmaxf(mx.z, h2); mx.w = fmaxf(mx.w, h3);
    }
    if (half == 1) mxs[(g << 5) | c4] = mx;
    __syncthreads();   // Hs staged + mxs visible
    if (half == 0) {   // waves 0-1: combine halves, emit x1 (FEAT cols 0..127)
      float4 o = mxs[(g << 5) | c4];
      mx.x = fmaxf(mx.x, o.x); mx.y = fmaxf(mx.y, o.y);
      mx.z = fmaxf(mx.z, o.z); mx.w = fmaxf(mx.w, o.w);
      split_store(FFH, FFL, ptg*512 + c4*4 + 0, mx.x);
      split_store(FFH, FFL, ptg*512 + c4*4 + 1, mx.y);
      split_store(FFH, FFL, ptg*512 + c4*4 + 2, mx.z);
      split_store(FFH, FFL, ptg*512 + c4*4 + 3, mx.w);
    }
  }

  // MFMA K-loop: each wave owns 32 M-rows (2 frags) x full 80 cols (5 frags)
  f32x4 acc[2][5];
  #pragma unroll
  for (int m = 0; m < 2; ++m)
    #pragma unroll
    for (int n = 0; n < 5; ++n) acc[m][n] = (f32x4){0.f, 0.f, 0.f, 0.f};

  #pragma unroll
  for (int ks = 0; ks < 4; ++ks) {
    f16x8 bh[5], bl[5];
    #pragma unroll
    for (int n = 0; n < 5; ++n) {
      int ro = (n*16 + fr)*RS + ks*32 + kg;
      bh[n] = *(const f16x8*)&HsH[ro];
      bl[n] = *(const f16x8*)&HsL[ro];
    }
    #pragma unroll
    for (int m = 0; m < 2; ++m)
      #pragma unroll
      for (int n = 0; n < 5; ++n) {
        acc[m][n] = __builtin_amdgcn_mfma_f32_16x16x32_f16(ah[m][ks], bh[n], acc[m][n], 0, 0, 0);
        acc[m][n] = __builtin_amdgcn_mfma_f32_16x16x32_f16(ah[m][ks], bl[n], acc[m][n], 0, 0, 0);
        acc[m][n] = __builtin_amdgcn_mfma_f32_16x16x32_f16(al[m][ks], bh[n], acc[m][n], 0, 0, 0);
      }
  }
  __syncthreads();   // Hs dead; reuse as Cs

  // scatter raw acc to Cs[128][84]; C/D map: col=lane&15, row=(lane>>4)*4+reg
  int rowg = (lane >> 4) * 4;
  #pragma unroll
  for (int m = 0; m < 2; ++m) {
    int r = wave*32 + m*16 + rowg;
    #pragma unroll
    for (int n = 0; n < 5; ++n) {
      int p = n*16 + fr;
      #pragma unroll
      for (int q = 0; q < 4; ++q) Cs[(r+q)*84 + p] = acc[m][n][q];
    }
  }
  __syncthreads();

  // group max (20 neighbors) + bias + lrelu -> x2 (FEAT cols 128..255)
  #pragma unroll
  for (int t = 0; t < 2; ++t) {
    int task = tid + t*256;
    int r = task & 127, g = task >> 7;
    const float* cr = &Cs[r*84 + g*20];
    float m = cr[0];
    #pragma unroll
    for (int k = 1; k < 20; ++k) m = fmaxf(m, cr[k]);
    float v = lrelu_f(m + bias[r]);
    split_store(FFH, FFL, (pt0 + g)*512 + 128 + r, v);
  }
}

// ---------------------------------------------------------------- sn block: x3 = max_k lrelu(U2[j] + V2[n])
__global__ __launch_bounds__(256) void sn_gather(
    const float* __restrict__ UV2, const int* __restrict__ IDXX,
    _Float16* __restrict__ FFH, _Float16* __restrict__ FFL)
{
  int tid = threadIdx.x;   // channel 0..255
  int p0 = blockIdx.x * 4;
  for (int pp = 0; pp < 4; ++pp) {
    size_t pt = (size_t)(p0 + pp);
    size_t bb = (size_t)((p0+pp) >> 12) << 12;
    float v = UV2[pt*512 + 256 + tid];
    float m = -1e30f;
    for (int k = 0; k < KNN; ++k) {
      int j = IDXX[pt*KNN + k];
      float h = lrelu_f(UV2[(bb + j)*512 + tid] + v);
      m = fmaxf(m, h);
    }
    split_store(FFH, FFL, pt*512 + 256 + tid, m);
  }
}

// ---------------------------------------------------------------- farthest point sampling (reg-resident, shuffle argmax)
__global__ __launch_bounds__(512) void fps_kernel(
    const float* __restrict__ xyz, int* __restrict__ SIDX)
{
  int b = blockIdx.x, tid = threadIdx.x;
  int lane = tid & 63, wave = tid >> 6;   // 8 waves
  const float* p = xyz + (size_t)b*3*NPTS;
  float px[8], py[8], pz[8], dist[8];
  #pragma unroll
  for (int j = 0; j < 8; ++j) {
    int i = tid + j*512;
    px[j] = p[i]; py[j] = p[NPTS+i]; pz[j] = p[2*NPTS+i];
    dist[j] = 1e10f;
  }
  __shared__ float bv[8], bx[8], by[8], bz[8];
  __shared__ int bi[8];
  float cx = p[0], cy = p[NPTS], cz = p[2*NPTS];
  int far = 0;
  for (int it = 0; it < 32; ++it) {
    if (tid == 0) SIDX[b*32 + it] = far;
    float lm = -1e30f, lx = 0.f, ly = 0.f, lz = 0.f; int li = 0;
    #pragma unroll
    for (int j = 0; j < 8; ++j) {
      float dx = px[j]-cx, dy = py[j]-cy, dz = pz[j]-cz;
      float d = dx*dx + dy*dy + dz*dz;
      float dm = fminf(dist[j], d);
      dist[j] = dm;
      bool sw = dm > lm;                  // strict: keep earliest index on ties
      lm = sw ? dm : lm;
      li = sw ? (tid + j*512) : li;
      lx = sw ? px[j] : lx; ly = sw ? py[j] : ly; lz = sw ? pz[j] : lz;
    }
    // wave butterfly: larger dist wins; tie -> smaller index
    #pragma unroll
    for (int k = 1; k < 64; k <<= 1) {
      float om = __shfl_xor(lm, k, 64);
      int   oi = __shfl_xor(li, k, 64);
      float ox = __shfl_xor(lx, k, 64);
      float oy = __shfl_xor(ly, k, 64);
      float oz = __shfl_xor(lz, k, 64);
      bool tk = (om > lm) || (om == lm && oi < li);
      lm = tk ? om : lm; li = tk ? oi : li;
      lx = tk ? ox : lx; ly = tk ? oy : ly; lz = tk ? oz : lz;
    }
    if (lane == 0) { bv[wave] = lm; bi[wave] = li; bx[wave] = lx; by[wave] = ly; bz[wave] = lz; }
    __syncthreads();
    float m0 = bv[0]; int i0 = bi[0];
    float X = bx[0], Y = by[0], Z = bz[0];
    #pragma unroll
    for (int w = 1; w < 8; ++w) {
      bool tk = (bv[w] > m0) || (bv[w] == m0 && bi[w] < i0);
      m0 = tk ? bv[w] : m0; i0 = tk ? bi[w] : i0;
      X = tk ? bx[w] : X; Y = tk ? by[w] : Y; Z = tk ? bz[w] : Z;
    }
    far = i0; cx = X; cy = Y; cz = Z;
    __syncthreads();
  }
}

// ---------------------------------------------------------------- k-farthest (8) among 32 samples
__global__ __launch_bounds__(128) void kfn_kernel(
    const float* __restrict__ xyz, const int* __restrict__ SIDX,
    int* __restrict__ NIDX)
{
  int tid = threadIdx.x;     // 0..127
  int b = tid >> 5, i = tid & 31;
  const float* p = xyz + (size_t)b*3*NPTS;
  __shared__ float sx[4][32], sy[4][32], sz[4][32];
  {
    int si = SIDX[b*32 + i];
    sx[b][i] = p[si]; sy[b][i] = p[NPTS+si]; sz[b][i] = p[2*NPTS+si];
  }
  __syncthreads();
  float xi = sx[b][i], yi = sy[b][i], zi = sz[b][i];
  float xxi = xi*xi + yi*yi + zi*zi;
  float bd[8]; int bi_[8];
  #pragma unroll
  for (int t = 0; t < 8; ++t) { bd[t] = -1e30f; bi_[t] = 0; }
  for (int j = 0; j < 32; ++j) {
    float xj = sx[b][j], yj = sy[b][j], zj = sz[b][j];
    float xxj = xj*xj + yj*yj + zj*zj;
    float d = xxi - 2.f*(xi*xj + yi*yj + zi*zj) + xxj;
    if (d > bd[7]) {
      float cd = d; int ci = j;
      #pragma unroll
      for (int t = 0; t < 8; ++t) {
        bool sw = bd[t] < cd;       // descending
        float nv = sw ? cd : bd[t];
        int   ni = sw ? ci : bi_[t];
        float ov = sw ? bd[t] : cd;
        int   oi = sw ? bi_[t] : ci;
        bd[t] = nv; bi_[t] = ni; cd = ov; ci = oi;
      }
    }
  }
  size_t o = (size_t)(b*32 + i)*8;
  #pragma unroll
  for (int t = 0; t < 8; ++t) NIDX[o+t] = bi_[t];
}

// ---------------------------------------------------------------- triplet terms
__global__ __launch_bounds__(256) void trip_kernel(
    const float* __restrict__ es0, const float* __restrict__ et0,
    const int* __restrict__ SIDX, const int* __restrict__ NIDX,
    float* __restrict__ ACC)
{
  int bi_ = blockIdx.x; int b = bi_ >> 5;
  int tid = threadIdx.x;
  __shared__ int js[8];
  __shared__ int ssi;
  if (tid == 0) ssi = SIDX[bi_];
  if (tid < 8) js[tid] = SIDX[b*32 + NIDX[bi_*8 + tid]];
  __syncthreads();
  int si = ssi;
  const float* es = es0 + (size_t)b*1024*NPTS;
  const float* et = et0 + (size_t)b*1024*NPTS;
  float sp = 0.f, sn = 0.f;
  for (int c = tid; c < 1024; c += 256) {
    const float* erow = et + (size_t)c*NPTS;
    float s = es[(size_t)c*NPTS + si];
    float d0 = s - erow[si]; sp += d0*d0;
    #pragma unroll
    for (int t = 0; t < 8; ++t) { float d1 = s - erow[js[t]]; sn += d1*d1; }
  }
  __shared__ float r1[256], r2[256];
  r1[tid] = sp; r2[tid] = sn; __syncthreads();
  for (int s2 = 128; s2 > 0; s2 >>= 1) {
    if (tid < s2) { r1[tid] += r1[tid+s2]; r2[tid] += r2[tid+s2]; }
    __syncthreads();
  }
  if (tid == 0) {
    float dp = r1[0] * (1.f/1024.f);
    float dn = r2[0] * (1.f/8192.f);
    float tr = fmaxf(0.f, 1.f - dn/(1.f + dp));
    atomicAdd(&ACC[0], tr);
  }
}

// ---------------------------------------------------------------- norms + mse + mae
__global__ __launch_bounds__(256) void stats_kernel(
    const float* __restrict__ es0, const float* __restrict__ et0,
    float* __restrict__ ACC)
{
  int tid = threadIdx.x;
  int p = tid & 63, g = tid >> 6;
  int pt0 = blockIdx.x * 64;
  int b = pt0 >> 12, n0 = pt0 & (NPTS-1);
  const float* es = es0 + (size_t)b*1024*NPTS + n0;
  const float* et = et0 + (size_t)b*1024*NPTS + n0;
  float ss = 0.f, tt = 0.f, sq = 0.f, ab = 0.f;
  for (int c = g; c < 1024; c += 4) {
    float s = es[(size_t)c*NPTS + p];
    float t = et[(size_t)c*NPTS + p];
    ss += s*s; tt += t*t;
    float d = s - t;
    sq += d*d; ab += fabsf(d);
  }
  __shared__ float rs[4][64], rt[4][64];
  __shared__ float red[256];
  rs[g][p] = ss; rt[g][p] = tt;
  red[tid] = sq;
  __syncthreads();
  for (int s2 = 128; s2 > 0; s2 >>= 1) {
    if (tid < s2) red[tid] += red[tid+s2];
    __syncthreads();
  }
  if (tid == 0) atomicAdd(&ACC[3], red[0]);
  __syncthreads();
  red[tid] = ab; __syncthreads();
  for (int s2 = 128; s2 > 0; s2 >>= 1) {
    if (tid < s2) red[tid] += red[tid+s2];
    __syncthreads();
  }
  if (tid == 0) atomicAdd(&ACC[4], red[0]);
  if (tid < 64) {
    float a = sqrtf(rs[0][tid]+rs[1][tid]+rs[2][tid]+rs[3][tid]) - 1.f;
    float c = sqrtf(rt[0][tid]+rt[1][tid]+rt[2][tid]+rt[3][tid]) - 1.f;
    float av = a*a, cv = c*c;
    #pragma unroll
    for (int s2 = 32; s2 > 0; s2 >>= 1) {
      av += __shfl_down(av, s2, 64);
      cv += __shfl_down(cv, s2, 64);
    }
    if (tid == 0) { atomicAdd(&ACC[1], av); atomicAdd(&ACC[2], cv); }
  }
}

// ---------------------------------------------------------------- finalize scalars
__global__ void finalize_kernel(const float* __restrict__ ACC, float* __restrict__ o3) {
  if (threadIdx.x == 0 && blockIdx.x == 0) {
    float ln1 = sqrtf(ACC[1] * (1.f/16384.f));
    float ln2 = sqrtf(ACC[2] * (1.f/16384.f));
    o3[0] = ACC[0]*(1.f/128.f) + (ln1 + ln2)*0.5f*0.03f;
    o3[1] = ACC[3] * (1.f/4194304.f);   // mean((s-t)^2)*B
    o3[2] = ACC[4] * (1.f/4194304.f);   // mean(|s-t|)*B
  }
}

// ================================================================ host
extern "C" void kernel_launch(void* const* d_in, const int* in_sizes, int n_in,
                              void* d_out, int out_size, void* d_ws, size_t ws_size,
                              hipStream_t stream) {
  (void)in_sizes; (void)n_in; (void)out_size; (void)ws_size;
  const float* src  = (const float*)d_in[0];
  const float* tgt  = (const float*)d_in[1];
  const float* w1   = (const float*)d_in[2];
  const float* b1   = (const float*)d_in[3];
  const float* w2   = (const float*)d_in[4];
  const float* b2   = (const float*)d_in[5];
  const float* wdg1 = (const float*)d_in[6];
  const float* bdg1 = (const float*)d_in[7];
  const float* wdg2 = (const float*)d_in[8];
  const float* bdg2 = (const float*)d_in[9];
  const float* wsn1 = (const float*)d_in[10];
  const float* bsn1 = (const float*)d_in[11];
  const float* w3   = (const float*)d_in[12];
  const float* b3   = (const float*)d_in[13];
  float* out = (float*)d_out;

  float* ws = (float*)d_ws;
  float*  XTP  = ws;                                   // BN*4 (float4 x,y,z,xx)
  float*  XT2  = XTP + (size_t)BN*4;                   // BN*64
  float*  XX2  = XT2 + (size_t)BN*64;                  // BN
  float*  UV1  = XX2 + BN;                             // BN*256
  _Float16* FFH = (_Float16*)(UV1 + (size_t)BN*256);   // BN*512 halves (x1|x2|x3 hi)
  _Float16* FFL = FFH + (size_t)BN*512;                // BN*512 halves (lo)
  float*  UV2  = (float*)(FFL + (size_t)BN*512);       // BN*512
  float*  Dbuf = (float*)FFH;                          // NPTS*NPTS fp32 aliases FFH|FFL|UV2 (dead then)
  float*  H1SLOT = UV2 + (size_t)BN*512;               // former H1 region (scratch)
  _Float16* XT2H = (_Float16*)H1SLOT;                  // BN*64 halves
  _Float16* XT2L = XT2H + (size_t)BN*64;               // BN*64 halves
  int*    IDXF = (int*)(H1SLOT + (size_t)NPTS*KNN*128);// BN*KNN
  int*    IDXX = IDXF + (size_t)BN*KNN;                // BN*KNN
  _Float16* W2H = (_Float16*)(IDXX + (size_t)BN*KNN);  // 128*128 halves (old WT2 slot)
  _Float16* W2L = W2H + 128*128;                       // 128*128 halves
  float*  BUV1 = (float*)(W2L + 128*128);              // 256
  float*  BUV2 = BUV1 + 256;                           // 512
  _Float16* W3H = (_Float16*)(BUV2 + 512);             // 1024*512 halves
  _Float16* W3L = W3H + 1024*512;
  _Float16* WH1 = W3L + 1024*512;                      // 256*64 halves
  _Float16* WL1 = WH1 + 256*64;
  _Float16* WH2 = WL1 + 256*64;                        // 512*128 halves
  _Float16* WL2 = WH2 + 512*128;
  int*    SIDX = (int*)(WL2 + 512*128);                // NB*32
  int*    NIDX = SIDX + NB*32;                         // NB*32*8
  float*  ACC  = (float*)(NIDX + NB*32*8);             // 8

  prep_weights<<<2048, 256, 0, stream>>>(wdg1, bdg1, wdg2, wsn1, bsn1, w3,
                                         W2H, W2L, BUV1, BUV2,
                                         W3H, W3L, WH1, WL1, WH2, WL2);

  auto run_cloud = [&](const float* xyz, float* emb) {
    pack_xyz<<<BN/256, 256, 0, stream>>>(xyz, (float4*)XTP);
    conv12<<<BN/4, 256, 0, stream>>>(xyz, w1, b1, w2, b2, XT2, XX2, XT2H, XT2L);
    for (int bb = 0; bb < NB; ++bb) {
      dist_gemm<<<dim3(32,32), 256, 0, stream>>>(
          XT2 + (size_t)bb*NPTS*64, XX2 + (size_t)bb*NPTS, Dbuf);
      knn_select<true><<<NPTS/4, 256, 0, stream>>>(Dbuf, (const float4*)XTP, bb, IDXF);
      knn_select<false><<<NPTS/4, 256, 0, stream>>>(nullptr, (const float4*)XTP, bb, IDXX);
    }
    // UV1 = WEFF1 * XT2 (f16x3 MFMA)
    mfma_gemm<false,false><<<dim3(BN/128, 2), 256, 0, stream>>>(
        WH1, WL1, 256, 64, XT2H, XT2L, 64, 0, BUV1, UV1, 256);
    // fused gather + dg2 MFMA -> x1 (cols 0..127) + x2 (cols 128..255)
    dg2_fused<<<BN/4, 256, 0, stream>>>(W2H, W2L, UV1, IDXF, bdg2, FFH, FFL);
    // UV2 = WEFF2 * x2 (f16x3 MFMA)
    mfma_gemm<false,false><<<dim3(BN/128, 4), 256, 0, stream>>>(
        WH2, WL2, 512, 128, FFH, FFL, 512, 128, BUV2, UV2, 512);
    sn_gather<<<BN/4, 256, 0, stream>>>(UV2, IDXX, FFH, FFL);
    // emb = lrelu(W3 * feat + b3), channel-major (f16x3 MFMA)
    mfma_gemm<true,true><<<dim3(BN/128, 8), 256, 0, stream>>>(
        W3H, W3L, 1024, 512, FFH, FFL, 512, 0, b3, emb, 0);
  };

  float* emb_s = out;
  float* emb_t = out + (size_t)BN*1024;
  run_cloud(src, emb_s);
  run_cloud(tgt, emb_t);

  hipMemsetAsync(ACC, 0, 8*sizeof(float), stream);
  fps_kernel<<<NB, 512, 0, stream>>>(src, SIDX);
  kfn_kernel<<<1, 128, 0, stream>>>(src, SIDX, NIDX);
  trip_kernel<<<NB*32, 256, 0, stream>>>(emb_s, emb_t, SIDX, NIDX, ACC);
  stats_kernel<<<BN/64, 256, 0, stream>>>(emb_s, emb_t, ACC);
  finalize_kernel<<<1, 64, 0, stream>>>(ACC, out + (size_t)2*BN*1024);
}

// Round 3
// 1393.595 us; speedup vs baseline: 1.6451x; 1.0855x over previous
//
#include <hip/hip_runtime.h>
#include <cstdint>

#define NB 4
#define NPTS 4096
#define KNN 20
#define BN (NB*NPTS)   // 16384

typedef _Float16 f16x8 __attribute__((ext_vector_type(8)));
typedef _Float16 f16x4 __attribute__((ext_vector_type(4)));
typedef float    f32x4 __attribute__((ext_vector_type(4)));

__device__ __forceinline__ float lrelu_f(float x) { return x > 0.f ? x : 0.2f * x; }

__device__ __forceinline__ float med3f(float c, float lo, float hi) {
#if defined(__has_builtin)
#if __has_builtin(__builtin_amdgcn_fmed3f)
  return __builtin_amdgcn_fmed3f(c, lo, hi);
#else
  return fminf(fmaxf(c, lo), hi);
#endif
#else
  return fminf(fmaxf(c, lo), hi);
#endif
}

// async global->LDS, 16B per lane (lane-linear LDS dest required)
__device__ __forceinline__ void gld16(const void* g, void* l) {
  __builtin_amdgcn_global_load_lds(
      (const __attribute__((address_space(1))) void*)g,
      (__attribute__((address_space(3))) void*)l,
      16, 0, 0);
}

__device__ __forceinline__ void split_store(_Float16* __restrict__ H, _Float16* __restrict__ L,
                                            size_t idx, float v) {
  _Float16 h = (_Float16)v;
  H[idx] = h;
  L[idx] = (_Float16)(v - (float)h);
}

// ---------------------------------------------------------------- prep weights
__global__ __launch_bounds__(256) void prep_weights(
    const float* __restrict__ wdg1, const float* __restrict__ bdg1,
    const float* __restrict__ wdg2,
    const float* __restrict__ wsn1, const float* __restrict__ bsn1,
    const float* __restrict__ w3,
    _Float16* __restrict__ W2H, _Float16* __restrict__ W2L,
    float* __restrict__ BUV1, float* __restrict__ BUV2,
    _Float16* __restrict__ W3H, _Float16* __restrict__ W3L,
    _Float16* __restrict__ WH1, _Float16* __restrict__ WL1,
    _Float16* __restrict__ WH2, _Float16* __restrict__ WL2)
{
  int i = blockIdx.x * 256 + threadIdx.x;
  if (i < 512*1024) {           // w3 is already [M=1024][K=512]
    float v = w3[i];
    split_store(W3H, W3L, i, v);
  }
  if (i < 256*64) {             // WEFF1: [M=256][K=64]
    int r = i >> 6, c = i & 63;
    float v = (r < 128) ? wdg1[r*128 + c]
                        : (wdg1[(r-128)*128 + 64 + c] - wdg1[(r-128)*128 + c]);
    split_store(WH1, WL1, i, v);
  }
  if (i < 512*128) {            // WEFF2: [M=512][K=128]
    int r = i >> 7, c = i & 127;
    float v = (r < 256) ? wsn1[r*256 + c]
                        : (wsn1[(r-256)*256 + 128 + c] - wsn1[(r-256)*256 + c]);
    split_store(WH2, WL2, i, v);
  }
  if (i < 128*128) split_store(W2H, W2L, i, wdg2[i]);  // [M=o][K=c] identity layout
  if (i < 256) BUV1[i] = (i < 128) ? 0.f : bdg1[i-128];
  if (i < 512) BUV2[i] = (i < 256) ? 0.f : bsn1[i-256];
}

// ---------------------------------------------------------------- pack xyz -> float4 (x,y,z,xx)
__global__ __launch_bounds__(256) void pack_xyz(
    const float* __restrict__ xyz, float4* __restrict__ XTP4)
{
  int i = blockIdx.x * 256 + threadIdx.x;
  if (i >= BN) return;
  int b = i >> 12, n = i & (NPTS-1);
  const float* p = xyz + (size_t)b*3*NPTS;
  float x = p[n], y = p[NPTS+n], z = p[2*NPTS+n];
  float4 v; v.x = x; v.y = y; v.z = z; v.w = x*x + y*y + z*z;
  XTP4[i] = v;
}

// ---------------------------------------------------------------- conv1 + conv2 fused (3->64->64)
__global__ __launch_bounds__(256) void conv12(
    const float* __restrict__ xyz,
    const float* __restrict__ w1, const float* __restrict__ b1,
    const float* __restrict__ w2, const float* __restrict__ b2,
    float* __restrict__ XT2, float* __restrict__ XX2,
    _Float16* __restrict__ XT2H, _Float16* __restrict__ XT2L)
{
  __shared__ float w2t[64*65];
  __shared__ float h1s[4][64];
  int tid = threadIdx.x;
  for (int i = tid; i < 4096; i += 256) {
    int o = i >> 6, c = i & 63;
    w2t[c*65 + o] = w2[i];
  }
  int g = tid >> 6, o = tid & 63;
  int pt = blockIdx.x*4 + g;
  int b = pt >> 12, n = pt & (NPTS-1);
  const float* p = xyz + (size_t)b*3*NPTS;
  float x = p[n], y = p[NPTS+n], z = p[2*NPTS+n];
  float h1 = b1[o] + w1[o*3]*x + w1[o*3+1]*y + w1[o*3+2]*z;
  h1 = lrelu_f(h1);
  __syncthreads();
  h1s[g][o] = h1;
  __syncthreads();
  float acc = b2[o];
  #pragma unroll
  for (int c = 0; c < 64; ++c) acc = fmaf(w2t[c*65+o], h1s[g][c], acc);
  acc = lrelu_f(acc);
  XT2[(size_t)pt*64 + o] = acc;
  split_store(XT2H, XT2L, (size_t)pt*64 + o, acc);
  float v = acc*acc;
  #pragma unroll
  for (int s = 32; s > 0; s >>= 1) v += __shfl_down(v, s, 64);
  if (o == 0) XX2[pt] = v;
}

// ---------------------------------------------------------------- triangular distance GEMM (per batch)
// D symmetric in the dot term: block (ti<=tj) computes the (q,j) tile once and
// writes both D[q][j] = xx_j - 2*dot and D[j][q] = xx_q - 2*dot (bitwise-identical
// to the square version: same K-order, commutative multiply).
__global__ __launch_bounds__(256) void dist_gemm_tri(
    const float* __restrict__ XQ,   // batch slice of XT2, [4096][64]
    const float* __restrict__ XXb,  // batch slice of XX2, [4096]
    float* __restrict__ D)          // [4096][4096]
{
  // map blockIdx.x in [0,528) -> (ti,tj) with ti<=tj, NT=32
  int r = blockIdx.x, ti = 0;
  #pragma unroll 1
  for (;;) { int len = 32 - ti; if (r < len) break; r -= len; ++ti; }
  int tj = ti + r;
  int q0 = ti * 128, j0 = tj * 128;

  __shared__ float Qs[16][132];
  __shared__ float Xs[16][132];
  int tid = threadIdx.x;
  int rg = tid & 15, cg = tid >> 4;
  float acc[8][8];
  #pragma unroll
  for (int u = 0; u < 8; ++u)
    #pragma unroll
    for (int v = 0; v < 8; ++v) acc[u][v] = 0.f;

  for (int c0 = 0; c0 < 64; c0 += 16) {
    #pragma unroll
    for (int i = 0; i < 8; ++i) {
      int idx = tid + i*256;
      int kk = idx & 15, p = idx >> 4;
      Qs[kk][p] = XQ[(size_t)(q0+p)*64 + c0 + kk];
      Xs[kk][p] = XQ[(size_t)(j0+p)*64 + c0 + kk];
    }
    __syncthreads();
    #pragma unroll
    for (int kk = 0; kk < 16; ++kk) {
      float a[8], bb[8];
      #pragma unroll
      for (int u = 0; u < 8; ++u) a[u] = Qs[kk][rg*8+u];
      #pragma unroll
      for (int v = 0; v < 8; ++v) bb[v] = Xs[kk][cg*8+v];
      #pragma unroll
      for (int u = 0; u < 8; ++u)
        #pragma unroll
        for (int v = 0; v < 8; ++v) acc[u][v] = fmaf(a[u], bb[v], acc[u][v]);
    }
    __syncthreads();
  }
  // epilogue 1: D[q][j] = xx_j - 2*dot
  {
    float xxv[8];
    #pragma unroll
    for (int v = 0; v < 8; ++v) xxv[v] = XXb[j0 + cg*8 + v];
    #pragma unroll
    for (int u = 0; u < 8; ++u) {
      float* po = D + (size_t)(q0 + rg*8 + u)*NPTS + j0 + cg*8;
      #pragma unroll
      for (int v = 0; v < 8; ++v) po[v] = fmaf(-2.f, acc[u][v], xxv[v]);
    }
  }
  // epilogue 2 (off-diagonal): D[j][q] = xx_q - 2*dot (register-transposed tile)
  if (ti != tj) {
    float xxq[8];
    #pragma unroll
    for (int u = 0; u < 8; ++u) xxq[u] = XXb[q0 + rg*8 + u];
    #pragma unroll
    for (int v = 0; v < 8; ++v) {
      float* po = D + (size_t)(j0 + cg*8 + v)*NPTS + q0 + rg*8;
      float4 w0, w1;
      w0.x = fmaf(-2.f, acc[0][v], xxq[0]);
      w0.y = fmaf(-2.f, acc[1][v], xxq[1]);
      w0.z = fmaf(-2.f, acc[2][v], xxq[2]);
      w0.w = fmaf(-2.f, acc[3][v], xxq[3]);
      w1.x = fmaf(-2.f, acc[4][v], xxq[4]);
      w1.y = fmaf(-2.f, acc[5][v], xxq[5]);
      w1.z = fmaf(-2.f, acc[6][v], xxq[6]);
      w1.w = fmaf(-2.f, acc[7][v], xxq[7]);
      *(float4*)po = w0;
      *(float4*)(po + 4) = w1;
    }
  }
}

// ---------------------------------------------------------------- knn select
// batch >= 0: per-batch grid (NPTS/4 blocks). batch < 0: merged grid (BN/4 blocks).
template<bool FEAT_MODE>
__global__ __launch_bounds__(256) void knn_select(
    const float* __restrict__ D, const float4* __restrict__ XTP4,
    int batch, int* __restrict__ IDX)
{
  int lane = threadIdx.x & 63;
  int blk = blockIdx.x, bq = batch;
  if (batch < 0) { bq = blk >> 10; blk &= 1023; }
  int ql = blk*4 + (threadIdx.x >> 6);          // query local to batch
  int qg = bq*NPTS + ql;                        // global point id
  const float4* drow4 = FEAT_MODE ? (const float4*)(D + (size_t)ql*NPTS) : nullptr;
  const float4* Xb4 = XTP4 + (size_t)bq*NPTS;
  float qx = 0.f, qy = 0.f, qz = 0.f;
  if (!FEAT_MODE) { float4 qp = XTP4[qg]; qx = qp.x; qy = qp.y; qz = qp.z; }

  auto key3 = [&](float4 p) -> float {
    float dot = qx*p.x;
    dot = fmaf(qy, p.y, dot);
    dot = fmaf(qz, p.z, dot);
    return fmaf(-2.f, dot, p.w);
  };
  auto getd4 = [&](int t) -> float4 {
    if (FEAT_MODE) {
      return drow4[t*64 + lane];
    } else {
      int jb = t*256 + lane*4;
      float4 r;
      r.x = key3(Xb4[jb+0]);
      r.y = key3(Xb4[jb+1]);
      r.z = key3(Xb4[jb+2]);
      r.w = key3(Xb4[jb+3]);
      return r;
    }
  };

  float bd[KNN];
  #pragma unroll
  for (int t = 0; t < KNN; ++t) bd[t] = 1e30f;
  for (int t = 0; t < 16; ++t) {
    float4 dv = getd4(t);
    float ds[4] = {dv.x, dv.y, dv.z, dv.w};
    #pragma unroll
    for (int e = 0; e < 4; ++e) {
      float cd = ds[e];
      #pragma unroll
      for (int s = KNN-1; s >= 1; --s) bd[s] = med3f(cd, bd[s-1], bd[s]);
      bd[0] = fminf(bd[0], cd);
    }
  }

  float thr = 1e30f;
  {
    int total = 0;
    #pragma unroll 1
    for (int r = 0; r < KNN; ++r) {
      float m = bd[0];
      #pragma unroll
      for (int k = 1; k < 64; k <<= 1) m = fminf(m, __shfl_xor(m, k, 64));
      unsigned long long bal = __ballot(bd[0] == m);
      total += __popcll(bal);
      if (total >= KNN) { thr = m; break; }
      if (bd[0] == m) {
        #pragma unroll
        for (int s = 0; s < KNN-1; ++s) bd[s] = bd[s+1];
        bd[KNN-1] = 1e30f;
      }
    }
  }

  unsigned long long lml = (1ull << lane) - 1ull;
  int S = 0;
  int myj = 0x7fffffff;
  for (int t = 0; t < 16; ++t) {
    float4 dv = getd4(t);
    float ds[4] = {dv.x, dv.y, dv.z, dv.w};
    int jb = t*256 + lane*4;
    #pragma unroll
    for (int e = 0; e < 4; ++e) {
      float d = ds[e];
      int j = jb + e;
      bool ps = d < thr;
      unsigned long long mk = __ballot(ps);
      int pos = S + __popcll(mk & lml);
      if (ps && pos < KNN) IDX[(size_t)qg*KNN + pos] = j;
      S += __popcll(mk);
      if (d == thr && j < myj) myj = j;
    }
  }
  int need = KNN - S;
  if (need == 1) {
    int mn = myj;
    #pragma unroll
    for (int k = 1; k < 64; k <<= 1) mn = min(mn, __shfl_xor(mn, k, 64));
    if (lane == 0) IDX[(size_t)qg*KNN + S] = mn;
  } else if (need > 1) {
    if (lane == 0) {
      int taken = 0;
      for (int j = 0; j < NPTS && taken < need; ++j) {
        float d;
        if (FEAT_MODE) d = D[(size_t)ql*NPTS + j];
        else           d = key3(Xb4[j]);
        if (d == thr) { IDX[(size_t)qg*KNN + S + taken] = j; ++taken; }
      }
    }
  }
}

// ---------------------------------------------------------------- f16x3 split MFMA GEMM (generic)
template<bool LRELU_, bool CM>
__global__ __launch_bounds__(256) void mfma_gemm(
    const _Float16* __restrict__ WH, const _Float16* __restrict__ WL,  // [Mtot][KT]
    int Mtot, int KT,
    const _Float16* __restrict__ FH, const _Float16* __restrict__ FL,  // [pt][fstride]
    int fstride, int foff,
    const float* __restrict__ bias,
    float* __restrict__ Out, int ostride)
{
  __shared__ _Float16 As[2][128*32];
  __shared__ _Float16 Bs[2][128*32];
  int tid = threadIdx.x;
  int lane = tid & 63, wave = tid >> 6;
  int wr = wave >> 1, wc = wave & 1;
  int rt = blockIdx.y * 128, ct = blockIdx.x * 128;

  int srow = tid >> 2;
  int skh  = (tid & 3) * 8;
  const _Float16* gA0 = WH + (size_t)(rt + srow)*KT + skh;
  const _Float16* gA1 = WL + (size_t)(rt + srow)*KT + skh;
  const _Float16* gB0 = FH + (size_t)(ct + srow)*fstride + foff + skh;
  const _Float16* gB1 = FL + (size_t)(ct + srow)*fstride + foff + skh;
  const size_t a2 = (size_t)64*KT;
  const size_t b2 = (size_t)64*fstride;
  _Float16* lA0 = &As[0][tid*8];
  _Float16* lA1 = &As[1][tid*8];
  _Float16* lB0 = &Bs[0][tid*8];
  _Float16* lB1 = &Bs[1][tid*8];

  f32x4 acc[4][4];
  #pragma unroll
  for (int m = 0; m < 4; ++m)
    #pragma unroll
    for (int n = 0; n < 4; ++n) acc[m][n] = (f32x4){0.f, 0.f, 0.f, 0.f};

  int fr = lane & 15;
  int kg = (lane >> 4) * 8;

  for (int k0 = 0; k0 < KT; k0 += 32) {
    gld16(gA0 + k0,      lA0);
    gld16(gA0 + k0 + a2, lA0 + 2048);
    gld16(gA1 + k0,      lA1);
    gld16(gA1 + k0 + a2, lA1 + 2048);
    gld16(gB0 + k0,      lB0);
    gld16(gB0 + k0 + b2, lB0 + 2048);
    gld16(gB1 + k0,      lB1);
    gld16(gB1 + k0 + b2, lB1 + 2048);
    __syncthreads();

    f16x8 ah[4], al[4], bh[4], bl[4];
    #pragma unroll
    for (int m = 0; m < 4; ++m) {
      int ro = (wr*64 + m*16 + fr)*32 + kg;
      ah[m] = *(const f16x8*)&As[0][ro];
      al[m] = *(const f16x8*)&As[1][ro];
    }
    #pragma unroll
    for (int n = 0; n < 4; ++n) {
      int co = (wc*64 + n*16 + fr)*32 + kg;
      bh[n] = *(const f16x8*)&Bs[0][co];
      bl[n] = *(const f16x8*)&Bs[1][co];
    }
    #pragma unroll
    for (int m = 0; m < 4; ++m)
      #pragma unroll
      for (int n = 0; n < 4; ++n) {
        acc[m][n] = __builtin_amdgcn_mfma_f32_16x16x32_f16(ah[m], bh[n], acc[m][n], 0, 0, 0);
        acc[m][n] = __builtin_amdgcn_mfma_f32_16x16x32_f16(ah[m], bl[n], acc[m][n], 0, 0, 0);
        acc[m][n] = __builtin_amdgcn_mfma_f32_16x16x32_f16(al[m], bh[n], acc[m][n], 0, 0, 0);
      }
    __syncthreads();
  }

  int rowg = (lane >> 4) * 4;
  if (CM) {
    int b = ct >> 12, n0 = ct & (NPTS-1);
    #pragma unroll
    for (int m = 0; m < 4; ++m) {
      int rbase = rt + wr*64 + m*16 + rowg;
      #pragma unroll
      for (int r4 = 0; r4 < 4; ++r4) {
        int r = rbase + r4;
        float bv = bias[r];
        float* po = Out + ((size_t)b*Mtot + r)*NPTS + n0 + wc*64 + fr;
        #pragma unroll
        for (int n = 0; n < 4; ++n) {
          float v = acc[m][n][r4] + bv;
          if (LRELU_) v = lrelu_f(v);
          po[n*16] = v;
        }
      }
    }
  } else {
    #pragma unroll
    for (int n = 0; n < 4; ++n) {
      int pt = ct + wc*64 + n*16 + fr;
      #pragma unroll
      for (int m = 0; m < 4; ++m) {
        int r0 = rt + wr*64 + m*16 + rowg;
        float4 v;
        v.x = acc[m][n][0] + bias[r0];
        v.y = acc[m][n][1] + bias[r0+1];
        v.z = acc[m][n][2] + bias[r0+2];
        v.w = acc[m][n][3] + bias[r0+3];
        if (LRELU_) { v.x = lrelu_f(v.x); v.y = lrelu_f(v.y); v.z = lrelu_f(v.z); v.w = lrelu_f(v.w); }
        *(float4*)&Out[(size_t)pt*ostride + r0] = v;
      }
    }
  }
}

// ---------------------------------------------------------------- fused gather + dg2 MFMA + x1/x2 group-max
__global__ __launch_bounds__(256) void dg2_fused(
    const _Float16* __restrict__ W2H, const _Float16* __restrict__ W2L, // [128][128]
    const float* __restrict__ UV1,      // [BN][256] (U|V)
    const int* __restrict__ IDXF,       // [BN][KNN]
    const float* __restrict__ bias,     // bdg2 [128]
    _Float16* __restrict__ FFH, _Float16* __restrict__ FFL)
{
  constexpr int RS = 136;
  __shared__ __align__(16) unsigned char smem[43520];
  _Float16* HsH = (_Float16*)smem;            // [80][RS]
  _Float16* HsL = (_Float16*)(smem + 21760);  // [80][RS]
  float*    Cs  = (float*)smem;               // [128][84] epilogue reuse
  __shared__ int js[80];
  __shared__ float4 mxs[128];

  int tid = threadIdx.x;
  int lane = tid & 63, wave = tid >> 6;
  size_t pt0 = (size_t)blockIdx.x * 4;
  size_t bbase = (pt0 >> 12) << 12;

  if (tid < 80) js[tid] = IDXF[pt0*KNN + tid];

  int fr = lane & 15, kg = (lane >> 4) * 8;
  f16x8 ah[2][4], al[2][4];
  #pragma unroll
  for (int m = 0; m < 2; ++m) {
    int row = wave*32 + m*16 + fr;
    #pragma unroll
    for (int ks = 0; ks < 4; ++ks) {
      ah[m][ks] = *(const f16x8*)&W2H[row*128 + ks*32 + kg];
      al[m][ks] = *(const f16x8*)&W2L[row*128 + ks*32 + kg];
    }
  }
  __syncthreads();   // js visible

  {
    int g = (tid >> 5) & 3, half = tid >> 7, c4 = tid & 31;
    size_t ptg = pt0 + g;
    float4 vv = *(const float4*)&UV1[ptg*256 + 128 + c4*4];
    float4 mx = make_float4(-1e30f, -1e30f, -1e30f, -1e30f);
    #pragma unroll
    for (int k = 0; k < 10; ++k) {
      int row = g*20 + half*10 + k;
      int j = js[row];
      float4 u = *(const float4*)&UV1[(bbase + (size_t)j)*256 + c4*4];
      float h0 = lrelu_f(u.x + vv.x);
      float h1 = lrelu_f(u.y + vv.y);
      float h2 = lrelu_f(u.z + vv.z);
      float h3 = lrelu_f(u.w + vv.w);
      f16x4 hh, hl;
      hh[0] = (_Float16)h0; hl[0] = (_Float16)(h0 - (float)hh[0]);
      hh[1] = (_Float16)h1; hl[1] = (_Float16)(h1 - (float)hh[1]);
      hh[2] = (_Float16)h2; hl[2] = (_Float16)(h2 - (float)hh[2]);
      hh[3] = (_Float16)h3; hl[3] = (_Float16)(h3 - (float)hh[3]);
      *(f16x4*)&HsH[row*RS + c4*4] = hh;
      *(f16x4*)&HsL[row*RS + c4*4] = hl;
      mx.x = fmaxf(mx.x, h0); mx.y = fmaxf(mx.y, h1);
      mx.z = fmaxf(mx.z, h2); mx.w = fmaxf(mx.w, h3);
    }
    if (half == 1) mxs[(g << 5) | c4] = mx;
    __syncthreads();
    if (half == 0) {
      float4 o = mxs[(g << 5) | c4];
      mx.x = fmaxf(mx.x, o.x); mx.y = fmaxf(mx.y, o.y);
      mx.z = fmaxf(mx.z, o.z); mx.w = fmaxf(mx.w, o.w);
      split_store(FFH, FFL, ptg*512 + c4*4 + 0, mx.x);
      split_store(FFH, FFL, ptg*512 + c4*4 + 1, mx.y);
      split_store(FFH, FFL, ptg*512 + c4*4 + 2, mx.z);
      split_store(FFH, FFL, ptg*512 + c4*4 + 3, mx.w);
    }
  }

  f32x4 acc[2][5];
  #pragma unroll
  for (int m = 0; m < 2; ++m)
    #pragma unroll
    for (int n = 0; n < 5; ++n) acc[m][n] = (f32x4){0.f, 0.f, 0.f, 0.f};

  #pragma unroll
  for (int ks = 0; ks < 4; ++ks) {
    f16x8 bh[5], bl[5];
    #pragma unroll
    for (int n = 0; n < 5; ++n) {
      int ro = (n*16 + fr)*RS + ks*32 + kg;
      bh[n] = *(const f16x8*)&HsH[ro];
      bl[n] = *(const f16x8*)&HsL[ro];
    }
    #pragma unroll
    for (int m = 0; m < 2; ++m)
      #pragma unroll
      for (int n = 0; n < 5; ++n) {
        acc[m][n] = __builtin_amdgcn_mfma_f32_16x16x32_f16(ah[m][ks], bh[n], acc[m][n], 0, 0, 0);
        acc[m][n] = __builtin_amdgcn_mfma_f32_16x16x32_f16(ah[m][ks], bl[n], acc[m][n], 0, 0, 0);
        acc[m][n] = __builtin_amdgcn_mfma_f32_16x16x32_f16(al[m][ks], bh[n], acc[m][n], 0, 0, 0);
      }
  }
  __syncthreads();

  int rowg = (lane >> 4) * 4;
  #pragma unroll
  for (int m = 0; m < 2; ++m) {
    int r = wave*32 + m*16 + rowg;
    #pragma unroll
    for (int n = 0; n < 5; ++n) {
      int p = n*16 + fr;
      #pragma unroll
      for (int q = 0; q < 4; ++q) Cs[(r+q)*84 + p] = acc[m][n][q];
    }
  }
  __syncthreads();

  #pragma unroll
  for (int t = 0; t < 2; ++t) {
    int task = tid + t*256;
    int r = task & 127, g = task >> 7;
    const float* cr = &Cs[r*84 + g*20];
    float m = cr[0];
    #pragma unroll
    for (int k = 1; k < 20; ++k) m = fmaxf(m, cr[k]);
    float v = lrelu_f(m + bias[r]);
    split_store(FFH, FFL, (pt0 + g)*512 + 128 + r, v);
  }
}

// ---------------------------------------------------------------- sn block: one point per block
__global__ __launch_bounds__(256) void sn_gather(
    const float* __restrict__ UV2, const int* __restrict__ IDXX,
    _Float16* __restrict__ FFH, _Float16* __restrict__ FFL)
{
  int tid = threadIdx.x;   // channel 0..255
  size_t pt = blockIdx.x;
  size_t bb = (pt >> 12) << 12;
  __shared__ int js[KNN];
  if (tid < KNN) js[tid] = IDXX[pt*KNN + tid];
  __syncthreads();
  float v = UV2[pt*512 + 256 + tid];
  float m = -1e30f;
  #pragma unroll
  for (int k = 0; k < KNN; ++k) {
    float h = lrelu_f(UV2[(bb + (size_t)js[k])*512 + tid] + v);
    m = fmaxf(m, h);
  }
  split_store(FFH, FFL, pt*512 + 256 + tid, m);
}

// ---------------------------------------------------------------- farthest point sampling (reg-resident, shuffle argmax)
__global__ __launch_bounds__(512) void fps_kernel(
    const float* __restrict__ xyz, int* __restrict__ SIDX)
{
  int b = blockIdx.x, tid = threadIdx.x;
  int lane = tid & 63, wave = tid >> 6;   // 8 waves
  const float* p = xyz + (size_t)b*3*NPTS;
  float px[8], py[8], pz[8], dist[8];
  #pragma unroll
  for (int j = 0; j < 8; ++j) {
    int i = tid + j*512;
    px[j] = p[i]; py[j] = p[NPTS+i]; pz[j] = p[2*NPTS+i];
    dist[j] = 1e10f;
  }
  __shared__ float bv[8], bx[8], by[8], bz[8];
  __shared__ int bi[8];
  float cx = p[0], cy = p[NPTS], cz = p[2*NPTS];
  int far = 0;
  for (int it = 0; it < 32; ++it) {
    if (tid == 0) SIDX[b*32 + it] = far;
    float lm = -1e30f, lx = 0.f, ly = 0.f, lz = 0.f; int li = 0;
    #pragma unroll
    for (int j = 0; j < 8; ++j) {
      float dx = px[j]-cx, dy = py[j]-cy, dz = pz[j]-cz;
      float d = dx*dx + dy*dy + dz*dz;
      float dm = fminf(dist[j], d);
      dist[j] = dm;
      bool sw = dm > lm;
      lm = sw ? dm : lm;
      li = sw ? (tid + j*512) : li;
      lx = sw ? px[j] : lx; ly = sw ? py[j] : ly; lz = sw ? pz[j] : lz;
    }
    #pragma unroll
    for (int k = 1; k < 64; k <<= 1) {
      float om = __shfl_xor(lm, k, 64);
      int   oi = __shfl_xor(li, k, 64);
      float ox = __shfl_xor(lx, k, 64);
      float oy = __shfl_xor(ly, k, 64);
      float oz = __shfl_xor(lz, k, 64);
      bool tk = (om > lm) || (om == lm && oi < li);
      lm = tk ? om : lm; li = tk ? oi : li;
      lx = tk ? ox : lx; ly = tk ? oy : ly; lz = tk ? oz : lz;
    }
    if (lane == 0) { bv[wave] = lm; bi[wave] = li; bx[wave] = lx; by[wave] = ly; bz[wave] = lz; }
    __syncthreads();
    float m0 = bv[0]; int i0 = bi[0];
    float X = bx[0], Y = by[0], Z = bz[0];
    #pragma unroll
    for (int w = 1; w < 8; ++w) {
      bool tk = (bv[w] > m0) || (bv[w] == m0 && bi[w] < i0);
      m0 = tk ? bv[w] : m0; i0 = tk ? bi[w] : i0;
      X = tk ? bx[w] : X; Y = tk ? by[w] : Y; Z = tk ? bz[w] : Z;
    }
    far = i0; cx = X; cy = Y; cz = Z;
    __syncthreads();
  }
}

// ---------------------------------------------------------------- k-farthest (8) among 32 samples
__global__ __launch_bounds__(128) void kfn_kernel(
    const float* __restrict__ xyz, const int* __restrict__ SIDX,
    int* __restrict__ NIDX)
{
  int tid = threadIdx.x;     // 0..127
  int b = tid >> 5, i = tid & 31;
  const float* p = xyz + (size_t)b*3*NPTS;
  __shared__ float sx[4][32], sy[4][32], sz[4][32];
  {
    int si = SIDX[b*32 + i];
    sx[b][i] = p[si]; sy[b][i] = p[NPTS+si]; sz[b][i] = p[2*NPTS+si];
  }
  __syncthreads();
  float xi = sx[b][i], yi = sy[b][i], zi = sz[b][i];
  float xxi = xi*xi + yi*yi + zi*zi;
  float bd[8]; int bi_[8];
  #pragma unroll
  for (int t = 0; t < 8; ++t) { bd[t] = -1e30f; bi_[t] = 0; }
  for (int j = 0; j < 32; ++j) {
    float xj = sx[b][j], yj = sy[b][j], zj = sz[b][j];
    float xxj = xj*xj + yj*yj + zj*zj;
    float d = xxi - 2.f*(xi*xj + yi*yj + zi*zj) + xxj;
    if (d > bd[7]) {
      float cd = d; int ci = j;
      #pragma unroll
      for (int t = 0; t < 8; ++t) {
        bool sw = bd[t] < cd;
        float nv = sw ? cd : bd[t];
        int   ni = sw ? ci : bi_[t];
        float ov = sw ? bd[t] : cd;
        int   oi = sw ? bi_[t] : ci;
        bd[t] = nv; bi_[t] = ni; cd = ov; ci = oi;
      }
    }
  }
  size_t o = (size_t)(b*32 + i)*8;
  #pragma unroll
  for (int t = 0; t < 8; ++t) NIDX[o+t] = bi_[t];
}

// ---------------------------------------------------------------- triplet terms
__global__ __launch_bounds__(256) void trip_kernel(
    const float* __restrict__ es0, const float* __restrict__ et0,
    const int* __restrict__ SIDX, const int* __restrict__ NIDX,
    float* __restrict__ ACC)
{
  int bi_ = blockIdx.x; int b = bi_ >> 5;
  int tid = threadIdx.x;
  __shared__ int js[8];
  __shared__ int ssi;
  if (tid == 0) ssi = SIDX[bi_];
  if (tid < 8) js[tid] = SIDX[b*32 + NIDX[bi_*8 + tid]];
  __syncthreads();
  int si = ssi;
  const float* es = es0 + (size_t)b*1024*NPTS;
  const float* et = et0 + (size_t)b*1024*NPTS;
  float sp = 0.f, sn = 0.f;
  for (int c = tid; c < 1024; c += 256) {
    const float* erow = et + (size_t)c*NPTS;
    float s = es[(size_t)c*NPTS + si];
    float d0 = s - erow[si]; sp += d0*d0;
    #pragma unroll
    for (int t = 0; t < 8; ++t) { float d1 = s - erow[js[t]]; sn += d1*d1; }
  }
  __shared__ float r1[256], r2[256];
  r1[tid] = sp; r2[tid] = sn; __syncthreads();
  for (int s2 = 128; s2 > 0; s2 >>= 1) {
    if (tid < s2) { r1[tid] += r1[tid+s2]; r2[tid] += r2[tid+s2]; }
    __syncthreads();
  }
  if (tid == 0) {
    float dp = r1[0] * (1.f/1024.f);
    float dn = r2[0] * (1.f/8192.f);
    float tr = fmaxf(0.f, 1.f - dn/(1.f + dp));
    atomicAdd(&ACC[0], tr);
  }
}

// ---------------------------------------------------------------- stats stage A: mse/mae + per-point partial norms
__global__ __launch_bounds__(256) void stats_a(
    const float* __restrict__ es0, const float* __restrict__ et0,
    float* __restrict__ PS, float* __restrict__ PT, float* __restrict__ ACC)
{
  int tid = threadIdx.x;
  int p = tid & 63, g = tid >> 6;
  int pt0 = (blockIdx.x & 255) * 64;     // 256 point-tiles of 64
  int chunk = blockIdx.x >> 8;           // 8 channel-chunks of 128
  int b = pt0 >> 12, n0 = pt0 & (NPTS-1);
  const float* es = es0 + (size_t)b*1024*NPTS + n0;
  const float* et = et0 + (size_t)b*1024*NPTS + n0;
  float ss = 0.f, tt = 0.f, sq = 0.f, ab = 0.f;
  int c0 = chunk * 128;
  for (int c = c0 + g; c < c0 + 128; c += 4) {
    float s = es[(size_t)c*NPTS + p];
    float t = et[(size_t)c*NPTS + p];
    ss += s*s; tt += t*t;
    float d = s - t;
    sq += d*d; ab += fabsf(d);
  }
  __shared__ float rs[4][64], rt[4][64];
  __shared__ float red[256];
  rs[g][p] = ss; rt[g][p] = tt;
  red[tid] = sq;
  __syncthreads();
  for (int s2 = 128; s2 > 0; s2 >>= 1) {
    if (tid < s2) red[tid] += red[tid+s2];
    __syncthreads();
  }
  if (tid == 0) atomicAdd(&ACC[3], red[0]);
  __syncthreads();
  red[tid] = ab; __syncthreads();
  for (int s2 = 128; s2 > 0; s2 >>= 1) {
    if (tid < s2) red[tid] += red[tid+s2];
    __syncthreads();
  }
  if (tid == 0) atomicAdd(&ACC[4], red[0]);
  if (tid < 64) {
    atomicAdd(&PS[pt0 + tid], rs[0][tid]+rs[1][tid]+rs[2][tid]+rs[3][tid]);
    atomicAdd(&PT[pt0 + tid], rt[0][tid]+rt[1][tid]+rt[2][tid]+rt[3][tid]);
  }
}

// ---------------------------------------------------------------- stats stage B: norm terms
__global__ __launch_bounds__(256) void stats_b(
    const float* __restrict__ PS, const float* __restrict__ PT,
    float* __restrict__ ACC)
{
  int i = blockIdx.x * 256 + threadIdx.x;
  float a = sqrtf(PS[i]) - 1.f;
  float c = sqrtf(PT[i]) - 1.f;
  float av = a*a, cv = c*c;
  #pragma unroll
  for (int s2 = 32; s2 > 0; s2 >>= 1) {
    av += __shfl_down(av, s2, 64);
    cv += __shfl_down(cv, s2, 64);
  }
  __shared__ float r1[4], r2[4];
  int lane = threadIdx.x & 63, wave = threadIdx.x >> 6;
  if (lane == 0) { r1[wave] = av; r2[wave] = cv; }
  __syncthreads();
  if (threadIdx.x == 0) {
    atomicAdd(&ACC[1], r1[0]+r1[1]+r1[2]+r1[3]);
    atomicAdd(&ACC[2], r2[0]+r2[1]+r2[2]+r2[3]);
  }
}

// ---------------------------------------------------------------- finalize scalars
__global__ void finalize_kernel(const float* __restrict__ ACC, float* __restrict__ o3) {
  if (threadIdx.x == 0 && blockIdx.x == 0) {
    float ln1 = sqrtf(ACC[1] * (1.f/16384.f));
    float ln2 = sqrtf(ACC[2] * (1.f/16384.f));
    o3[0] = ACC[0]*(1.f/128.f) + (ln1 + ln2)*0.5f*0.03f;
    o3[1] = ACC[3] * (1.f/4194304.f);   // mean((s-t)^2)*B
    o3[2] = ACC[4] * (1.f/4194304.f);   // mean(|s-t|)*B
  }
}

// ================================================================ host
extern "C" void kernel_launch(void* const* d_in, const int* in_sizes, int n_in,
                              void* d_out, int out_size, void* d_ws, size_t ws_size,
                              hipStream_t stream) {
  (void)in_sizes; (void)n_in; (void)out_size; (void)ws_size;
  const float* src  = (const float*)d_in[0];
  const float* tgt  = (const float*)d_in[1];
  const float* w1   = (const float*)d_in[2];
  const float* b1   = (const float*)d_in[3];
  const float* w2   = (const float*)d_in[4];
  const float* b2   = (const float*)d_in[5];
  const float* wdg1 = (const float*)d_in[6];
  const float* bdg1 = (const float*)d_in[7];
  const float* wdg2 = (const float*)d_in[8];
  const float* bdg2 = (const float*)d_in[9];
  const float* wsn1 = (const float*)d_in[10];
  const float* bsn1 = (const float*)d_in[11];
  const float* w3   = (const float*)d_in[12];
  const float* b3   = (const float*)d_in[13];
  float* out = (float*)d_out;

  float* ws = (float*)d_ws;
  float*  XTP  = ws;                                   // BN*4 (float4 x,y,z,xx)
  float*  XT2  = XTP + (size_t)BN*4;                   // BN*64
  float*  XX2  = XT2 + (size_t)BN*64;                  // BN
  float*  UV1  = XX2 + BN;                             // BN*256
  _Float16* FFH = (_Float16*)(UV1 + (size_t)BN*256);   // BN*512 halves
  _Float16* FFL = FFH + (size_t)BN*512;                // BN*512 halves
  float*  UV2  = (float*)(FFL + (size_t)BN*512);       // BN*512
  float*  Dbuf = (float*)FFH;                          // NPTS*NPTS fp32 == FFH+FFL+UV2 (dead then)
  _Float16* XT2H = (_Float16*)(UV2 + (size_t)BN*512);  // BN*64 halves
  _Float16* XT2L = XT2H + (size_t)BN*64;               // BN*64 halves
  int*    IDXF = (int*)(XT2L + (size_t)BN*64);         // BN*KNN
  int*    IDXX = IDXF + (size_t)BN*KNN;                // BN*KNN
  _Float16* W2H = (_Float16*)(IDXX + (size_t)BN*KNN);  // 128*128 halves
  _Float16* W2L = W2H + 128*128;                       // 128*128 halves
  float*  BUV1 = (float*)(W2L + 128*128);              // 256
  float*  BUV2 = BUV1 + 256;                           // 512
  _Float16* W3H = (_Float16*)(BUV2 + 512);             // 1024*512 halves
  _Float16* W3L = W3H + 1024*512;
  _Float16* WH1 = W3L + 1024*512;                      // 256*64 halves
  _Float16* WL1 = WH1 + 256*64;
  _Float16* WH2 = WL1 + 256*64;                        // 512*128 halves
  _Float16* WL2 = WH2 + 512*128;
  int*    SIDX = (int*)(WL2 + 512*128);                // NB*32
  int*    NIDX = SIDX + NB*32;                         // NB*32*8
  float*  ACC  = (float*)(NIDX + NB*32*8);             // 8
  float*  PS   = ACC + 8;                              // BN
  float*  PT   = PS + BN;                              // BN

  prep_weights<<<2048, 256, 0, stream>>>(wdg1, bdg1, wdg2, wsn1, bsn1, w3,
                                         W2H, W2L, BUV1, BUV2,
                                         W3H, W3L, WH1, WL1, WH2, WL2);

  auto run_cloud = [&](const float* xyz, float* emb) {
    pack_xyz<<<BN/256, 256, 0, stream>>>(xyz, (float4*)XTP);
    conv12<<<BN/4, 256, 0, stream>>>(xyz, w1, b1, w2, b2, XT2, XX2, XT2H, XT2L);
    // xyz-space KNN: one merged launch over all batches (no D dependency)
    knn_select<false><<<BN/4, 256, 0, stream>>>(nullptr, (const float4*)XTP, -1, IDXX);
    // feature-space KNN: per batch (single D buffer), triangular dist GEMM
    for (int bb = 0; bb < NB; ++bb) {
      dist_gemm_tri<<<528, 256, 0, stream>>>(
          XT2 + (size_t)bb*NPTS*64, XX2 + (size_t)bb*NPTS, Dbuf);
      knn_select<true><<<NPTS/4, 256, 0, stream>>>(Dbuf, (const float4*)XTP, bb, IDXF);
    }
    // UV1 = WEFF1 * XT2 (f16x3 MFMA)
    mfma_gemm<false,false><<<dim3(BN/128, 2), 256, 0, stream>>>(
        WH1, WL1, 256, 64, XT2H, XT2L, 64, 0, BUV1, UV1, 256);
    // fused gather + dg2 MFMA -> x1 (cols 0..127) + x2 (cols 128..255)
    dg2_fused<<<BN/4, 256, 0, stream>>>(W2H, W2L, UV1, IDXF, bdg2, FFH, FFL);
    // UV2 = WEFF2 * x2 (f16x3 MFMA)
    mfma_gemm<false,false><<<dim3(BN/128, 4), 256, 0, stream>>>(
        WH2, WL2, 512, 128, FFH, FFL, 512, 128, BUV2, UV2, 512);
    sn_gather<<<BN, 256, 0, stream>>>(UV2, IDXX, FFH, FFL);
    // emb = lrelu(W3 * feat + b3), channel-major (f16x3 MFMA)
    mfma_gemm<true,true><<<dim3(BN/128, 8), 256, 0, stream>>>(
        W3H, W3L, 1024, 512, FFH, FFL, 512, 0, b3, emb, 0);
  };

  float* emb_s = out;
  float* emb_t = out + (size_t)BN*1024;
  run_cloud(src, emb_s);
  run_cloud(tgt, emb_t);

  hipMemsetAsync(ACC, 0, (8 + 2*BN)*sizeof(float), stream);
  fps_kernel<<<NB, 512, 0, stream>>>(src, SIDX);
  kfn_kernel<<<1, 128, 0, stream>>>(src, SIDX, NIDX);
  trip_kernel<<<NB*32, 256, 0, stream>>>(emb_s, emb_t, SIDX, NIDX, ACC);
  stats_a<<<2048, 256, 0, stream>>>(emb_s, emb_t, PS, PT, ACC);
  stats_b<<<BN/256, 256, 0, stream>>>(PS, PT, ACC);
  finalize_kernel<<<1, 64, 0, stream>>>(ACC, out + (size_t)2*BN*1024);
}

// Round 4
// 1391.438 us; speedup vs baseline: 1.6476x; 1.0016x over previous
//
#include <hip/hip_runtime.h>
#include <cstdint>

#define NB 4
#define NPTS 4096
#define KNN 20
#define BN (NB*NPTS)   // 16384

typedef _Float16 f16x8 __attribute__((ext_vector_type(8)));
typedef _Float16 f16x4 __attribute__((ext_vector_type(4)));
typedef float    f32x4 __attribute__((ext_vector_type(4)));

__device__ __forceinline__ float lrelu_f(float x) { return x > 0.f ? x : 0.2f * x; }

__device__ __forceinline__ float med3f(float c, float lo, float hi) {
#if defined(__has_builtin)
#if __has_builtin(__builtin_amdgcn_fmed3f)
  return __builtin_amdgcn_fmed3f(c, lo, hi);
#else
  return fminf(fmaxf(c, lo), hi);
#endif
#else
  return fminf(fmaxf(c, lo), hi);
#endif
}

// async global->LDS, 16B per lane (lane-linear LDS dest required)
__device__ __forceinline__ void gld16(const void* g, void* l) {
  __builtin_amdgcn_global_load_lds(
      (const __attribute__((address_space(1))) void*)g,
      (__attribute__((address_space(3))) void*)l,
      16, 0, 0);
}

__device__ __forceinline__ void split_store(_Float16* __restrict__ H, _Float16* __restrict__ L,
                                            size_t idx, float v) {
  _Float16 h = (_Float16)v;
  H[idx] = h;
  L[idx] = (_Float16)(v - (float)h);
}

// ---------------------------------------------------------------- prep weights
__global__ __launch_bounds__(256) void prep_weights(
    const float* __restrict__ wdg1, const float* __restrict__ bdg1,
    const float* __restrict__ wdg2,
    const float* __restrict__ wsn1, const float* __restrict__ bsn1,
    const float* __restrict__ w3,
    _Float16* __restrict__ W2H, _Float16* __restrict__ W2L,
    float* __restrict__ BUV1, float* __restrict__ BUV2,
    _Float16* __restrict__ W3H, _Float16* __restrict__ W3L,
    _Float16* __restrict__ WH1, _Float16* __restrict__ WL1,
    _Float16* __restrict__ WH2, _Float16* __restrict__ WL2)
{
  int i = blockIdx.x * 256 + threadIdx.x;
  if (i < 512*1024) {           // w3 is already [M=1024][K=512]
    float v = w3[i];
    split_store(W3H, W3L, i, v);
  }
  if (i < 256*64) {             // WEFF1: [M=256][K=64]
    int r = i >> 6, c = i & 63;
    float v = (r < 128) ? wdg1[r*128 + c]
                        : (wdg1[(r-128)*128 + 64 + c] - wdg1[(r-128)*128 + c]);
    split_store(WH1, WL1, i, v);
  }
  if (i < 512*128) {            // WEFF2: [M=512][K=128]
    int r = i >> 7, c = i & 127;
    float v = (r < 256) ? wsn1[r*256 + c]
                        : (wsn1[(r-256)*256 + 128 + c] - wsn1[(r-256)*256 + c]);
    split_store(WH2, WL2, i, v);
  }
  if (i < 128*128) split_store(W2H, W2L, i, wdg2[i]);  // [M=o][K=c] identity layout
  if (i < 256) BUV1[i] = (i < 128) ? 0.f : bdg1[i-128];
  if (i < 512) BUV2[i] = (i < 256) ? 0.f : bsn1[i-256];
}

// ---------------------------------------------------------------- pack xyz -> float4 (x,y,z,xx)
__global__ __launch_bounds__(256) void pack_xyz(
    const float* __restrict__ xyz, float4* __restrict__ XTP4)
{
  int i = blockIdx.x * 256 + threadIdx.x;
  if (i >= BN) return;
  int b = i >> 12, n = i & (NPTS-1);
  const float* p = xyz + (size_t)b*3*NPTS;
  float x = p[n], y = p[NPTS+n], z = p[2*NPTS+n];
  float4 v; v.x = x; v.y = y; v.z = z; v.w = x*x + y*y + z*z;
  XTP4[i] = v;
}

// ---------------------------------------------------------------- conv1 + conv2 fused (3->64->64)
__global__ __launch_bounds__(256) void conv12(
    const float* __restrict__ xyz,
    const float* __restrict__ w1, const float* __restrict__ b1,
    const float* __restrict__ w2, const float* __restrict__ b2,
    float* __restrict__ XT2, float* __restrict__ XX2,
    _Float16* __restrict__ XT2H, _Float16* __restrict__ XT2L)
{
  __shared__ float w2t[64*65];
  __shared__ float h1s[4][64];
  int tid = threadIdx.x;
  for (int i = tid; i < 4096; i += 256) {
    int o = i >> 6, c = i & 63;
    w2t[c*65 + o] = w2[i];
  }
  int g = tid >> 6, o = tid & 63;
  int pt = blockIdx.x*4 + g;
  int b = pt >> 12, n = pt & (NPTS-1);
  const float* p = xyz + (size_t)b*3*NPTS;
  float x = p[n], y = p[NPTS+n], z = p[2*NPTS+n];
  float h1 = b1[o] + w1[o*3]*x + w1[o*3+1]*y + w1[o*3+2]*z;
  h1 = lrelu_f(h1);
  __syncthreads();
  h1s[g][o] = h1;
  __syncthreads();
  float acc = b2[o];
  #pragma unroll
  for (int c = 0; c < 64; ++c) acc = fmaf(w2t[c*65+o], h1s[g][c], acc);
  acc = lrelu_f(acc);
  XT2[(size_t)pt*64 + o] = acc;
  split_store(XT2H, XT2L, (size_t)pt*64 + o, acc);
  float v = acc*acc;
  #pragma unroll
  for (int s = 32; s > 0; s >>= 1) v += __shfl_down(v, s, 64);
  if (o == 0) XX2[pt] = v;
}

// ---------------------------------------------------------------- triangular distance GEMM (per batch)
__global__ __launch_bounds__(256) void dist_gemm_tri(
    const float* __restrict__ XQ,   // batch slice of XT2, [4096][64]
    const float* __restrict__ XXb,  // batch slice of XX2, [4096]
    float* __restrict__ D)          // [4096][4096]
{
  // map blockIdx.x in [0,528) -> (ti,tj) with ti<=tj, NT=32
  int r = blockIdx.x, ti = 0;
  #pragma unroll 1
  for (;;) { int len = 32 - ti; if (r < len) break; r -= len; ++ti; }
  int tj = ti + r;
  int q0 = ti * 128, j0 = tj * 128;

  __shared__ float Qs[16][132];
  __shared__ float Xs[16][132];
  int tid = threadIdx.x;
  int rg = tid & 15, cg = tid >> 4;
  float acc[8][8];
  #pragma unroll
  for (int u = 0; u < 8; ++u)
    #pragma unroll
    for (int v = 0; v < 8; ++v) acc[u][v] = 0.f;

  for (int c0 = 0; c0 < 64; c0 += 16) {
    #pragma unroll
    for (int i = 0; i < 8; ++i) {
      int idx = tid + i*256;
      int kk = idx & 15, p = idx >> 4;
      Qs[kk][p] = XQ[(size_t)(q0+p)*64 + c0 + kk];
      Xs[kk][p] = XQ[(size_t)(j0+p)*64 + c0 + kk];
    }
    __syncthreads();
    #pragma unroll
    for (int kk = 0; kk < 16; ++kk) {
      float a[8], bb[8];
      #pragma unroll
      for (int u = 0; u < 8; ++u) a[u] = Qs[kk][rg*8+u];
      #pragma unroll
      for (int v = 0; v < 8; ++v) bb[v] = Xs[kk][cg*8+v];
      #pragma unroll
      for (int u = 0; u < 8; ++u)
        #pragma unroll
        for (int v = 0; v < 8; ++v) acc[u][v] = fmaf(a[u], bb[v], acc[u][v]);
    }
    __syncthreads();
  }
  // epilogue 1: D[q][j] = xx_j - 2*dot
  {
    float xxv[8];
    #pragma unroll
    for (int v = 0; v < 8; ++v) xxv[v] = XXb[j0 + cg*8 + v];
    #pragma unroll
    for (int u = 0; u < 8; ++u) {
      float* po = D + (size_t)(q0 + rg*8 + u)*NPTS + j0 + cg*8;
      #pragma unroll
      for (int v = 0; v < 8; ++v) po[v] = fmaf(-2.f, acc[u][v], xxv[v]);
    }
  }
  // epilogue 2 (off-diagonal): D[j][q] = xx_q - 2*dot (register-transposed tile)
  if (ti != tj) {
    float xxq[8];
    #pragma unroll
    for (int u = 0; u < 8; ++u) xxq[u] = XXb[q0 + rg*8 + u];
    #pragma unroll
    for (int v = 0; v < 8; ++v) {
      float* po = D + (size_t)(j0 + cg*8 + v)*NPTS + q0 + rg*8;
      float4 w0, w1;
      w0.x = fmaf(-2.f, acc[0][v], xxq[0]);
      w0.y = fmaf(-2.f, acc[1][v], xxq[1]);
      w0.z = fmaf(-2.f, acc[2][v], xxq[2]);
      w0.w = fmaf(-2.f, acc[3][v], xxq[3]);
      w1.x = fmaf(-2.f, acc[4][v], xxq[4]);
      w1.y = fmaf(-2.f, acc[5][v], xxq[5]);
      w1.z = fmaf(-2.f, acc[6][v], xxq[6]);
      w1.w = fmaf(-2.f, acc[7][v], xxq[7]);
      *(float4*)po = w0;
      *(float4*)(po + 4) = w1;
    }
  }
}

// ---------------------------------------------------------------- exact wave-level 20th-smallest
// Per-lane top-S + pop-min. EXACTNESS: every candidate a lane discards is >= the
// lane's FINAL bd[S-1] (retained-max is monotone non-increasing). So if all lanes
// satisfy lane_max >= thr, no candidate < thr was discarded anywhere -> thr is the
// true 20th-smallest value. safe=false (P~1e-10/query) -> caller retries with S=20,
// which is unconditionally exact (a lane cannot hold >=20 of the <=19 values < thr).
template<int S, typename F>
__device__ __forceinline__ float find_thr(F getd4, bool& safe) {
  float bd[S];
  #pragma unroll
  for (int t = 0; t < S; ++t) bd[t] = 1e30f;
  for (int t = 0; t < 16; ++t) {
    float4 dv = getd4(t);
    float ds[4] = {dv.x, dv.y, dv.z, dv.w};
    #pragma unroll
    for (int e = 0; e < 4; ++e) {
      float cd = ds[e];
      #pragma unroll
      for (int s = S-1; s >= 1; --s) bd[s] = med3f(cd, bd[s-1], bd[s]);
      bd[0] = fminf(bd[0], cd);
    }
  }
  float lane_max = bd[S-1];
  float thr = 1e30f;
  int total = 0;
  #pragma unroll 1
  for (int r = 0; r < KNN; ++r) {
    float m = bd[0];
    #pragma unroll
    for (int k = 1; k < 64; k <<= 1) m = fminf(m, __shfl_xor(m, k, 64));
    unsigned long long bal = __ballot(bd[0] == m);
    total += __popcll(bal);
    if (total >= KNN) { thr = m; break; }
    if (bd[0] == m) {
      #pragma unroll
      for (int s = 0; s < S-1; ++s) bd[s] = bd[s+1];
      bd[S-1] = 1e30f;
    }
  }
  safe = !__any(lane_max < thr);
  return thr;
}

// ---------------------------------------------------------------- knn select
// batch >= 0: per-batch grid (NPTS/4 blocks). batch < 0: merged grid (BN/4 blocks).
template<bool FEAT_MODE>
__global__ __launch_bounds__(256) void knn_select(
    const float* __restrict__ D, const float4* __restrict__ XTP4,
    int batch, int* __restrict__ IDX)
{
  int lane = threadIdx.x & 63;
  int blk = blockIdx.x, bq = batch;
  if (batch < 0) { bq = blk >> 10; blk &= 1023; }
  int ql = blk*4 + (threadIdx.x >> 6);          // query local to batch
  int qg = bq*NPTS + ql;                        // global point id
  const float4* drow4 = FEAT_MODE ? (const float4*)(D + (size_t)ql*NPTS) : nullptr;
  const float4* Xb4 = XTP4 + (size_t)bq*NPTS;
  float qx = 0.f, qy = 0.f, qz = 0.f;
  if (!FEAT_MODE) { float4 qp = XTP4[qg]; qx = qp.x; qy = qp.y; qz = qp.z; }

  auto key3 = [&](float4 p) -> float {
    float dot = qx*p.x;
    dot = fmaf(qy, p.y, dot);
    dot = fmaf(qz, p.z, dot);
    return fmaf(-2.f, dot, p.w);
  };
  auto getd4 = [&](int t) -> float4 {
    if (FEAT_MODE) {
      return drow4[t*64 + lane];
    } else {
      int jb = t*256 + lane*4;
      float4 r;
      r.x = key3(Xb4[jb+0]);
      r.y = key3(Xb4[jb+1]);
      r.z = key3(Xb4[jb+2]);
      r.w = key3(Xb4[jb+3]);
      return r;
    }
  };

  // ---- phases 1+2: wave-level 20th-smallest value (thr), top-8 fast path
  bool safe;
  float thr = find_thr<8>(getd4, safe);
  if (!safe) {                       // ~never taken; exact fallback
    bool s2;
    thr = find_thr<KNN>(getd4, s2);
  }

  // ---- phase 3: rescan, emit strict (d<thr) via ballot-compaction; ties by smallest j
  unsigned long long lml = (1ull << lane) - 1ull;
  int S = 0;
  int myj = 0x7fffffff;
  for (int t = 0; t < 16; ++t) {
    float4 dv = getd4(t);
    float ds[4] = {dv.x, dv.y, dv.z, dv.w};
    int jb = t*256 + lane*4;
    #pragma unroll
    for (int e = 0; e < 4; ++e) {
      float d = ds[e];
      int j = jb + e;
      bool ps = d < thr;
      unsigned long long mk = __ballot(ps);
      int pos = S + __popcll(mk & lml);
      if (ps && pos < KNN) IDX[(size_t)qg*KNN + pos] = j;
      S += __popcll(mk);
      if (d == thr && j < myj) myj = j;
    }
  }
  int need = KNN - S;
  if (need == 1) {
    int mn = myj;
    #pragma unroll
    for (int k = 1; k < 64; k <<= 1) mn = min(mn, __shfl_xor(mn, k, 64));
    if (lane == 0) IDX[(size_t)qg*KNN + S] = mn;
  } else if (need > 1) {
    if (lane == 0) {
      int taken = 0;
      for (int j = 0; j < NPTS && taken < need; ++j) {
        float d;
        if (FEAT_MODE) d = D[(size_t)ql*NPTS + j];
        else           d = key3(Xb4[j]);
        if (d == thr) { IDX[(size_t)qg*KNN + S + taken] = j; ++taken; }
      }
    }
  }
}

// ---------------------------------------------------------------- f16x3 split MFMA GEMM (generic)
template<bool LRELU_, bool CM>
__global__ __launch_bounds__(256) void mfma_gemm(
    const _Float16* __restrict__ WH, const _Float16* __restrict__ WL,  // [Mtot][KT]
    int Mtot, int KT,
    const _Float16* __restrict__ FH, const _Float16* __restrict__ FL,  // [pt][fstride]
    int fstride, int foff,
    const float* __restrict__ bias,
    float* __restrict__ Out, int ostride)
{
  __shared__ _Float16 As[2][128*32];
  __shared__ _Float16 Bs[2][128*32];
  int tid = threadIdx.x;
  int lane = tid & 63, wave = tid >> 6;
  int wr = wave >> 1, wc = wave & 1;
  int rt = blockIdx.y * 128, ct = blockIdx.x * 128;

  int srow = tid >> 2;
  int skh  = (tid & 3) * 8;
  const _Float16* gA0 = WH + (size_t)(rt + srow)*KT + skh;
  const _Float16* gA1 = WL + (size_t)(rt + srow)*KT + skh;
  const _Float16* gB0 = FH + (size_t)(ct + srow)*fstride + foff + skh;
  const _Float16* gB1 = FL + (size_t)(ct + srow)*fstride + foff + skh;
  const size_t a2 = (size_t)64*KT;
  const size_t b2 = (size_t)64*fstride;
  _Float16* lA0 = &As[0][tid*8];
  _Float16* lA1 = &As[1][tid*8];
  _Float16* lB0 = &Bs[0][tid*8];
  _Float16* lB1 = &Bs[1][tid*8];

  f32x4 acc[4][4];
  #pragma unroll
  for (int m = 0; m < 4; ++m)
    #pragma unroll
    for (int n = 0; n < 4; ++n) acc[m][n] = (f32x4){0.f, 0.f, 0.f, 0.f};

  int fr = lane & 15;
  int kg = (lane >> 4) * 8;

  for (int k0 = 0; k0 < KT; k0 += 32) {
    gld16(gA0 + k0,      lA0);
    gld16(gA0 + k0 + a2, lA0 + 2048);
    gld16(gA1 + k0,      lA1);
    gld16(gA1 + k0 + a2, lA1 + 2048);
    gld16(gB0 + k0,      lB0);
    gld16(gB0 + k0 + b2, lB0 + 2048);
    gld16(gB1 + k0,      lB1);
    gld16(gB1 + k0 + b2, lB1 + 2048);
    __syncthreads();

    f16x8 ah[4], al[4], bh[4], bl[4];
    #pragma unroll
    for (int m = 0; m < 4; ++m) {
      int ro = (wr*64 + m*16 + fr)*32 + kg;
      ah[m] = *(const f16x8*)&As[0][ro];
      al[m] = *(const f16x8*)&As[1][ro];
    }
    #pragma unroll
    for (int n = 0; n < 4; ++n) {
      int co = (wc*64 + n*16 + fr)*32 + kg;
      bh[n] = *(const f16x8*)&Bs[0][co];
      bl[n] = *(const f16x8*)&Bs[1][co];
    }
    #pragma unroll
    for (int m = 0; m < 4; ++m)
      #pragma unroll
      for (int n = 0; n < 4; ++n) {
        acc[m][n] = __builtin_amdgcn_mfma_f32_16x16x32_f16(ah[m], bh[n], acc[m][n], 0, 0, 0);
        acc[m][n] = __builtin_amdgcn_mfma_f32_16x16x32_f16(ah[m], bl[n], acc[m][n], 0, 0, 0);
        acc[m][n] = __builtin_amdgcn_mfma_f32_16x16x32_f16(al[m], bh[n], acc[m][n], 0, 0, 0);
      }
    __syncthreads();
  }

  int rowg = (lane >> 4) * 4;
  if (CM) {
    int b = ct >> 12, n0 = ct & (NPTS-1);
    #pragma unroll
    for (int m = 0; m < 4; ++m) {
      int rbase = rt + wr*64 + m*16 + rowg;
      #pragma unroll
      for (int r4 = 0; r4 < 4; ++r4) {
        int r = rbase + r4;
        float bv = bias[r];
        float* po = Out + ((size_t)b*Mtot + r)*NPTS + n0 + wc*64 + fr;
        #pragma unroll
        for (int n = 0; n < 4; ++n) {
          float v = acc[m][n][r4] + bv;
          if (LRELU_) v = lrelu_f(v);
          po[n*16] = v;
        }
      }
    }
  } else {
    #pragma unroll
    for (int n = 0; n < 4; ++n) {
      int pt = ct + wc*64 + n*16 + fr;
      #pragma unroll
      for (int m = 0; m < 4; ++m) {
        int r0 = rt + wr*64 + m*16 + rowg;
        float4 v;
        v.x = acc[m][n][0] + bias[r0];
        v.y = acc[m][n][1] + bias[r0+1];
        v.z = acc[m][n][2] + bias[r0+2];
        v.w = acc[m][n][3] + bias[r0+3];
        if (LRELU_) { v.x = lrelu_f(v.x); v.y = lrelu_f(v.y); v.z = lrelu_f(v.z); v.w = lrelu_f(v.w); }
        *(float4*)&Out[(size_t)pt*ostride + r0] = v;
      }
    }
  }
}

// ---------------------------------------------------------------- fused gather + dg2 MFMA + x1/x2 group-max
__global__ __launch_bounds__(256) void dg2_fused(
    const _Float16* __restrict__ W2H, const _Float16* __restrict__ W2L, // [128][128]
    const float* __restrict__ UV1,      // [BN][256] (U|V)
    const int* __restrict__ IDXF,       // [BN][KNN]
    const float* __restrict__ bias,     // bdg2 [128]
    _Float16* __restrict__ FFH, _Float16* __restrict__ FFL)
{
  constexpr int RS = 136;
  __shared__ __align__(16) unsigned char smem[43520];
  _Float16* HsH = (_Float16*)smem;            // [80][RS]
  _Float16* HsL = (_Float16*)(smem + 21760);  // [80][RS]
  float*    Cs  = (float*)smem;               // [128][84] epilogue reuse
  __shared__ int js[80];
  __shared__ float4 mxs[128];

  int tid = threadIdx.x;
  int lane = tid & 63, wave = tid >> 6;
  size_t pt0 = (size_t)blockIdx.x * 4;
  size_t bbase = (pt0 >> 12) << 12;

  if (tid < 80) js[tid] = IDXF[pt0*KNN + tid];

  int fr = lane & 15, kg = (lane >> 4) * 8;
  f16x8 ah[2][4], al[2][4];
  #pragma unroll
  for (int m = 0; m < 2; ++m) {
    int row = wave*32 + m*16 + fr;
    #pragma unroll
    for (int ks = 0; ks < 4; ++ks) {
      ah[m][ks] = *(const f16x8*)&W2H[row*128 + ks*32 + kg];
      al[m][ks] = *(const f16x8*)&W2L[row*128 + ks*32 + kg];
    }
  }
  __syncthreads();   // js visible

  {
    int g = (tid >> 5) & 3, half = tid >> 7, c4 = tid & 31;
    size_t ptg = pt0 + g;
    float4 vv = *(const float4*)&UV1[ptg*256 + 128 + c4*4];
    float4 mx = make_float4(-1e30f, -1e30f, -1e30f, -1e30f);
    #pragma unroll
    for (int k = 0; k < 10; ++k) {
      int row = g*20 + half*10 + k;
      int j = js[row];
      float4 u = *(const float4*)&UV1[(bbase + (size_t)j)*256 + c4*4];
      float h0 = lrelu_f(u.x + vv.x);
      float h1 = lrelu_f(u.y + vv.y);
      float h2 = lrelu_f(u.z + vv.z);
      float h3 = lrelu_f(u.w + vv.w);
      f16x4 hh, hl;
      hh[0] = (_Float16)h0; hl[0] = (_Float16)(h0 - (float)hh[0]);
      hh[1] = (_Float16)h1; hl[1] = (_Float16)(h1 - (float)hh[1]);
      hh[2] = (_Float16)h2; hl[2] = (_Float16)(h2 - (float)hh[2]);
      hh[3] = (_Float16)h3; hl[3] = (_Float16)(h3 - (float)hh[3]);
      *(f16x4*)&HsH[row*RS + c4*4] = hh;
      *(f16x4*)&HsL[row*RS + c4*4] = hl;
      mx.x = fmaxf(mx.x, h0); mx.y = fmaxf(mx.y, h1);
      mx.z = fmaxf(mx.z, h2); mx.w = fmaxf(mx.w, h3);
    }
    if (half == 1) mxs[(g << 5) | c4] = mx;
    __syncthreads();
    if (half == 0) {
      float4 o = mxs[(g << 5) | c4];
      mx.x = fmaxf(mx.x, o.x); mx.y = fmaxf(mx.y, o.y);
      mx.z = fmaxf(mx.z, o.z); mx.w = fmaxf(mx.w, o.w);
      split_store(FFH, FFL, ptg*512 + c4*4 + 0, mx.x);
      split_store(FFH, FFL, ptg*512 + c4*4 + 1, mx.y);
      split_store(FFH, FFL, ptg*512 + c4*4 + 2, mx.z);
      split_store(FFH, FFL, ptg*512 + c4*4 + 3, mx.w);
    }
  }

  f32x4 acc[2][5];
  #pragma unroll
  for (int m = 0; m < 2; ++m)
    #pragma unroll
    for (int n = 0; n < 5; ++n) acc[m][n] = (f32x4){0.f, 0.f, 0.f, 0.f};

  #pragma unroll
  for (int ks = 0; ks < 4; ++ks) {
    f16x8 bh[5], bl[5];
    #pragma unroll
    for (int n = 0; n < 5; ++n) {
      int ro = (n*16 + fr)*RS + ks*32 + kg;
      bh[n] = *(const f16x8*)&HsH[ro];
      bl[n] = *(const f16x8*)&HsL[ro];
    }
    #pragma unroll
    for (int m = 0; m < 2; ++m)
      #pragma unroll
      for (int n = 0; n < 5; ++n) {
        acc[m][n] = __builtin_amdgcn_mfma_f32_16x16x32_f16(ah[m][ks], bh[n], acc[m][n], 0, 0, 0);
        acc[m][n] = __builtin_amdgcn_mfma_f32_16x16x32_f16(ah[m][ks], bl[n], acc[m][n], 0, 0, 0);
        acc[m][n] = __builtin_amdgcn_mfma_f32_16x16x32_f16(al[m][ks], bh[n], acc[m][n], 0, 0, 0);
      }
  }
  __syncthreads();

  int rowg = (lane >> 4) * 4;
  #pragma unroll
  for (int m = 0; m < 2; ++m) {
    int r = wave*32 + m*16 + rowg;
    #pragma unroll
    for (int n = 0; n < 5; ++n) {
      int p = n*16 + fr;
      #pragma unroll
      for (int q = 0; q < 4; ++q) Cs[(r+q)*84 + p] = acc[m][n][q];
    }
  }
  __syncthreads();

  #pragma unroll
  for (int t = 0; t < 2; ++t) {
    int task = tid + t*256;
    int r = task & 127, g = task >> 7;
    const float* cr = &Cs[r*84 + g*20];
    float m = cr[0];
    #pragma unroll
    for (int k = 1; k < 20; ++k) m = fmaxf(m, cr[k]);
    float v = lrelu_f(m + bias[r]);
    split_store(FFH, FFL, (pt0 + g)*512 + 128 + r, v);
  }
}

// ---------------------------------------------------------------- sn block: one point per block
__global__ __launch_bounds__(256) void sn_gather(
    const float* __restrict__ UV2, const int* __restrict__ IDXX,
    _Float16* __restrict__ FFH, _Float16* __restrict__ FFL)
{
  int tid = threadIdx.x;   // channel 0..255
  size_t pt = blockIdx.x;
  size_t bb = (pt >> 12) << 12;
  __shared__ int js[KNN];
  if (tid < KNN) js[tid] = IDXX[pt*KNN + tid];
  __syncthreads();
  float v = UV2[pt*512 + 256 + tid];
  float m = -1e30f;
  #pragma unroll
  for (int k = 0; k < KNN; ++k) {
    float h = lrelu_f(UV2[(bb + (size_t)js[k])*512 + tid] + v);
    m = fmaxf(m, h);
  }
  split_store(FFH, FFL, pt*512 + 256 + tid, m);
}

// ---------------------------------------------------------------- farthest point sampling (reg-resident, shuffle argmax)
__global__ __launch_bounds__(512) void fps_kernel(
    const float* __restrict__ xyz, int* __restrict__ SIDX)
{
  int b = blockIdx.x, tid = threadIdx.x;
  int lane = tid & 63, wave = tid >> 6;   // 8 waves
  const float* p = xyz + (size_t)b*3*NPTS;
  float px[8], py[8], pz[8], dist[8];
  #pragma unroll
  for (int j = 0; j < 8; ++j) {
    int i = tid + j*512;
    px[j] = p[i]; py[j] = p[NPTS+i]; pz[j] = p[2*NPTS+i];
    dist[j] = 1e10f;
  }
  __shared__ float bv[8], bx[8], by[8], bz[8];
  __shared__ int bi[8];
  float cx = p[0], cy = p[NPTS], cz = p[2*NPTS];
  int far = 0;
  for (int it = 0; it < 32; ++it) {
    if (tid == 0) SIDX[b*32 + it] = far;
    float lm = -1e30f, lx = 0.f, ly = 0.f, lz = 0.f; int li = 0;
    #pragma unroll
    for (int j = 0; j < 8; ++j) {
      float dx = px[j]-cx, dy = py[j]-cy, dz = pz[j]-cz;
      float d = dx*dx + dy*dy + dz*dz;
      float dm = fminf(dist[j], d);
      dist[j] = dm;
      bool sw = dm > lm;
      lm = sw ? dm : lm;
      li = sw ? (tid + j*512) : li;
      lx = sw ? px[j] : lx; ly = sw ? py[j] : ly; lz = sw ? pz[j] : lz;
    }
    #pragma unroll
    for (int k = 1; k < 64; k <<= 1) {
      float om = __shfl_xor(lm, k, 64);
      int   oi = __shfl_xor(li, k, 64);
      float ox = __shfl_xor(lx, k, 64);
      float oy = __shfl_xor(ly, k, 64);
      float oz = __shfl_xor(lz, k, 64);
      bool tk = (om > lm) || (om == lm && oi < li);
      lm = tk ? om : lm; li = tk ? oi : li;
      lx = tk ? ox : lx; ly = tk ? oy : ly; lz = tk ? oz : lz;
    }
    if (lane == 0) { bv[wave] = lm; bi[wave] = li; bx[wave] = lx; by[wave] = ly; bz[wave] = lz; }
    __syncthreads();
    float m0 = bv[0]; int i0 = bi[0];
    float X = bx[0], Y = by[0], Z = bz[0];
    #pragma unroll
    for (int w = 1; w < 8; ++w) {
      bool tk = (bv[w] > m0) || (bv[w] == m0 && bi[w] < i0);
      m0 = tk ? bv[w] : m0; i0 = tk ? bi[w] : i0;
      X = tk ? bx[w] : X; Y = tk ? by[w] : Y; Z = tk ? bz[w] : Z;
    }
    far = i0; cx = X; cy = Y; cz = Z;
    __syncthreads();
  }
}

// ---------------------------------------------------------------- k-farthest (8) among 32 samples
__global__ __launch_bounds__(128) void kfn_kernel(
    const float* __restrict__ xyz, const int* __restrict__ SIDX,
    int* __restrict__ NIDX)
{
  int tid = threadIdx.x;     // 0..127
  int b = tid >> 5, i = tid & 31;
  const float* p = xyz + (size_t)b*3*NPTS;
  __shared__ float sx[4][32], sy[4][32], sz[4][32];
  {
    int si = SIDX[b*32 + i];
    sx[b][i] = p[si]; sy[b][i] = p[NPTS+si]; sz[b][i] = p[2*NPTS+si];
  }
  __syncthreads();
  float xi = sx[b][i], yi = sy[b][i], zi = sz[b][i];
  float xxi = xi*xi + yi*yi + zi*zi;
  float bd[8]; int bi_[8];
  #pragma unroll
  for (int t = 0; t < 8; ++t) { bd[t] = -1e30f; bi_[t] = 0; }
  for (int j = 0; j < 32; ++j) {
    float xj = sx[b][j], yj = sy[b][j], zj = sz[b][j];
    float xxj = xj*xj + yj*yj + zj*zj;
    float d = xxi - 2.f*(xi*xj + yi*yj + zi*zj) + xxj;
    if (d > bd[7]) {
      float cd = d; int ci = j;
      #pragma unroll
      for (int t = 0; t < 8; ++t) {
        bool sw = bd[t] < cd;
        float nv = sw ? cd : bd[t];
        int   ni = sw ? ci : bi_[t];
        float ov = sw ? bd[t] : cd;
        int   oi = sw ? bi_[t] : ci;
        bd[t] = nv; bi_[t] = ni; cd = ov; ci = oi;
      }
    }
  }
  size_t o = (size_t)(b*32 + i)*8;
  #pragma unroll
  for (int t = 0; t < 8; ++t) NIDX[o+t] = bi_[t];
}

// ---------------------------------------------------------------- triplet terms
__global__ __launch_bounds__(256) void trip_kernel(
    const float* __restrict__ es0, const float* __restrict__ et0,
    const int* __restrict__ SIDX, const int* __restrict__ NIDX,
    float* __restrict__ ACC)
{
  int bi_ = blockIdx.x; int b = bi_ >> 5;
  int tid = threadIdx.x;
  __shared__ int js[8];
  __shared__ int ssi;
  if (tid == 0) ssi = SIDX[bi_];
  if (tid < 8) js[tid] = SIDX[b*32 + NIDX[bi_*8 + tid]];
  __syncthreads();
  int si = ssi;
  const float* es = es0 + (size_t)b*1024*NPTS;
  const float* et = et0 + (size_t)b*1024*NPTS;
  float sp = 0.f, sn = 0.f;
  for (int c = tid; c < 1024; c += 256) {
    const float* erow = et + (size_t)c*NPTS;
    float s = es[(size_t)c*NPTS + si];
    float d0 = s - erow[si]; sp += d0*d0;
    #pragma unroll
    for (int t = 0; t < 8; ++t) { float d1 = s - erow[js[t]]; sn += d1*d1; }
  }
  __shared__ float r1[256], r2[256];
  r1[tid] = sp; r2[tid] = sn; __syncthreads();
  for (int s2 = 128; s2 > 0; s2 >>= 1) {
    if (tid < s2) { r1[tid] += r1[tid+s2]; r2[tid] += r2[tid+s2]; }
    __syncthreads();
  }
  if (tid == 0) {
    float dp = r1[0] * (1.f/1024.f);
    float dn = r2[0] * (1.f/8192.f);
    float tr = fmaxf(0.f, 1.f - dn/(1.f + dp));
    atomicAdd(&ACC[0], tr);
  }
}

// ---------------------------------------------------------------- stats stage A: mse/mae + per-point partial norms
__global__ __launch_bounds__(256) void stats_a(
    const float* __restrict__ es0, const float* __restrict__ et0,
    float* __restrict__ PS, float* __restrict__ PT, float* __restrict__ ACC)
{
  int tid = threadIdx.x;
  int p = tid & 63, g = tid >> 6;
  int pt0 = (blockIdx.x & 255) * 64;     // 256 point-tiles of 64
  int chunk = blockIdx.x >> 8;           // 8 channel-chunks of 128
  int b = pt0 >> 12, n0 = pt0 & (NPTS-1);
  const float* es = es0 + (size_t)b*1024*NPTS + n0;
  const float* et = et0 + (size_t)b*1024*NPTS + n0;
  float ss = 0.f, tt = 0.f, sq = 0.f, ab = 0.f;
  int c0 = chunk * 128;
  for (int c = c0 + g; c < c0 + 128; c += 4) {
    float s = es[(size_t)c*NPTS + p];
    float t = et[(size_t)c*NPTS + p];
    ss += s*s; tt += t*t;
    float d = s - t;
    sq += d*d; ab += fabsf(d);
  }
  __shared__ float rs[4][64], rt[4][64];
  __shared__ float red[256];
  rs[g][p] = ss; rt[g][p] = tt;
  red[tid] = sq;
  __syncthreads();
  for (int s2 = 128; s2 > 0; s2 >>= 1) {
    if (tid < s2) red[tid] += red[tid+s2];
    __syncthreads();
  }
  if (tid == 0) atomicAdd(&ACC[3], red[0]);
  __syncthreads();
  red[tid] = ab; __syncthreads();
  for (int s2 = 128; s2 > 0; s2 >>= 1) {
    if (tid < s2) red[tid] += red[tid+s2];
    __syncthreads();
  }
  if (tid == 0) atomicAdd(&ACC[4], red[0]);
  if (tid < 64) {
    atomicAdd(&PS[pt0 + tid], rs[0][tid]+rs[1][tid]+rs[2][tid]+rs[3][tid]);
    atomicAdd(&PT[pt0 + tid], rt[0][tid]+rt[1][tid]+rt[2][tid]+rt[3][tid]);
  }
}

// ---------------------------------------------------------------- stats stage B: norm terms
__global__ __launch_bounds__(256) void stats_b(
    const float* __restrict__ PS, const float* __restrict__ PT,
    float* __restrict__ ACC)
{
  int i = blockIdx.x * 256 + threadIdx.x;
  float a = sqrtf(PS[i]) - 1.f;
  float c = sqrtf(PT[i]) - 1.f;
  float av = a*a, cv = c*c;
  #pragma unroll
  for (int s2 = 32; s2 > 0; s2 >>= 1) {
    av += __shfl_down(av, s2, 64);
    cv += __shfl_down(cv, s2, 64);
  }
  __shared__ float r1[4], r2[4];
  int lane = threadIdx.x & 63, wave = threadIdx.x >> 6;
  if (lane == 0) { r1[wave] = av; r2[wave] = cv; }
  __syncthreads();
  if (threadIdx.x == 0) {
    atomicAdd(&ACC[1], r1[0]+r1[1]+r1[2]+r1[3]);
    atomicAdd(&ACC[2], r2[0]+r2[1]+r2[2]+r2[3]);
  }
}

// ---------------------------------------------------------------- finalize scalars
__global__ void finalize_kernel(const float* __restrict__ ACC, float* __restrict__ o3) {
  if (threadIdx.x == 0 && blockIdx.x == 0) {
    float ln1 = sqrtf(ACC[1] * (1.f/16384.f));
    float ln2 = sqrtf(ACC[2] * (1.f/16384.f));
    o3[0] = ACC[0]*(1.f/128.f) + (ln1 + ln2)*0.5f*0.03f;
    o3[1] = ACC[3] * (1.f/4194304.f);   // mean((s-t)^2)*B
    o3[2] = ACC[4] * (1.f/4194304.f);   // mean(|s-t|)*B
  }
}

// ================================================================ host
extern "C" void kernel_launch(void* const* d_in, const int* in_sizes, int n_in,
                              void* d_out, int out_size, void* d_ws, size_t ws_size,
                              hipStream_t stream) {
  (void)in_sizes; (void)n_in; (void)out_size; (void)ws_size;
  const float* src  = (const float*)d_in[0];
  const float* tgt  = (const float*)d_in[1];
  const float* w1   = (const float*)d_in[2];
  const float* b1   = (const float*)d_in[3];
  const float* w2   = (const float*)d_in[4];
  const float* b2   = (const float*)d_in[5];
  const float* wdg1 = (const float*)d_in[6];
  const float* bdg1 = (const float*)d_in[7];
  const float* wdg2 = (const float*)d_in[8];
  const float* bdg2 = (const float*)d_in[9];
  const float* wsn1 = (const float*)d_in[10];
  const float* bsn1 = (const float*)d_in[11];
  const float* w3   = (const float*)d_in[12];
  const float* b3   = (const float*)d_in[13];
  float* out = (float*)d_out;

  float* ws = (float*)d_ws;
  float*  XTP  = ws;                                   // BN*4 (float4 x,y,z,xx)
  float*  XT2  = XTP + (size_t)BN*4;                   // BN*64
  float*  XX2  = XT2 + (size_t)BN*64;                  // BN
  float*  UV1  = XX2 + BN;                             // BN*256
  _Float16* FFH = (_Float16*)(UV1 + (size_t)BN*256);   // BN*512 halves
  _Float16* FFL = FFH + (size_t)BN*512;                // BN*512 halves
  float*  UV2  = (float*)(FFL + (size_t)BN*512);       // BN*512
  float*  Dbuf = (float*)FFH;                          // NPTS*NPTS fp32 == FFH+FFL+UV2 (dead then)
  _Float16* XT2H = (_Float16*)(UV2 + (size_t)BN*512);  // BN*64 halves
  _Float16* XT2L = XT2H + (size_t)BN*64;               // BN*64 halves
  int*    IDXF = (int*)(XT2L + (size_t)BN*64);         // BN*KNN
  int*    IDXX = IDXF + (size_t)BN*KNN;                // BN*KNN
  _Float16* W2H = (_Float16*)(IDXX + (size_t)BN*KNN);  // 128*128 halves
  _Float16* W2L = W2H + 128*128;                       // 128*128 halves
  float*  BUV1 = (float*)(W2L + 128*128);              // 256
  float*  BUV2 = BUV1 + 256;                           // 512
  _Float16* W3H = (_Float16*)(BUV2 + 512);             // 1024*512 halves
  _Float16* W3L = W3H + 1024*512;
  _Float16* WH1 = W3L + 1024*512;                      // 256*64 halves
  _Float16* WL1 = WH1 + 256*64;
  _Float16* WH2 = WL1 + 256*64;                        // 512*128 halves
  _Float16* WL2 = WH2 + 512*128;
  int*    SIDX = (int*)(WL2 + 512*128);                // NB*32
  int*    NIDX = SIDX + NB*32;                         // NB*32*8
  float*  ACC  = (float*)(NIDX + NB*32*8);             // 8
  float*  PS   = ACC + 8;                              // BN
  float*  PT   = PS + BN;                              // BN

  prep_weights<<<2048, 256, 0, stream>>>(wdg1, bdg1, wdg2, wsn1, bsn1, w3,
                                         W2H, W2L, BUV1, BUV2,
                                         W3H, W3L, WH1, WL1, WH2, WL2);

  auto run_cloud = [&](const float* xyz, float* emb) {
    pack_xyz<<<BN/256, 256, 0, stream>>>(xyz, (float4*)XTP);
    conv12<<<BN/4, 256, 0, stream>>>(xyz, w1, b1, w2, b2, XT2, XX2, XT2H, XT2L);
    // xyz-space KNN: one merged launch over all batches (no D dependency)
    knn_select<false><<<BN/4, 256, 0, stream>>>(nullptr, (const float4*)XTP, -1, IDXX);
    // feature-space KNN: per batch (single D buffer), triangular dist GEMM
    for (int bb = 0; bb < NB; ++bb) {
      dist_gemm_tri<<<528, 256, 0, stream>>>(
          XT2 + (size_t)bb*NPTS*64, XX2 + (size_t)bb*NPTS, Dbuf);
      knn_select<true><<<NPTS/4, 256, 0, stream>>>(Dbuf, (const float4*)XTP, bb, IDXF);
    }
    // UV1 = WEFF1 * XT2 (f16x3 MFMA)
    mfma_gemm<false,false><<<dim3(BN/128, 2), 256, 0, stream>>>(
        WH1, WL1, 256, 64, XT2H, XT2L, 64, 0, BUV1, UV1, 256);
    // fused gather + dg2 MFMA -> x1 (cols 0..127) + x2 (cols 128..255)
    dg2_fused<<<BN/4, 256, 0, stream>>>(W2H, W2L, UV1, IDXF, bdg2, FFH, FFL);
    // UV2 = WEFF2 * x2 (f16x3 MFMA)
    mfma_gemm<false,false><<<dim3(BN/128, 4), 256, 0, stream>>>(
        WH2, WL2, 512, 128, FFH, FFL, 512, 128, BUV2, UV2, 512);
    sn_gather<<<BN, 256, 0, stream>>>(UV2, IDXX, FFH, FFL);
    // emb = lrelu(W3 * feat + b3), channel-major (f16x3 MFMA)
    mfma_gemm<true,true><<<dim3(BN/128, 8), 256, 0, stream>>>(
        W3H, W3L, 1024, 512, FFH, FFL, 512, 0, b3, emb, 0);
  };

  float* emb_s = out;
  float* emb_t = out + (size_t)BN*1024;
  run_cloud(src, emb_s);
  run_cloud(tgt, emb_t);

  hipMemsetAsync(ACC, 0, (8 + 2*BN)*sizeof(float), stream);
  fps_kernel<<<NB, 512, 0, stream>>>(src, SIDX);
  kfn_kernel<<<1, 128, 0, stream>>>(src, SIDX, NIDX);
  trip_kernel<<<NB*32, 256, 0, stream>>>(emb_s, emb_t, SIDX, NIDX, ACC);
  stats_a<<<2048, 256, 0, stream>>>(emb_s, emb_t, PS, PT, ACC);
  stats_b<<<BN/256, 256, 0, stream>>>(PS, PT, ACC);
  finalize_kernel<<<1, 64, 0, stream>>>(ACC, out + (size_t)2*BN*1024);
}

// Round 5
// 1334.902 us; speedup vs baseline: 1.7174x; 1.0424x over previous
//
#include <hip/hip_runtime.h>
#include <cstdint>

#define NB 4
#define NPTS 4096
#define KNN 20
#define BN (NB*NPTS)   // 16384

typedef _Float16 f16x8 __attribute__((ext_vector_type(8)));
typedef _Float16 f16x4 __attribute__((ext_vector_type(4)));
typedef float    f32x4 __attribute__((ext_vector_type(4)));

__device__ __forceinline__ float lrelu_f(float x) { return x > 0.f ? x : 0.2f * x; }

__device__ __forceinline__ float med3f(float c, float lo, float hi) {
#if defined(__has_builtin)
#if __has_builtin(__builtin_amdgcn_fmed3f)
  return __builtin_amdgcn_fmed3f(c, lo, hi);
#else
  return fminf(fmaxf(c, lo), hi);
#endif
#else
  return fminf(fmaxf(c, lo), hi);
#endif
}

// async global->LDS, 16B per lane (lane-linear LDS dest required)
__device__ __forceinline__ void gld16(const void* g, void* l) {
  __builtin_amdgcn_global_load_lds(
      (const __attribute__((address_space(1))) void*)g,
      (__attribute__((address_space(3))) void*)l,
      16, 0, 0);
}

__device__ __forceinline__ void split_store(_Float16* __restrict__ H, _Float16* __restrict__ L,
                                            size_t idx, float v) {
  _Float16 h = (_Float16)v;
  H[idx] = h;
  L[idx] = (_Float16)(v - (float)h);
}

// ---------------------------------------------------------------- DPP wave reductions (VALU pipe, no LDS round-trips)
// row_shr 1/2/4/8 accumulate within each row of 16; row_bcast15/31 merge rows.
// Invalid source lanes keep `old` (= current x) -> harmless for min.
// Lane 63 ends with the full-wave min; readlane broadcasts it as a uniform.
__device__ __forceinline__ float wave_min_f32_dpp(float x) {
  int xi = __float_as_int(x); int t;
  t = __builtin_amdgcn_update_dpp(xi, xi, 0x111, 0xf, 0xf, false);
  x = fminf(x, __int_as_float(t)); xi = __float_as_int(x);
  t = __builtin_amdgcn_update_dpp(xi, xi, 0x112, 0xf, 0xf, false);
  x = fminf(x, __int_as_float(t)); xi = __float_as_int(x);
  t = __builtin_amdgcn_update_dpp(xi, xi, 0x114, 0xf, 0xf, false);
  x = fminf(x, __int_as_float(t)); xi = __float_as_int(x);
  t = __builtin_amdgcn_update_dpp(xi, xi, 0x118, 0xf, 0xf, false);
  x = fminf(x, __int_as_float(t)); xi = __float_as_int(x);
  t = __builtin_amdgcn_update_dpp(xi, xi, 0x142, 0xf, 0xf, false);
  x = fminf(x, __int_as_float(t)); xi = __float_as_int(x);
  t = __builtin_amdgcn_update_dpp(xi, xi, 0x143, 0xf, 0xf, false);
  x = fminf(x, __int_as_float(t)); xi = __float_as_int(x);
  return __int_as_float(__builtin_amdgcn_readlane(xi, 63));
}

__device__ __forceinline__ int wave_min_i32_dpp(int x) {
  int t;
  t = __builtin_amdgcn_update_dpp(x, x, 0x111, 0xf, 0xf, false); x = min(x, t);
  t = __builtin_amdgcn_update_dpp(x, x, 0x112, 0xf, 0xf, false); x = min(x, t);
  t = __builtin_amdgcn_update_dpp(x, x, 0x114, 0xf, 0xf, false); x = min(x, t);
  t = __builtin_amdgcn_update_dpp(x, x, 0x118, 0xf, 0xf, false); x = min(x, t);
  t = __builtin_amdgcn_update_dpp(x, x, 0x142, 0xf, 0xf, false); x = min(x, t);
  t = __builtin_amdgcn_update_dpp(x, x, 0x143, 0xf, 0xf, false); x = min(x, t);
  return __builtin_amdgcn_readlane(x, 63);
}

// ---------------------------------------------------------------- prep weights
__global__ __launch_bounds__(256) void prep_weights(
    const float* __restrict__ wdg1, const float* __restrict__ bdg1,
    const float* __restrict__ wdg2,
    const float* __restrict__ wsn1, const float* __restrict__ bsn1,
    const float* __restrict__ w3,
    _Float16* __restrict__ W2H, _Float16* __restrict__ W2L,
    float* __restrict__ BUV1, float* __restrict__ BUV2,
    _Float16* __restrict__ W3H, _Float16* __restrict__ W3L,
    _Float16* __restrict__ WH1, _Float16* __restrict__ WL1,
    _Float16* __restrict__ WH2, _Float16* __restrict__ WL2)
{
  int i = blockIdx.x * 256 + threadIdx.x;
  if (i < 512*1024) {           // w3 is already [M=1024][K=512]
    float v = w3[i];
    split_store(W3H, W3L, i, v);
  }
  if (i < 256*64) {             // WEFF1: [M=256][K=64]
    int r = i >> 6, c = i & 63;
    float v = (r < 128) ? wdg1[r*128 + c]
                        : (wdg1[(r-128)*128 + 64 + c] - wdg1[(r-128)*128 + c]);
    split_store(WH1, WL1, i, v);
  }
  if (i < 512*128) {            // WEFF2: [M=512][K=128]
    int r = i >> 7, c = i & 127;
    float v = (r < 256) ? wsn1[r*256 + c]
                        : (wsn1[(r-256)*256 + 128 + c] - wsn1[(r-256)*256 + c]);
    split_store(WH2, WL2, i, v);
  }
  if (i < 128*128) split_store(W2H, W2L, i, wdg2[i]);  // [M=o][K=c] identity layout
  if (i < 256) BUV1[i] = (i < 128) ? 0.f : bdg1[i-128];
  if (i < 512) BUV2[i] = (i < 256) ? 0.f : bsn1[i-256];
}

// ---------------------------------------------------------------- pack xyz -> float4 (x,y,z,xx)
__global__ __launch_bounds__(256) void pack_xyz(
    const float* __restrict__ xyz, float4* __restrict__ XTP4)
{
  int i = blockIdx.x * 256 + threadIdx.x;
  if (i >= BN) return;
  int b = i >> 12, n = i & (NPTS-1);
  const float* p = xyz + (size_t)b*3*NPTS;
  float x = p[n], y = p[NPTS+n], z = p[2*NPTS+n];
  float4 v; v.x = x; v.y = y; v.z = z; v.w = x*x + y*y + z*z;
  XTP4[i] = v;
}

// ---------------------------------------------------------------- conv1 + conv2 fused (3->64->64)
__global__ __launch_bounds__(256) void conv12(
    const float* __restrict__ xyz,
    const float* __restrict__ w1, const float* __restrict__ b1,
    const float* __restrict__ w2, const float* __restrict__ b2,
    float* __restrict__ XT2, float* __restrict__ XX2,
    _Float16* __restrict__ XT2H, _Float16* __restrict__ XT2L)
{
  __shared__ float w2t[64*65];
  __shared__ float h1s[4][64];
  int tid = threadIdx.x;
  for (int i = tid; i < 4096; i += 256) {
    int o = i >> 6, c = i & 63;
    w2t[c*65 + o] = w2[i];
  }
  int g = tid >> 6, o = tid & 63;
  int pt = blockIdx.x*4 + g;
  int b = pt >> 12, n = pt & (NPTS-1);
  const float* p = xyz + (size_t)b*3*NPTS;
  float x = p[n], y = p[NPTS+n], z = p[2*NPTS+n];
  float h1 = b1[o] + w1[o*3]*x + w1[o*3+1]*y + w1[o*3+2]*z;
  h1 = lrelu_f(h1);
  __syncthreads();
  h1s[g][o] = h1;
  __syncthreads();
  float acc = b2[o];
  #pragma unroll
  for (int c = 0; c < 64; ++c) acc = fmaf(w2t[c*65+o], h1s[g][c], acc);
  acc = lrelu_f(acc);
  XT2[(size_t)pt*64 + o] = acc;
  split_store(XT2H, XT2L, (size_t)pt*64 + o, acc);
  float v = acc*acc;
  #pragma unroll
  for (int s = 32; s > 0; s >>= 1) v += __shfl_down(v, s, 64);
  if (o == 0) XX2[pt] = v;
}

// ---------------------------------------------------------------- triangular distance GEMM (per batch)
__global__ __launch_bounds__(256) void dist_gemm_tri(
    const float* __restrict__ XQ,   // batch slice of XT2, [4096][64]
    const float* __restrict__ XXb,  // batch slice of XX2, [4096]
    float* __restrict__ D)          // [4096][4096]
{
  // map blockIdx.x in [0,528) -> (ti,tj) with ti<=tj, NT=32
  int r = blockIdx.x, ti = 0;
  #pragma unroll 1
  for (;;) { int len = 32 - ti; if (r < len) break; r -= len; ++ti; }
  int tj = ti + r;
  int q0 = ti * 128, j0 = tj * 128;

  __shared__ float Qs[16][132];
  __shared__ float Xs[16][132];
  int tid = threadIdx.x;
  int rg = tid & 15, cg = tid >> 4;
  float acc[8][8];
  #pragma unroll
  for (int u = 0; u < 8; ++u)
    #pragma unroll
    for (int v = 0; v < 8; ++v) acc[u][v] = 0.f;

  for (int c0 = 0; c0 < 64; c0 += 16) {
    #pragma unroll
    for (int i = 0; i < 8; ++i) {
      int idx = tid + i*256;
      int kk = idx & 15, p = idx >> 4;
      Qs[kk][p] = XQ[(size_t)(q0+p)*64 + c0 + kk];
      Xs[kk][p] = XQ[(size_t)(j0+p)*64 + c0 + kk];
    }
    __syncthreads();
    #pragma unroll
    for (int kk = 0; kk < 16; ++kk) {
      float a[8], bb[8];
      #pragma unroll
      for (int u = 0; u < 8; ++u) a[u] = Qs[kk][rg*8+u];
      #pragma unroll
      for (int v = 0; v < 8; ++v) bb[v] = Xs[kk][cg*8+v];
      #pragma unroll
      for (int u = 0; u < 8; ++u)
        #pragma unroll
        for (int v = 0; v < 8; ++v) acc[u][v] = fmaf(a[u], bb[v], acc[u][v]);
    }
    __syncthreads();
  }
  // epilogue 1: D[q][j] = xx_j - 2*dot
  {
    float xxv[8];
    #pragma unroll
    for (int v = 0; v < 8; ++v) xxv[v] = XXb[j0 + cg*8 + v];
    #pragma unroll
    for (int u = 0; u < 8; ++u) {
      float* po = D + (size_t)(q0 + rg*8 + u)*NPTS + j0 + cg*8;
      #pragma unroll
      for (int v = 0; v < 8; ++v) po[v] = fmaf(-2.f, acc[u][v], xxv[v]);
    }
  }
  // epilogue 2 (off-diagonal): D[j][q] = xx_q - 2*dot (register-transposed tile)
  if (ti != tj) {
    float xxq[8];
    #pragma unroll
    for (int u = 0; u < 8; ++u) xxq[u] = XXb[q0 + rg*8 + u];
    #pragma unroll
    for (int v = 0; v < 8; ++v) {
      float* po = D + (size_t)(j0 + cg*8 + v)*NPTS + q0 + rg*8;
      float4 w0, w1;
      w0.x = fmaf(-2.f, acc[0][v], xxq[0]);
      w0.y = fmaf(-2.f, acc[1][v], xxq[1]);
      w0.z = fmaf(-2.f, acc[2][v], xxq[2]);
      w0.w = fmaf(-2.f, acc[3][v], xxq[3]);
      w1.x = fmaf(-2.f, acc[4][v], xxq[4]);
      w1.y = fmaf(-2.f, acc[5][v], xxq[5]);
      w1.z = fmaf(-2.f, acc[6][v], xxq[6]);
      w1.w = fmaf(-2.f, acc[7][v], xxq[7]);
      *(float4*)po = w0;
      *(float4*)(po + 4) = w1;
    }
  }
}

// ---------------------------------------------------------------- exact wave-level 20th-smallest
// Per-lane top-S + pop-min. EXACTNESS: every candidate a lane discards is >= the
// lane's FINAL bd[S-1] (retained-max is monotone non-increasing). So if all lanes
// satisfy lane_max >= thr, no candidate < thr was discarded anywhere -> thr is the
// true 20th-smallest value. safe=false (P~1e-10/query) -> caller retries with S=20,
// which is unconditionally exact (a lane cannot hold >=20 of the <=19 values < thr).
template<int S, typename F>
__device__ __forceinline__ float find_thr(F getd4, bool& safe) {
  float bd[S];
  #pragma unroll
  for (int t = 0; t < S; ++t) bd[t] = 1e30f;
  #pragma unroll 2
  for (int t = 0; t < 16; ++t) {
    float4 dv = getd4(t);
    float ds[4] = {dv.x, dv.y, dv.z, dv.w};
    #pragma unroll
    for (int e = 0; e < 4; ++e) {
      float cd = ds[e];
      #pragma unroll
      for (int s = S-1; s >= 1; --s) bd[s] = med3f(cd, bd[s-1], bd[s]);
      bd[0] = fminf(bd[0], cd);
    }
  }
  float lane_max = bd[S-1];
  float thr = 1e30f;
  int total = 0;
  #pragma unroll 1
  for (int r = 0; r < KNN; ++r) {
    float m = wave_min_f32_dpp(bd[0]);
    unsigned long long bal = __ballot(bd[0] == m);
    total += __popcll(bal);
    if (total >= KNN) { thr = m; break; }
    if (bd[0] == m) {
      #pragma unroll
      for (int s = 0; s < S-1; ++s) bd[s] = bd[s+1];
      bd[S-1] = 1e30f;
    }
  }
  safe = !__any(lane_max < thr);
  return thr;
}

// ---------------------------------------------------------------- knn select
// batch >= 0: per-batch grid (NPTS/4 blocks). batch < 0: merged grid (BN/4 blocks).
template<bool FEAT_MODE>
__global__ __launch_bounds__(256) void knn_select(
    const float* __restrict__ D, const float4* __restrict__ XTP4,
    int batch, int* __restrict__ IDX)
{
  int lane = threadIdx.x & 63;
  int blk = blockIdx.x, bq = batch;
  if (batch < 0) { bq = blk >> 10; blk &= 1023; }
  int ql = blk*4 + (threadIdx.x >> 6);          // query local to batch
  int qg = bq*NPTS + ql;                        // global point id
  const float4* drow4 = FEAT_MODE ? (const float4*)(D + (size_t)ql*NPTS) : nullptr;
  const float4* Xb4 = XTP4 + (size_t)bq*NPTS;
  float qx = 0.f, qy = 0.f, qz = 0.f;
  if (!FEAT_MODE) { float4 qp = XTP4[qg]; qx = qp.x; qy = qp.y; qz = qp.z; }

  auto key3 = [&](float4 p) -> float {
    float dot = qx*p.x;
    dot = fmaf(qy, p.y, dot);
    dot = fmaf(qz, p.z, dot);
    return fmaf(-2.f, dot, p.w);
  };
  auto getd4 = [&](int t) -> float4 {
    if (FEAT_MODE) {
      return drow4[t*64 + lane];
    } else {
      int jb = t*256 + lane*4;
      float4 r;
      r.x = key3(Xb4[jb+0]);
      r.y = key3(Xb4[jb+1]);
      r.z = key3(Xb4[jb+2]);
      r.w = key3(Xb4[jb+3]);
      return r;
    }
  };

  // ---- phases 1+2: wave-level 20th-smallest value (thr), top-8 fast path
  bool safe;
  float thr = find_thr<8>(getd4, safe);
  if (!safe) {                       // ~never taken; exact fallback
    bool s2;
    thr = find_thr<KNN>(getd4, s2);
  }

  // ---- phase 3: rescan, emit strict (d<thr) via ballot-compaction; ties by smallest j
  unsigned long long lml = (1ull << lane) - 1ull;
  int S = 0;
  int myj = 0x7fffffff;
  #pragma unroll 2
  for (int t = 0; t < 16; ++t) {
    float4 dv = getd4(t);
    float ds[4] = {dv.x, dv.y, dv.z, dv.w};
    int jb = t*256 + lane*4;
    #pragma unroll
    for (int e = 0; e < 4; ++e) {
      float d = ds[e];
      int j = jb + e;
      bool ps = d < thr;
      unsigned long long mk = __ballot(ps);
      int pos = S + __popcll(mk & lml);
      if (ps && pos < KNN) IDX[(size_t)qg*KNN + pos] = j;
      S += __popcll(mk);
      if (d == thr && j < myj) myj = j;
    }
  }
  int need = KNN - S;
  if (need == 1) {
    int mn = wave_min_i32_dpp(myj);
    if (lane == 0) IDX[(size_t)qg*KNN + S] = mn;
  } else if (need > 1) {
    if (lane == 0) {
      int taken = 0;
      for (int j = 0; j < NPTS && taken < need; ++j) {
        float d;
        if (FEAT_MODE) d = D[(size_t)ql*NPTS + j];
        else           d = key3(Xb4[j]);
        if (d == thr) { IDX[(size_t)qg*KNN + S + taken] = j; ++taken; }
      }
    }
  }
}

// ---------------------------------------------------------------- f16x3 split MFMA GEMM (generic)
template<bool LRELU_, bool CM>
__global__ __launch_bounds__(256) void mfma_gemm(
    const _Float16* __restrict__ WH, const _Float16* __restrict__ WL,  // [Mtot][KT]
    int Mtot, int KT,
    const _Float16* __restrict__ FH, const _Float16* __restrict__ FL,  // [pt][fstride]
    int fstride, int foff,
    const float* __restrict__ bias,
    float* __restrict__ Out, int ostride)
{
  __shared__ _Float16 As[2][128*32];
  __shared__ _Float16 Bs[2][128*32];
  int tid = threadIdx.x;
  int lane = tid & 63, wave = tid >> 6;
  int wr = wave >> 1, wc = wave & 1;
  int rt = blockIdx.y * 128, ct = blockIdx.x * 128;

  int srow = tid >> 2;
  int skh  = (tid & 3) * 8;
  const _Float16* gA0 = WH + (size_t)(rt + srow)*KT + skh;
  const _Float16* gA1 = WL + (size_t)(rt + srow)*KT + skh;
  const _Float16* gB0 = FH + (size_t)(ct + srow)*fstride + foff + skh;
  const _Float16* gB1 = FL + (size_t)(ct + srow)*fstride + foff + skh;
  const size_t a2 = (size_t)64*KT;
  const size_t b2 = (size_t)64*fstride;
  _Float16* lA0 = &As[0][tid*8];
  _Float16* lA1 = &As[1][tid*8];
  _Float16* lB0 = &Bs[0][tid*8];
  _Float16* lB1 = &Bs[1][tid*8];

  f32x4 acc[4][4];
  #pragma unroll
  for (int m = 0; m < 4; ++m)
    #pragma unroll
    for (int n = 0; n < 4; ++n) acc[m][n] = (f32x4){0.f, 0.f, 0.f, 0.f};

  int fr = lane & 15;
  int kg = (lane >> 4) * 8;

  for (int k0 = 0; k0 < KT; k0 += 32) {
    gld16(gA0 + k0,      lA0);
    gld16(gA0 + k0 + a2, lA0 + 2048);
    gld16(gA1 + k0,      lA1);
    gld16(gA1 + k0 + a2, lA1 + 2048);
    gld16(gB0 + k0,      lB0);
    gld16(gB0 + k0 + b2, lB0 + 2048);
    gld16(gB1 + k0,      lB1);
    gld16(gB1 + k0 + b2, lB1 + 2048);
    __syncthreads();

    f16x8 ah[4], al[4], bh[4], bl[4];
    #pragma unroll
    for (int m = 0; m < 4; ++m) {
      int ro = (wr*64 + m*16 + fr)*32 + kg;
      ah[m] = *(const f16x8*)&As[0][ro];
      al[m] = *(const f16x8*)&As[1][ro];
    }
    #pragma unroll
    for (int n = 0; n < 4; ++n) {
      int co = (wc*64 + n*16 + fr)*32 + kg;
      bh[n] = *(const f16x8*)&Bs[0][co];
      bl[n] = *(const f16x8*)&Bs[1][co];
    }
    #pragma unroll
    for (int m = 0; m < 4; ++m)
      #pragma unroll
      for (int n = 0; n < 4; ++n) {
        acc[m][n] = __builtin_amdgcn_mfma_f32_16x16x32_f16(ah[m], bh[n], acc[m][n], 0, 0, 0);
        acc[m][n] = __builtin_amdgcn_mfma_f32_16x16x32_f16(ah[m], bl[n], acc[m][n], 0, 0, 0);
        acc[m][n] = __builtin_amdgcn_mfma_f32_16x16x32_f16(al[m], bh[n], acc[m][n], 0, 0, 0);
      }
    __syncthreads();
  }

  int rowg = (lane >> 4) * 4;
  if (CM) {
    int b = ct >> 12, n0 = ct & (NPTS-1);
    #pragma unroll
    for (int m = 0; m < 4; ++m) {
      int rbase = rt + wr*64 + m*16 + rowg;
      #pragma unroll
      for (int r4 = 0; r4 < 4; ++r4) {
        int r = rbase + r4;
        float bv = bias[r];
        float* po = Out + ((size_t)b*Mtot + r)*NPTS + n0 + wc*64 + fr;
        #pragma unroll
        for (int n = 0; n < 4; ++n) {
          float v = acc[m][n][r4] + bv;
          if (LRELU_) v = lrelu_f(v);
          po[n*16] = v;
        }
      }
    }
  } else {
    #pragma unroll
    for (int n = 0; n < 4; ++n) {
      int pt = ct + wc*64 + n*16 + fr;
      #pragma unroll
      for (int m = 0; m < 4; ++m) {
        int r0 = rt + wr*64 + m*16 + rowg;
        float4 v;
        v.x = acc[m][n][0] + bias[r0];
        v.y = acc[m][n][1] + bias[r0+1];
        v.z = acc[m][n][2] + bias[r0+2];
        v.w = acc[m][n][3] + bias[r0+3];
        if (LRELU_) { v.x = lrelu_f(v.x); v.y = lrelu_f(v.y); v.z = lrelu_f(v.z); v.w = lrelu_f(v.w); }
        *(float4*)&Out[(size_t)pt*ostride + r0] = v;
      }
    }
  }
}

// ---------------------------------------------------------------- fused gather + dg2 MFMA + x1/x2 group-max
__global__ __launch_bounds__(256) void dg2_fused(
    const _Float16* __restrict__ W2H, const _Float16* __restrict__ W2L, // [128][128]
    const float* __restrict__ UV1,      // [BN][256] (U|V)
    const int* __restrict__ IDXF,       // [BN][KNN]
    const float* __restrict__ bias,     // bdg2 [128]
    _Float16* __restrict__ FFH, _Float16* __restrict__ FFL)
{
  constexpr int RS = 136;
  __shared__ __align__(16) unsigned char smem[43520];
  _Float16* HsH = (_Float16*)smem;            // [80][RS]
  _Float16* HsL = (_Float16*)(smem + 21760);  // [80][RS]
  float*    Cs  = (float*)smem;               // [128][84] epilogue reuse
  __shared__ int js[80];
  __shared__ float4 mxs[128];

  int tid = threadIdx.x;
  int lane = tid & 63, wave = tid >> 6;
  size_t pt0 = (size_t)blockIdx.x * 4;
  size_t bbase = (pt0 >> 12) << 12;

  if (tid < 80) js[tid] = IDXF[pt0*KNN + tid];

  int fr = lane & 15, kg = (lane >> 4) * 8;
  f16x8 ah[2][4], al[2][4];
  #pragma unroll
  for (int m = 0; m < 2; ++m) {
    int row = wave*32 + m*16 + fr;
    #pragma unroll
    for (int ks = 0; ks < 4; ++ks) {
      ah[m][ks] = *(const f16x8*)&W2H[row*128 + ks*32 + kg];
      al[m][ks] = *(const f16x8*)&W2L[row*128 + ks*32 + kg];
    }
  }
  __syncthreads();   // js visible

  {
    int g = (tid >> 5) & 3, half = tid >> 7, c4 = tid & 31;
    size_t ptg = pt0 + g;
    float4 vv = *(const float4*)&UV1[ptg*256 + 128 + c4*4];
    float4 mx = make_float4(-1e30f, -1e30f, -1e30f, -1e30f);
    #pragma unroll
    for (int k = 0; k < 10; ++k) {
      int row = g*20 + half*10 + k;
      int j = js[row];
      float4 u = *(const float4*)&UV1[(bbase + (size_t)j)*256 + c4*4];
      float h0 = lrelu_f(u.x + vv.x);
      float h1 = lrelu_f(u.y + vv.y);
      float h2 = lrelu_f(u.z + vv.z);
      float h3 = lrelu_f(u.w + vv.w);
      f16x4 hh, hl;
      hh[0] = (_Float16)h0; hl[0] = (_Float16)(h0 - (float)hh[0]);
      hh[1] = (_Float16)h1; hl[1] = (_Float16)(h1 - (float)hh[1]);
      hh[2] = (_Float16)h2; hl[2] = (_Float16)(h2 - (float)hh[2]);
      hh[3] = (_Float16)h3; hl[3] = (_Float16)(h3 - (float)hh[3]);
      *(f16x4*)&HsH[row*RS + c4*4] = hh;
      *(f16x4*)&HsL[row*RS + c4*4] = hl;
      mx.x = fmaxf(mx.x, h0); mx.y = fmaxf(mx.y, h1);
      mx.z = fmaxf(mx.z, h2); mx.w = fmaxf(mx.w, h3);
    }
    if (half == 1) mxs[(g << 5) | c4] = mx;
    __syncthreads();
    if (half == 0) {
      float4 o = mxs[(g << 5) | c4];
      mx.x = fmaxf(mx.x, o.x); mx.y = fmaxf(mx.y, o.y);
      mx.z = fmaxf(mx.z, o.z); mx.w = fmaxf(mx.w, o.w);
      split_store(FFH, FFL, ptg*512 + c4*4 + 0, mx.x);
      split_store(FFH, FFL, ptg*512 + c4*4 + 1, mx.y);
      split_store(FFH, FFL, ptg*512 + c4*4 + 2, mx.z);
      split_store(FFH, FFL, ptg*512 + c4*4 + 3, mx.w);
    }
  }

  f32x4 acc[2][5];
  #pragma unroll
  for (int m = 0; m < 2; ++m)
    #pragma unroll
    for (int n = 0; n < 5; ++n) acc[m][n] = (f32x4){0.f, 0.f, 0.f, 0.f};

  #pragma unroll
  for (int ks = 0; ks < 4; ++ks) {
    f16x8 bh[5], bl[5];
    #pragma unroll
    for (int n = 0; n < 5; ++n) {
      int ro = (n*16 + fr)*RS + ks*32 + kg;
      bh[n] = *(const f16x8*)&HsH[ro];
      bl[n] = *(const f16x8*)&HsL[ro];
    }
    #pragma unroll
    for (int m = 0; m < 2; ++m)
      #pragma unroll
      for (int n = 0; n < 5; ++n) {
        acc[m][n] = __builtin_amdgcn_mfma_f32_16x16x32_f16(ah[m][ks], bh[n], acc[m][n], 0, 0, 0);
        acc[m][n] = __builtin_amdgcn_mfma_f32_16x16x32_f16(ah[m][ks], bl[n], acc[m][n], 0, 0, 0);
        acc[m][n] = __builtin_amdgcn_mfma_f32_16x16x32_f16(al[m][ks], bh[n], acc[m][n], 0, 0, 0);
      }
  }
  __syncthreads();

  int rowg = (lane >> 4) * 4;
  #pragma unroll
  for (int m = 0; m < 2; ++m) {
    int r = wave*32 + m*16 + rowg;
    #pragma unroll
    for (int n = 0; n < 5; ++n) {
      int p = n*16 + fr;
      #pragma unroll
      for (int q = 0; q < 4; ++q) Cs[(r+q)*84 + p] = acc[m][n][q];
    }
  }
  __syncthreads();

  #pragma unroll
  for (int t = 0; t < 2; ++t) {
    int task = tid + t*256;
    int r = task & 127, g = task >> 7;
    const float* cr = &Cs[r*84 + g*20];
    float m = cr[0];
    #pragma unroll
    for (int k = 1; k < 20; ++k) m = fmaxf(m, cr[k]);
    float v = lrelu_f(m + bias[r]);
    split_store(FFH, FFL, (pt0 + g)*512 + 128 + r, v);
  }
}

// ---------------------------------------------------------------- sn block: one point per block
__global__ __launch_bounds__(256) void sn_gather(
    const float* __restrict__ UV2, const int* __restrict__ IDXX,
    _Float16* __restrict__ FFH, _Float16* __restrict__ FFL)
{
  int tid = threadIdx.x;   // channel 0..255
  size_t pt = blockIdx.x;
  size_t bb = (pt >> 12) << 12;
  __shared__ int js[KNN];
  if (tid < KNN) js[tid] = IDXX[pt*KNN + tid];
  __syncthreads();
  float v = UV2[pt*512 + 256 + tid];
  float m = -1e30f;
  #pragma unroll
  for (int k = 0; k < KNN; ++k) {
    float h = lrelu_f(UV2[(bb + (size_t)js[k])*512 + tid] + v);
    m = fmaxf(m, h);
  }
  split_store(FFH, FFL, pt*512 + 256 + tid, m);
}

// ---------------------------------------------------------------- farthest point sampling (reg-resident, shuffle argmax)
__global__ __launch_bounds__(512) void fps_kernel(
    const float* __restrict__ xyz, int* __restrict__ SIDX)
{
  int b = blockIdx.x, tid = threadIdx.x;
  int lane = tid & 63, wave = tid >> 6;   // 8 waves
  const float* p = xyz + (size_t)b*3*NPTS;
  float px[8], py[8], pz[8], dist[8];
  #pragma unroll
  for (int j = 0; j < 8; ++j) {
    int i = tid + j*512;
    px[j] = p[i]; py[j] = p[NPTS+i]; pz[j] = p[2*NPTS+i];
    dist[j] = 1e10f;
  }
  __shared__ float bv[8], bx[8], by[8], bz[8];
  __shared__ int bi[8];
  float cx = p[0], cy = p[NPTS], cz = p[2*NPTS];
  int far = 0;
  for (int it = 0; it < 32; ++it) {
    if (tid == 0) SIDX[b*32 + it] = far;
    float lm = -1e30f, lx = 0.f, ly = 0.f, lz = 0.f; int li = 0;
    #pragma unroll
    for (int j = 0; j < 8; ++j) {
      float dx = px[j]-cx, dy = py[j]-cy, dz = pz[j]-cz;
      float d = dx*dx + dy*dy + dz*dz;
      float dm = fminf(dist[j], d);
      dist[j] = dm;
      bool sw = dm > lm;
      lm = sw ? dm : lm;
      li = sw ? (tid + j*512) : li;
      lx = sw ? px[j] : lx; ly = sw ? py[j] : ly; lz = sw ? pz[j] : lz;
    }
    #pragma unroll
    for (int k = 1; k < 64; k <<= 1) {
      float om = __shfl_xor(lm, k, 64);
      int   oi = __shfl_xor(li, k, 64);
      float ox = __shfl_xor(lx, k, 64);
      float oy = __shfl_xor(ly, k, 64);
      float oz = __shfl_xor(lz, k, 64);
      bool tk = (om > lm) || (om == lm && oi < li);
      lm = tk ? om : lm; li = tk ? oi : li;
      lx = tk ? ox : lx; ly = tk ? oy : ly; lz = tk ? oz : lz;
    }
    if (lane == 0) { bv[wave] = lm; bi[wave] = li; bx[wave] = lx; by[wave] = ly; bz[wave] = lz; }
    __syncthreads();
    float m0 = bv[0]; int i0 = bi[0];
    float X = bx[0], Y = by[0], Z = bz[0];
    #pragma unroll
    for (int w = 1; w < 8; ++w) {
      bool tk = (bv[w] > m0) || (bv[w] == m0 && bi[w] < i0);
      m0 = tk ? bv[w] : m0; i0 = tk ? bi[w] : i0;
      X = tk ? bx[w] : X; Y = tk ? by[w] : Y; Z = tk ? bz[w] : Z;
    }
    far = i0; cx = X; cy = Y; cz = Z;
    __syncthreads();
  }
}

// ---------------------------------------------------------------- k-farthest (8) among 32 samples
__global__ __launch_bounds__(128) void kfn_kernel(
    const float* __restrict__ xyz, const int* __restrict__ SIDX,
    int* __restrict__ NIDX)
{
  int tid = threadIdx.x;     // 0..127
  int b = tid >> 5, i = tid & 31;
  const float* p = xyz + (size_t)b*3*NPTS;
  __shared__ float sx[4][32], sy[4][32], sz[4][32];
  {
    int si = SIDX[b*32 + i];
    sx[b][i] = p[si]; sy[b][i] = p[NPTS+si]; sz[b][i] = p[2*NPTS+si];
  }
  __syncthreads();
  float xi = sx[b][i], yi = sy[b][i], zi = sz[b][i];
  float xxi = xi*xi + yi*yi + zi*zi;
  float bd[8]; int bi_[8];
  #pragma unroll
  for (int t = 0; t < 8; ++t) { bd[t] = -1e30f; bi_[t] = 0; }
  for (int j = 0; j < 32; ++j) {
    float xj = sx[b][j], yj = sy[b][j], zj = sz[b][j];
    float xxj = xj*xj + yj*yj + zj*zj;
    float d = xxi - 2.f*(xi*xj + yi*yj + zi*zj) + xxj;
    if (d > bd[7]) {
      float cd = d; int ci = j;
      #pragma unroll
      for (int t = 0; t < 8; ++t) {
        bool sw = bd[t] < cd;
        float nv = sw ? cd : bd[t];
        int   ni = sw ? ci : bi_[t];
        float ov = sw ? bd[t] : cd;
        int   oi = sw ? bi_[t] : ci;
        bd[t] = nv; bi_[t] = ni; cd = ov; ci = oi;
      }
    }
  }
  size_t o = (size_t)(b*32 + i)*8;
  #pragma unroll
  for (int t = 0; t < 8; ++t) NIDX[o+t] = bi_[t];
}

// ---------------------------------------------------------------- triplet terms
__global__ __launch_bounds__(256) void trip_kernel(
    const float* __restrict__ es0, const float* __restrict__ et0,
    const int* __restrict__ SIDX, const int* __restrict__ NIDX,
    float* __restrict__ ACC)
{
  int bi_ = blockIdx.x; int b = bi_ >> 5;
  int tid = threadIdx.x;
  __shared__ int js[8];
  __shared__ int ssi;
  if (tid == 0) ssi = SIDX[bi_];
  if (tid < 8) js[tid] = SIDX[b*32 + NIDX[bi_*8 + tid]];
  __syncthreads();
  int si = ssi;
  const float* es = es0 + (size_t)b*1024*NPTS;
  const float* et = et0 + (size_t)b*1024*NPTS;
  float sp = 0.f, sn = 0.f;
  for (int c = tid; c < 1024; c += 256) {
    const float* erow = et + (size_t)c*NPTS;
    float s = es[(size_t)c*NPTS + si];
    float d0 = s - erow[si]; sp += d0*d0;
    #pragma unroll
    for (int t = 0; t < 8; ++t) { float d1 = s - erow[js[t]]; sn += d1*d1; }
  }
  __shared__ float r1[256], r2[256];
  r1[tid] = sp; r2[tid] = sn; __syncthreads();
  for (int s2 = 128; s2 > 0; s2 >>= 1) {
    if (tid < s2) { r1[tid] += r1[tid+s2]; r2[tid] += r2[tid+s2]; }
    __syncthreads();
  }
  if (tid == 0) {
    float dp = r1[0] * (1.f/1024.f);
    float dn = r2[0] * (1.f/8192.f);
    float tr = fmaxf(0.f, 1.f - dn/(1.f + dp));
    atomicAdd(&ACC[0], tr);
  }
}

// ---------------------------------------------------------------- stats stage A: mse/mae + per-point partial norms
__global__ __launch_bounds__(256) void stats_a(
    const float* __restrict__ es0, const float* __restrict__ et0,
    float* __restrict__ PS, float* __restrict__ PT, float* __restrict__ ACC)
{
  int tid = threadIdx.x;
  int p = tid & 63, g = tid >> 6;
  int pt0 = (blockIdx.x & 255) * 64;     // 256 point-tiles of 64
  int chunk = blockIdx.x >> 8;           // 8 channel-chunks of 128
  int b = pt0 >> 12, n0 = pt0 & (NPTS-1);
  const float* es = es0 + (size_t)b*1024*NPTS + n0;
  const float* et = et0 + (size_t)b*1024*NPTS + n0;
  float ss = 0.f, tt = 0.f, sq = 0.f, ab = 0.f;
  int c0 = chunk * 128;
  for (int c = c0 + g; c < c0 + 128; c += 4) {
    float s = es[(size_t)c*NPTS + p];
    float t = et[(size_t)c*NPTS + p];
    ss += s*s; tt += t*t;
    float d = s - t;
    sq += d*d; ab += fabsf(d);
  }
  __shared__ float rs[4][64], rt[4][64];
  __shared__ float red[256];
  rs[g][p] = ss; rt[g][p] = tt;
  red[tid] = sq;
  __syncthreads();
  for (int s2 = 128; s2 > 0; s2 >>= 1) {
    if (tid < s2) red[tid] += red[tid+s2];
    __syncthreads();
  }
  if (tid == 0) atomicAdd(&ACC[3], red[0]);
  __syncthreads();
  red[tid] = ab; __syncthreads();
  for (int s2 = 128; s2 > 0; s2 >>= 1) {
    if (tid < s2) red[tid] += red[tid+s2];
    __syncthreads();
  }
  if (tid == 0) atomicAdd(&ACC[4], red[0]);
  if (tid < 64) {
    atomicAdd(&PS[pt0 + tid], rs[0][tid]+rs[1][tid]+rs[2][tid]+rs[3][tid]);
    atomicAdd(&PT[pt0 + tid], rt[0][tid]+rt[1][tid]+rt[2][tid]+rt[3][tid]);
  }
}

// ---------------------------------------------------------------- stats stage B: norm terms
__global__ __launch_bounds__(256) void stats_b(
    const float* __restrict__ PS, const float* __restrict__ PT,
    float* __restrict__ ACC)
{
  int i = blockIdx.x * 256 + threadIdx.x;
  float a = sqrtf(PS[i]) - 1.f;
  float c = sqrtf(PT[i]) - 1.f;
  float av = a*a, cv = c*c;
  #pragma unroll
  for (int s2 = 32; s2 > 0; s2 >>= 1) {
    av += __shfl_down(av, s2, 64);
    cv += __shfl_down(cv, s2, 64);
  }
  __shared__ float r1[4], r2[4];
  int lane = threadIdx.x & 63, wave = threadIdx.x >> 6;
  if (lane == 0) { r1[wave] = av; r2[wave] = cv; }
  __syncthreads();
  if (threadIdx.x == 0) {
    atomicAdd(&ACC[1], r1[0]+r1[1]+r1[2]+r1[3]);
    atomicAdd(&ACC[2], r2[0]+r2[1]+r2[2]+r2[3]);
  }
}

// ---------------------------------------------------------------- finalize scalars
__global__ void finalize_kernel(const float* __restrict__ ACC, float* __restrict__ o3) {
  if (threadIdx.x == 0 && blockIdx.x == 0) {
    float ln1 = sqrtf(ACC[1] * (1.f/16384.f));
    float ln2 = sqrtf(ACC[2] * (1.f/16384.f));
    o3[0] = ACC[0]*(1.f/128.f) + (ln1 + ln2)*0.5f*0.03f;
    o3[1] = ACC[3] * (1.f/4194304.f);   // mean((s-t)^2)*B
    o3[2] = ACC[4] * (1.f/4194304.f);   // mean(|s-t|)*B
  }
}

// ================================================================ host
extern "C" void kernel_launch(void* const* d_in, const int* in_sizes, int n_in,
                              void* d_out, int out_size, void* d_ws, size_t ws_size,
                              hipStream_t stream) {
  (void)in_sizes; (void)n_in; (void)out_size; (void)ws_size;
  const float* src  = (const float*)d_in[0];
  const float* tgt  = (const float*)d_in[1];
  const float* w1   = (const float*)d_in[2];
  const float* b1   = (const float*)d_in[3];
  const float* w2   = (const float*)d_in[4];
  const float* b2   = (const float*)d_in[5];
  const float* wdg1 = (const float*)d_in[6];
  const float* bdg1 = (const float*)d_in[7];
  const float* wdg2 = (const float*)d_in[8];
  const float* bdg2 = (const float*)d_in[9];
  const float* wsn1 = (const float*)d_in[10];
  const float* bsn1 = (const float*)d_in[11];
  const float* w3   = (const float*)d_in[12];
  const float* b3   = (const float*)d_in[13];
  float* out = (float*)d_out;

  float* ws = (float*)d_ws;
  float*  XTP  = ws;                                   // BN*4 (float4 x,y,z,xx)
  float*  XT2  = XTP + (size_t)BN*4;                   // BN*64
  float*  XX2  = XT2 + (size_t)BN*64;                  // BN
  float*  UV1  = XX2 + BN;                             // BN*256
  _Float16* FFH = (_Float16*)(UV1 + (size_t)BN*256);   // BN*512 halves
  _Float16* FFL = FFH + (size_t)BN*512;                // BN*512 halves
  float*  UV2  = (float*)(FFL + (size_t)BN*512);       // BN*512
  float*  Dbuf = (float*)FFH;                          // NPTS*NPTS fp32 == FFH+FFL+UV2 (dead then)
  _Float16* XT2H = (_Float16*)(UV2 + (size_t)BN*512);  // BN*64 halves
  _Float16* XT2L = XT2H + (size_t)BN*64;               // BN*64 halves
  int*    IDXF = (int*)(XT2L + (size_t)BN*64);         // BN*KNN
  int*    IDXX = IDXF + (size_t)BN*KNN;                // BN*KNN
  _Float16* W2H = (_Float16*)(IDXX + (size_t)BN*KNN);  // 128*128 halves
  _Float16* W2L = W2H + 128*128;                       // 128*128 halves
  float*  BUV1 = (float*)(W2L + 128*128);              // 256
  float*  BUV2 = BUV1 + 256;                           // 512
  _Float16* W3H = (_Float16*)(BUV2 + 512);             // 1024*512 halves
  _Float16* W3L = W3H + 1024*512;
  _Float16* WH1 = W3L + 1024*512;                      // 256*64 halves
  _Float16* WL1 = WH1 + 256*64;
  _Float16* WH2 = WL1 + 256*64;                        // 512*128 halves
  _Float16* WL2 = WH2 + 512*128;
  int*    SIDX = (int*)(WL2 + 512*128);                // NB*32
  int*    NIDX = SIDX + NB*32;                         // NB*32*8
  float*  ACC  = (float*)(NIDX + NB*32*8);             // 8
  float*  PS   = ACC + 8;                              // BN
  float*  PT   = PS + BN;                              // BN

  prep_weights<<<2048, 256, 0, stream>>>(wdg1, bdg1, wdg2, wsn1, bsn1, w3,
                                         W2H, W2L, BUV1, BUV2,
                                         W3H, W3L, WH1, WL1, WH2, WL2);

  auto run_cloud = [&](const float* xyz, float* emb) {
    pack_xyz<<<BN/256, 256, 0, stream>>>(xyz, (float4*)XTP);
    conv12<<<BN/4, 256, 0, stream>>>(xyz, w1, b1, w2, b2, XT2, XX2, XT2H, XT2L);
    // xyz-space KNN: one merged launch over all batches (no D dependency)
    knn_select<false><<<BN/4, 256, 0, stream>>>(nullptr, (const float4*)XTP, -1, IDXX);
    // feature-space KNN: per batch (single D buffer), triangular dist GEMM
    for (int bb = 0; bb < NB; ++bb) {
      dist_gemm_tri<<<528, 256, 0, stream>>>(
          XT2 + (size_t)bb*NPTS*64, XX2 + (size_t)bb*NPTS, Dbuf);
      knn_select<true><<<NPTS/4, 256, 0, stream>>>(Dbuf, (const float4*)XTP, bb, IDXF);
    }
    // UV1 = WEFF1 * XT2 (f16x3 MFMA)
    mfma_gemm<false,false><<<dim3(BN/128, 2), 256, 0, stream>>>(
        WH1, WL1, 256, 64, XT2H, XT2L, 64, 0, BUV1, UV1, 256);
    // fused gather + dg2 MFMA -> x1 (cols 0..127) + x2 (cols 128..255)
    dg2_fused<<<BN/4, 256, 0, stream>>>(W2H, W2L, UV1, IDXF, bdg2, FFH, FFL);
    // UV2 = WEFF2 * x2 (f16x3 MFMA)
    mfma_gemm<false,false><<<dim3(BN/128, 4), 256, 0, stream>>>(
        WH2, WL2, 512, 128, FFH, FFL, 512, 128, BUV2, UV2, 512);
    sn_gather<<<BN, 256, 0, stream>>>(UV2, IDXX, FFH, FFL);
    // emb = lrelu(W3 * feat + b3), channel-major (f16x3 MFMA)
    mfma_gemm<true,true><<<dim3(BN/128, 8), 256, 0, stream>>>(
        W3H, W3L, 1024, 512, FFH, FFL, 512, 0, b3, emb, 0);
  };

  float* emb_s = out;
  float* emb_t = out + (size_t)BN*1024;
  run_cloud(src, emb_s);
  run_cloud(tgt, emb_t);

  hipMemsetAsync(ACC, 0, (8 + 2*BN)*sizeof(float), stream);
  fps_kernel<<<NB, 512, 0, stream>>>(src, SIDX);
  kfn_kernel<<<1, 128, 0, stream>>>(src, SIDX, NIDX);
  trip_kernel<<<NB*32, 256, 0, stream>>>(emb_s, emb_t, SIDX, NIDX, ACC);
  stats_a<<<2048, 256, 0, stream>>>(emb_s, emb_t, PS, PT, ACC);
  stats_b<<<BN/256, 256, 0, stream>>>(PS, PT, ACC);
  finalize_kernel<<<1, 64, 0, stream>>>(ACC, out + (size_t)2*BN*1024);
}

// Round 6
// 1251.472 us; speedup vs baseline: 1.8319x; 1.0667x over previous
//
#include <hip/hip_runtime.h>
#include <cstdint>

#define NB 4
#define NPTS 4096
#define KNN 20
#define BN (NB*NPTS)   // 16384

typedef _Float16 f16x8 __attribute__((ext_vector_type(8)));
typedef _Float16 f16x4 __attribute__((ext_vector_type(4)));
typedef float    f32x4 __attribute__((ext_vector_type(4)));

__device__ __forceinline__ float lrelu_f(float x) { return x > 0.f ? x : 0.2f * x; }

__device__ __forceinline__ float med3f(float c, float lo, float hi) {
#if defined(__has_builtin)
#if __has_builtin(__builtin_amdgcn_fmed3f)
  return __builtin_amdgcn_fmed3f(c, lo, hi);
#else
  return fminf(fmaxf(c, lo), hi);
#endif
#else
  return fminf(fmaxf(c, lo), hi);
#endif
}

// async global->LDS, 16B per lane (lane-linear LDS dest required)
__device__ __forceinline__ void gld16(const void* g, void* l) {
  __builtin_amdgcn_global_load_lds(
      (const __attribute__((address_space(1))) void*)g,
      (__attribute__((address_space(3))) void*)l,
      16, 0, 0);
}

__device__ __forceinline__ void split_store(_Float16* __restrict__ H, _Float16* __restrict__ L,
                                            size_t idx, float v) {
  _Float16 h = (_Float16)v;
  H[idx] = h;
  L[idx] = (_Float16)(v - (float)h);
}

// ---------------------------------------------------------------- DPP wave reductions (VALU pipe, no LDS round-trips)
__device__ __forceinline__ float wave_min_f32_dpp(float x) {
  int xi = __float_as_int(x); int t;
  t = __builtin_amdgcn_update_dpp(xi, xi, 0x111, 0xf, 0xf, false);
  x = fminf(x, __int_as_float(t)); xi = __float_as_int(x);
  t = __builtin_amdgcn_update_dpp(xi, xi, 0x112, 0xf, 0xf, false);
  x = fminf(x, __int_as_float(t)); xi = __float_as_int(x);
  t = __builtin_amdgcn_update_dpp(xi, xi, 0x114, 0xf, 0xf, false);
  x = fminf(x, __int_as_float(t)); xi = __float_as_int(x);
  t = __builtin_amdgcn_update_dpp(xi, xi, 0x118, 0xf, 0xf, false);
  x = fminf(x, __int_as_float(t)); xi = __float_as_int(x);
  t = __builtin_amdgcn_update_dpp(xi, xi, 0x142, 0xf, 0xf, false);
  x = fminf(x, __int_as_float(t)); xi = __float_as_int(x);
  t = __builtin_amdgcn_update_dpp(xi, xi, 0x143, 0xf, 0xf, false);
  x = fminf(x, __int_as_float(t)); xi = __float_as_int(x);
  return __int_as_float(__builtin_amdgcn_readlane(xi, 63));
}

__device__ __forceinline__ int wave_min_i32_dpp(int x) {
  int t;
  t = __builtin_amdgcn_update_dpp(x, x, 0x111, 0xf, 0xf, false); x = min(x, t);
  t = __builtin_amdgcn_update_dpp(x, x, 0x112, 0xf, 0xf, false); x = min(x, t);
  t = __builtin_amdgcn_update_dpp(x, x, 0x114, 0xf, 0xf, false); x = min(x, t);
  t = __builtin_amdgcn_update_dpp(x, x, 0x118, 0xf, 0xf, false); x = min(x, t);
  t = __builtin_amdgcn_update_dpp(x, x, 0x142, 0xf, 0xf, false); x = min(x, t);
  t = __builtin_amdgcn_update_dpp(x, x, 0x143, 0xf, 0xf, false); x = min(x, t);
  return __builtin_amdgcn_readlane(x, 63);
}

// ---------------------------------------------------------------- prep weights
__global__ __launch_bounds__(256) void prep_weights(
    const float* __restrict__ wdg1, const float* __restrict__ bdg1,
    const float* __restrict__ wdg2,
    const float* __restrict__ wsn1, const float* __restrict__ bsn1,
    const float* __restrict__ w3,
    _Float16* __restrict__ W2H, _Float16* __restrict__ W2L,
    float* __restrict__ BUV1, float* __restrict__ BUV2,
    _Float16* __restrict__ W3H, _Float16* __restrict__ W3L,
    _Float16* __restrict__ WH1, _Float16* __restrict__ WL1,
    _Float16* __restrict__ WH2, _Float16* __restrict__ WL2)
{
  int i = blockIdx.x * 256 + threadIdx.x;
  if (i < 512*1024) {           // w3 is already [M=1024][K=512]
    float v = w3[i];
    split_store(W3H, W3L, i, v);
  }
  if (i < 256*64) {             // WEFF1: [M=256][K=64]
    int r = i >> 6, c = i & 63;
    float v = (r < 128) ? wdg1[r*128 + c]
                        : (wdg1[(r-128)*128 + 64 + c] - wdg1[(r-128)*128 + c]);
    split_store(WH1, WL1, i, v);
  }
  if (i < 512*128) {            // WEFF2: [M=512][K=128]
    int r = i >> 7, c = i & 127;
    float v = (r < 256) ? wsn1[r*256 + c]
                        : (wsn1[(r-256)*256 + 128 + c] - wsn1[(r-256)*256 + c]);
    split_store(WH2, WL2, i, v);
  }
  if (i < 128*128) split_store(W2H, W2L, i, wdg2[i]);  // [M=o][K=c] identity layout
  if (i < 256) BUV1[i] = (i < 128) ? 0.f : bdg1[i-128];
  if (i < 512) BUV2[i] = (i < 256) ? 0.f : bsn1[i-256];
}

// ---------------------------------------------------------------- pack xyz -> float4 (x,y,z,xx)
__global__ __launch_bounds__(256) void pack_xyz(
    const float* __restrict__ xyz, float4* __restrict__ XTP4)
{
  int i = blockIdx.x * 256 + threadIdx.x;
  if (i >= BN) return;
  int b = i >> 12, n = i & (NPTS-1);
  const float* p = xyz + (size_t)b*3*NPTS;
  float x = p[n], y = p[NPTS+n], z = p[2*NPTS+n];
  float4 v; v.x = x; v.y = y; v.z = z; v.w = x*x + y*y + z*z;
  XTP4[i] = v;
}

// ---------------------------------------------------------------- conv1 + conv2 fused (3->64->64)
__global__ __launch_bounds__(256) void conv12(
    const float* __restrict__ xyz,
    const float* __restrict__ w1, const float* __restrict__ b1,
    const float* __restrict__ w2, const float* __restrict__ b2,
    float* __restrict__ XT2, float* __restrict__ XX2,
    _Float16* __restrict__ XT2H, _Float16* __restrict__ XT2L)
{
  __shared__ float w2t[64*65];
  __shared__ float h1s[4][64];
  int tid = threadIdx.x;
  for (int i = tid; i < 4096; i += 256) {
    int o = i >> 6, c = i & 63;
    w2t[c*65 + o] = w2[i];
  }
  int g = tid >> 6, o = tid & 63;
  int pt = blockIdx.x*4 + g;
  int b = pt >> 12, n = pt & (NPTS-1);
  const float* p = xyz + (size_t)b*3*NPTS;
  float x = p[n], y = p[NPTS+n], z = p[2*NPTS+n];
  float h1 = b1[o] + w1[o*3]*x + w1[o*3+1]*y + w1[o*3+2]*z;
  h1 = lrelu_f(h1);
  __syncthreads();
  h1s[g][o] = h1;
  __syncthreads();
  float acc = b2[o];
  #pragma unroll
  for (int c = 0; c < 64; ++c) acc = fmaf(w2t[c*65+o], h1s[g][c], acc);
  acc = lrelu_f(acc);
  XT2[(size_t)pt*64 + o] = acc;
  split_store(XT2H, XT2L, (size_t)pt*64 + o, acc);
  float v = acc*acc;
  #pragma unroll
  for (int s = 32; s > 0; s >>= 1) v += __shfl_down(v, s, 64);
  if (o == 0) XX2[pt] = v;
}

// ---------------------------------------------------------------- triangular distance GEMM (per batch)
__global__ __launch_bounds__(256) void dist_gemm_tri(
    const float* __restrict__ XQ,   // batch slice of XT2, [4096][64]
    const float* __restrict__ XXb,  // batch slice of XX2, [4096]
    float* __restrict__ D)          // [4096][4096]
{
  // map blockIdx.x in [0,528) -> (ti,tj) with ti<=tj, NT=32
  int r = blockIdx.x, ti = 0;
  #pragma unroll 1
  for (;;) { int len = 32 - ti; if (r < len) break; r -= len; ++ti; }
  int tj = ti + r;
  int q0 = ti * 128, j0 = tj * 128;

  __shared__ float Qs[16][132];
  __shared__ float Xs[16][132];
  int tid = threadIdx.x;
  int rg = tid & 15, cg = tid >> 4;
  float acc[8][8];
  #pragma unroll
  for (int u = 0; u < 8; ++u)
    #pragma unroll
    for (int v = 0; v < 8; ++v) acc[u][v] = 0.f;

  for (int c0 = 0; c0 < 64; c0 += 16) {
    #pragma unroll
    for (int i = 0; i < 8; ++i) {
      int idx = tid + i*256;
      int kk = idx & 15, p = idx >> 4;
      Qs[kk][p] = XQ[(size_t)(q0+p)*64 + c0 + kk];
      Xs[kk][p] = XQ[(size_t)(j0+p)*64 + c0 + kk];
    }
    __syncthreads();
    #pragma unroll
    for (int kk = 0; kk < 16; ++kk) {
      float a[8], bb[8];
      #pragma unroll
      for (int u = 0; u < 8; ++u) a[u] = Qs[kk][rg*8+u];
      #pragma unroll
      for (int v = 0; v < 8; ++v) bb[v] = Xs[kk][cg*8+v];
      #pragma unroll
      for (int u = 0; u < 8; ++u)
        #pragma unroll
        for (int v = 0; v < 8; ++v) acc[u][v] = fmaf(a[u], bb[v], acc[u][v]);
    }
    __syncthreads();
  }
  // epilogue 1: D[q][j] = xx_j - 2*dot
  {
    float xxv[8];
    #pragma unroll
    for (int v = 0; v < 8; ++v) xxv[v] = XXb[j0 + cg*8 + v];
    #pragma unroll
    for (int u = 0; u < 8; ++u) {
      float* po = D + (size_t)(q0 + rg*8 + u)*NPTS + j0 + cg*8;
      #pragma unroll
      for (int v = 0; v < 8; ++v) po[v] = fmaf(-2.f, acc[u][v], xxv[v]);
    }
  }
  // epilogue 2 (off-diagonal): D[j][q] = xx_q - 2*dot (register-transposed tile)
  if (ti != tj) {
    float xxq[8];
    #pragma unroll
    for (int u = 0; u < 8; ++u) xxq[u] = XXb[q0 + rg*8 + u];
    #pragma unroll
    for (int v = 0; v < 8; ++v) {
      float* po = D + (size_t)(j0 + cg*8 + v)*NPTS + q0 + rg*8;
      float4 w0, w1;
      w0.x = fmaf(-2.f, acc[0][v], xxq[0]);
      w0.y = fmaf(-2.f, acc[1][v], xxq[1]);
      w0.z = fmaf(-2.f, acc[2][v], xxq[2]);
      w0.w = fmaf(-2.f, acc[3][v], xxq[3]);
      w1.x = fmaf(-2.f, acc[4][v], xxq[4]);
      w1.y = fmaf(-2.f, acc[5][v], xxq[5]);
      w1.z = fmaf(-2.f, acc[6][v], xxq[6]);
      w1.w = fmaf(-2.f, acc[7][v], xxq[7]);
      *(float4*)po = w0;
      *(float4*)(po + 4) = w1;
    }
  }
}

// ---------------------------------------------------------------- exact wave-level 20th-smallest
// Per-lane top-S + pop-min. EXACTNESS: every candidate a lane discards is >= the
// lane's FINAL bd[S-1]. So if all lanes satisfy lane_max >= thr, no candidate < thr
// was discarded -> thr is the true 20th-smallest. safe=false -> caller retries S=20
// (unconditionally exact).
template<int S, typename F>
__device__ __forceinline__ float find_thr(F getd4, bool& safe) {
  float bd[S];
  #pragma unroll
  for (int t = 0; t < S; ++t) bd[t] = 1e30f;
  #pragma unroll 4
  for (int t = 0; t < 16; ++t) {
    float4 dv = getd4(t);
    float ds[4] = {dv.x, dv.y, dv.z, dv.w};
    #pragma unroll
    for (int e = 0; e < 4; ++e) {
      float cd = ds[e];
      #pragma unroll
      for (int s = S-1; s >= 1; --s) bd[s] = med3f(cd, bd[s-1], bd[s]);
      bd[0] = fminf(bd[0], cd);
    }
  }
  float lane_max = bd[S-1];
  float thr = 1e30f;
  int total = 0;
  #pragma unroll 1
  for (int r = 0; r < KNN; ++r) {
    float m = wave_min_f32_dpp(bd[0]);
    unsigned long long bal = __ballot(bd[0] == m);
    total += __popcll(bal);
    if (total >= KNN) { thr = m; break; }
    if (bd[0] == m) {
      #pragma unroll
      for (int s = 0; s < S-1; ++s) bd[s] = bd[s+1];
      bd[S-1] = 1e30f;
    }
  }
  safe = !__any(lane_max < thr);
  return thr;
}

// ---------------------------------------------------------------- xyz-space knn: LDS-staged candidates
// 8 queries/block (8 waves), whole batch's packed points (64 KB) staged once into LDS.
// Candidate mapping j = t*256 + e*64 + lane -> stride-16B ds_read_b128, conflict-free.
// Emitted SET identical to the scan version (thr is order-independent; set {d<thr} +
// smallest-j tie rule; downstream max-pool is order-blind).
__global__ __launch_bounds__(512) void knn_xyz(
    const float4* __restrict__ XTP4, int* __restrict__ IDX)
{
  __shared__ float4 pts4[NPTS];   // 64 KB
  int tid = threadIdx.x;
  int lane = tid & 63;
  int wv = tid >> 6;                    // 0..7
  int blk = blockIdx.x;
  int bq = blk >> 9;                    // 512 blocks per batch
  int ql = (blk & 511)*8 + wv;
  int qg = bq*NPTS + ql;
  const float4* Xb4 = XTP4 + (size_t)bq*NPTS;

  #pragma unroll
  for (int i = 0; i < 8; ++i)
    gld16(&Xb4[i*512 + tid], &pts4[i*512 + tid]);
  __syncthreads();   // drains vmcnt before reads

  float4 qp = pts4[ql];
  float qx = qp.x, qy = qp.y, qz = qp.z;

  auto key3 = [&](float4 p) -> float {
    float dot = qx*p.x;
    dot = fmaf(qy, p.y, dot);
    dot = fmaf(qz, p.z, dot);
    return fmaf(-2.f, dot, p.w);
  };
  auto getd4 = [&](int t) -> float4 {
    int jb = t*256 + lane;
    float4 r;
    r.x = key3(pts4[jb]);
    r.y = key3(pts4[jb+64]);
    r.z = key3(pts4[jb+128]);
    r.w = key3(pts4[jb+192]);
    return r;
  };

  bool safe;
  float thr = find_thr<8>(getd4, safe);
  if (!safe) { bool s2; thr = find_thr<KNN>(getd4, s2); }

  unsigned long long lml = (1ull << lane) - 1ull;
  int S = 0;
  int myj = 0x7fffffff;
  #pragma unroll 4
  for (int t = 0; t < 16; ++t) {
    float4 dv = getd4(t);
    float ds[4] = {dv.x, dv.y, dv.z, dv.w};
    int jb = t*256 + lane;
    #pragma unroll
    for (int e = 0; e < 4; ++e) {
      float d = ds[e];
      int j = jb + e*64;
      bool ps = d < thr;
      unsigned long long mk = __ballot(ps);
      int pos = S + __popcll(mk & lml);
      if (ps && pos < KNN) IDX[(size_t)qg*KNN + pos] = j;
      S += __popcll(mk);
      if (d == thr && j < myj) myj = j;
    }
  }
  int need = KNN - S;
  if (need == 1) {
    int mn = wave_min_i32_dpp(myj);
    if (lane == 0) IDX[(size_t)qg*KNN + S] = mn;
  } else if (need > 1) {
    if (lane == 0) {
      int taken = 0;
      for (int j = 0; j < NPTS && taken < need; ++j) {
        float d = key3(pts4[j]);
        if (d == thr) { IDX[(size_t)qg*KNN + S + taken] = j; ++taken; }
      }
    }
  }
}

// ---------------------------------------------------------------- feat-space knn select (reads D rows)
__global__ __launch_bounds__(256) void knn_select_feat(
    const float* __restrict__ D, int batch, int* __restrict__ IDX)
{
  int lane = threadIdx.x & 63;
  int ql = blockIdx.x*4 + (threadIdx.x >> 6);   // query local to batch
  int qg = batch*NPTS + ql;                     // global point id
  const float4* drow4 = (const float4*)(D + (size_t)ql*NPTS);

  auto getd4 = [&](int t) -> float4 {
    return drow4[t*64 + lane];
  };

  bool safe;
  float thr = find_thr<8>(getd4, safe);
  if (!safe) { bool s2; thr = find_thr<KNN>(getd4, s2); }

  unsigned long long lml = (1ull << lane) - 1ull;
  int S = 0;
  int myj = 0x7fffffff;
  #pragma unroll 4
  for (int t = 0; t < 16; ++t) {
    float4 dv = getd4(t);
    float ds[4] = {dv.x, dv.y, dv.z, dv.w};
    int jb = t*256 + lane*4;
    #pragma unroll
    for (int e = 0; e < 4; ++e) {
      float d = ds[e];
      int j = jb + e;
      bool ps = d < thr;
      unsigned long long mk = __ballot(ps);
      int pos = S + __popcll(mk & lml);
      if (ps && pos < KNN) IDX[(size_t)qg*KNN + pos] = j;
      S += __popcll(mk);
      if (d == thr && j < myj) myj = j;
    }
  }
  int need = KNN - S;
  if (need == 1) {
    int mn = wave_min_i32_dpp(myj);
    if (lane == 0) IDX[(size_t)qg*KNN + S] = mn;
  } else if (need > 1) {
    if (lane == 0) {
      int taken = 0;
      for (int j = 0; j < NPTS && taken < need; ++j) {
        float d = D[(size_t)ql*NPTS + j];
        if (d == thr) { IDX[(size_t)qg*KNN + S + taken] = j; ++taken; }
      }
    }
  }
}

// ---------------------------------------------------------------- f16x3 split MFMA GEMM (generic)
template<bool LRELU_, bool CM>
__global__ __launch_bounds__(256) void mfma_gemm(
    const _Float16* __restrict__ WH, const _Float16* __restrict__ WL,  // [Mtot][KT]
    int Mtot, int KT,
    const _Float16* __restrict__ FH, const _Float16* __restrict__ FL,  // [pt][fstride]
    int fstride, int foff,
    const float* __restrict__ bias,
    float* __restrict__ Out, int ostride)
{
  __shared__ _Float16 As[2][128*32];
  __shared__ _Float16 Bs[2][128*32];
  int tid = threadIdx.x;
  int lane = tid & 63, wave = tid >> 6;
  int wr = wave >> 1, wc = wave & 1;
  int rt = blockIdx.y * 128, ct = blockIdx.x * 128;

  int srow = tid >> 2;
  int skh  = (tid & 3) * 8;
  const _Float16* gA0 = WH + (size_t)(rt + srow)*KT + skh;
  const _Float16* gA1 = WL + (size_t)(rt + srow)*KT + skh;
  const _Float16* gB0 = FH + (size_t)(ct + srow)*fstride + foff + skh;
  const _Float16* gB1 = FL + (size_t)(ct + srow)*fstride + foff + skh;
  const size_t a2 = (size_t)64*KT;
  const size_t b2 = (size_t)64*fstride;
  _Float16* lA0 = &As[0][tid*8];
  _Float16* lA1 = &As[1][tid*8];
  _Float16* lB0 = &Bs[0][tid*8];
  _Float16* lB1 = &Bs[1][tid*8];

  f32x4 acc[4][4];
  #pragma unroll
  for (int m = 0; m < 4; ++m)
    #pragma unroll
    for (int n = 0; n < 4; ++n) acc[m][n] = (f32x4){0.f, 0.f, 0.f, 0.f};

  int fr = lane & 15;
  int kg = (lane >> 4) * 8;

  for (int k0 = 0; k0 < KT; k0 += 32) {
    gld16(gA0 + k0,      lA0);
    gld16(gA0 + k0 + a2, lA0 + 2048);
    gld16(gA1 + k0,      lA1);
    gld16(gA1 + k0 + a2, lA1 + 2048);
    gld16(gB0 + k0,      lB0);
    gld16(gB0 + k0 + b2, lB0 + 2048);
    gld16(gB1 + k0,      lB1);
    gld16(gB1 + k0 + b2, lB1 + 2048);
    __syncthreads();

    f16x8 ah[4], al[4], bh[4], bl[4];
    #pragma unroll
    for (int m = 0; m < 4; ++m) {
      int ro = (wr*64 + m*16 + fr)*32 + kg;
      ah[m] = *(const f16x8*)&As[0][ro];
      al[m] = *(const f16x8*)&As[1][ro];
    }
    #pragma unroll
    for (int n = 0; n < 4; ++n) {
      int co = (wc*64 + n*16 + fr)*32 + kg;
      bh[n] = *(const f16x8*)&Bs[0][co];
      bl[n] = *(const f16x8*)&Bs[1][co];
    }
    #pragma unroll
    for (int m = 0; m < 4; ++m)
      #pragma unroll
      for (int n = 0; n < 4; ++n) {
        acc[m][n] = __builtin_amdgcn_mfma_f32_16x16x32_f16(ah[m], bh[n], acc[m][n], 0, 0, 0);
        acc[m][n] = __builtin_amdgcn_mfma_f32_16x16x32_f16(ah[m], bl[n], acc[m][n], 0, 0, 0);
        acc[m][n] = __builtin_amdgcn_mfma_f32_16x16x32_f16(al[m], bh[n], acc[m][n], 0, 0, 0);
      }
    __syncthreads();
  }

  int rowg = (lane >> 4) * 4;
  if (CM) {
    int b = ct >> 12, n0 = ct & (NPTS-1);
    #pragma unroll
    for (int m = 0; m < 4; ++m) {
      int rbase = rt + wr*64 + m*16 + rowg;
      #pragma unroll
      for (int r4 = 0; r4 < 4; ++r4) {
        int r = rbase + r4;
        float bv = bias[r];
        float* po = Out + ((size_t)b*Mtot + r)*NPTS + n0 + wc*64 + fr;
        #pragma unroll
        for (int n = 0; n < 4; ++n) {
          float v = acc[m][n][r4] + bv;
          if (LRELU_) v = lrelu_f(v);
          po[n*16] = v;
        }
      }
    }
  } else {
    #pragma unroll
    for (int n = 0; n < 4; ++n) {
      int pt = ct + wc*64 + n*16 + fr;
      #pragma unroll
      for (int m = 0; m < 4; ++m) {
        int r0 = rt + wr*64 + m*16 + rowg;
        float4 v;
        v.x = acc[m][n][0] + bias[r0];
        v.y = acc[m][n][1] + bias[r0+1];
        v.z = acc[m][n][2] + bias[r0+2];
        v.w = acc[m][n][3] + bias[r0+3];
        if (LRELU_) { v.x = lrelu_f(v.x); v.y = lrelu_f(v.y); v.z = lrelu_f(v.z); v.w = lrelu_f(v.w); }
        *(float4*)&Out[(size_t)pt*ostride + r0] = v;
      }
    }
  }
}

// ---------------------------------------------------------------- fused gather + dg2 MFMA + x1/x2 group-max
__global__ __launch_bounds__(256) void dg2_fused(
    const _Float16* __restrict__ W2H, const _Float16* __restrict__ W2L, // [128][128]
    const float* __restrict__ UV1,      // [BN][256] (U|V)
    const int* __restrict__ IDXF,       // [BN][KNN]
    const float* __restrict__ bias,     // bdg2 [128]
    _Float16* __restrict__ FFH, _Float16* __restrict__ FFL)
{
  constexpr int RS = 136;
  __shared__ __align__(16) unsigned char smem[43520];
  _Float16* HsH = (_Float16*)smem;            // [80][RS]
  _Float16* HsL = (_Float16*)(smem + 21760);  // [80][RS]
  float*    Cs  = (float*)smem;               // [128][84] epilogue reuse
  __shared__ int js[80];
  __shared__ float4 mxs[128];

  int tid = threadIdx.x;
  int lane = tid & 63, wave = tid >> 6;
  size_t pt0 = (size_t)blockIdx.x * 4;
  size_t bbase = (pt0 >> 12) << 12;

  if (tid < 80) js[tid] = IDXF[pt0*KNN + tid];

  int fr = lane & 15, kg = (lane >> 4) * 8;
  f16x8 ah[2][4], al[2][4];
  #pragma unroll
  for (int m = 0; m < 2; ++m) {
    int row = wave*32 + m*16 + fr;
    #pragma unroll
    for (int ks = 0; ks < 4; ++ks) {
      ah[m][ks] = *(const f16x8*)&W2H[row*128 + ks*32 + kg];
      al[m][ks] = *(const f16x8*)&W2L[row*128 + ks*32 + kg];
    }
  }
  __syncthreads();   // js visible

  {
    int g = (tid >> 5) & 3, half = tid >> 7, c4 = tid & 31;
    size_t ptg = pt0 + g;
    float4 vv = *(const float4*)&UV1[ptg*256 + 128 + c4*4];
    float4 mx = make_float4(-1e30f, -1e30f, -1e30f, -1e30f);
    #pragma unroll
    for (int k = 0; k < 10; ++k) {
      int row = g*20 + half*10 + k;
      int j = js[row];
      float4 u = *(const float4*)&UV1[(bbase + (size_t)j)*256 + c4*4];
      float h0 = lrelu_f(u.x + vv.x);
      float h1 = lrelu_f(u.y + vv.y);
      float h2 = lrelu_f(u.z + vv.z);
      float h3 = lrelu_f(u.w + vv.w);
      f16x4 hh, hl;
      hh[0] = (_Float16)h0; hl[0] = (_Float16)(h0 - (float)hh[0]);
      hh[1] = (_Float16)h1; hl[1] = (_Float16)(h1 - (float)hh[1]);
      hh[2] = (_Float16)h2; hl[2] = (_Float16)(h2 - (float)hh[2]);
      hh[3] = (_Float16)h3; hl[3] = (_Float16)(h3 - (float)hh[3]);
      *(f16x4*)&HsH[row*RS + c4*4] = hh;
      *(f16x4*)&HsL[row*RS + c4*4] = hl;
      mx.x = fmaxf(mx.x, h0); mx.y = fmaxf(mx.y, h1);
      mx.z = fmaxf(mx.z, h2); mx.w = fmaxf(mx.w, h3);
    }
    if (half == 1) mxs[(g << 5) | c4] = mx;
    __syncthreads();
    if (half == 0) {
      float4 o = mxs[(g << 5) | c4];
      mx.x = fmaxf(mx.x, o.x); mx.y = fmaxf(mx.y, o.y);
      mx.z = fmaxf(mx.z, o.z); mx.w = fmaxf(mx.w, o.w);
      split_store(FFH, FFL, ptg*512 + c4*4 + 0, mx.x);
      split_store(FFH, FFL, ptg*512 + c4*4 + 1, mx.y);
      split_store(FFH, FFL, ptg*512 + c4*4 + 2, mx.z);
      split_store(FFH, FFL, ptg*512 + c4*4 + 3, mx.w);
    }
  }

  f32x4 acc[2][5];
  #pragma unroll
  for (int m = 0; m < 2; ++m)
    #pragma unroll
    for (int n = 0; n < 5; ++n) acc[m][n] = (f32x4){0.f, 0.f, 0.f, 0.f};

  #pragma unroll
  for (int ks = 0; ks < 4; ++ks) {
    f16x8 bh[5], bl[5];
    #pragma unroll
    for (int n = 0; n < 5; ++n) {
      int ro = (n*16 + fr)*RS + ks*32 + kg;
      bh[n] = *(const f16x8*)&HsH[ro];
      bl[n] = *(const f16x8*)&HsL[ro];
    }
    #pragma unroll
    for (int m = 0; m < 2; ++m)
      #pragma unroll
      for (int n = 0; n < 5; ++n) {
        acc[m][n] = __builtin_amdgcn_mfma_f32_16x16x32_f16(ah[m][ks], bh[n], acc[m][n], 0, 0, 0);
        acc[m][n] = __builtin_amdgcn_mfma_f32_16x16x32_f16(ah[m][ks], bl[n], acc[m][n], 0, 0, 0);
        acc[m][n] = __builtin_amdgcn_mfma_f32_16x16x32_f16(al[m][ks], bh[n], acc[m][n], 0, 0, 0);
      }
  }
  __syncthreads();

  int rowg = (lane >> 4) * 4;
  #pragma unroll
  for (int m = 0; m < 2; ++m) {
    int r = wave*32 + m*16 + rowg;
    #pragma unroll
    for (int n = 0; n < 5; ++n) {
      int p = n*16 + fr;
      #pragma unroll
      for (int q = 0; q < 4; ++q) Cs[(r+q)*84 + p] = acc[m][n][q];
    }
  }
  __syncthreads();

  #pragma unroll
  for (int t = 0; t < 2; ++t) {
    int task = tid + t*256;
    int r = task & 127, g = task >> 7;
    const float* cr = &Cs[r*84 + g*20];
    float m = cr[0];
    #pragma unroll
    for (int k = 1; k < 20; ++k) m = fmaxf(m, cr[k]);
    float v = lrelu_f(m + bias[r]);
    split_store(FFH, FFL, (pt0 + g)*512 + 128 + r, v);
  }
}

// ---------------------------------------------------------------- sn block: one point per block
__global__ __launch_bounds__(256) void sn_gather(
    const float* __restrict__ UV2, const int* __restrict__ IDXX,
    _Float16* __restrict__ FFH, _Float16* __restrict__ FFL)
{
  int tid = threadIdx.x;   // channel 0..255
  size_t pt = blockIdx.x;
  size_t bb = (pt >> 12) << 12;
  __shared__ int js[KNN];
  if (tid < KNN) js[tid] = IDXX[pt*KNN + tid];
  __syncthreads();
  float v = UV2[pt*512 + 256 + tid];
  float m = -1e30f;
  #pragma unroll
  for (int k = 0; k < KNN; ++k) {
    float h = lrelu_f(UV2[(bb + (size_t)js[k])*512 + tid] + v);
    m = fmaxf(m, h);
  }
  split_store(FFH, FFL, pt*512 + 256 + tid, m);
}

// ---------------------------------------------------------------- farthest point sampling (reg-resident, shuffle argmax)
__global__ __launch_bounds__(512) void fps_kernel(
    const float* __restrict__ xyz, int* __restrict__ SIDX)
{
  int b = blockIdx.x, tid = threadIdx.x;
  int lane = tid & 63, wave = tid >> 6;   // 8 waves
  const float* p = xyz + (size_t)b*3*NPTS;
  float px[8], py[8], pz[8], dist[8];
  #pragma unroll
  for (int j = 0; j < 8; ++j) {
    int i = tid + j*512;
    px[j] = p[i]; py[j] = p[NPTS+i]; pz[j] = p[2*NPTS+i];
    dist[j] = 1e10f;
  }
  __shared__ float bv[8], bx[8], by[8], bz[8];
  __shared__ int bi[8];
  float cx = p[0], cy = p[NPTS], cz = p[2*NPTS];
  int far = 0;
  for (int it = 0; it < 32; ++it) {
    if (tid == 0) SIDX[b*32 + it] = far;
    float lm = -1e30f, lx = 0.f, ly = 0.f, lz = 0.f; int li = 0;
    #pragma unroll
    for (int j = 0; j < 8; ++j) {
      float dx = px[j]-cx, dy = py[j]-cy, dz = pz[j]-cz;
      float d = dx*dx + dy*dy + dz*dz;
      float dm = fminf(dist[j], d);
      dist[j] = dm;
      bool sw = dm > lm;
      lm = sw ? dm : lm;
      li = sw ? (tid + j*512) : li;
      lx = sw ? px[j] : lx; ly = sw ? py[j] : ly; lz = sw ? pz[j] : lz;
    }
    #pragma unroll
    for (int k = 1; k < 64; k <<= 1) {
      float om = __shfl_xor(lm, k, 64);
      int   oi = __shfl_xor(li, k, 64);
      float ox = __shfl_xor(lx, k, 64);
      float oy = __shfl_xor(ly, k, 64);
      float oz = __shfl_xor(lz, k, 64);
      bool tk = (om > lm) || (om == lm && oi < li);
      lm = tk ? om : lm; li = tk ? oi : li;
      lx = tk ? ox : lx; ly = tk ? oy : ly; lz = tk ? oz : lz;
    }
    if (lane == 0) { bv[wave] = lm; bi[wave] = li; bx[wave] = lx; by[wave] = ly; bz[wave] = lz; }
    __syncthreads();
    float m0 = bv[0]; int i0 = bi[0];
    float X = bx[0], Y = by[0], Z = bz[0];
    #pragma unroll
    for (int w = 1; w < 8; ++w) {
      bool tk = (bv[w] > m0) || (bv[w] == m0 && bi[w] < i0);
      m0 = tk ? bv[w] : m0; i0 = tk ? bi[w] : i0;
      X = tk ? bx[w] : X; Y = tk ? by[w] : Y; Z = tk ? bz[w] : Z;
    }
    far = i0; cx = X; cy = Y; cz = Z;
    __syncthreads();
  }
}

// ---------------------------------------------------------------- k-farthest (8) among 32 samples
__global__ __launch_bounds__(128) void kfn_kernel(
    const float* __restrict__ xyz, const int* __restrict__ SIDX,
    int* __restrict__ NIDX)
{
  int tid = threadIdx.x;     // 0..127
  int b = tid >> 5, i = tid & 31;
  const float* p = xyz + (size_t)b*3*NPTS;
  __shared__ float sx[4][32], sy[4][32], sz[4][32];
  {
    int si = SIDX[b*32 + i];
    sx[b][i] = p[si]; sy[b][i] = p[NPTS+si]; sz[b][i] = p[2*NPTS+si];
  }
  __syncthreads();
  float xi = sx[b][i], yi = sy[b][i], zi = sz[b][i];
  float xxi = xi*xi + yi*yi + zi*zi;
  float bd[8]; int bi_[8];
  #pragma unroll
  for (int t = 0; t < 8; ++t) { bd[t] = -1e30f; bi_[t] = 0; }
  for (int j = 0; j < 32; ++j) {
    float xj = sx[b][j], yj = sy[b][j], zj = sz[b][j];
    float xxj = xj*xj + yj*yj + zj*zj;
    float d = xxi - 2.f*(xi*xj + yi*yj + zi*zj) + xxj;
    if (d > bd[7]) {
      float cd = d; int ci = j;
      #pragma unroll
      for (int t = 0; t < 8; ++t) {
        bool sw = bd[t] < cd;
        float nv = sw ? cd : bd[t];
        int   ni = sw ? ci : bi_[t];
        float ov = sw ? bd[t] : cd;
        int   oi = sw ? bi_[t] : ci;
        bd[t] = nv; bi_[t] = ni; cd = ov; ci = oi;
      }
    }
  }
  size_t o = (size_t)(b*32 + i)*8;
  #pragma unroll
  for (int t = 0; t < 8; ++t) NIDX[o+t] = bi_[t];
}

// ---------------------------------------------------------------- triplet terms
__global__ __launch_bounds__(256) void trip_kernel(
    const float* __restrict__ es0, const float* __restrict__ et0,
    const int* __restrict__ SIDX, const int* __restrict__ NIDX,
    float* __restrict__ ACC)
{
  int bi_ = blockIdx.x; int b = bi_ >> 5;
  int tid = threadIdx.x;
  __shared__ int js[8];
  __shared__ int ssi;
  if (tid == 0) ssi = SIDX[bi_];
  if (tid < 8) js[tid] = SIDX[b*32 + NIDX[bi_*8 + tid]];
  __syncthreads();
  int si = ssi;
  const float* es = es0 + (size_t)b*1024*NPTS;
  const float* et = et0 + (size_t)b*1024*NPTS;
  float sp = 0.f, sn = 0.f;
  for (int c = tid; c < 1024; c += 256) {
    const float* erow = et + (size_t)c*NPTS;
    float s = es[(size_t)c*NPTS + si];
    float d0 = s - erow[si]; sp += d0*d0;
    #pragma unroll
    for (int t = 0; t < 8; ++t) { float d1 = s - erow[js[t]]; sn += d1*d1; }
  }
  __shared__ float r1[256], r2[256];
  r1[tid] = sp; r2[tid] = sn; __syncthreads();
  for (int s2 = 128; s2 > 0; s2 >>= 1) {
    if (tid < s2) { r1[tid] += r1[tid+s2]; r2[tid] += r2[tid+s2]; }
    __syncthreads();
  }
  if (tid == 0) {
    float dp = r1[0] * (1.f/1024.f);
    float dn = r2[0] * (1.f/8192.f);
    float tr = fmaxf(0.f, 1.f - dn/(1.f + dp));
    atomicAdd(&ACC[0], tr);
  }
}

// ---------------------------------------------------------------- stats stage A: mse/mae + per-point partial norms
__global__ __launch_bounds__(256) void stats_a(
    const float* __restrict__ es0, const float* __restrict__ et0,
    float* __restrict__ PS, float* __restrict__ PT, float* __restrict__ ACC)
{
  int tid = threadIdx.x;
  int p = tid & 63, g = tid >> 6;
  int pt0 = (blockIdx.x & 255) * 64;     // 256 point-tiles of 64
  int chunk = blockIdx.x >> 8;           // 8 channel-chunks of 128
  int b = pt0 >> 12, n0 = pt0 & (NPTS-1);
  const float* es = es0 + (size_t)b*1024*NPTS + n0;
  const float* et = et0 + (size_t)b*1024*NPTS + n0;
  float ss = 0.f, tt = 0.f, sq = 0.f, ab = 0.f;
  int c0 = chunk * 128;
  for (int c = c0 + g; c < c0 + 128; c += 4) {
    float s = es[(size_t)c*NPTS + p];
    float t = et[(size_t)c*NPTS + p];
    ss += s*s; tt += t*t;
    float d = s - t;
    sq += d*d; ab += fabsf(d);
  }
  __shared__ float rs[4][64], rt[4][64];
  __shared__ float red[256];
  rs[g][p] = ss; rt[g][p] = tt;
  red[tid] = sq;
  __syncthreads();
  for (int s2 = 128; s2 > 0; s2 >>= 1) {
    if (tid < s2) red[tid] += red[tid+s2];
    __syncthreads();
  }
  if (tid == 0) atomicAdd(&ACC[3], red[0]);
  __syncthreads();
  red[tid] = ab; __syncthreads();
  for (int s2 = 128; s2 > 0; s2 >>= 1) {
    if (tid < s2) red[tid] += red[tid+s2];
    __syncthreads();
  }
  if (tid == 0) atomicAdd(&ACC[4], red[0]);
  if (tid < 64) {
    atomicAdd(&PS[pt0 + tid], rs[0][tid]+rs[1][tid]+rs[2][tid]+rs[3][tid]);
    atomicAdd(&PT[pt0 + tid], rt[0][tid]+rt[1][tid]+rt[2][tid]+rt[3][tid]);
  }
}

// ---------------------------------------------------------------- stats stage B: norm terms
__global__ __launch_bounds__(256) void stats_b(
    const float* __restrict__ PS, const float* __restrict__ PT,
    float* __restrict__ ACC)
{
  int i = blockIdx.x * 256 + threadIdx.x;
  float a = sqrtf(PS[i]) - 1.f;
  float c = sqrtf(PT[i]) - 1.f;
  float av = a*a, cv = c*c;
  #pragma unroll
  for (int s2 = 32; s2 > 0; s2 >>= 1) {
    av += __shfl_down(av, s2, 64);
    cv += __shfl_down(cv, s2, 64);
  }
  __shared__ float r1[4], r2[4];
  int lane = threadIdx.x & 63, wave = threadIdx.x >> 6;
  if (lane == 0) { r1[wave] = av; r2[wave] = cv; }
  __syncthreads();
  if (threadIdx.x == 0) {
    atomicAdd(&ACC[1], r1[0]+r1[1]+r1[2]+r1[3]);
    atomicAdd(&ACC[2], r2[0]+r2[1]+r2[2]+r2[3]);
  }
}

// ---------------------------------------------------------------- finalize scalars
__global__ void finalize_kernel(const float* __restrict__ ACC, float* __restrict__ o3) {
  if (threadIdx.x == 0 && blockIdx.x == 0) {
    float ln1 = sqrtf(ACC[1] * (1.f/16384.f));
    float ln2 = sqrtf(ACC[2] * (1.f/16384.f));
    o3[0] = ACC[0]*(1.f/128.f) + (ln1 + ln2)*0.5f*0.03f;
    o3[1] = ACC[3] * (1.f/4194304.f);   // mean((s-t)^2)*B
    o3[2] = ACC[4] * (1.f/4194304.f);   // mean(|s-t|)*B
  }
}

// ================================================================ host
extern "C" void kernel_launch(void* const* d_in, const int* in_sizes, int n_in,
                              void* d_out, int out_size, void* d_ws, size_t ws_size,
                              hipStream_t stream) {
  (void)in_sizes; (void)n_in; (void)out_size; (void)ws_size;
  const float* src  = (const float*)d_in[0];
  const float* tgt  = (const float*)d_in[1];
  const float* w1   = (const float*)d_in[2];
  const float* b1   = (const float*)d_in[3];
  const float* w2   = (const float*)d_in[4];
  const float* b2   = (const float*)d_in[5];
  const float* wdg1 = (const float*)d_in[6];
  const float* bdg1 = (const float*)d_in[7];
  const float* wdg2 = (const float*)d_in[8];
  const float* bdg2 = (const float*)d_in[9];
  const float* wsn1 = (const float*)d_in[10];
  const float* bsn1 = (const float*)d_in[11];
  const float* w3   = (const float*)d_in[12];
  const float* b3   = (const float*)d_in[13];
  float* out = (float*)d_out;

  float* ws = (float*)d_ws;
  float*  XTP  = ws;                                   // BN*4 (float4 x,y,z,xx)
  float*  XT2  = XTP + (size_t)BN*4;                   // BN*64
  float*  XX2  = XT2 + (size_t)BN*64;                  // BN
  float*  UV1  = XX2 + BN;                             // BN*256
  _Float16* FFH = (_Float16*)(UV1 + (size_t)BN*256);   // BN*512 halves
  _Float16* FFL = FFH + (size_t)BN*512;                // BN*512 halves
  float*  UV2  = (float*)(FFL + (size_t)BN*512);       // BN*512
  float*  Dbuf = (float*)FFH;                          // NPTS*NPTS fp32 == FFH+FFL+UV2 (dead then)
  _Float16* XT2H = (_Float16*)(UV2 + (size_t)BN*512);  // BN*64 halves
  _Float16* XT2L = XT2H + (size_t)BN*64;               // BN*64 halves
  int*    IDXF = (int*)(XT2L + (size_t)BN*64);         // BN*KNN
  int*    IDXX = IDXF + (size_t)BN*KNN;                // BN*KNN
  _Float16* W2H = (_Float16*)(IDXX + (size_t)BN*KNN);  // 128*128 halves
  _Float16* W2L = W2H + 128*128;                       // 128*128 halves
  float*  BUV1 = (float*)(W2L + 128*128);              // 256
  float*  BUV2 = BUV1 + 256;                           // 512
  _Float16* W3H = (_Float16*)(BUV2 + 512);             // 1024*512 halves
  _Float16* W3L = W3H + 1024*512;
  _Float16* WH1 = W3L + 1024*512;                      // 256*64 halves
  _Float16* WL1 = WH1 + 256*64;
  _Float16* WH2 = WL1 + 256*64;                        // 512*128 halves
  _Float16* WL2 = WH2 + 512*128;
  int*    SIDX = (int*)(WL2 + 512*128);                // NB*32
  int*    NIDX = SIDX + NB*32;                         // NB*32*8
  float*  ACC  = (float*)(NIDX + NB*32*8);             // 8
  float*  PS   = ACC + 8;                              // BN
  float*  PT   = PS + BN;                              // BN

  prep_weights<<<2048, 256, 0, stream>>>(wdg1, bdg1, wdg2, wsn1, bsn1, w3,
                                         W2H, W2L, BUV1, BUV2,
                                         W3H, W3L, WH1, WL1, WH2, WL2);

  auto run_cloud = [&](const float* xyz, float* emb) {
    pack_xyz<<<BN/256, 256, 0, stream>>>(xyz, (float4*)XTP);
    conv12<<<BN/4, 256, 0, stream>>>(xyz, w1, b1, w2, b2, XT2, XX2, XT2H, XT2L);
    // xyz-space KNN: LDS-staged, 8 queries/block, all batches in one launch
    knn_xyz<<<BN/8, 512, 0, stream>>>((const float4*)XTP, IDXX);
    // feature-space KNN: per batch (single D buffer), triangular dist GEMM
    for (int bb = 0; bb < NB; ++bb) {
      dist_gemm_tri<<<528, 256, 0, stream>>>(
          XT2 + (size_t)bb*NPTS*64, XX2 + (size_t)bb*NPTS, Dbuf);
      knn_select_feat<<<NPTS/4, 256, 0, stream>>>(Dbuf, bb, IDXF);
    }
    // UV1 = WEFF1 * XT2 (f16x3 MFMA)
    mfma_gemm<false,false><<<dim3(BN/128, 2), 256, 0, stream>>>(
        WH1, WL1, 256, 64, XT2H, XT2L, 64, 0, BUV1, UV1, 256);
    // fused gather + dg2 MFMA -> x1 (cols 0..127) + x2 (cols 128..255)
    dg2_fused<<<BN/4, 256, 0, stream>>>(W2H, W2L, UV1, IDXF, bdg2, FFH, FFL);
    // UV2 = WEFF2 * x2 (f16x3 MFMA)
    mfma_gemm<false,false><<<dim3(BN/128, 4), 256, 0, stream>>>(
        WH2, WL2, 512, 128, FFH, FFL, 512, 128, BUV2, UV2, 512);
    sn_gather<<<BN, 256, 0, stream>>>(UV2, IDXX, FFH, FFL);
    // emb = lrelu(W3 * feat + b3), channel-major (f16x3 MFMA)
    mfma_gemm<true,true><<<dim3(BN/128, 8), 256, 0, stream>>>(
        W3H, W3L, 1024, 512, FFH, FFL, 512, 0, b3, emb, 0);
  };

  float* emb_s = out;
  float* emb_t = out + (size_t)BN*1024;
  run_cloud(src, emb_s);
  run_cloud(tgt, emb_t);

  hipMemsetAsync(ACC, 0, (8 + 2*BN)*sizeof(float), stream);
  fps_kernel<<<NB, 512, 0, stream>>>(src, SIDX);
  kfn_kernel<<<1, 128, 0, stream>>>(src, SIDX, NIDX);
  trip_kernel<<<NB*32, 256, 0, stream>>>(emb_s, emb_t, SIDX, NIDX, ACC);
  stats_a<<<2048, 256, 0, stream>>>(emb_s, emb_t, PS, PT, ACC);
  stats_b<<<BN/256, 256, 0, stream>>>(PS, PT, ACC);
  finalize_kernel<<<1, 64, 0, stream>>>(ACC, out + (size_t)2*BN*1024);
}

// Round 7
// 1216.532 us; speedup vs baseline: 1.8845x; 1.0287x over previous
//
#include <hip/hip_runtime.h>
#include <cstdint>

#define NB 4
#define NPTS 4096
#define KNN 20
#define BN (NB*NPTS)   // 16384

typedef _Float16 f16x8 __attribute__((ext_vector_type(8)));
typedef _Float16 f16x4 __attribute__((ext_vector_type(4)));
typedef float    f32x4 __attribute__((ext_vector_type(4)));

__device__ __forceinline__ float lrelu_f(float x) { return x > 0.f ? x : 0.2f * x; }

__device__ __forceinline__ float med3f(float c, float lo, float hi) {
#if defined(__has_builtin)
#if __has_builtin(__builtin_amdgcn_fmed3f)
  return __builtin_amdgcn_fmed3f(c, lo, hi);
#else
  return fminf(fmaxf(c, lo), hi);
#endif
#else
  return fminf(fmaxf(c, lo), hi);
#endif
}

// async global->LDS, 16B per lane (lane-linear LDS dest required)
__device__ __forceinline__ void gld16(const void* g, void* l) {
  __builtin_amdgcn_global_load_lds(
      (const __attribute__((address_space(1))) void*)g,
      (__attribute__((address_space(3))) void*)l,
      16, 0, 0);
}

__device__ __forceinline__ void split_store(_Float16* __restrict__ H, _Float16* __restrict__ L,
                                            size_t idx, float v) {
  _Float16 h = (_Float16)v;
  H[idx] = h;
  L[idx] = (_Float16)(v - (float)h);
}

// ---------------------------------------------------------------- DPP wave reductions (VALU pipe, no LDS round-trips)
__device__ __forceinline__ float wave_min_f32_dpp(float x) {
  int xi = __float_as_int(x); int t;
  t = __builtin_amdgcn_update_dpp(xi, xi, 0x111, 0xf, 0xf, false);
  x = fminf(x, __int_as_float(t)); xi = __float_as_int(x);
  t = __builtin_amdgcn_update_dpp(xi, xi, 0x112, 0xf, 0xf, false);
  x = fminf(x, __int_as_float(t)); xi = __float_as_int(x);
  t = __builtin_amdgcn_update_dpp(xi, xi, 0x114, 0xf, 0xf, false);
  x = fminf(x, __int_as_float(t)); xi = __float_as_int(x);
  t = __builtin_amdgcn_update_dpp(xi, xi, 0x118, 0xf, 0xf, false);
  x = fminf(x, __int_as_float(t)); xi = __float_as_int(x);
  t = __builtin_amdgcn_update_dpp(xi, xi, 0x142, 0xf, 0xf, false);
  x = fminf(x, __int_as_float(t)); xi = __float_as_int(x);
  t = __builtin_amdgcn_update_dpp(xi, xi, 0x143, 0xf, 0xf, false);
  x = fminf(x, __int_as_float(t)); xi = __float_as_int(x);
  return __int_as_float(__builtin_amdgcn_readlane(xi, 63));
}

__device__ __forceinline__ int wave_min_i32_dpp(int x) {
  int t;
  t = __builtin_amdgcn_update_dpp(x, x, 0x111, 0xf, 0xf, false); x = min(x, t);
  t = __builtin_amdgcn_update_dpp(x, x, 0x112, 0xf, 0xf, false); x = min(x, t);
  t = __builtin_amdgcn_update_dpp(x, x, 0x114, 0xf, 0xf, false); x = min(x, t);
  t = __builtin_amdgcn_update_dpp(x, x, 0x118, 0xf, 0xf, false); x = min(x, t);
  t = __builtin_amdgcn_update_dpp(x, x, 0x142, 0xf, 0xf, false); x = min(x, t);
  t = __builtin_amdgcn_update_dpp(x, x, 0x143, 0xf, 0xf, false); x = min(x, t);
  return __builtin_amdgcn_readlane(x, 63);
}

// ---------------------------------------------------------------- prep weights
__global__ __launch_bounds__(256) void prep_weights(
    const float* __restrict__ wdg1, const float* __restrict__ bdg1,
    const float* __restrict__ wdg2,
    const float* __restrict__ wsn1, const float* __restrict__ bsn1,
    const float* __restrict__ w3,
    _Float16* __restrict__ W2H, _Float16* __restrict__ W2L,
    float* __restrict__ BUV1, float* __restrict__ BUV2,
    _Float16* __restrict__ W3H, _Float16* __restrict__ W3L,
    _Float16* __restrict__ WH1, _Float16* __restrict__ WL1,
    _Float16* __restrict__ WH2, _Float16* __restrict__ WL2)
{
  int i = blockIdx.x * 256 + threadIdx.x;
  if (i < 512*1024) {           // w3 is already [M=1024][K=512]
    float v = w3[i];
    split_store(W3H, W3L, i, v);
  }
  if (i < 256*64) {             // WEFF1: [M=256][K=64]
    int r = i >> 6, c = i & 63;
    float v = (r < 128) ? wdg1[r*128 + c]
                        : (wdg1[(r-128)*128 + 64 + c] - wdg1[(r-128)*128 + c]);
    split_store(WH1, WL1, i, v);
  }
  if (i < 512*128) {            // WEFF2: [M=512][K=128]
    int r = i >> 7, c = i & 127;
    float v = (r < 256) ? wsn1[r*256 + c]
                        : (wsn1[(r-256)*256 + 128 + c] - wsn1[(r-256)*256 + c]);
    split_store(WH2, WL2, i, v);
  }
  if (i < 128*128) split_store(W2H, W2L, i, wdg2[i]);  // [M=o][K=c] identity layout
  if (i < 256) BUV1[i] = (i < 128) ? 0.f : bdg1[i-128];
  if (i < 512) BUV2[i] = (i < 256) ? 0.f : bsn1[i-256];
}

// ---------------------------------------------------------------- conv1 + conv2 fused (3->64->64) + packed xyz out
__global__ __launch_bounds__(256) void conv12(
    const float* __restrict__ xyz,
    const float* __restrict__ w1, const float* __restrict__ b1,
    const float* __restrict__ w2, const float* __restrict__ b2,
    float* __restrict__ XT2, float* __restrict__ XX2,
    _Float16* __restrict__ XT2H, _Float16* __restrict__ XT2L,
    float4* __restrict__ XTP4)
{
  __shared__ float w2t[64*65];
  __shared__ float h1s[4][64];
  int tid = threadIdx.x;
  for (int i = tid; i < 4096; i += 256) {
    int o = i >> 6, c = i & 63;
    w2t[c*65 + o] = w2[i];
  }
  int g = tid >> 6, o = tid & 63;
  int pt = blockIdx.x*4 + g;
  int b = pt >> 12, n = pt & (NPTS-1);
  const float* p = xyz + (size_t)b*3*NPTS;
  float x = p[n], y = p[NPTS+n], z = p[2*NPTS+n];
  if (o == 0) {   // fused pack_xyz (x,y,z live in every lane of this group)
    float4 v; v.x = x; v.y = y; v.z = z; v.w = x*x + y*y + z*z;
    XTP4[pt] = v;
  }
  float h1 = b1[o] + w1[o*3]*x + w1[o*3+1]*y + w1[o*3+2]*z;
  h1 = lrelu_f(h1);
  __syncthreads();
  h1s[g][o] = h1;
  __syncthreads();
  float acc = b2[o];
  #pragma unroll
  for (int c = 0; c < 64; ++c) acc = fmaf(w2t[c*65+o], h1s[g][c], acc);
  acc = lrelu_f(acc);
  XT2[(size_t)pt*64 + o] = acc;
  split_store(XT2H, XT2L, (size_t)pt*64 + o, acc);
  float v = acc*acc;
  #pragma unroll
  for (int s = 32; s > 0; s >>= 1) v += __shfl_down(v, s, 64);
  if (o == 0) XX2[pt] = v;
}

// ---------------------------------------------------------------- triangular distance GEMM
// blockIdx.y = local batch within group; batch = g0 + blockIdx.y.
__global__ __launch_bounds__(256) void dist_gemm_tri(
    const float* __restrict__ XT2, const float* __restrict__ XX2,
    float* __restrict__ Dbase, int g0)
{
  int lb = blockIdx.y;
  int batch = g0 + lb;
  const float* XQ  = XT2 + (size_t)batch*NPTS*64;
  const float* XXb = XX2 + (size_t)batch*NPTS;
  float* D = Dbase + (size_t)lb*NPTS*NPTS;

  // map blockIdx.x in [0,528) -> (ti,tj) with ti<=tj, NT=32
  int r = blockIdx.x, ti = 0;
  #pragma unroll 1
  for (;;) { int len = 32 - ti; if (r < len) break; r -= len; ++ti; }
  int tj = ti + r;
  int q0 = ti * 128, j0 = tj * 128;

  __shared__ float Qs[16][132];
  __shared__ float Xs[16][132];
  int tid = threadIdx.x;
  int rg = tid & 15, cg = tid >> 4;
  float acc[8][8];
  #pragma unroll
  for (int u = 0; u < 8; ++u)
    #pragma unroll
    for (int v = 0; v < 8; ++v) acc[u][v] = 0.f;

  for (int c0 = 0; c0 < 64; c0 += 16) {
    #pragma unroll
    for (int i = 0; i < 8; ++i) {
      int idx = tid + i*256;
      int kk = idx & 15, p = idx >> 4;
      Qs[kk][p] = XQ[(size_t)(q0+p)*64 + c0 + kk];
      Xs[kk][p] = XQ[(size_t)(j0+p)*64 + c0 + kk];
    }
    __syncthreads();
    #pragma unroll
    for (int kk = 0; kk < 16; ++kk) {
      float a[8], bb[8];
      #pragma unroll
      for (int u = 0; u < 8; ++u) a[u] = Qs[kk][rg*8+u];
      #pragma unroll
      for (int v = 0; v < 8; ++v) bb[v] = Xs[kk][cg*8+v];
      #pragma unroll
      for (int u = 0; u < 8; ++u)
        #pragma unroll
        for (int v = 0; v < 8; ++v) acc[u][v] = fmaf(a[u], bb[v], acc[u][v]);
    }
    __syncthreads();
  }
  // epilogue 1: D[q][j] = xx_j - 2*dot
  {
    float xxv[8];
    #pragma unroll
    for (int v = 0; v < 8; ++v) xxv[v] = XXb[j0 + cg*8 + v];
    #pragma unroll
    for (int u = 0; u < 8; ++u) {
      float* po = D + (size_t)(q0 + rg*8 + u)*NPTS + j0 + cg*8;
      #pragma unroll
      for (int v = 0; v < 8; ++v) po[v] = fmaf(-2.f, acc[u][v], xxv[v]);
    }
  }
  // epilogue 2 (off-diagonal): D[j][q] = xx_q - 2*dot (register-transposed tile)
  if (ti != tj) {
    float xxq[8];
    #pragma unroll
    for (int u = 0; u < 8; ++u) xxq[u] = XXb[q0 + rg*8 + u];
    #pragma unroll
    for (int v = 0; v < 8; ++v) {
      float* po = D + (size_t)(j0 + cg*8 + v)*NPTS + q0 + rg*8;
      float4 w0, w1;
      w0.x = fmaf(-2.f, acc[0][v], xxq[0]);
      w0.y = fmaf(-2.f, acc[1][v], xxq[1]);
      w0.z = fmaf(-2.f, acc[2][v], xxq[2]);
      w0.w = fmaf(-2.f, acc[3][v], xxq[3]);
      w1.x = fmaf(-2.f, acc[4][v], xxq[4]);
      w1.y = fmaf(-2.f, acc[5][v], xxq[5]);
      w1.z = fmaf(-2.f, acc[6][v], xxq[6]);
      w1.w = fmaf(-2.f, acc[7][v], xxq[7]);
      *(float4*)po = w0;
      *(float4*)(po + 4) = w1;
    }
  }
}

// ---------------------------------------------------------------- exact wave-level 20th-smallest
// Per-lane top-S + pop-min. EXACTNESS: every candidate a lane discards is >= the
// lane's FINAL bd[S-1]. So if all lanes satisfy lane_max >= thr, no candidate < thr
// was discarded -> thr is the true 20th-smallest. safe=false -> caller retries S=20
// (unconditionally exact).
template<int S, typename F>
__device__ __forceinline__ float find_thr(F getd4, bool& safe) {
  float bd[S];
  #pragma unroll
  for (int t = 0; t < S; ++t) bd[t] = 1e30f;
  #pragma unroll 4
  for (int t = 0; t < 16; ++t) {
    float4 dv = getd4(t);
    float ds[4] = {dv.x, dv.y, dv.z, dv.w};
    #pragma unroll
    for (int e = 0; e < 4; ++e) {
      float cd = ds[e];
      #pragma unroll
      for (int s = S-1; s >= 1; --s) bd[s] = med3f(cd, bd[s-1], bd[s]);
      bd[0] = fminf(bd[0], cd);
    }
  }
  float lane_max = bd[S-1];
  float thr = 1e30f;
  int total = 0;
  #pragma unroll 1
  for (int r = 0; r < KNN; ++r) {
    float m = wave_min_f32_dpp(bd[0]);
    unsigned long long bal = __ballot(bd[0] == m);
    total += __popcll(bal);
    if (total >= KNN) { thr = m; break; }
    if (bd[0] == m) {
      #pragma unroll
      for (int s = 0; s < S-1; ++s) bd[s] = bd[s+1];
      bd[S-1] = 1e30f;
    }
  }
  safe = !__any(lane_max < thr);
  return thr;
}

// ---------------------------------------------------------------- xyz-space knn: LDS-staged candidates
__global__ __launch_bounds__(512) void knn_xyz(
    const float4* __restrict__ XTP4, int* __restrict__ IDX)
{
  __shared__ float4 pts4[NPTS];   // 64 KB
  int tid = threadIdx.x;
  int lane = tid & 63;
  int wv = tid >> 6;                    // 0..7
  int blk = blockIdx.x;
  int bq = blk >> 9;                    // 512 blocks per batch
  int ql = (blk & 511)*8 + wv;
  int qg = bq*NPTS + ql;
  const float4* Xb4 = XTP4 + (size_t)bq*NPTS;

  #pragma unroll
  for (int i = 0; i < 8; ++i)
    gld16(&Xb4[i*512 + tid], &pts4[i*512 + tid]);
  __syncthreads();   // drains vmcnt before reads

  float4 qp = pts4[ql];
  float qx = qp.x, qy = qp.y, qz = qp.z;

  auto key3 = [&](float4 p) -> float {
    float dot = qx*p.x;
    dot = fmaf(qy, p.y, dot);
    dot = fmaf(qz, p.z, dot);
    return fmaf(-2.f, dot, p.w);
  };
  auto getd4 = [&](int t) -> float4 {
    int jb = t*256 + lane;
    float4 r;
    r.x = key3(pts4[jb]);
    r.y = key3(pts4[jb+64]);
    r.z = key3(pts4[jb+128]);
    r.w = key3(pts4[jb+192]);
    return r;
  };

  bool safe;
  float thr = find_thr<8>(getd4, safe);
  if (!safe) { bool s2; thr = find_thr<KNN>(getd4, s2); }

  unsigned long long lml = (1ull << lane) - 1ull;
  int S = 0;
  int myj = 0x7fffffff;
  #pragma unroll 4
  for (int t = 0; t < 16; ++t) {
    float4 dv = getd4(t);
    float ds[4] = {dv.x, dv.y, dv.z, dv.w};
    int jb = t*256 + lane;
    #pragma unroll
    for (int e = 0; e < 4; ++e) {
      float d = ds[e];
      int j = jb + e*64;
      bool ps = d < thr;
      unsigned long long mk = __ballot(ps);
      int pos = S + __popcll(mk & lml);
      if (ps && pos < KNN) IDX[(size_t)qg*KNN + pos] = j;
      S += __popcll(mk);
      if (d == thr && j < myj) myj = j;
    }
  }
  int need = KNN - S;
  if (need == 1) {
    int mn = wave_min_i32_dpp(myj);
    if (lane == 0) IDX[(size_t)qg*KNN + S] = mn;
  } else if (need > 1) {
    if (lane == 0) {
      int taken = 0;
      for (int j = 0; j < NPTS && taken < need; ++j) {
        float d = key3(pts4[j]);
        if (d == thr) { IDX[(size_t)qg*KNN + S + taken] = j; ++taken; }
      }
    }
  }
}

// ---------------------------------------------------------------- feat-space knn select (reads D rows)
// blockIdx.y = local batch within group; batch = g0 + blockIdx.y.
__global__ __launch_bounds__(256) void knn_select_feat(
    const float* __restrict__ Dbase, int g0, int* __restrict__ IDX)
{
  int lb = blockIdx.y;
  int batch = g0 + lb;
  const float* D = Dbase + (size_t)lb*NPTS*NPTS;
  int lane = threadIdx.x & 63;
  int ql = blockIdx.x*4 + (threadIdx.x >> 6);   // query local to batch
  int qg = batch*NPTS + ql;                     // global point id
  const float4* drow4 = (const float4*)(D + (size_t)ql*NPTS);

  auto getd4 = [&](int t) -> float4 {
    return drow4[t*64 + lane];
  };

  bool safe;
  float thr = find_thr<8>(getd4, safe);
  if (!safe) { bool s2; thr = find_thr<KNN>(getd4, s2); }

  unsigned long long lml = (1ull << lane) - 1ull;
  int S = 0;
  int myj = 0x7fffffff;
  #pragma unroll 4
  for (int t = 0; t < 16; ++t) {
    float4 dv = getd4(t);
    float ds[4] = {dv.x, dv.y, dv.z, dv.w};
    int jb = t*256 + lane*4;
    #pragma unroll
    for (int e = 0; e < 4; ++e) {
      float d = ds[e];
      int j = jb + e;
      bool ps = d < thr;
      unsigned long long mk = __ballot(ps);
      int pos = S + __popcll(mk & lml);
      if (ps && pos < KNN) IDX[(size_t)qg*KNN + pos] = j;
      S += __popcll(mk);
      if (d == thr && j < myj) myj = j;
    }
  }
  int need = KNN - S;
  if (need == 1) {
    int mn = wave_min_i32_dpp(myj);
    if (lane == 0) IDX[(size_t)qg*KNN + S] = mn;
  } else if (need > 1) {
    if (lane == 0) {
      int taken = 0;
      for (int j = 0; j < NPTS && taken < need; ++j) {
        float d = D[(size_t)ql*NPTS + j];
        if (d == thr) { IDX[(size_t)qg*KNN + S + taken] = j; ++taken; }
      }
    }
  }
}

// ---------------------------------------------------------------- f16x3 split MFMA GEMM (generic)
template<bool LRELU_, bool CM>
__global__ __launch_bounds__(256) void mfma_gemm(
    const _Float16* __restrict__ WH, const _Float16* __restrict__ WL,  // [Mtot][KT]
    int Mtot, int KT,
    const _Float16* __restrict__ FH, const _Float16* __restrict__ FL,  // [pt][fstride]
    int fstride, int foff,
    const float* __restrict__ bias,
    float* __restrict__ Out, int ostride)
{
  __shared__ _Float16 As[2][128*32];
  __shared__ _Float16 Bs[2][128*32];
  int tid = threadIdx.x;
  int lane = tid & 63, wave = tid >> 6;
  int wr = wave >> 1, wc = wave & 1;
  int rt = blockIdx.y * 128, ct = blockIdx.x * 128;

  int srow = tid >> 2;
  int skh  = (tid & 3) * 8;
  const _Float16* gA0 = WH + (size_t)(rt + srow)*KT + skh;
  const _Float16* gA1 = WL + (size_t)(rt + srow)*KT + skh;
  const _Float16* gB0 = FH + (size_t)(ct + srow)*fstride + foff + skh;
  const _Float16* gB1 = FL + (size_t)(ct + srow)*fstride + foff + skh;
  const size_t a2 = (size_t)64*KT;
  const size_t b2 = (size_t)64*fstride;
  _Float16* lA0 = &As[0][tid*8];
  _Float16* lA1 = &As[1][tid*8];
  _Float16* lB0 = &Bs[0][tid*8];
  _Float16* lB1 = &Bs[1][tid*8];

  f32x4 acc[4][4];
  #pragma unroll
  for (int m = 0; m < 4; ++m)
    #pragma unroll
    for (int n = 0; n < 4; ++n) acc[m][n] = (f32x4){0.f, 0.f, 0.f, 0.f};

  int fr = lane & 15;
  int kg = (lane >> 4) * 8;

  for (int k0 = 0; k0 < KT; k0 += 32) {
    gld16(gA0 + k0,      lA0);
    gld16(gA0 + k0 + a2, lA0 + 2048);
    gld16(gA1 + k0,      lA1);
    gld16(gA1 + k0 + a2, lA1 + 2048);
    gld16(gB0 + k0,      lB0);
    gld16(gB0 + k0 + b2, lB0 + 2048);
    gld16(gB1 + k0,      lB1);
    gld16(gB1 + k0 + b2, lB1 + 2048);
    __syncthreads();

    f16x8 ah[4], al[4], bh[4], bl[4];
    #pragma unroll
    for (int m = 0; m < 4; ++m) {
      int ro = (wr*64 + m*16 + fr)*32 + kg;
      ah[m] = *(const f16x8*)&As[0][ro];
      al[m] = *(const f16x8*)&As[1][ro];
    }
    #pragma unroll
    for (int n = 0; n < 4; ++n) {
      int co = (wc*64 + n*16 + fr)*32 + kg;
      bh[n] = *(const f16x8*)&Bs[0][co];
      bl[n] = *(const f16x8*)&Bs[1][co];
    }
    #pragma unroll
    for (int m = 0; m < 4; ++m)
      #pragma unroll
      for (int n = 0; n < 4; ++n) {
        acc[m][n] = __builtin_amdgcn_mfma_f32_16x16x32_f16(ah[m], bh[n], acc[m][n], 0, 0, 0);
        acc[m][n] = __builtin_amdgcn_mfma_f32_16x16x32_f16(ah[m], bl[n], acc[m][n], 0, 0, 0);
        acc[m][n] = __builtin_amdgcn_mfma_f32_16x16x32_f16(al[m], bh[n], acc[m][n], 0, 0, 0);
      }
    __syncthreads();
  }

  int rowg = (lane >> 4) * 4;
  if (CM) {
    int b = ct >> 12, n0 = ct & (NPTS-1);
    #pragma unroll
    for (int m = 0; m < 4; ++m) {
      int rbase = rt + wr*64 + m*16 + rowg;
      #pragma unroll
      for (int r4 = 0; r4 < 4; ++r4) {
        int r = rbase + r4;
        float bv = bias[r];
        float* po = Out + ((size_t)b*Mtot + r)*NPTS + n0 + wc*64 + fr;
        #pragma unroll
        for (int n = 0; n < 4; ++n) {
          float v = acc[m][n][r4] + bv;
          if (LRELU_) v = lrelu_f(v);
          po[n*16] = v;
        }
      }
    }
  } else {
    #pragma unroll
    for (int n = 0; n < 4; ++n) {
      int pt = ct + wc*64 + n*16 + fr;
      #pragma unroll
      for (int m = 0; m < 4; ++m) {
        int r0 = rt + wr*64 + m*16 + rowg;
        float4 v;
        v.x = acc[m][n][0] + bias[r0];
        v.y = acc[m][n][1] + bias[r0+1];
        v.z = acc[m][n][2] + bias[r0+2];
        v.w = acc[m][n][3] + bias[r0+3];
        if (LRELU_) { v.x = lrelu_f(v.x); v.y = lrelu_f(v.y); v.z = lrelu_f(v.z); v.w = lrelu_f(v.w); }
        *(float4*)&Out[(size_t)pt*ostride + r0] = v;
      }
    }
  }
}

// ---------------------------------------------------------------- fused gather + dg2 MFMA + x1/x2 group-max
__global__ __launch_bounds__(256) void dg2_fused(
    const _Float16* __restrict__ W2H, const _Float16* __restrict__ W2L, // [128][128]
    const float* __restrict__ UV1,      // [BN][256] (U|V)
    const int* __restrict__ IDXF,       // [BN][KNN]
    const float* __restrict__ bias,     // bdg2 [128]
    _Float16* __restrict__ FFH, _Float16* __restrict__ FFL)
{
  constexpr int RS = 136;
  __shared__ __align__(16) unsigned char smem[43520];
  _Float16* HsH = (_Float16*)smem;            // [80][RS]
  _Float16* HsL = (_Float16*)(smem + 21760);  // [80][RS]
  float*    Cs  = (float*)smem;               // [128][84] epilogue reuse
  __shared__ int js[80];
  __shared__ float4 mxs[128];

  int tid = threadIdx.x;
  int lane = tid & 63, wave = tid >> 6;
  size_t pt0 = (size_t)blockIdx.x * 4;
  size_t bbase = (pt0 >> 12) << 12;

  if (tid < 80) js[tid] = IDXF[pt0*KNN + tid];

  int fr = lane & 15, kg = (lane >> 4) * 8;
  f16x8 ah[2][4], al[2][4];
  #pragma unroll
  for (int m = 0; m < 2; ++m) {
    int row = wave*32 + m*16 + fr;
    #pragma unroll
    for (int ks = 0; ks < 4; ++ks) {
      ah[m][ks] = *(const f16x8*)&W2H[row*128 + ks*32 + kg];
      al[m][ks] = *(const f16x8*)&W2L[row*128 + ks*32 + kg];
    }
  }
  __syncthreads();   // js visible

  {
    int g = (tid >> 5) & 3, half = tid >> 7, c4 = tid & 31;
    size_t ptg = pt0 + g;
    float4 vv = *(const float4*)&UV1[ptg*256 + 128 + c4*4];
    float4 mx = make_float4(-1e30f, -1e30f, -1e30f, -1e30f);
    #pragma unroll
    for (int k = 0; k < 10; ++k) {
      int row = g*20 + half*10 + k;
      int j = js[row];
      float4 u = *(const float4*)&UV1[(bbase + (size_t)j)*256 + c4*4];
      float h0 = lrelu_f(u.x + vv.x);
      float h1 = lrelu_f(u.y + vv.y);
      float h2 = lrelu_f(u.z + vv.z);
      float h3 = lrelu_f(u.w + vv.w);
      f16x4 hh, hl;
      hh[0] = (_Float16)h0; hl[0] = (_Float16)(h0 - (float)hh[0]);
      hh[1] = (_Float16)h1; hl[1] = (_Float16)(h1 - (float)hh[1]);
      hh[2] = (_Float16)h2; hl[2] = (_Float16)(h2 - (float)hh[2]);
      hh[3] = (_Float16)h3; hl[3] = (_Float16)(h3 - (float)hh[3]);
      *(f16x4*)&HsH[row*RS + c4*4] = hh;
      *(f16x4*)&HsL[row*RS + c4*4] = hl;
      mx.x = fmaxf(mx.x, h0); mx.y = fmaxf(mx.y, h1);
      mx.z = fmaxf(mx.z, h2); mx.w = fmaxf(mx.w, h3);
    }
    if (half == 1) mxs[(g << 5) | c4] = mx;
    __syncthreads();
    if (half == 0) {
      float4 o = mxs[(g << 5) | c4];
      mx.x = fmaxf(mx.x, o.x); mx.y = fmaxf(mx.y, o.y);
      mx.z = fmaxf(mx.z, o.z); mx.w = fmaxf(mx.w, o.w);
      split_store(FFH, FFL, ptg*512 + c4*4 + 0, mx.x);
      split_store(FFH, FFL, ptg*512 + c4*4 + 1, mx.y);
      split_store(FFH, FFL, ptg*512 + c4*4 + 2, mx.z);
      split_store(FFH, FFL, ptg*512 + c4*4 + 3, mx.w);
    }
  }

  f32x4 acc[2][5];
  #pragma unroll
  for (int m = 0; m < 2; ++m)
    #pragma unroll
    for (int n = 0; n < 5; ++n) acc[m][n] = (f32x4){0.f, 0.f, 0.f, 0.f};

  #pragma unroll
  for (int ks = 0; ks < 4; ++ks) {
    f16x8 bh[5], bl[5];
    #pragma unroll
    for (int n = 0; n < 5; ++n) {
      int ro = (n*16 + fr)*RS + ks*32 + kg;
      bh[n] = *(const f16x8*)&HsH[ro];
      bl[n] = *(const f16x8*)&HsL[ro];
    }
    #pragma unroll
    for (int m = 0; m < 2; ++m)
      #pragma unroll
      for (int n = 0; n < 5; ++n) {
        acc[m][n] = __builtin_amdgcn_mfma_f32_16x16x32_f16(ah[m][ks], bh[n], acc[m][n], 0, 0, 0);
        acc[m][n] = __builtin_amdgcn_mfma_f32_16x16x32_f16(ah[m][ks], bl[n], acc[m][n], 0, 0, 0);
        acc[m][n] = __builtin_amdgcn_mfma_f32_16x16x32_f16(al[m][ks], bh[n], acc[m][n], 0, 0, 0);
      }
  }
  __syncthreads();

  int rowg = (lane >> 4) * 4;
  #pragma unroll
  for (int m = 0; m < 2; ++m) {
    int r = wave*32 + m*16 + rowg;
    #pragma unroll
    for (int n = 0; n < 5; ++n) {
      int p = n*16 + fr;
      #pragma unroll
      for (int q = 0; q < 4; ++q) Cs[(r+q)*84 + p] = acc[m][n][q];
    }
  }
  __syncthreads();

  #pragma unroll
  for (int t = 0; t < 2; ++t) {
    int task = tid + t*256;
    int r = task & 127, g = task >> 7;
    const float* cr = &Cs[r*84 + g*20];
    float m = cr[0];
    #pragma unroll
    for (int k = 1; k < 20; ++k) m = fmaxf(m, cr[k]);
    float v = lrelu_f(m + bias[r]);
    split_store(FFH, FFL, (pt0 + g)*512 + 128 + r, v);
  }
}

// ---------------------------------------------------------------- sn block: one point per block
__global__ __launch_bounds__(256) void sn_gather(
    const float* __restrict__ UV2, const int* __restrict__ IDXX,
    _Float16* __restrict__ FFH, _Float16* __restrict__ FFL)
{
  int tid = threadIdx.x;   // channel 0..255
  size_t pt = blockIdx.x;
  size_t bb = (pt >> 12) << 12;
  __shared__ int js[KNN];
  if (tid < KNN) js[tid] = IDXX[pt*KNN + tid];
  __syncthreads();
  float v = UV2[pt*512 + 256 + tid];
  float m = -1e30f;
  #pragma unroll
  for (int k = 0; k < KNN; ++k) {
    float h = lrelu_f(UV2[(bb + (size_t)js[k])*512 + tid] + v);
    m = fmaxf(m, h);
  }
  split_store(FFH, FFL, pt*512 + 256 + tid, m);
}

// ---------------------------------------------------------------- farthest point sampling (reg-resident, shuffle argmax)
__global__ __launch_bounds__(512) void fps_kernel(
    const float* __restrict__ xyz, int* __restrict__ SIDX)
{
  int b = blockIdx.x, tid = threadIdx.x;
  int lane = tid & 63, wave = tid >> 6;   // 8 waves
  const float* p = xyz + (size_t)b*3*NPTS;
  float px[8], py[8], pz[8], dist[8];
  #pragma unroll
  for (int j = 0; j < 8; ++j) {
    int i = tid + j*512;
    px[j] = p[i]; py[j] = p[NPTS+i]; pz[j] = p[2*NPTS+i];
    dist[j] = 1e10f;
  }
  __shared__ float bv[8], bx[8], by[8], bz[8];
  __shared__ int bi[8];
  float cx = p[0], cy = p[NPTS], cz = p[2*NPTS];
  int far = 0;
  for (int it = 0; it < 32; ++it) {
    if (tid == 0) SIDX[b*32 + it] = far;
    float lm = -1e30f, lx = 0.f, ly = 0.f, lz = 0.f; int li = 0;
    #pragma unroll
    for (int j = 0; j < 8; ++j) {
      float dx = px[j]-cx, dy = py[j]-cy, dz = pz[j]-cz;
      float d = dx*dx + dy*dy + dz*dz;
      float dm = fminf(dist[j], d);
      dist[j] = dm;
      bool sw = dm > lm;
      lm = sw ? dm : lm;
      li = sw ? (tid + j*512) : li;
      lx = sw ? px[j] : lx; ly = sw ? py[j] : ly; lz = sw ? pz[j] : lz;
    }
    #pragma unroll
    for (int k = 1; k < 64; k <<= 1) {
      float om = __shfl_xor(lm, k, 64);
      int   oi = __shfl_xor(li, k, 64);
      float ox = __shfl_xor(lx, k, 64);
      float oy = __shfl_xor(ly, k, 64);
      float oz = __shfl_xor(lz, k, 64);
      bool tk = (om > lm) || (om == lm && oi < li);
      lm = tk ? om : lm; li = tk ? oi : li;
      lx = tk ? ox : lx; ly = tk ? oy : ly; lz = tk ? oz : lz;
    }
    if (lane == 0) { bv[wave] = lm; bi[wave] = li; bx[wave] = lx; by[wave] = ly; bz[wave] = lz; }
    __syncthreads();
    float m0 = bv[0]; int i0 = bi[0];
    float X = bx[0], Y = by[0], Z = bz[0];
    #pragma unroll
    for (int w = 1; w < 8; ++w) {
      bool tk = (bv[w] > m0) || (bv[w] == m0 && bi[w] < i0);
      m0 = tk ? bv[w] : m0; i0 = tk ? bi[w] : i0;
      X = tk ? bx[w] : X; Y = tk ? by[w] : Y; Z = tk ? bz[w] : Z;
    }
    far = i0; cx = X; cy = Y; cz = Z;
    __syncthreads();
  }
}

// ---------------------------------------------------------------- k-farthest (8) among 32 samples
__global__ __launch_bounds__(128) void kfn_kernel(
    const float* __restrict__ xyz, const int* __restrict__ SIDX,
    int* __restrict__ NIDX)
{
  int tid = threadIdx.x;     // 0..127
  int b = tid >> 5, i = tid & 31;
  const float* p = xyz + (size_t)b*3*NPTS;
  __shared__ float sx[4][32], sy[4][32], sz[4][32];
  {
    int si = SIDX[b*32 + i];
    sx[b][i] = p[si]; sy[b][i] = p[NPTS+si]; sz[b][i] = p[2*NPTS+si];
  }
  __syncthreads();
  float xi = sx[b][i], yi = sy[b][i], zi = sz[b][i];
  float xxi = xi*xi + yi*yi + zi*zi;
  float bd[8]; int bi_[8];
  #pragma unroll
  for (int t = 0; t < 8; ++t) { bd[t] = -1e30f; bi_[t] = 0; }
  for (int j = 0; j < 32; ++j) {
    float xj = sx[b][j], yj = sy[b][j], zj = sz[b][j];
    float xxj = xj*xj + yj*yj + zj*zj;
    float d = xxi - 2.f*(xi*xj + yi*yj + zi*zj) + xxj;
    if (d > bd[7]) {
      float cd = d; int ci = j;
      #pragma unroll
      for (int t = 0; t < 8; ++t) {
        bool sw = bd[t] < cd;
        float nv = sw ? cd : bd[t];
        int   ni = sw ? ci : bi_[t];
        float ov = sw ? bd[t] : cd;
        int   oi = sw ? bi_[t] : ci;
        bd[t] = nv; bi_[t] = ni; cd = ov; ci = oi;
      }
    }
  }
  size_t o = (size_t)(b*32 + i)*8;
  #pragma unroll
  for (int t = 0; t < 8; ++t) NIDX[o+t] = bi_[t];
}

// ---------------------------------------------------------------- triplet terms
__global__ __launch_bounds__(256) void trip_kernel(
    const float* __restrict__ es0, const float* __restrict__ et0,
    const int* __restrict__ SIDX, const int* __restrict__ NIDX,
    float* __restrict__ ACC)
{
  int bi_ = blockIdx.x; int b = bi_ >> 5;
  int tid = threadIdx.x;
  __shared__ int js[8];
  __shared__ int ssi;
  if (tid == 0) ssi = SIDX[bi_];
  if (tid < 8) js[tid] = SIDX[b*32 + NIDX[bi_*8 + tid]];
  __syncthreads();
  int si = ssi;
  const float* es = es0 + (size_t)b*1024*NPTS;
  const float* et = et0 + (size_t)b*1024*NPTS;
  float sp = 0.f, sn = 0.f;
  for (int c = tid; c < 1024; c += 256) {
    const float* erow = et + (size_t)c*NPTS;
    float s = es[(size_t)c*NPTS + si];
    float d0 = s - erow[si]; sp += d0*d0;
    #pragma unroll
    for (int t = 0; t < 8; ++t) { float d1 = s - erow[js[t]]; sn += d1*d1; }
  }
  __shared__ float r1[256], r2[256];
  r1[tid] = sp; r2[tid] = sn; __syncthreads();
  for (int s2 = 128; s2 > 0; s2 >>= 1) {
    if (tid < s2) { r1[tid] += r1[tid+s2]; r2[tid] += r2[tid+s2]; }
    __syncthreads();
  }
  if (tid == 0) {
    float dp = r1[0] * (1.f/1024.f);
    float dn = r2[0] * (1.f/8192.f);
    float tr = fmaxf(0.f, 1.f - dn/(1.f + dp));
    atomicAdd(&ACC[0], tr);
  }
}

// ---------------------------------------------------------------- stats stage A: mse/mae + per-point partial norms
__global__ __launch_bounds__(256) void stats_a(
    const float* __restrict__ es0, const float* __restrict__ et0,
    float* __restrict__ PS, float* __restrict__ PT, float* __restrict__ ACC)
{
  int tid = threadIdx.x;
  int p = tid & 63, g = tid >> 6;
  int pt0 = (blockIdx.x & 255) * 64;     // 256 point-tiles of 64
  int chunk = blockIdx.x >> 8;           // 16 channel-chunks of 64
  int b = pt0 >> 12, n0 = pt0 & (NPTS-1);
  const float* es = es0 + (size_t)b*1024*NPTS + n0;
  const float* et = et0 + (size_t)b*1024*NPTS + n0;
  float ss = 0.f, tt = 0.f, sq = 0.f, ab = 0.f;
  int c0 = chunk * 64;
  for (int c = c0 + g; c < c0 + 64; c += 4) {
    float s = es[(size_t)c*NPTS + p];
    float t = et[(size_t)c*NPTS + p];
    ss += s*s; tt += t*t;
    float d = s - t;
    sq += d*d; ab += fabsf(d);
  }
  __shared__ float rs[4][64], rt[4][64];
  __shared__ float red[256];
  rs[g][p] = ss; rt[g][p] = tt;
  red[tid] = sq;
  __syncthreads();
  for (int s2 = 128; s2 > 0; s2 >>= 1) {
    if (tid < s2) red[tid] += red[tid+s2];
    __syncthreads();
  }
  if (tid == 0) atomicAdd(&ACC[3], red[0]);
  __syncthreads();
  red[tid] = ab; __syncthreads();
  for (int s2 = 128; s2 > 0; s2 >>= 1) {
    if (tid < s2) red[tid] += red[tid+s2];
    __syncthreads();
  }
  if (tid == 0) atomicAdd(&ACC[4], red[0]);
  if (tid < 64) {
    atomicAdd(&PS[pt0 + tid], rs[0][tid]+rs[1][tid]+rs[2][tid]+rs[3][tid]);
    atomicAdd(&PT[pt0 + tid], rt[0][tid]+rt[1][tid]+rt[2][tid]+rt[3][tid]);
  }
}

// ---------------------------------------------------------------- stats stage B: norm terms
__global__ __launch_bounds__(256) void stats_b(
    const float* __restrict__ PS, const float* __restrict__ PT,
    float* __restrict__ ACC)
{
  int i = blockIdx.x * 256 + threadIdx.x;
  float a = sqrtf(PS[i]) - 1.f;
  float c = sqrtf(PT[i]) - 1.f;
  float av = a*a, cv = c*c;
  #pragma unroll
  for (int s2 = 32; s2 > 0; s2 >>= 1) {
    av += __shfl_down(av, s2, 64);
    cv += __shfl_down(cv, s2, 64);
  }
  __shared__ float r1[4], r2[4];
  int lane = threadIdx.x & 63, wave = threadIdx.x >> 6;
  if (lane == 0) { r1[wave] = av; r2[wave] = cv; }
  __syncthreads();
  if (threadIdx.x == 0) {
    atomicAdd(&ACC[1], r1[0]+r1[1]+r1[2]+r1[3]);
    atomicAdd(&ACC[2], r2[0]+r2[1]+r2[2]+r2[3]);
  }
}

// ---------------------------------------------------------------- finalize scalars
__global__ void finalize_kernel(const float* __restrict__ ACC, float* __restrict__ o3) {
  if (threadIdx.x == 0 && blockIdx.x == 0) {
    float ln1 = sqrtf(ACC[1] * (1.f/16384.f));
    float ln2 = sqrtf(ACC[2] * (1.f/16384.f));
    o3[0] = ACC[0]*(1.f/128.f) + (ln1 + ln2)*0.5f*0.03f;
    o3[1] = ACC[3] * (1.f/4194304.f);   // mean((s-t)^2)*B
    o3[2] = ACC[4] * (1.f/4194304.f);   // mean(|s-t|)*B
  }
}

// ================================================================ host
extern "C" void kernel_launch(void* const* d_in, const int* in_sizes, int n_in,
                              void* d_out, int out_size, void* d_ws, size_t ws_size,
                              hipStream_t stream) {
  (void)in_sizes; (void)n_in; (void)out_size;
  const float* src  = (const float*)d_in[0];
  const float* tgt  = (const float*)d_in[1];
  const float* w1   = (const float*)d_in[2];
  const float* b1   = (const float*)d_in[3];
  const float* w2   = (const float*)d_in[4];
  const float* b2   = (const float*)d_in[5];
  const float* wdg1 = (const float*)d_in[6];
  const float* bdg1 = (const float*)d_in[7];
  const float* wdg2 = (const float*)d_in[8];
  const float* bdg2 = (const float*)d_in[9];
  const float* wsn1 = (const float*)d_in[10];
  const float* bsn1 = (const float*)d_in[11];
  const float* w3   = (const float*)d_in[12];
  const float* b3   = (const float*)d_in[13];
  float* out = (float*)d_out;

  float* ws = (float*)d_ws;
  float*  XTP  = ws;                                   // BN*4 (float4 x,y,z,xx)
  float*  XT2  = XTP + (size_t)BN*4;                   // BN*64
  float*  XX2  = XT2 + (size_t)BN*64;                  // BN
  float*  UV1  = XX2 + BN;                             // BN*256
  _Float16* FFH = (_Float16*)(UV1 + (size_t)BN*256);   // BN*512 halves
  _Float16* FFL = FFH + (size_t)BN*512;                // BN*512 halves
  float*  UV2  = (float*)(FFL + (size_t)BN*512);       // BN*512
  float*  Dbuf = (float*)FFH;                          // NPTS*NPTS fp32 == FFH+FFL+UV2 (dead then)
  _Float16* XT2H = (_Float16*)(UV2 + (size_t)BN*512);  // BN*64 halves
  _Float16* XT2L = XT2H + (size_t)BN*64;               // BN*64 halves
  int*    IDXF = (int*)(XT2L + (size_t)BN*64);         // BN*KNN
  int*    IDXX = IDXF + (size_t)BN*KNN;                // BN*KNN
  _Float16* W2H = (_Float16*)(IDXX + (size_t)BN*KNN);  // 128*128 halves
  _Float16* W2L = W2H + 128*128;                       // 128*128 halves
  float*  BUV1 = (float*)(W2L + 128*128);              // 256
  float*  BUV2 = BUV1 + 256;                           // 512
  _Float16* W3H = (_Float16*)(BUV2 + 512);             // 1024*512 halves
  _Float16* W3L = W3H + 1024*512;
  _Float16* WH1 = W3L + 1024*512;                      // 256*64 halves
  _Float16* WL1 = WH1 + 256*64;
  _Float16* WH2 = WL1 + 256*64;                        // 512*128 halves
  _Float16* WL2 = WH2 + 512*128;
  int*    SIDX = (int*)(WL2 + 512*128);                // NB*32
  int*    NIDX = SIDX + NB*32;                         // NB*32*8
  float*  ACC  = (float*)(NIDX + NB*32*8);             // 8
  float*  PS   = ACC + 8;                              // BN
  float*  PT   = PS + BN;                              // BN
  float*  Dmulti = PT + BN;                            // optional: nd x NPTS*NPTS

  // how many dedicated D buffers fit? cap at 2 (keeps live D within L3)
  size_t used_floats = (size_t)(Dmulti - ws);
  size_t avail_floats = (ws_size / sizeof(float) > used_floats)
                      ? ws_size / sizeof(float) - used_floats : 0;
  int nd = (int)(avail_floats / ((size_t)NPTS * NPTS));
  if (nd > 2) nd = 2;

  prep_weights<<<2048, 256, 0, stream>>>(wdg1, bdg1, wdg2, wsn1, bsn1, w3,
                                         W2H, W2L, BUV1, BUV2,
                                         W3H, W3L, WH1, WL1, WH2, WL2);

  auto run_cloud = [&](const float* xyz, float* emb) {
    conv12<<<BN/4, 256, 0, stream>>>(xyz, w1, b1, w2, b2, XT2, XX2, XT2H, XT2L,
                                     (float4*)XTP);
    // xyz-space KNN: LDS-staged, 8 queries/block, all batches in one launch
    knn_xyz<<<BN/8, 512, 0, stream>>>((const float4*)XTP, IDXX);
    // feature-space KNN: triangular dist GEMM + select, nd batches per launch-pair
    if (nd >= 2) {
      for (int g0 = 0; g0 < NB; g0 += 2) {
        dist_gemm_tri<<<dim3(528, 2), 256, 0, stream>>>(XT2, XX2, Dmulti, g0);
        knn_select_feat<<<dim3(NPTS/4, 2), 256, 0, stream>>>(Dmulti, g0, IDXF);
      }
    } else {
      for (int bb = 0; bb < NB; ++bb) {
        dist_gemm_tri<<<dim3(528, 1), 256, 0, stream>>>(XT2, XX2, Dbuf, bb);
        knn_select_feat<<<dim3(NPTS/4, 1), 256, 0, stream>>>(Dbuf, bb, IDXF);
      }
    }
    // UV1 = WEFF1 * XT2 (f16x3 MFMA)
    mfma_gemm<false,false><<<dim3(BN/128, 2), 256, 0, stream>>>(
        WH1, WL1, 256, 64, XT2H, XT2L, 64, 0, BUV1, UV1, 256);
    // fused gather + dg2 MFMA -> x1 (cols 0..127) + x2 (cols 128..255)
    dg2_fused<<<BN/4, 256, 0, stream>>>(W2H, W2L, UV1, IDXF, bdg2, FFH, FFL);
    // UV2 = WEFF2 * x2 (f16x3 MFMA)
    mfma_gemm<false,false><<<dim3(BN/128, 4), 256, 0, stream>>>(
        WH2, WL2, 512, 128, FFH, FFL, 512, 128, BUV2, UV2, 512);
    sn_gather<<<BN, 256, 0, stream>>>(UV2, IDXX, FFH, FFL);
    // emb = lrelu(W3 * feat + b3), channel-major (f16x3 MFMA)
    mfma_gemm<true,true><<<dim3(BN/128, 8), 256, 0, stream>>>(
        W3H, W3L, 1024, 512, FFH, FFL, 512, 0, b3, emb, 0);
  };

  float* emb_s = out;
  float* emb_t = out + (size_t)BN*1024;
  run_cloud(src, emb_s);
  run_cloud(tgt, emb_t);

  hipMemsetAsync(ACC, 0, (8 + 2*BN)*sizeof(float), stream);
  fps_kernel<<<NB, 512, 0, stream>>>(src, SIDX);
  kfn_kernel<<<1, 128, 0, stream>>>(src, SIDX, NIDX);
  trip_kernel<<<NB*32, 256, 0, stream>>>(emb_s, emb_t, SIDX, NIDX, ACC);
  stats_a<<<4096, 256, 0, stream>>>(emb_s, emb_t, PS, PT, ACC);
  stats_b<<<BN/256, 256, 0, stream>>>(PS, PT, ACC);
  finalize_kernel<<<1, 64, 0, stream>>>(ACC, out + (size_t)2*BN*1024);
}

// Round 8
// 1141.496 us; speedup vs baseline: 2.0084x; 1.0657x over previous
//
#include <hip/hip_runtime.h>
#include <cstdint>

#define NB 4
#define NPTS 4096
#define KNN 20
#define BN (NB*NPTS)   // 16384

typedef _Float16 f16x8 __attribute__((ext_vector_type(8)));
typedef _Float16 f16x4 __attribute__((ext_vector_type(4)));
typedef float    f32x4 __attribute__((ext_vector_type(4)));

__device__ __forceinline__ float lrelu_f(float x) { return x > 0.f ? x : 0.2f * x; }

__device__ __forceinline__ float med3f(float c, float lo, float hi) {
#if defined(__has_builtin)
#if __has_builtin(__builtin_amdgcn_fmed3f)
  return __builtin_amdgcn_fmed3f(c, lo, hi);
#else
  return fminf(fmaxf(c, lo), hi);
#endif
#else
  return fminf(fmaxf(c, lo), hi);
#endif
}

// async global->LDS, 16B per lane (lane-linear LDS dest required)
__device__ __forceinline__ void gld16(const void* g, void* l) {
  __builtin_amdgcn_global_load_lds(
      (const __attribute__((address_space(1))) void*)g,
      (__attribute__((address_space(3))) void*)l,
      16, 0, 0);
}

__device__ __forceinline__ void split_store(_Float16* __restrict__ H, _Float16* __restrict__ L,
                                            size_t idx, float v) {
  _Float16 h = (_Float16)v;
  H[idx] = h;
  L[idx] = (_Float16)(v - (float)h);
}

// ---------------------------------------------------------------- DPP wave reductions (VALU pipe, no LDS round-trips)
__device__ __forceinline__ float wave_min_f32_dpp(float x) {
  int xi = __float_as_int(x); int t;
  t = __builtin_amdgcn_update_dpp(xi, xi, 0x111, 0xf, 0xf, false);
  x = fminf(x, __int_as_float(t)); xi = __float_as_int(x);
  t = __builtin_amdgcn_update_dpp(xi, xi, 0x112, 0xf, 0xf, false);
  x = fminf(x, __int_as_float(t)); xi = __float_as_int(x);
  t = __builtin_amdgcn_update_dpp(xi, xi, 0x114, 0xf, 0xf, false);
  x = fminf(x, __int_as_float(t)); xi = __float_as_int(x);
  t = __builtin_amdgcn_update_dpp(xi, xi, 0x118, 0xf, 0xf, false);
  x = fminf(x, __int_as_float(t)); xi = __float_as_int(x);
  t = __builtin_amdgcn_update_dpp(xi, xi, 0x142, 0xf, 0xf, false);
  x = fminf(x, __int_as_float(t)); xi = __float_as_int(x);
  t = __builtin_amdgcn_update_dpp(xi, xi, 0x143, 0xf, 0xf, false);
  x = fminf(x, __int_as_float(t)); xi = __float_as_int(x);
  return __int_as_float(__builtin_amdgcn_readlane(xi, 63));
}

__device__ __forceinline__ int wave_min_i32_dpp(int x) {
  int t;
  t = __builtin_amdgcn_update_dpp(x, x, 0x111, 0xf, 0xf, false); x = min(x, t);
  t = __builtin_amdgcn_update_dpp(x, x, 0x112, 0xf, 0xf, false); x = min(x, t);
  t = __builtin_amdgcn_update_dpp(x, x, 0x114, 0xf, 0xf, false); x = min(x, t);
  t = __builtin_amdgcn_update_dpp(x, x, 0x118, 0xf, 0xf, false); x = min(x, t);
  t = __builtin_amdgcn_update_dpp(x, x, 0x142, 0xf, 0xf, false); x = min(x, t);
  t = __builtin_amdgcn_update_dpp(x, x, 0x143, 0xf, 0xf, false); x = min(x, t);
  return __builtin_amdgcn_readlane(x, 63);
}

// ---------------------------------------------------------------- prep weights
__global__ __launch_bounds__(256) void prep_weights(
    const float* __restrict__ wdg1, const float* __restrict__ bdg1,
    const float* __restrict__ wdg2,
    const float* __restrict__ wsn1, const float* __restrict__ bsn1,
    const float* __restrict__ w3,
    _Float16* __restrict__ W2H, _Float16* __restrict__ W2L,
    float* __restrict__ BUV1, float* __restrict__ BUV2,
    _Float16* __restrict__ W3H, _Float16* __restrict__ W3L,
    _Float16* __restrict__ WH1, _Float16* __restrict__ WL1,
    _Float16* __restrict__ WH2, _Float16* __restrict__ WL2)
{
  int i = blockIdx.x * 256 + threadIdx.x;
  if (i < 512*1024) {           // w3 is already [M=1024][K=512]
    float v = w3[i];
    split_store(W3H, W3L, i, v);
  }
  if (i < 256*64) {             // WEFF1: [M=256][K=64]
    int r = i >> 6, c = i & 63;
    float v = (r < 128) ? wdg1[r*128 + c]
                        : (wdg1[(r-128)*128 + 64 + c] - wdg1[(r-128)*128 + c]);
    split_store(WH1, WL1, i, v);
  }
  if (i < 512*128) {            // WEFF2: [M=512][K=128]
    int r = i >> 7, c = i & 127;
    float v = (r < 256) ? wsn1[r*256 + c]
                        : (wsn1[(r-256)*256 + 128 + c] - wsn1[(r-256)*256 + c]);
    split_store(WH2, WL2, i, v);
  }
  if (i < 128*128) split_store(W2H, W2L, i, wdg2[i]);  // [M=o][K=c] identity layout
  if (i < 256) BUV1[i] = (i < 128) ? 0.f : bdg1[i-128];
  if (i < 512) BUV2[i] = (i < 256) ? 0.f : bsn1[i-256];
}

// ---------------------------------------------------------------- conv1 + conv2 fused (3->64->64) + packed xyz out
__global__ __launch_bounds__(256) void conv12(
    const float* __restrict__ xyz,
    const float* __restrict__ w1, const float* __restrict__ b1,
    const float* __restrict__ w2, const float* __restrict__ b2,
    float* __restrict__ XT2, float* __restrict__ XX2,
    _Float16* __restrict__ XT2H, _Float16* __restrict__ XT2L,
    float4* __restrict__ XTP4)
{
  __shared__ float w2t[64*65];
  __shared__ float h1s[4][64];
  int tid = threadIdx.x;
  for (int i = tid; i < 4096; i += 256) {
    int o = i >> 6, c = i & 63;
    w2t[c*65 + o] = w2[i];
  }
  int g = tid >> 6, o = tid & 63;
  int pt = blockIdx.x*4 + g;
  int b = pt >> 12, n = pt & (NPTS-1);
  const float* p = xyz + (size_t)b*3*NPTS;
  float x = p[n], y = p[NPTS+n], z = p[2*NPTS+n];
  if (o == 0) {   // fused pack_xyz (x,y,z live in every lane of this group)
    float4 v; v.x = x; v.y = y; v.z = z; v.w = x*x + y*y + z*z;
    XTP4[pt] = v;
  }
  float h1 = b1[o] + w1[o*3]*x + w1[o*3+1]*y + w1[o*3+2]*z;
  h1 = lrelu_f(h1);
  __syncthreads();
  h1s[g][o] = h1;
  __syncthreads();
  float acc = b2[o];
  #pragma unroll
  for (int c = 0; c < 64; ++c) acc = fmaf(w2t[c*65+o], h1s[g][c], acc);
  acc = lrelu_f(acc);
  XT2[(size_t)pt*64 + o] = acc;
  split_store(XT2H, XT2L, (size_t)pt*64 + o, acc);
  float v = acc*acc;
  #pragma unroll
  for (int s = 32; s > 0; s >>= 1) v += __shfl_down(v, s, 64);
  if (o == 0) XX2[pt] = v;
}

// ---------------------------------------------------------------- triangular distance GEMM
// blockIdx.y = local batch within group; batch = g0 + blockIdx.y.
__global__ __launch_bounds__(256) void dist_gemm_tri(
    const float* __restrict__ XT2, const float* __restrict__ XX2,
    float* __restrict__ Dbase, int g0)
{
  int lb = blockIdx.y;
  int batch = g0 + lb;
  const float* XQ  = XT2 + (size_t)batch*NPTS*64;
  const float* XXb = XX2 + (size_t)batch*NPTS;
  float* D = Dbase + (size_t)lb*NPTS*NPTS;

  // map blockIdx.x in [0,528) -> (ti,tj) with ti<=tj, NT=32
  int r = blockIdx.x, ti = 0;
  #pragma unroll 1
  for (;;) { int len = 32 - ti; if (r < len) break; r -= len; ++ti; }
  int tj = ti + r;
  int q0 = ti * 128, j0 = tj * 128;

  __shared__ float Qs[16][132];
  __shared__ float Xs[16][132];
  int tid = threadIdx.x;
  int rg = tid & 15, cg = tid >> 4;
  float acc[8][8];
  #pragma unroll
  for (int u = 0; u < 8; ++u)
    #pragma unroll
    for (int v = 0; v < 8; ++v) acc[u][v] = 0.f;

  for (int c0 = 0; c0 < 64; c0 += 16) {
    #pragma unroll
    for (int i = 0; i < 8; ++i) {
      int idx = tid + i*256;
      int kk = idx & 15, p = idx >> 4;
      Qs[kk][p] = XQ[(size_t)(q0+p)*64 + c0 + kk];
      Xs[kk][p] = XQ[(size_t)(j0+p)*64 + c0 + kk];
    }
    __syncthreads();
    #pragma unroll
    for (int kk = 0; kk < 16; ++kk) {
      float a[8], bb[8];
      #pragma unroll
      for (int u = 0; u < 8; ++u) a[u] = Qs[kk][rg*8+u];
      #pragma unroll
      for (int v = 0; v < 8; ++v) bb[v] = Xs[kk][cg*8+v];
      #pragma unroll
      for (int u = 0; u < 8; ++u)
        #pragma unroll
        for (int v = 0; v < 8; ++v) acc[u][v] = fmaf(a[u], bb[v], acc[u][v]);
    }
    __syncthreads();
  }
  // epilogue 1: D[q][j] = xx_j - 2*dot
  {
    float xxv[8];
    #pragma unroll
    for (int v = 0; v < 8; ++v) xxv[v] = XXb[j0 + cg*8 + v];
    #pragma unroll
    for (int u = 0; u < 8; ++u) {
      float* po = D + (size_t)(q0 + rg*8 + u)*NPTS + j0 + cg*8;
      #pragma unroll
      for (int v = 0; v < 8; ++v) po[v] = fmaf(-2.f, acc[u][v], xxv[v]);
    }
  }
  // epilogue 2 (off-diagonal): D[j][q] = xx_q - 2*dot (register-transposed tile)
  if (ti != tj) {
    float xxq[8];
    #pragma unroll
    for (int u = 0; u < 8; ++u) xxq[u] = XXb[q0 + rg*8 + u];
    #pragma unroll
    for (int v = 0; v < 8; ++v) {
      float* po = D + (size_t)(j0 + cg*8 + v)*NPTS + q0 + rg*8;
      float4 w0, w1;
      w0.x = fmaf(-2.f, acc[0][v], xxq[0]);
      w0.y = fmaf(-2.f, acc[1][v], xxq[1]);
      w0.z = fmaf(-2.f, acc[2][v], xxq[2]);
      w0.w = fmaf(-2.f, acc[3][v], xxq[3]);
      w1.x = fmaf(-2.f, acc[4][v], xxq[4]);
      w1.y = fmaf(-2.f, acc[5][v], xxq[5]);
      w1.z = fmaf(-2.f, acc[6][v], xxq[6]);
      w1.w = fmaf(-2.f, acc[7][v], xxq[7]);
      *(float4*)po = w0;
      *(float4*)(po + 4) = w1;
    }
  }
}

// ---------------------------------------------------------------- exact wave-level 20th-smallest
// Per-lane top-S + pop-min. EXACTNESS: every candidate a lane discards is >= the
// lane's FINAL bd[S-1]. So if all lanes satisfy lane_max >= thr, no candidate < thr
// was discarded -> thr is the true 20th-smallest. safe=false -> caller retries S=20
// (unconditionally exact).
template<int S, typename F>
__device__ __forceinline__ float find_thr(F getd4, bool& safe) {
  float bd[S];
  #pragma unroll
  for (int t = 0; t < S; ++t) bd[t] = 1e30f;
  #pragma unroll 4
  for (int t = 0; t < 16; ++t) {
    float4 dv = getd4(t);
    float ds[4] = {dv.x, dv.y, dv.z, dv.w};
    #pragma unroll
    for (int e = 0; e < 4; ++e) {
      float cd = ds[e];
      #pragma unroll
      for (int s = S-1; s >= 1; --s) bd[s] = med3f(cd, bd[s-1], bd[s]);
      bd[0] = fminf(bd[0], cd);
    }
  }
  float lane_max = bd[S-1];
  float thr = 1e30f;
  int total = 0;
  #pragma unroll 1
  for (int r = 0; r < KNN; ++r) {
    float m = wave_min_f32_dpp(bd[0]);
    unsigned long long bal = __ballot(bd[0] == m);
    total += __popcll(bal);
    if (total >= KNN) { thr = m; break; }
    if (bd[0] == m) {
      #pragma unroll
      for (int s = 0; s < S-1; ++s) bd[s] = bd[s+1];
      bd[S-1] = 1e30f;
    }
  }
  safe = !__any(lane_max < thr);
  return thr;
}

// ---------------------------------------------------------------- xyz-space knn: LDS-staged candidates
__global__ __launch_bounds__(512) void knn_xyz(
    const float4* __restrict__ XTP4, int* __restrict__ IDX)
{
  __shared__ float4 pts4[NPTS];   // 64 KB
  int tid = threadIdx.x;
  int lane = tid & 63;
  int wv = tid >> 6;                    // 0..7
  int blk = blockIdx.x;
  int bq = blk >> 9;                    // 512 blocks per batch
  int ql = (blk & 511)*8 + wv;
  int qg = bq*NPTS + ql;
  const float4* Xb4 = XTP4 + (size_t)bq*NPTS;

  #pragma unroll
  for (int i = 0; i < 8; ++i)
    gld16(&Xb4[i*512 + tid], &pts4[i*512 + tid]);
  __syncthreads();   // drains vmcnt before reads

  float4 qp = pts4[ql];
  float qx = qp.x, qy = qp.y, qz = qp.z;

  auto key3 = [&](float4 p) -> float {
    float dot = qx*p.x;
    dot = fmaf(qy, p.y, dot);
    dot = fmaf(qz, p.z, dot);
    return fmaf(-2.f, dot, p.w);
  };
  auto getd4 = [&](int t) -> float4 {
    int jb = t*256 + lane;
    float4 r;
    r.x = key3(pts4[jb]);
    r.y = key3(pts4[jb+64]);
    r.z = key3(pts4[jb+128]);
    r.w = key3(pts4[jb+192]);
    return r;
  };

  bool safe;
  float thr = find_thr<8>(getd4, safe);
  if (!safe) { bool s2; thr = find_thr<KNN>(getd4, s2); }

  unsigned long long lml = (1ull << lane) - 1ull;
  int S = 0;
  int myj = 0x7fffffff;
  #pragma unroll 4
  for (int t = 0; t < 16; ++t) {
    float4 dv = getd4(t);
    float ds[4] = {dv.x, dv.y, dv.z, dv.w};
    int jb = t*256 + lane;
    #pragma unroll
    for (int e = 0; e < 4; ++e) {
      float d = ds[e];
      int j = jb + e*64;
      bool ps = d < thr;
      unsigned long long mk = __ballot(ps);
      int pos = S + __popcll(mk & lml);
      if (ps && pos < KNN) IDX[(size_t)qg*KNN + pos] = j;
      S += __popcll(mk);
      if (d == thr && j < myj) myj = j;
    }
  }
  int need = KNN - S;
  if (need == 1) {
    int mn = wave_min_i32_dpp(myj);
    if (lane == 0) IDX[(size_t)qg*KNN + S] = mn;
  } else if (need > 1) {
    if (lane == 0) {
      int taken = 0;
      for (int j = 0; j < NPTS && taken < need; ++j) {
        float d = key3(pts4[j]);
        if (d == thr) { IDX[(size_t)qg*KNN + S + taken] = j; ++taken; }
      }
    }
  }
}

// ---------------------------------------------------------------- feat-space knn select (reads D rows)
// blockIdx.y = local batch within group; batch = g0 + blockIdx.y.
__global__ __launch_bounds__(256) void knn_select_feat(
    const float* __restrict__ Dbase, int g0, int* __restrict__ IDX)
{
  int lb = blockIdx.y;
  int batch = g0 + lb;
  const float* D = Dbase + (size_t)lb*NPTS*NPTS;
  int lane = threadIdx.x & 63;
  int ql = blockIdx.x*4 + (threadIdx.x >> 6);   // query local to batch
  int qg = batch*NPTS + ql;                     // global point id
  const float4* drow4 = (const float4*)(D + (size_t)ql*NPTS);

  auto getd4 = [&](int t) -> float4 {
    return drow4[t*64 + lane];
  };

  bool safe;
  float thr = find_thr<8>(getd4, safe);
  if (!safe) { bool s2; thr = find_thr<KNN>(getd4, s2); }

  unsigned long long lml = (1ull << lane) - 1ull;
  int S = 0;
  int myj = 0x7fffffff;
  #pragma unroll 4
  for (int t = 0; t < 16; ++t) {
    float4 dv = getd4(t);
    float ds[4] = {dv.x, dv.y, dv.z, dv.w};
    int jb = t*256 + lane*4;
    #pragma unroll
    for (int e = 0; e < 4; ++e) {
      float d = ds[e];
      int j = jb + e;
      bool ps = d < thr;
      unsigned long long mk = __ballot(ps);
      int pos = S + __popcll(mk & lml);
      if (ps && pos < KNN) IDX[(size_t)qg*KNN + pos] = j;
      S += __popcll(mk);
      if (d == thr && j < myj) myj = j;
    }
  }
  int need = KNN - S;
  if (need == 1) {
    int mn = wave_min_i32_dpp(myj);
    if (lane == 0) IDX[(size_t)qg*KNN + S] = mn;
  } else if (need > 1) {
    if (lane == 0) {
      int taken = 0;
      for (int j = 0; j < NPTS && taken < need; ++j) {
        float d = D[(size_t)ql*NPTS + j];
        if (d == thr) { IDX[(size_t)qg*KNN + S + taken] = j; ++taken; }
      }
    }
  }
}

// ---------------------------------------------------------------- f16x3 split MFMA GEMM (generic)
template<bool LRELU_, bool CM>
__global__ __launch_bounds__(256) void mfma_gemm(
    const _Float16* __restrict__ WH, const _Float16* __restrict__ WL,  // [Mtot][KT]
    int Mtot, int KT,
    const _Float16* __restrict__ FH, const _Float16* __restrict__ FL,  // [pt][fstride]
    int fstride, int foff,
    const float* __restrict__ bias,
    float* __restrict__ Out, int ostride)
{
  __shared__ _Float16 As[2][128*32];
  __shared__ _Float16 Bs[2][128*32];
  int tid = threadIdx.x;
  int lane = tid & 63, wave = tid >> 6;
  int wr = wave >> 1, wc = wave & 1;
  int rt = blockIdx.y * 128, ct = blockIdx.x * 128;

  int srow = tid >> 2;
  int skh  = (tid & 3) * 8;
  const _Float16* gA0 = WH + (size_t)(rt + srow)*KT + skh;
  const _Float16* gA1 = WL + (size_t)(rt + srow)*KT + skh;
  const _Float16* gB0 = FH + (size_t)(ct + srow)*fstride + foff + skh;
  const _Float16* gB1 = FL + (size_t)(ct + srow)*fstride + foff + skh;
  const size_t a2 = (size_t)64*KT;
  const size_t b2 = (size_t)64*fstride;
  _Float16* lA0 = &As[0][tid*8];
  _Float16* lA1 = &As[1][tid*8];
  _Float16* lB0 = &Bs[0][tid*8];
  _Float16* lB1 = &Bs[1][tid*8];

  f32x4 acc[4][4];
  #pragma unroll
  for (int m = 0; m < 4; ++m)
    #pragma unroll
    for (int n = 0; n < 4; ++n) acc[m][n] = (f32x4){0.f, 0.f, 0.f, 0.f};

  int fr = lane & 15;
  int kg = (lane >> 4) * 8;

  for (int k0 = 0; k0 < KT; k0 += 32) {
    gld16(gA0 + k0,      lA0);
    gld16(gA0 + k0 + a2, lA0 + 2048);
    gld16(gA1 + k0,      lA1);
    gld16(gA1 + k0 + a2, lA1 + 2048);
    gld16(gB0 + k0,      lB0);
    gld16(gB0 + k0 + b2, lB0 + 2048);
    gld16(gB1 + k0,      lB1);
    gld16(gB1 + k0 + b2, lB1 + 2048);
    __syncthreads();

    f16x8 ah[4], al[4], bh[4], bl[4];
    #pragma unroll
    for (int m = 0; m < 4; ++m) {
      int ro = (wr*64 + m*16 + fr)*32 + kg;
      ah[m] = *(const f16x8*)&As[0][ro];
      al[m] = *(const f16x8*)&As[1][ro];
    }
    #pragma unroll
    for (int n = 0; n < 4; ++n) {
      int co = (wc*64 + n*16 + fr)*32 + kg;
      bh[n] = *(const f16x8*)&Bs[0][co];
      bl[n] = *(const f16x8*)&Bs[1][co];
    }
    #pragma unroll
    for (int m = 0; m < 4; ++m)
      #pragma unroll
      for (int n = 0; n < 4; ++n) {
        acc[m][n] = __builtin_amdgcn_mfma_f32_16x16x32_f16(ah[m], bh[n], acc[m][n], 0, 0, 0);
        acc[m][n] = __builtin_amdgcn_mfma_f32_16x16x32_f16(ah[m], bl[n], acc[m][n], 0, 0, 0);
        acc[m][n] = __builtin_amdgcn_mfma_f32_16x16x32_f16(al[m], bh[n], acc[m][n], 0, 0, 0);
      }
    __syncthreads();
  }

  int rowg = (lane >> 4) * 4;
  if (CM) {
    int b = ct >> 12, n0 = ct & (NPTS-1);
    #pragma unroll
    for (int m = 0; m < 4; ++m) {
      int rbase = rt + wr*64 + m*16 + rowg;
      #pragma unroll
      for (int r4 = 0; r4 < 4; ++r4) {
        int r = rbase + r4;
        float bv = bias[r];
        float* po = Out + ((size_t)b*Mtot + r)*NPTS + n0 + wc*64 + fr;
        #pragma unroll
        for (int n = 0; n < 4; ++n) {
          float v = acc[m][n][r4] + bv;
          if (LRELU_) v = lrelu_f(v);
          po[n*16] = v;
        }
      }
    }
  } else {
    #pragma unroll
    for (int n = 0; n < 4; ++n) {
      int pt = ct + wc*64 + n*16 + fr;
      #pragma unroll
      for (int m = 0; m < 4; ++m) {
        int r0 = rt + wr*64 + m*16 + rowg;
        float4 v;
        v.x = acc[m][n][0] + bias[r0];
        v.y = acc[m][n][1] + bias[r0+1];
        v.z = acc[m][n][2] + bias[r0+2];
        v.w = acc[m][n][3] + bias[r0+3];
        if (LRELU_) { v.x = lrelu_f(v.x); v.y = lrelu_f(v.y); v.z = lrelu_f(v.z); v.w = lrelu_f(v.w); }
        *(float4*)&Out[(size_t)pt*ostride + r0] = v;
      }
    }
  }
}

// ---------------------------------------------------------------- fused gather + dg2 MFMA + x1/x2 group-max
__global__ __launch_bounds__(256) void dg2_fused(
    const _Float16* __restrict__ W2H, const _Float16* __restrict__ W2L, // [128][128]
    const float* __restrict__ UV1,      // [BN][256] (U|V)
    const int* __restrict__ IDXF,       // [BN][KNN]
    const float* __restrict__ bias,     // bdg2 [128]
    _Float16* __restrict__ FFH, _Float16* __restrict__ FFL)
{
  constexpr int RS = 136;
  __shared__ __align__(16) unsigned char smem[43520];
  _Float16* HsH = (_Float16*)smem;            // [80][RS]
  _Float16* HsL = (_Float16*)(smem + 21760);  // [80][RS]
  float*    Cs  = (float*)smem;               // [128][84] epilogue reuse
  __shared__ int js[80];
  __shared__ float4 mxs[128];

  int tid = threadIdx.x;
  int lane = tid & 63, wave = tid >> 6;
  size_t pt0 = (size_t)blockIdx.x * 4;
  size_t bbase = (pt0 >> 12) << 12;

  if (tid < 80) js[tid] = IDXF[pt0*KNN + tid];

  int fr = lane & 15, kg = (lane >> 4) * 8;
  f16x8 ah[2][4], al[2][4];
  #pragma unroll
  for (int m = 0; m < 2; ++m) {
    int row = wave*32 + m*16 + fr;
    #pragma unroll
    for (int ks = 0; ks < 4; ++ks) {
      ah[m][ks] = *(const f16x8*)&W2H[row*128 + ks*32 + kg];
      al[m][ks] = *(const f16x8*)&W2L[row*128 + ks*32 + kg];
    }
  }
  __syncthreads();   // js visible

  {
    int g = (tid >> 5) & 3, half = tid >> 7, c4 = tid & 31;
    size_t ptg = pt0 + g;
    float4 vv = *(const float4*)&UV1[ptg*256 + 128 + c4*4];
    float4 mx = make_float4(-1e30f, -1e30f, -1e30f, -1e30f);
    #pragma unroll
    for (int k = 0; k < 10; ++k) {
      int row = g*20 + half*10 + k;
      int j = js[row];
      float4 u = *(const float4*)&UV1[(bbase + (size_t)j)*256 + c4*4];
      float h0 = lrelu_f(u.x + vv.x);
      float h1 = lrelu_f(u.y + vv.y);
      float h2 = lrelu_f(u.z + vv.z);
      float h3 = lrelu_f(u.w + vv.w);
      f16x4 hh, hl;
      hh[0] = (_Float16)h0; hl[0] = (_Float16)(h0 - (float)hh[0]);
      hh[1] = (_Float16)h1; hl[1] = (_Float16)(h1 - (float)hh[1]);
      hh[2] = (_Float16)h2; hl[2] = (_Float16)(h2 - (float)hh[2]);
      hh[3] = (_Float16)h3; hl[3] = (_Float16)(h3 - (float)hh[3]);
      *(f16x4*)&HsH[row*RS + c4*4] = hh;
      *(f16x4*)&HsL[row*RS + c4*4] = hl;
      mx.x = fmaxf(mx.x, h0); mx.y = fmaxf(mx.y, h1);
      mx.z = fmaxf(mx.z, h2); mx.w = fmaxf(mx.w, h3);
    }
    if (half == 1) mxs[(g << 5) | c4] = mx;
    __syncthreads();
    if (half == 0) {
      float4 o = mxs[(g << 5) | c4];
      mx.x = fmaxf(mx.x, o.x); mx.y = fmaxf(mx.y, o.y);
      mx.z = fmaxf(mx.z, o.z); mx.w = fmaxf(mx.w, o.w);
      split_store(FFH, FFL, ptg*512 + c4*4 + 0, mx.x);
      split_store(FFH, FFL, ptg*512 + c4*4 + 1, mx.y);
      split_store(FFH, FFL, ptg*512 + c4*4 + 2, mx.z);
      split_store(FFH, FFL, ptg*512 + c4*4 + 3, mx.w);
    }
  }

  f32x4 acc[2][5];
  #pragma unroll
  for (int m = 0; m < 2; ++m)
    #pragma unroll
    for (int n = 0; n < 5; ++n) acc[m][n] = (f32x4){0.f, 0.f, 0.f, 0.f};

  #pragma unroll
  for (int ks = 0; ks < 4; ++ks) {
    f16x8 bh[5], bl[5];
    #pragma unroll
    for (int n = 0; n < 5; ++n) {
      int ro = (n*16 + fr)*RS + ks*32 + kg;
      bh[n] = *(const f16x8*)&HsH[ro];
      bl[n] = *(const f16x8*)&HsL[ro];
    }
    #pragma unroll
    for (int m = 0; m < 2; ++m)
      #pragma unroll
      for (int n = 0; n < 5; ++n) {
        acc[m][n] = __builtin_amdgcn_mfma_f32_16x16x32_f16(ah[m][ks], bh[n], acc[m][n], 0, 0, 0);
        acc[m][n] = __builtin_amdgcn_mfma_f32_16x16x32_f16(ah[m][ks], bl[n], acc[m][n], 0, 0, 0);
        acc[m][n] = __builtin_amdgcn_mfma_f32_16x16x32_f16(al[m][ks], bh[n], acc[m][n], 0, 0, 0);
      }
  }
  __syncthreads();

  int rowg = (lane >> 4) * 4;
  #pragma unroll
  for (int m = 0; m < 2; ++m) {
    int r = wave*32 + m*16 + rowg;
    #pragma unroll
    for (int n = 0; n < 5; ++n) {
      int p = n*16 + fr;
      #pragma unroll
      for (int q = 0; q < 4; ++q) Cs[(r+q)*84 + p] = acc[m][n][q];
    }
  }
  __syncthreads();

  #pragma unroll
  for (int t = 0; t < 2; ++t) {
    int task = tid + t*256;
    int r = task & 127, g = task >> 7;
    const float* cr = &Cs[r*84 + g*20];
    float m = cr[0];
    #pragma unroll
    for (int k = 1; k < 20; ++k) m = fmaxf(m, cr[k]);
    float v = lrelu_f(m + bias[r]);
    split_store(FFH, FFL, (pt0 + g)*512 + 128 + r, v);
  }
}

// ---------------------------------------------------------------- sn block: one point per block
__global__ __launch_bounds__(256) void sn_gather(
    const float* __restrict__ UV2, const int* __restrict__ IDXX,
    _Float16* __restrict__ FFH, _Float16* __restrict__ FFL)
{
  int tid = threadIdx.x;   // channel 0..255
  size_t pt = blockIdx.x;
  size_t bb = (pt >> 12) << 12;
  __shared__ int js[KNN];
  if (tid < KNN) js[tid] = IDXX[pt*KNN + tid];
  __syncthreads();
  float v = UV2[pt*512 + 256 + tid];
  float m = -1e30f;
  #pragma unroll
  for (int k = 0; k < KNN; ++k) {
    float h = lrelu_f(UV2[(bb + (size_t)js[k])*512 + tid] + v);
    m = fmaxf(m, h);
  }
  split_store(FFH, FFL, pt*512 + 256 + tid, m);
}

// ---------------------------------------------------------------- farthest point sampling (reg-resident, shuffle argmax)
__global__ __launch_bounds__(512) void fps_kernel(
    const float* __restrict__ xyz, int* __restrict__ SIDX)
{
  int b = blockIdx.x, tid = threadIdx.x;
  int lane = tid & 63, wave = tid >> 6;   // 8 waves
  const float* p = xyz + (size_t)b*3*NPTS;
  float px[8], py[8], pz[8], dist[8];
  #pragma unroll
  for (int j = 0; j < 8; ++j) {
    int i = tid + j*512;
    px[j] = p[i]; py[j] = p[NPTS+i]; pz[j] = p[2*NPTS+i];
    dist[j] = 1e10f;
  }
  __shared__ float bv[8], bx[8], by[8], bz[8];
  __shared__ int bi[8];
  float cx = p[0], cy = p[NPTS], cz = p[2*NPTS];
  int far = 0;
  for (int it = 0; it < 32; ++it) {
    if (tid == 0) SIDX[b*32 + it] = far;
    float lm = -1e30f, lx = 0.f, ly = 0.f, lz = 0.f; int li = 0;
    #pragma unroll
    for (int j = 0; j < 8; ++j) {
      float dx = px[j]-cx, dy = py[j]-cy, dz = pz[j]-cz;
      float d = dx*dx + dy*dy + dz*dz;
      float dm = fminf(dist[j], d);
      dist[j] = dm;
      bool sw = dm > lm;
      lm = sw ? dm : lm;
      li = sw ? (tid + j*512) : li;
      lx = sw ? px[j] : lx; ly = sw ? py[j] : ly; lz = sw ? pz[j] : lz;
    }
    #pragma unroll
    for (int k = 1; k < 64; k <<= 1) {
      float om = __shfl_xor(lm, k, 64);
      int   oi = __shfl_xor(li, k, 64);
      float ox = __shfl_xor(lx, k, 64);
      float oy = __shfl_xor(ly, k, 64);
      float oz = __shfl_xor(lz, k, 64);
      bool tk = (om > lm) || (om == lm && oi < li);
      lm = tk ? om : lm; li = tk ? oi : li;
      lx = tk ? ox : lx; ly = tk ? oy : ly; lz = tk ? oz : lz;
    }
    if (lane == 0) { bv[wave] = lm; bi[wave] = li; bx[wave] = lx; by[wave] = ly; bz[wave] = lz; }
    __syncthreads();
    float m0 = bv[0]; int i0 = bi[0];
    float X = bx[0], Y = by[0], Z = bz[0];
    #pragma unroll
    for (int w = 1; w < 8; ++w) {
      bool tk = (bv[w] > m0) || (bv[w] == m0 && bi[w] < i0);
      m0 = tk ? bv[w] : m0; i0 = tk ? bi[w] : i0;
      X = tk ? bx[w] : X; Y = tk ? by[w] : Y; Z = tk ? bz[w] : Z;
    }
    far = i0; cx = X; cy = Y; cz = Z;
    __syncthreads();
  }
}

// ---------------------------------------------------------------- k-farthest (8) among 32 samples
__global__ __launch_bounds__(128) void kfn_kernel(
    const float* __restrict__ xyz, const int* __restrict__ SIDX,
    int* __restrict__ NIDX)
{
  int tid = threadIdx.x;     // 0..127
  int b = tid >> 5, i = tid & 31;
  const float* p = xyz + (size_t)b*3*NPTS;
  __shared__ float sx[4][32], sy[4][32], sz[4][32];
  {
    int si = SIDX[b*32 + i];
    sx[b][i] = p[si]; sy[b][i] = p[NPTS+si]; sz[b][i] = p[2*NPTS+si];
  }
  __syncthreads();
  float xi = sx[b][i], yi = sy[b][i], zi = sz[b][i];
  float xxi = xi*xi + yi*yi + zi*zi;
  float bd[8]; int bi_[8];
  #pragma unroll
  for (int t = 0; t < 8; ++t) { bd[t] = -1e30f; bi_[t] = 0; }
  for (int j = 0; j < 32; ++j) {
    float xj = sx[b][j], yj = sy[b][j], zj = sz[b][j];
    float xxj = xj*xj + yj*yj + zj*zj;
    float d = xxi - 2.f*(xi*xj + yi*yj + zi*zj) + xxj;
    if (d > bd[7]) {
      float cd = d; int ci = j;
      #pragma unroll
      for (int t = 0; t < 8; ++t) {
        bool sw = bd[t] < cd;
        float nv = sw ? cd : bd[t];
        int   ni = sw ? ci : bi_[t];
        float ov = sw ? bd[t] : cd;
        int   oi = sw ? bi_[t] : ci;
        bd[t] = nv; bi_[t] = ni; cd = ov; ci = oi;
      }
    }
  }
  size_t o = (size_t)(b*32 + i)*8;
  #pragma unroll
  for (int t = 0; t < 8; ++t) NIDX[o+t] = bi_[t];
}

// ---------------------------------------------------------------- triplet terms
__global__ __launch_bounds__(256) void trip_kernel(
    const float* __restrict__ es0, const float* __restrict__ et0,
    const int* __restrict__ SIDX, const int* __restrict__ NIDX,
    float* __restrict__ ACC)
{
  int bi_ = blockIdx.x; int b = bi_ >> 5;
  int tid = threadIdx.x;
  __shared__ int js[8];
  __shared__ int ssi;
  if (tid == 0) ssi = SIDX[bi_];
  if (tid < 8) js[tid] = SIDX[b*32 + NIDX[bi_*8 + tid]];
  __syncthreads();
  int si = ssi;
  const float* es = es0 + (size_t)b*1024*NPTS;
  const float* et = et0 + (size_t)b*1024*NPTS;
  float sp = 0.f, sn = 0.f;
  for (int c = tid; c < 1024; c += 256) {
    const float* erow = et + (size_t)c*NPTS;
    float s = es[(size_t)c*NPTS + si];
    float d0 = s - erow[si]; sp += d0*d0;
    #pragma unroll
    for (int t = 0; t < 8; ++t) { float d1 = s - erow[js[t]]; sn += d1*d1; }
  }
  __shared__ float r1[256], r2[256];
  r1[tid] = sp; r2[tid] = sn; __syncthreads();
  for (int s2 = 128; s2 > 0; s2 >>= 1) {
    if (tid < s2) { r1[tid] += r1[tid+s2]; r2[tid] += r2[tid+s2]; }
    __syncthreads();
  }
  if (tid == 0) {
    float dp = r1[0] * (1.f/1024.f);
    float dn = r2[0] * (1.f/8192.f);
    float tr = fmaxf(0.f, 1.f - dn/(1.f + dp));
    atomicAdd(&ACC[0], tr);
  }
}

// ---------------------------------------------------------------- stats stage A: mse/mae partials + per-point partial norms
// 2048 blocks = 256 point-tiles x 8 channel-chunks. NO hot-address atomics:
// mse/mae partials go to per-block slots (plain stores); PS/PT atomics are
// spread over 16384 addresses (8 hitters each).
__global__ __launch_bounds__(256) void stats_a(
    const float* __restrict__ es0, const float* __restrict__ et0,
    float* __restrict__ PS, float* __restrict__ PT,
    float* __restrict__ MSEP, float* __restrict__ MAEP)
{
  int tid = threadIdx.x;
  int p = tid & 63, g = tid >> 6;        // g: wave index == channel subgroup
  int pt0 = (blockIdx.x & 255) * 64;     // 256 point-tiles of 64
  int chunk = blockIdx.x >> 8;           // 8 channel-chunks of 128
  int b = pt0 >> 12, n0 = pt0 & (NPTS-1);
  const float* es = es0 + (size_t)b*1024*NPTS + n0;
  const float* et = et0 + (size_t)b*1024*NPTS + n0;
  float ss = 0.f, tt = 0.f, sq = 0.f, ab = 0.f;
  int c0 = chunk * 128;
  for (int c = c0 + g; c < c0 + 128; c += 4) {
    float s = es[(size_t)c*NPTS + p];
    float t = et[(size_t)c*NPTS + p];
    ss += s*s; tt += t*t;
    float d = s - t;
    sq += d*d; ab += fabsf(d);
  }
  __shared__ float rs[4][64], rt[4][64];
  __shared__ float wq[4], wa[4];
  rs[g][p] = ss; rt[g][p] = tt;
  // wave-level sums for mse/mae (one barrier total, no tree)
  #pragma unroll
  for (int s2 = 32; s2 > 0; s2 >>= 1) {
    sq += __shfl_down(sq, s2, 64);
    ab += __shfl_down(ab, s2, 64);
  }
  if (p == 0) { wq[g] = sq; wa[g] = ab; }
  __syncthreads();
  if (tid < 64) {
    atomicAdd(&PS[pt0 + tid], rs[0][tid]+rs[1][tid]+rs[2][tid]+rs[3][tid]);
    atomicAdd(&PT[pt0 + tid], rt[0][tid]+rt[1][tid]+rt[2][tid]+rt[3][tid]);
  }
  if (tid == 0) {
    MSEP[blockIdx.x] = wq[0]+wq[1]+wq[2]+wq[3];
    MAEP[blockIdx.x] = wa[0]+wa[1]+wa[2]+wa[3];
  }
}

// ---------------------------------------------------------------- stats stage B: norm terms
__global__ __launch_bounds__(256) void stats_b(
    const float* __restrict__ PS, const float* __restrict__ PT,
    float* __restrict__ ACC)
{
  int i = blockIdx.x * 256 + threadIdx.x;
  float a = sqrtf(PS[i]) - 1.f;
  float c = sqrtf(PT[i]) - 1.f;
  float av = a*a, cv = c*c;
  #pragma unroll
  for (int s2 = 32; s2 > 0; s2 >>= 1) {
    av += __shfl_down(av, s2, 64);
    cv += __shfl_down(cv, s2, 64);
  }
  __shared__ float r1[4], r2[4];
  int lane = threadIdx.x & 63, wave = threadIdx.x >> 6;
  if (lane == 0) { r1[wave] = av; r2[wave] = cv; }
  __syncthreads();
  if (threadIdx.x == 0) {
    atomicAdd(&ACC[1], r1[0]+r1[1]+r1[2]+r1[3]);
    atomicAdd(&ACC[2], r2[0]+r2[1]+r2[2]+r2[3]);
  }
}

// ---------------------------------------------------------------- stats stage C: fold per-block mse/mae partials (single block)
__global__ __launch_bounds__(256) void stats_c(
    const float* __restrict__ MSEP, const float* __restrict__ MAEP,
    float* __restrict__ ACC)
{
  float sq = 0.f, ab = 0.f;
  for (int i = threadIdx.x; i < 2048; i += 256) { sq += MSEP[i]; ab += MAEP[i]; }
  #pragma unroll
  for (int s2 = 32; s2 > 0; s2 >>= 1) {
    sq += __shfl_down(sq, s2, 64);
    ab += __shfl_down(ab, s2, 64);
  }
  __shared__ float r1[4], r2[4];
  int lane = threadIdx.x & 63, wave = threadIdx.x >> 6;
  if (lane == 0) { r1[wave] = sq; r2[wave] = ab; }
  __syncthreads();
  if (threadIdx.x == 0) {
    ACC[3] = r1[0]+r1[1]+r1[2]+r1[3];
    ACC[4] = r2[0]+r2[1]+r2[2]+r2[3];
  }
}

// ---------------------------------------------------------------- finalize scalars
__global__ void finalize_kernel(const float* __restrict__ ACC, float* __restrict__ o3) {
  if (threadIdx.x == 0 && blockIdx.x == 0) {
    float ln1 = sqrtf(ACC[1] * (1.f/16384.f));
    float ln2 = sqrtf(ACC[2] * (1.f/16384.f));
    o3[0] = ACC[0]*(1.f/128.f) + (ln1 + ln2)*0.5f*0.03f;
    o3[1] = ACC[3] * (1.f/4194304.f);   // mean((s-t)^2)*B
    o3[2] = ACC[4] * (1.f/4194304.f);   // mean(|s-t|)*B
  }
}

// ================================================================ host
extern "C" void kernel_launch(void* const* d_in, const int* in_sizes, int n_in,
                              void* d_out, int out_size, void* d_ws, size_t ws_size,
                              hipStream_t stream) {
  (void)in_sizes; (void)n_in; (void)out_size;
  const float* src  = (const float*)d_in[0];
  const float* tgt  = (const float*)d_in[1];
  const float* w1   = (const float*)d_in[2];
  const float* b1   = (const float*)d_in[3];
  const float* w2   = (const float*)d_in[4];
  const float* b2   = (const float*)d_in[5];
  const float* wdg1 = (const float*)d_in[6];
  const float* bdg1 = (const float*)d_in[7];
  const float* wdg2 = (const float*)d_in[8];
  const float* bdg2 = (const float*)d_in[9];
  const float* wsn1 = (const float*)d_in[10];
  const float* bsn1 = (const float*)d_in[11];
  const float* w3   = (const float*)d_in[12];
  const float* b3   = (const float*)d_in[13];
  float* out = (float*)d_out;

  float* ws = (float*)d_ws;
  float*  XTP  = ws;                                   // BN*4 (float4 x,y,z,xx)
  float*  XT2  = XTP + (size_t)BN*4;                   // BN*64
  float*  XX2  = XT2 + (size_t)BN*64;                  // BN
  float*  UV1  = XX2 + BN;                             // BN*256
  _Float16* FFH = (_Float16*)(UV1 + (size_t)BN*256);   // BN*512 halves
  _Float16* FFL = FFH + (size_t)BN*512;                // BN*512 halves
  float*  UV2  = (float*)(FFL + (size_t)BN*512);       // BN*512
  float*  Dbuf = (float*)FFH;                          // NPTS*NPTS fp32 == FFH+FFL+UV2 (dead then)
  _Float16* XT2H = (_Float16*)(UV2 + (size_t)BN*512);  // BN*64 halves
  _Float16* XT2L = XT2H + (size_t)BN*64;               // BN*64 halves
  int*    IDXF = (int*)(XT2L + (size_t)BN*64);         // BN*KNN
  int*    IDXX = IDXF + (size_t)BN*KNN;                // BN*KNN
  _Float16* W2H = (_Float16*)(IDXX + (size_t)BN*KNN);  // 128*128 halves
  _Float16* W2L = W2H + 128*128;                       // 128*128 halves
  float*  BUV1 = (float*)(W2L + 128*128);              // 256
  float*  BUV2 = BUV1 + 256;                           // 512
  _Float16* W3H = (_Float16*)(BUV2 + 512);             // 1024*512 halves
  _Float16* W3L = W3H + 1024*512;
  _Float16* WH1 = W3L + 1024*512;                      // 256*64 halves
  _Float16* WL1 = WH1 + 256*64;
  _Float16* WH2 = WL1 + 256*64;                        // 512*128 halves
  _Float16* WL2 = WH2 + 512*128;
  int*    SIDX = (int*)(WL2 + 512*128);                // NB*32
  int*    NIDX = SIDX + NB*32;                         // NB*32*8
  float*  ACC  = (float*)(NIDX + NB*32*8);             // 8
  float*  PS   = ACC + 8;                              // BN
  float*  PT   = PS + BN;                              // BN
  float*  MSEP = PT + BN;                              // 2048
  float*  MAEP = MSEP + 2048;                          // 2048
  float*  Dmulti = MAEP + 2048;                        // optional: nd x NPTS*NPTS

  // how many dedicated D buffers fit? cap at 2 (keeps live D within L3)
  size_t used_floats = (size_t)(Dmulti - ws);
  size_t avail_floats = (ws_size / sizeof(float) > used_floats)
                      ? ws_size / sizeof(float) - used_floats : 0;
  int nd = (int)(avail_floats / ((size_t)NPTS * NPTS));
  if (nd > 2) nd = 2;

  prep_weights<<<2048, 256, 0, stream>>>(wdg1, bdg1, wdg2, wsn1, bsn1, w3,
                                         W2H, W2L, BUV1, BUV2,
                                         W3H, W3L, WH1, WL1, WH2, WL2);

  auto run_cloud = [&](const float* xyz, float* emb) {
    conv12<<<BN/4, 256, 0, stream>>>(xyz, w1, b1, w2, b2, XT2, XX2, XT2H, XT2L,
                                     (float4*)XTP);
    // xyz-space KNN: LDS-staged, 8 queries/block, all batches in one launch
    knn_xyz<<<BN/8, 512, 0, stream>>>((const float4*)XTP, IDXX);
    // feature-space KNN: triangular dist GEMM + select, nd batches per launch-pair
    if (nd >= 2) {
      for (int g0 = 0; g0 < NB; g0 += 2) {
        dist_gemm_tri<<<dim3(528, 2), 256, 0, stream>>>(XT2, XX2, Dmulti, g0);
        knn_select_feat<<<dim3(NPTS/4, 2), 256, 0, stream>>>(Dmulti, g0, IDXF);
      }
    } else {
      for (int bb = 0; bb < NB; ++bb) {
        dist_gemm_tri<<<dim3(528, 1), 256, 0, stream>>>(XT2, XX2, Dbuf, bb);
        knn_select_feat<<<dim3(NPTS/4, 1), 256, 0, stream>>>(Dbuf, bb, IDXF);
      }
    }
    // UV1 = WEFF1 * XT2 (f16x3 MFMA)
    mfma_gemm<false,false><<<dim3(BN/128, 2), 256, 0, stream>>>(
        WH1, WL1, 256, 64, XT2H, XT2L, 64, 0, BUV1, UV1, 256);
    // fused gather + dg2 MFMA -> x1 (cols 0..127) + x2 (cols 128..255)
    dg2_fused<<<BN/4, 256, 0, stream>>>(W2H, W2L, UV1, IDXF, bdg2, FFH, FFL);
    // UV2 = WEFF2 * x2 (f16x3 MFMA)
    mfma_gemm<false,false><<<dim3(BN/128, 4), 256, 0, stream>>>(
        WH2, WL2, 512, 128, FFH, FFL, 512, 128, BUV2, UV2, 512);
    sn_gather<<<BN, 256, 0, stream>>>(UV2, IDXX, FFH, FFL);
    // emb = lrelu(W3 * feat + b3), channel-major (f16x3 MFMA)
    mfma_gemm<true,true><<<dim3(BN/128, 8), 256, 0, stream>>>(
        W3H, W3L, 1024, 512, FFH, FFL, 512, 0, b3, emb, 0);
  };

  float* emb_s = out;
  float* emb_t = out + (size_t)BN*1024;
  run_cloud(src, emb_s);
  run_cloud(tgt, emb_t);

  hipMemsetAsync(ACC, 0, (8 + 2*BN)*sizeof(float), stream);
  fps_kernel<<<NB, 512, 0, stream>>>(src, SIDX);
  kfn_kernel<<<1, 128, 0, stream>>>(src, SIDX, NIDX);
  trip_kernel<<<NB*32, 256, 0, stream>>>(emb_s, emb_t, SIDX, NIDX, ACC);
  stats_a<<<2048, 256, 0, stream>>>(emb_s, emb_t, PS, PT, MSEP, MAEP);
  stats_b<<<BN/256, 256, 0, stream>>>(PS, PT, ACC);
  stats_c<<<1, 256, 0, stream>>>(MSEP, MAEP, ACC);
  finalize_kernel<<<1, 64, 0, stream>>>(ACC, out + (size_t)2*BN*1024);
}

// Round 9
// 1123.755 us; speedup vs baseline: 2.0401x; 1.0158x over previous
//
#include <hip/hip_runtime.h>
#include <cstdint>

#define NB 4
#define NPTS 4096
#define KNN 20
#define BN (NB*NPTS)     // 16384 (one cloud)
#define NBATCH 8         // both clouds: 0-3 src, 4-7 tgt
#define BN2 (2*BN)       // 32768

typedef _Float16 f16x8 __attribute__((ext_vector_type(8)));
typedef _Float16 f16x4 __attribute__((ext_vector_type(4)));
typedef float    f32x4 __attribute__((ext_vector_type(4)));

__device__ __forceinline__ float lrelu_f(float x) { return x > 0.f ? x : 0.2f * x; }

__device__ __forceinline__ float med3f(float c, float lo, float hi) {
#if defined(__has_builtin)
#if __has_builtin(__builtin_amdgcn_fmed3f)
  return __builtin_amdgcn_fmed3f(c, lo, hi);
#else
  return fminf(fmaxf(c, lo), hi);
#endif
#else
  return fminf(fmaxf(c, lo), hi);
#endif
}

// async global->LDS, 16B per lane (lane-linear LDS dest required)
__device__ __forceinline__ void gld16(const void* g, void* l) {
  __builtin_amdgcn_global_load_lds(
      (const __attribute__((address_space(1))) void*)g,
      (__attribute__((address_space(3))) void*)l,
      16, 0, 0);
}

__device__ __forceinline__ void split_store(_Float16* __restrict__ H, _Float16* __restrict__ L,
                                            size_t idx, float v) {
  _Float16 h = (_Float16)v;
  H[idx] = h;
  L[idx] = (_Float16)(v - (float)h);
}

// ---------------------------------------------------------------- DPP wave reductions (VALU pipe, no LDS round-trips)
__device__ __forceinline__ float wave_min_f32_dpp(float x) {
  int xi = __float_as_int(x); int t;
  t = __builtin_amdgcn_update_dpp(xi, xi, 0x111, 0xf, 0xf, false);
  x = fminf(x, __int_as_float(t)); xi = __float_as_int(x);
  t = __builtin_amdgcn_update_dpp(xi, xi, 0x112, 0xf, 0xf, false);
  x = fminf(x, __int_as_float(t)); xi = __float_as_int(x);
  t = __builtin_amdgcn_update_dpp(xi, xi, 0x114, 0xf, 0xf, false);
  x = fminf(x, __int_as_float(t)); xi = __float_as_int(x);
  t = __builtin_amdgcn_update_dpp(xi, xi, 0x118, 0xf, 0xf, false);
  x = fminf(x, __int_as_float(t)); xi = __float_as_int(x);
  t = __builtin_amdgcn_update_dpp(xi, xi, 0x142, 0xf, 0xf, false);
  x = fminf(x, __int_as_float(t)); xi = __float_as_int(x);
  t = __builtin_amdgcn_update_dpp(xi, xi, 0x143, 0xf, 0xf, false);
  x = fminf(x, __int_as_float(t)); xi = __float_as_int(x);
  return __int_as_float(__builtin_amdgcn_readlane(xi, 63));
}

__device__ __forceinline__ int wave_min_i32_dpp(int x) {
  int t;
  t = __builtin_amdgcn_update_dpp(x, x, 0x111, 0xf, 0xf, false); x = min(x, t);
  t = __builtin_amdgcn_update_dpp(x, x, 0x112, 0xf, 0xf, false); x = min(x, t);
  t = __builtin_amdgcn_update_dpp(x, x, 0x114, 0xf, 0xf, false); x = min(x, t);
  t = __builtin_amdgcn_update_dpp(x, x, 0x118, 0xf, 0xf, false); x = min(x, t);
  t = __builtin_amdgcn_update_dpp(x, x, 0x142, 0xf, 0xf, false); x = min(x, t);
  t = __builtin_amdgcn_update_dpp(x, x, 0x143, 0xf, 0xf, false); x = min(x, t);
  return __builtin_amdgcn_readlane(x, 63);
}

// ---------------------------------------------------------------- prep weights
__global__ __launch_bounds__(256) void prep_weights(
    const float* __restrict__ wdg1, const float* __restrict__ bdg1,
    const float* __restrict__ wdg2,
    const float* __restrict__ wsn1, const float* __restrict__ bsn1,
    const float* __restrict__ w3,
    _Float16* __restrict__ W2H, _Float16* __restrict__ W2L,
    float* __restrict__ BUV1, float* __restrict__ BUV2,
    _Float16* __restrict__ W3H, _Float16* __restrict__ W3L,
    _Float16* __restrict__ WH1, _Float16* __restrict__ WL1,
    _Float16* __restrict__ WH2, _Float16* __restrict__ WL2)
{
  int i = blockIdx.x * 256 + threadIdx.x;
  if (i < 512*1024) {           // w3 is already [M=1024][K=512]
    float v = w3[i];
    split_store(W3H, W3L, i, v);
  }
  if (i < 256*64) {             // WEFF1: [M=256][K=64]
    int r = i >> 6, c = i & 63;
    float v = (r < 128) ? wdg1[r*128 + c]
                        : (wdg1[(r-128)*128 + 64 + c] - wdg1[(r-128)*128 + c]);
    split_store(WH1, WL1, i, v);
  }
  if (i < 512*128) {            // WEFF2: [M=512][K=128]
    int r = i >> 7, c = i & 127;
    float v = (r < 256) ? wsn1[r*256 + c]
                        : (wsn1[(r-256)*256 + 128 + c] - wsn1[(r-256)*256 + c]);
    split_store(WH2, WL2, i, v);
  }
  if (i < 128*128) split_store(W2H, W2L, i, wdg2[i]);  // [M=o][K=c] identity layout
  if (i < 256) BUV1[i] = (i < 128) ? 0.f : bdg1[i-128];
  if (i < 512) BUV2[i] = (i < 256) ? 0.f : bsn1[i-256];
}

// ---------------------------------------------------------------- conv1 + conv2 fused (3->64->64) + packed xyz out
// Both clouds in one launch: batch 0-3 = src, 4-7 = tgt.
__global__ __launch_bounds__(256) void conv12(
    const float* __restrict__ src, const float* __restrict__ tgt,
    const float* __restrict__ w1, const float* __restrict__ b1,
    const float* __restrict__ w2, const float* __restrict__ b2,
    float* __restrict__ XT2, float* __restrict__ XX2,
    _Float16* __restrict__ XT2H, _Float16* __restrict__ XT2L,
    float4* __restrict__ XTP4)
{
  __shared__ float w2t[64*65];
  __shared__ float h1s[4][64];
  int tid = threadIdx.x;
  for (int i = tid; i < 4096; i += 256) {
    int o = i >> 6, c = i & 63;
    w2t[c*65 + o] = w2[i];
  }
  int g = tid >> 6, o = tid & 63;
  int pt = blockIdx.x*4 + g;
  int b = pt >> 12, n = pt & (NPTS-1);
  const float* p = ((b < NB) ? src : tgt) + (size_t)(b & (NB-1))*3*NPTS;
  float x = p[n], y = p[NPTS+n], z = p[2*NPTS+n];
  if (o == 0) {   // fused pack_xyz
    float4 v; v.x = x; v.y = y; v.z = z; v.w = x*x + y*y + z*z;
    XTP4[pt] = v;
  }
  float h1 = b1[o] + w1[o*3]*x + w1[o*3+1]*y + w1[o*3+2]*z;
  h1 = lrelu_f(h1);
  __syncthreads();
  h1s[g][o] = h1;
  __syncthreads();
  float acc = b2[o];
  #pragma unroll
  for (int c = 0; c < 64; ++c) acc = fmaf(w2t[c*65+o], h1s[g][c], acc);
  acc = lrelu_f(acc);
  XT2[(size_t)pt*64 + o] = acc;
  split_store(XT2H, XT2L, (size_t)pt*64 + o, acc);
  float v = acc*acc;
  #pragma unroll
  for (int s = 32; s > 0; s >>= 1) v += __shfl_down(v, s, 64);
  if (o == 0) XX2[pt] = v;
}

// ---------------------------------------------------------------- triangular distance GEMM
// blockIdx.y = local batch within group; batch = g0 + blockIdx.y (0..7 global).
__global__ __launch_bounds__(256) void dist_gemm_tri(
    const float* __restrict__ XT2, const float* __restrict__ XX2,
    float* __restrict__ Dbase, int g0)
{
  int lb = blockIdx.y;
  int batch = g0 + lb;
  const float* XQ  = XT2 + (size_t)batch*NPTS*64;
  const float* XXb = XX2 + (size_t)batch*NPTS;
  float* D = Dbase + (size_t)lb*NPTS*NPTS;

  // map blockIdx.x in [0,528) -> (ti,tj) with ti<=tj, NT=32
  int r = blockIdx.x, ti = 0;
  #pragma unroll 1
  for (;;) { int len = 32 - ti; if (r < len) break; r -= len; ++ti; }
  int tj = ti + r;
  int q0 = ti * 128, j0 = tj * 128;

  __shared__ float Qs[16][132];
  __shared__ float Xs[16][132];
  int tid = threadIdx.x;
  int rg = tid & 15, cg = tid >> 4;
  float acc[8][8];
  #pragma unroll
  for (int u = 0; u < 8; ++u)
    #pragma unroll
    for (int v = 0; v < 8; ++v) acc[u][v] = 0.f;

  for (int c0 = 0; c0 < 64; c0 += 16) {
    #pragma unroll
    for (int i = 0; i < 8; ++i) {
      int idx = tid + i*256;
      int kk = idx & 15, p = idx >> 4;
      Qs[kk][p] = XQ[(size_t)(q0+p)*64 + c0 + kk];
      Xs[kk][p] = XQ[(size_t)(j0+p)*64 + c0 + kk];
    }
    __syncthreads();
    #pragma unroll
    for (int kk = 0; kk < 16; ++kk) {
      float a[8], bb[8];
      #pragma unroll
      for (int u = 0; u < 8; ++u) a[u] = Qs[kk][rg*8+u];
      #pragma unroll
      for (int v = 0; v < 8; ++v) bb[v] = Xs[kk][cg*8+v];
      #pragma unroll
      for (int u = 0; u < 8; ++u)
        #pragma unroll
        for (int v = 0; v < 8; ++v) acc[u][v] = fmaf(a[u], bb[v], acc[u][v]);
    }
    __syncthreads();
  }
  // epilogue 1: D[q][j] = xx_j - 2*dot
  {
    float xxv[8];
    #pragma unroll
    for (int v = 0; v < 8; ++v) xxv[v] = XXb[j0 + cg*8 + v];
    #pragma unroll
    for (int u = 0; u < 8; ++u) {
      float* po = D + (size_t)(q0 + rg*8 + u)*NPTS + j0 + cg*8;
      #pragma unroll
      for (int v = 0; v < 8; ++v) po[v] = fmaf(-2.f, acc[u][v], xxv[v]);
    }
  }
  // epilogue 2 (off-diagonal): D[j][q] = xx_q - 2*dot (register-transposed tile)
  if (ti != tj) {
    float xxq[8];
    #pragma unroll
    for (int u = 0; u < 8; ++u) xxq[u] = XXb[q0 + rg*8 + u];
    #pragma unroll
    for (int v = 0; v < 8; ++v) {
      float* po = D + (size_t)(j0 + cg*8 + v)*NPTS + q0 + rg*8;
      float4 w0, w1;
      w0.x = fmaf(-2.f, acc[0][v], xxq[0]);
      w0.y = fmaf(-2.f, acc[1][v], xxq[1]);
      w0.z = fmaf(-2.f, acc[2][v], xxq[2]);
      w0.w = fmaf(-2.f, acc[3][v], xxq[3]);
      w1.x = fmaf(-2.f, acc[4][v], xxq[4]);
      w1.y = fmaf(-2.f, acc[5][v], xxq[5]);
      w1.z = fmaf(-2.f, acc[6][v], xxq[6]);
      w1.w = fmaf(-2.f, acc[7][v], xxq[7]);
      *(float4*)po = w0;
      *(float4*)(po + 4) = w1;
    }
  }
}

// ---------------------------------------------------------------- exact wave-level 20th-smallest
// Per-lane top-S + pop-min. EXACTNESS: every candidate a lane discards is >= the
// lane's FINAL bd[S-1]. So if all lanes satisfy lane_max >= thr, no candidate < thr
// was discarded -> thr is the true 20th-smallest. safe=false -> caller retries S=20
// (unconditionally exact).
template<int S, typename F>
__device__ __forceinline__ float find_thr(F getd4, bool& safe) {
  float bd[S];
  #pragma unroll
  for (int t = 0; t < S; ++t) bd[t] = 1e30f;
  #pragma unroll 4
  for (int t = 0; t < 16; ++t) {
    float4 dv = getd4(t);
    float ds[4] = {dv.x, dv.y, dv.z, dv.w};
    #pragma unroll
    for (int e = 0; e < 4; ++e) {
      float cd = ds[e];
      #pragma unroll
      for (int s = S-1; s >= 1; --s) bd[s] = med3f(cd, bd[s-1], bd[s]);
      bd[0] = fminf(bd[0], cd);
    }
  }
  float lane_max = bd[S-1];
  float thr = 1e30f;
  int total = 0;
  #pragma unroll 1
  for (int r = 0; r < KNN; ++r) {
    float m = wave_min_f32_dpp(bd[0]);
    unsigned long long bal = __ballot(bd[0] == m);
    total += __popcll(bal);
    if (total >= KNN) { thr = m; break; }
    if (bd[0] == m) {
      #pragma unroll
      for (int s = 0; s < S-1; ++s) bd[s] = bd[s+1];
      bd[S-1] = 1e30f;
    }
  }
  safe = !__any(lane_max < thr);
  return thr;
}

// ---------------------------------------------------------------- xyz-space knn: LDS-staged candidates (all 8 batches, one launch)
__global__ __launch_bounds__(512) void knn_xyz(
    const float4* __restrict__ XTP4, int* __restrict__ IDX)
{
  __shared__ float4 pts4[NPTS];   // 64 KB
  int tid = threadIdx.x;
  int lane = tid & 63;
  int wv = tid >> 6;                    // 0..7
  int blk = blockIdx.x;
  int bq = blk >> 9;                    // 512 blocks per batch, batch 0..7
  int ql = (blk & 511)*8 + wv;
  int qg = bq*NPTS + ql;
  const float4* Xb4 = XTP4 + (size_t)bq*NPTS;

  #pragma unroll
  for (int i = 0; i < 8; ++i)
    gld16(&Xb4[i*512 + tid], &pts4[i*512 + tid]);
  __syncthreads();   // drains vmcnt before reads

  float4 qp = pts4[ql];
  float qx = qp.x, qy = qp.y, qz = qp.z;

  auto key3 = [&](float4 p) -> float {
    float dot = qx*p.x;
    dot = fmaf(qy, p.y, dot);
    dot = fmaf(qz, p.z, dot);
    return fmaf(-2.f, dot, p.w);
  };
  auto getd4 = [&](int t) -> float4 {
    int jb = t*256 + lane;
    float4 r;
    r.x = key3(pts4[jb]);
    r.y = key3(pts4[jb+64]);
    r.z = key3(pts4[jb+128]);
    r.w = key3(pts4[jb+192]);
    return r;
  };

  bool safe;
  float thr = find_thr<8>(getd4, safe);
  if (!safe) { bool s2; thr = find_thr<KNN>(getd4, s2); }

  unsigned long long lml = (1ull << lane) - 1ull;
  int S = 0;
  int myj = 0x7fffffff;
  #pragma unroll 4
  for (int t = 0; t < 16; ++t) {
    float4 dv = getd4(t);
    float ds[4] = {dv.x, dv.y, dv.z, dv.w};
    int jb = t*256 + lane;
    #pragma unroll
    for (int e = 0; e < 4; ++e) {
      float d = ds[e];
      int j = jb + e*64;
      bool ps = d < thr;
      unsigned long long mk = __ballot(ps);
      int pos = S + __popcll(mk & lml);
      if (ps && pos < KNN) IDX[(size_t)qg*KNN + pos] = j;
      S += __popcll(mk);
      if (d == thr && j < myj) myj = j;
    }
  }
  int need = KNN - S;
  if (need == 1) {
    int mn = wave_min_i32_dpp(myj);
    if (lane == 0) IDX[(size_t)qg*KNN + S] = mn;
  } else if (need > 1) {
    if (lane == 0) {
      int taken = 0;
      for (int j = 0; j < NPTS && taken < need; ++j) {
        float d = key3(pts4[j]);
        if (d == thr) { IDX[(size_t)qg*KNN + S + taken] = j; ++taken; }
      }
    }
  }
}

// ---------------------------------------------------------------- feat-space knn select (reads D rows)
// blockIdx.y = local batch within group; batch = g0 + blockIdx.y (0..7 global).
__global__ __launch_bounds__(256) void knn_select_feat(
    const float* __restrict__ Dbase, int g0, int* __restrict__ IDX)
{
  int lb = blockIdx.y;
  int batch = g0 + lb;
  const float* D = Dbase + (size_t)lb*NPTS*NPTS;
  int lane = threadIdx.x & 63;
  int ql = blockIdx.x*4 + (threadIdx.x >> 6);   // query local to batch
  int qg = batch*NPTS + ql;                     // global point id (0..BN2)
  const float4* drow4 = (const float4*)(D + (size_t)ql*NPTS);

  auto getd4 = [&](int t) -> float4 {
    return drow4[t*64 + lane];
  };

  bool safe;
  float thr = find_thr<8>(getd4, safe);
  if (!safe) { bool s2; thr = find_thr<KNN>(getd4, s2); }

  unsigned long long lml = (1ull << lane) - 1ull;
  int S = 0;
  int myj = 0x7fffffff;
  #pragma unroll 4
  for (int t = 0; t < 16; ++t) {
    float4 dv = getd4(t);
    float ds[4] = {dv.x, dv.y, dv.z, dv.w};
    int jb = t*256 + lane*4;
    #pragma unroll
    for (int e = 0; e < 4; ++e) {
      float d = ds[e];
      int j = jb + e;
      bool ps = d < thr;
      unsigned long long mk = __ballot(ps);
      int pos = S + __popcll(mk & lml);
      if (ps && pos < KNN) IDX[(size_t)qg*KNN + pos] = j;
      S += __popcll(mk);
      if (d == thr && j < myj) myj = j;
    }
  }
  int need = KNN - S;
  if (need == 1) {
    int mn = wave_min_i32_dpp(myj);
    if (lane == 0) IDX[(size_t)qg*KNN + S] = mn;
  } else if (need > 1) {
    if (lane == 0) {
      int taken = 0;
      for (int j = 0; j < NPTS && taken < need; ++j) {
        float d = D[(size_t)ql*NPTS + j];
        if (d == thr) { IDX[(size_t)qg*KNN + S + taken] = j; ++taken; }
      }
    }
  }
}

// ---------------------------------------------------------------- f16x3 split MFMA GEMM (generic)
template<bool LRELU_, bool CM>
__global__ __launch_bounds__(256) void mfma_gemm(
    const _Float16* __restrict__ WH, const _Float16* __restrict__ WL,  // [Mtot][KT]
    int Mtot, int KT,
    const _Float16* __restrict__ FH, const _Float16* __restrict__ FL,  // [pt][fstride]
    int fstride, int foff,
    const float* __restrict__ bias,
    float* __restrict__ Out, int ostride)
{
  __shared__ _Float16 As[2][128*32];
  __shared__ _Float16 Bs[2][128*32];
  int tid = threadIdx.x;
  int lane = tid & 63, wave = tid >> 6;
  int wr = wave >> 1, wc = wave & 1;
  int rt = blockIdx.y * 128, ct = blockIdx.x * 128;

  int srow = tid >> 2;
  int skh  = (tid & 3) * 8;
  const _Float16* gA0 = WH + (size_t)(rt + srow)*KT + skh;
  const _Float16* gA1 = WL + (size_t)(rt + srow)*KT + skh;
  const _Float16* gB0 = FH + (size_t)(ct + srow)*fstride + foff + skh;
  const _Float16* gB1 = FL + (size_t)(ct + srow)*fstride + foff + skh;
  const size_t a2 = (size_t)64*KT;
  const size_t b2 = (size_t)64*fstride;
  _Float16* lA0 = &As[0][tid*8];
  _Float16* lA1 = &As[1][tid*8];
  _Float16* lB0 = &Bs[0][tid*8];
  _Float16* lB1 = &Bs[1][tid*8];

  f32x4 acc[4][4];
  #pragma unroll
  for (int m = 0; m < 4; ++m)
    #pragma unroll
    for (int n = 0; n < 4; ++n) acc[m][n] = (f32x4){0.f, 0.f, 0.f, 0.f};

  int fr = lane & 15;
  int kg = (lane >> 4) * 8;

  for (int k0 = 0; k0 < KT; k0 += 32) {
    gld16(gA0 + k0,      lA0);
    gld16(gA0 + k0 + a2, lA0 + 2048);
    gld16(gA1 + k0,      lA1);
    gld16(gA1 + k0 + a2, lA1 + 2048);
    gld16(gB0 + k0,      lB0);
    gld16(gB0 + k0 + b2, lB0 + 2048);
    gld16(gB1 + k0,      lB1);
    gld16(gB1 + k0 + b2, lB1 + 2048);
    __syncthreads();

    f16x8 ah[4], al[4], bh[4], bl[4];
    #pragma unroll
    for (int m = 0; m < 4; ++m) {
      int ro = (wr*64 + m*16 + fr)*32 + kg;
      ah[m] = *(const f16x8*)&As[0][ro];
      al[m] = *(const f16x8*)&As[1][ro];
    }
    #pragma unroll
    for (int n = 0; n < 4; ++n) {
      int co = (wc*64 + n*16 + fr)*32 + kg;
      bh[n] = *(const f16x8*)&Bs[0][co];
      bl[n] = *(const f16x8*)&Bs[1][co];
    }
    #pragma unroll
    for (int m = 0; m < 4; ++m)
      #pragma unroll
      for (int n = 0; n < 4; ++n) {
        acc[m][n] = __builtin_amdgcn_mfma_f32_16x16x32_f16(ah[m], bh[n], acc[m][n], 0, 0, 0);
        acc[m][n] = __builtin_amdgcn_mfma_f32_16x16x32_f16(ah[m], bl[n], acc[m][n], 0, 0, 0);
        acc[m][n] = __builtin_amdgcn_mfma_f32_16x16x32_f16(al[m], bh[n], acc[m][n], 0, 0, 0);
      }
    __syncthreads();
  }

  int rowg = (lane >> 4) * 4;
  if (CM) {
    int b = ct >> 12, n0 = ct & (NPTS-1);
    #pragma unroll
    for (int m = 0; m < 4; ++m) {
      int rbase = rt + wr*64 + m*16 + rowg;
      #pragma unroll
      for (int r4 = 0; r4 < 4; ++r4) {
        int r = rbase + r4;
        float bv = bias[r];
        float* po = Out + ((size_t)b*Mtot + r)*NPTS + n0 + wc*64 + fr;
        #pragma unroll
        for (int n = 0; n < 4; ++n) {
          float v = acc[m][n][r4] + bv;
          if (LRELU_) v = lrelu_f(v);
          po[n*16] = v;
        }
      }
    }
  } else {
    #pragma unroll
    for (int n = 0; n < 4; ++n) {
      int pt = ct + wc*64 + n*16 + fr;
      #pragma unroll
      for (int m = 0; m < 4; ++m) {
        int r0 = rt + wr*64 + m*16 + rowg;
        float4 v;
        v.x = acc[m][n][0] + bias[r0];
        v.y = acc[m][n][1] + bias[r0+1];
        v.z = acc[m][n][2] + bias[r0+2];
        v.w = acc[m][n][3] + bias[r0+3];
        if (LRELU_) { v.x = lrelu_f(v.x); v.y = lrelu_f(v.y); v.z = lrelu_f(v.z); v.w = lrelu_f(v.w); }
        *(float4*)&Out[(size_t)pt*ostride + r0] = v;
      }
    }
  }
}

// ---------------------------------------------------------------- fused gather + dg2 MFMA + x1/x2 group-max
__global__ __launch_bounds__(256) void dg2_fused(
    const _Float16* __restrict__ W2H, const _Float16* __restrict__ W2L, // [128][128]
    const float* __restrict__ UV1,      // [BN2][256] (U|V)
    const int* __restrict__ IDXF,       // [BN2][KNN]
    const float* __restrict__ bias,     // bdg2 [128]
    _Float16* __restrict__ FFH, _Float16* __restrict__ FFL)
{
  constexpr int RS = 136;
  __shared__ __align__(16) unsigned char smem[43520];
  _Float16* HsH = (_Float16*)smem;            // [80][RS]
  _Float16* HsL = (_Float16*)(smem + 21760);  // [80][RS]
  float*    Cs  = (float*)smem;               // [128][84] epilogue reuse
  __shared__ int js[80];
  __shared__ float4 mxs[128];

  int tid = threadIdx.x;
  int lane = tid & 63, wave = tid >> 6;
  size_t pt0 = (size_t)blockIdx.x * 4;
  size_t bbase = (pt0 >> 12) << 12;

  if (tid < 80) js[tid] = IDXF[pt0*KNN + tid];

  int fr = lane & 15, kg = (lane >> 4) * 8;
  f16x8 ah[2][4], al[2][4];
  #pragma unroll
  for (int m = 0; m < 2; ++m) {
    int row = wave*32 + m*16 + fr;
    #pragma unroll
    for (int ks = 0; ks < 4; ++ks) {
      ah[m][ks] = *(const f16x8*)&W2H[row*128 + ks*32 + kg];
      al[m][ks] = *(const f16x8*)&W2L[row*128 + ks*32 + kg];
    }
  }
  __syncthreads();   // js visible

  {
    int g = (tid >> 5) & 3, half = tid >> 7, c4 = tid & 31;
    size_t ptg = pt0 + g;
    float4 vv = *(const float4*)&UV1[ptg*256 + 128 + c4*4];
    float4 mx = make_float4(-1e30f, -1e30f, -1e30f, -1e30f);
    #pragma unroll
    for (int k = 0; k < 10; ++k) {
      int row = g*20 + half*10 + k;
      int j = js[row];
      float4 u = *(const float4*)&UV1[(bbase + (size_t)j)*256 + c4*4];
      float h0 = lrelu_f(u.x + vv.x);
      float h1 = lrelu_f(u.y + vv.y);
      float h2 = lrelu_f(u.z + vv.z);
      float h3 = lrelu_f(u.w + vv.w);
      f16x4 hh, hl;
      hh[0] = (_Float16)h0; hl[0] = (_Float16)(h0 - (float)hh[0]);
      hh[1] = (_Float16)h1; hl[1] = (_Float16)(h1 - (float)hh[1]);
      hh[2] = (_Float16)h2; hl[2] = (_Float16)(h2 - (float)hh[2]);
      hh[3] = (_Float16)h3; hl[3] = (_Float16)(h3 - (float)hh[3]);
      *(f16x4*)&HsH[row*RS + c4*4] = hh;
      *(f16x4*)&HsL[row*RS + c4*4] = hl;
      mx.x = fmaxf(mx.x, h0); mx.y = fmaxf(mx.y, h1);
      mx.z = fmaxf(mx.z, h2); mx.w = fmaxf(mx.w, h3);
    }
    if (half == 1) mxs[(g << 5) | c4] = mx;
    __syncthreads();
    if (half == 0) {
      float4 o = mxs[(g << 5) | c4];
      mx.x = fmaxf(mx.x, o.x); mx.y = fmaxf(mx.y, o.y);
      mx.z = fmaxf(mx.z, o.z); mx.w = fmaxf(mx.w, o.w);
      split_store(FFH, FFL, ptg*512 + c4*4 + 0, mx.x);
      split_store(FFH, FFL, ptg*512 + c4*4 + 1, mx.y);
      split_store(FFH, FFL, ptg*512 + c4*4 + 2, mx.z);
      split_store(FFH, FFL, ptg*512 + c4*4 + 3, mx.w);
    }
  }

  f32x4 acc[2][5];
  #pragma unroll
  for (int m = 0; m < 2; ++m)
    #pragma unroll
    for (int n = 0; n < 5; ++n) acc[m][n] = (f32x4){0.f, 0.f, 0.f, 0.f};

  #pragma unroll
  for (int ks = 0; ks < 4; ++ks) {
    f16x8 bh[5], bl[5];
    #pragma unroll
    for (int n = 0; n < 5; ++n) {
      int ro = (n*16 + fr)*RS + ks*32 + kg;
      bh[n] = *(const f16x8*)&HsH[ro];
      bl[n] = *(const f16x8*)&HsL[ro];
    }
    #pragma unroll
    for (int m = 0; m < 2; ++m)
      #pragma unroll
      for (int n = 0; n < 5; ++n) {
        acc[m][n] = __builtin_amdgcn_mfma_f32_16x16x32_f16(ah[m][ks], bh[n], acc[m][n], 0, 0, 0);
        acc[m][n] = __builtin_amdgcn_mfma_f32_16x16x32_f16(ah[m][ks], bl[n], acc[m][n], 0, 0, 0);
        acc[m][n] = __builtin_amdgcn_mfma_f32_16x16x32_f16(al[m][ks], bh[n], acc[m][n], 0, 0, 0);
      }
  }
  __syncthreads();

  int rowg = (lane >> 4) * 4;
  #pragma unroll
  for (int m = 0; m < 2; ++m) {
    int r = wave*32 + m*16 + rowg;
    #pragma unroll
    for (int n = 0; n < 5; ++n) {
      int p = n*16 + fr;
      #pragma unroll
      for (int q = 0; q < 4; ++q) Cs[(r+q)*84 + p] = acc[m][n][q];
    }
  }
  __syncthreads();

  #pragma unroll
  for (int t = 0; t < 2; ++t) {
    int task = tid + t*256;
    int r = task & 127, g = task >> 7;
    const float* cr = &Cs[r*84 + g*20];
    float m = cr[0];
    #pragma unroll
    for (int k = 1; k < 20; ++k) m = fmaxf(m, cr[k]);
    float v = lrelu_f(m + bias[r]);
    split_store(FFH, FFL, (pt0 + g)*512 + 128 + r, v);
  }
}

// ---------------------------------------------------------------- sn block: one point per block
__global__ __launch_bounds__(256) void sn_gather(
    const float* __restrict__ UV2, const int* __restrict__ IDXX,
    _Float16* __restrict__ FFH, _Float16* __restrict__ FFL)
{
  int tid = threadIdx.x;   // channel 0..255
  size_t pt = blockIdx.x;
  size_t bb = (pt >> 12) << 12;
  __shared__ int js[KNN];
  if (tid < KNN) js[tid] = IDXX[pt*KNN + tid];
  __syncthreads();
  float v = UV2[pt*512 + 256 + tid];
  float m = -1e30f;
  #pragma unroll
  for (int k = 0; k < KNN; ++k) {
    float h = lrelu_f(UV2[(bb + (size_t)js[k])*512 + tid] + v);
    m = fmaxf(m, h);
  }
  split_store(FFH, FFL, pt*512 + 256 + tid, m);
}

// ---------------------------------------------------------------- farthest point sampling (reg-resident, shuffle argmax)
__global__ __launch_bounds__(512) void fps_kernel(
    const float* __restrict__ xyz, int* __restrict__ SIDX)
{
  int b = blockIdx.x, tid = threadIdx.x;
  int lane = tid & 63, wave = tid >> 6;   // 8 waves
  const float* p = xyz + (size_t)b*3*NPTS;
  float px[8], py[8], pz[8], dist[8];
  #pragma unroll
  for (int j = 0; j < 8; ++j) {
    int i = tid + j*512;
    px[j] = p[i]; py[j] = p[NPTS+i]; pz[j] = p[2*NPTS+i];
    dist[j] = 1e10f;
  }
  __shared__ float bv[8], bx[8], by[8], bz[8];
  __shared__ int bi[8];
  float cx = p[0], cy = p[NPTS], cz = p[2*NPTS];
  int far = 0;
  for (int it = 0; it < 32; ++it) {
    if (tid == 0) SIDX[b*32 + it] = far;
    float lm = -1e30f, lx = 0.f, ly = 0.f, lz = 0.f; int li = 0;
    #pragma unroll
    for (int j = 0; j < 8; ++j) {
      float dx = px[j]-cx, dy = py[j]-cy, dz = pz[j]-cz;
      float d = dx*dx + dy*dy + dz*dz;
      float dm = fminf(dist[j], d);
      dist[j] = dm;
      bool sw = dm > lm;
      lm = sw ? dm : lm;
      li = sw ? (tid + j*512) : li;
      lx = sw ? px[j] : lx; ly = sw ? py[j] : ly; lz = sw ? pz[j] : lz;
    }
    #pragma unroll
    for (int k = 1; k < 64; k <<= 1) {
      float om = __shfl_xor(lm, k, 64);
      int   oi = __shfl_xor(li, k, 64);
      float ox = __shfl_xor(lx, k, 64);
      float oy = __shfl_xor(ly, k, 64);
      float oz = __shfl_xor(lz, k, 64);
      bool tk = (om > lm) || (om == lm && oi < li);
      lm = tk ? om : lm; li = tk ? oi : li;
      lx = tk ? ox : lx; ly = tk ? oy : ly; lz = tk ? oz : lz;
    }
    if (lane == 0) { bv[wave] = lm; bi[wave] = li; bx[wave] = lx; by[wave] = ly; bz[wave] = lz; }
    __syncthreads();
    float m0 = bv[0]; int i0 = bi[0];
    float X = bx[0], Y = by[0], Z = bz[0];
    #pragma unroll
    for (int w = 1; w < 8; ++w) {
      bool tk = (bv[w] > m0) || (bv[w] == m0 && bi[w] < i0);
      m0 = tk ? bv[w] : m0; i0 = tk ? bi[w] : i0;
      X = tk ? bx[w] : X; Y = tk ? by[w] : Y; Z = tk ? bz[w] : Z;
    }
    far = i0; cx = X; cy = Y; cz = Z;
    __syncthreads();
  }
}

// ---------------------------------------------------------------- k-farthest (8) among 32 samples
__global__ __launch_bounds__(128) void kfn_kernel(
    const float* __restrict__ xyz, const int* __restrict__ SIDX,
    int* __restrict__ NIDX)
{
  int tid = threadIdx.x;     // 0..127
  int b = tid >> 5, i = tid & 31;
  const float* p = xyz + (size_t)b*3*NPTS;
  __shared__ float sx[4][32], sy[4][32], sz[4][32];
  {
    int si = SIDX[b*32 + i];
    sx[b][i] = p[si]; sy[b][i] = p[NPTS+si]; sz[b][i] = p[2*NPTS+si];
  }
  __syncthreads();
  float xi = sx[b][i], yi = sy[b][i], zi = sz[b][i];
  float xxi = xi*xi + yi*yi + zi*zi;
  float bd[8]; int bi_[8];
  #pragma unroll
  for (int t = 0; t < 8; ++t) { bd[t] = -1e30f; bi_[t] = 0; }
  for (int j = 0; j < 32; ++j) {
    float xj = sx[b][j], yj = sy[b][j], zj = sz[b][j];
    float xxj = xj*xj + yj*yj + zj*zj;
    float d = xxi - 2.f*(xi*xj + yi*yj + zi*zj) + xxj;
    if (d > bd[7]) {
      float cd = d; int ci = j;
      #pragma unroll
      for (int t = 0; t < 8; ++t) {
        bool sw = bd[t] < cd;
        float nv = sw ? cd : bd[t];
        int   ni = sw ? ci : bi_[t];
        float ov = sw ? bd[t] : cd;
        int   oi = sw ? bi_[t] : ci;
        bd[t] = nv; bi_[t] = ni; cd = ov; ci = oi;
      }
    }
  }
  size_t o = (size_t)(b*32 + i)*8;
  #pragma unroll
  for (int t = 0; t < 8; ++t) NIDX[o+t] = bi_[t];
}

// ---------------------------------------------------------------- triplet terms
__global__ __launch_bounds__(256) void trip_kernel(
    const float* __restrict__ es0, const float* __restrict__ et0,
    const int* __restrict__ SIDX, const int* __restrict__ NIDX,
    float* __restrict__ ACC)
{
  int bi_ = blockIdx.x; int b = bi_ >> 5;
  int tid = threadIdx.x;
  __shared__ int js[8];
  __shared__ int ssi;
  if (tid == 0) ssi = SIDX[bi_];
  if (tid < 8) js[tid] = SIDX[b*32 + NIDX[bi_*8 + tid]];
  __syncthreads();
  int si = ssi;
  const float* es = es0 + (size_t)b*1024*NPTS;
  const float* et = et0 + (size_t)b*1024*NPTS;
  float sp = 0.f, sn = 0.f;
  for (int c = tid; c < 1024; c += 256) {
    const float* erow = et + (size_t)c*NPTS;
    float s = es[(size_t)c*NPTS + si];
    float d0 = s - erow[si]; sp += d0*d0;
    #pragma unroll
    for (int t = 0; t < 8; ++t) { float d1 = s - erow[js[t]]; sn += d1*d1; }
  }
  __shared__ float r1[256], r2[256];
  r1[tid] = sp; r2[tid] = sn; __syncthreads();
  for (int s2 = 128; s2 > 0; s2 >>= 1) {
    if (tid < s2) { r1[tid] += r1[tid+s2]; r2[tid] += r2[tid+s2]; }
    __syncthreads();
  }
  if (tid == 0) {
    float dp = r1[0] * (1.f/1024.f);
    float dn = r2[0] * (1.f/8192.f);
    float tr = fmaxf(0.f, 1.f - dn/(1.f + dp));
    atomicAdd(&ACC[0], tr);
  }
}

// ---------------------------------------------------------------- stats stage A: mse/mae partials + per-point partial norms
__global__ __launch_bounds__(256) void stats_a(
    const float* __restrict__ es0, const float* __restrict__ et0,
    float* __restrict__ PS, float* __restrict__ PT,
    float* __restrict__ MSEP, float* __restrict__ MAEP)
{
  int tid = threadIdx.x;
  int p = tid & 63, g = tid >> 6;        // g: wave index == channel subgroup
  int pt0 = (blockIdx.x & 255) * 64;     // 256 point-tiles of 64
  int chunk = blockIdx.x >> 8;           // 8 channel-chunks of 128
  int b = pt0 >> 12, n0 = pt0 & (NPTS-1);
  const float* es = es0 + (size_t)b*1024*NPTS + n0;
  const float* et = et0 + (size_t)b*1024*NPTS + n0;
  float ss = 0.f, tt = 0.f, sq = 0.f, ab = 0.f;
  int c0 = chunk * 128;
  for (int c = c0 + g; c < c0 + 128; c += 4) {
    float s = es[(size_t)c*NPTS + p];
    float t = et[(size_t)c*NPTS + p];
    ss += s*s; tt += t*t;
    float d = s - t;
    sq += d*d; ab += fabsf(d);
  }
  __shared__ float rs[4][64], rt[4][64];
  __shared__ float wq[4], wa[4];
  rs[g][p] = ss; rt[g][p] = tt;
  #pragma unroll
  for (int s2 = 32; s2 > 0; s2 >>= 1) {
    sq += __shfl_down(sq, s2, 64);
    ab += __shfl_down(ab, s2, 64);
  }
  if (p == 0) { wq[g] = sq; wa[g] = ab; }
  __syncthreads();
  if (tid < 64) {
    atomicAdd(&PS[pt0 + tid], rs[0][tid]+rs[1][tid]+rs[2][tid]+rs[3][tid]);
    atomicAdd(&PT[pt0 + tid], rt[0][tid]+rt[1][tid]+rt[2][tid]+rt[3][tid]);
  }
  if (tid == 0) {
    MSEP[blockIdx.x] = wq[0]+wq[1]+wq[2]+wq[3];
    MAEP[blockIdx.x] = wa[0]+wa[1]+wa[2]+wa[3];
  }
}

// ---------------------------------------------------------------- stats stage B: norm terms
__global__ __launch_bounds__(256) void stats_b(
    const float* __restrict__ PS, const float* __restrict__ PT,
    float* __restrict__ ACC)
{
  int i = blockIdx.x * 256 + threadIdx.x;
  float a = sqrtf(PS[i]) - 1.f;
  float c = sqrtf(PT[i]) - 1.f;
  float av = a*a, cv = c*c;
  #pragma unroll
  for (int s2 = 32; s2 > 0; s2 >>= 1) {
    av += __shfl_down(av, s2, 64);
    cv += __shfl_down(cv, s2, 64);
  }
  __shared__ float r1[4], r2[4];
  int lane = threadIdx.x & 63, wave = threadIdx.x >> 6;
  if (lane == 0) { r1[wave] = av; r2[wave] = cv; }
  __syncthreads();
  if (threadIdx.x == 0) {
    atomicAdd(&ACC[1], r1[0]+r1[1]+r1[2]+r1[3]);
    atomicAdd(&ACC[2], r2[0]+r2[1]+r2[2]+r2[3]);
  }
}

// ---------------------------------------------------------------- stats stage C: fold per-block mse/mae partials (single block)
__global__ __launch_bounds__(256) void stats_c(
    const float* __restrict__ MSEP, const float* __restrict__ MAEP,
    float* __restrict__ ACC)
{
  float sq = 0.f, ab = 0.f;
  for (int i = threadIdx.x; i < 2048; i += 256) { sq += MSEP[i]; ab += MAEP[i]; }
  #pragma unroll
  for (int s2 = 32; s2 > 0; s2 >>= 1) {
    sq += __shfl_down(sq, s2, 64);
    ab += __shfl_down(ab, s2, 64);
  }
  __shared__ float r1[4], r2[4];
  int lane = threadIdx.x & 63, wave = threadIdx.x >> 6;
  if (lane == 0) { r1[wave] = sq; r2[wave] = ab; }
  __syncthreads();
  if (threadIdx.x == 0) {
    ACC[3] = r1[0]+r1[1]+r1[2]+r1[3];
    ACC[4] = r2[0]+r2[1]+r2[2]+r2[3];
  }
}

// ---------------------------------------------------------------- finalize scalars
__global__ void finalize_kernel(const float* __restrict__ ACC, float* __restrict__ o3) {
  if (threadIdx.x == 0 && blockIdx.x == 0) {
    float ln1 = sqrtf(ACC[1] * (1.f/16384.f));
    float ln2 = sqrtf(ACC[2] * (1.f/16384.f));
    o3[0] = ACC[0]*(1.f/128.f) + (ln1 + ln2)*0.5f*0.03f;
    o3[1] = ACC[3] * (1.f/4194304.f);   // mean((s-t)^2)*B
    o3[2] = ACC[4] * (1.f/4194304.f);   // mean(|s-t|)*B
  }
}

// ================================================================ host
extern "C" void kernel_launch(void* const* d_in, const int* in_sizes, int n_in,
                              void* d_out, int out_size, void* d_ws, size_t ws_size,
                              hipStream_t stream) {
  (void)in_sizes; (void)n_in; (void)out_size;
  const float* src  = (const float*)d_in[0];
  const float* tgt  = (const float*)d_in[1];
  const float* w1   = (const float*)d_in[2];
  const float* b1   = (const float*)d_in[3];
  const float* w2   = (const float*)d_in[4];
  const float* b2   = (const float*)d_in[5];
  const float* wdg1 = (const float*)d_in[6];
  const float* bdg1 = (const float*)d_in[7];
  const float* wdg2 = (const float*)d_in[8];
  const float* bdg2 = (const float*)d_in[9];
  const float* wsn1 = (const float*)d_in[10];
  const float* bsn1 = (const float*)d_in[11];
  const float* w3   = (const float*)d_in[12];
  const float* b3   = (const float*)d_in[13];
  float* out = (float*)d_out;

  float* ws = (float*)d_ws;
  float*  XTP  = ws;                                   // BN2*4 (float4 x,y,z,xx)
  float*  XT2  = XTP + (size_t)BN2*4;                  // BN2*64
  float*  XX2  = XT2 + (size_t)BN2*64;                 // BN2
  float*  UV1  = XX2 + BN2;                            // BN2*256
  _Float16* FFH = (_Float16*)(UV1 + (size_t)BN2*256);  // BN2*512 halves
  _Float16* FFL = FFH + (size_t)BN2*512;               // BN2*512 halves
  float*  UV2  = (float*)(FFL + (size_t)BN2*512);      // BN2*512
  float*  Dbuf = (float*)FFH;                          // fallback: NPTS*NPTS fp32 aliases FFH+FFL (dead then)
  _Float16* XT2H = (_Float16*)(UV2 + (size_t)BN2*512); // BN2*64 halves
  _Float16* XT2L = XT2H + (size_t)BN2*64;              // BN2*64 halves
  int*    IDXF = (int*)(XT2L + (size_t)BN2*64);        // BN2*KNN
  int*    IDXX = IDXF + (size_t)BN2*KNN;               // BN2*KNN
  _Float16* W2H = (_Float16*)(IDXX + (size_t)BN2*KNN); // 128*128 halves
  _Float16* W2L = W2H + 128*128;                       // 128*128 halves
  float*  BUV1 = (float*)(W2L + 128*128);              // 256
  float*  BUV2 = BUV1 + 256;                           // 512
  _Float16* W3H = (_Float16*)(BUV2 + 512);             // 1024*512 halves
  _Float16* W3L = W3H + 1024*512;
  _Float16* WH1 = W3L + 1024*512;                      // 256*64 halves
  _Float16* WL1 = WH1 + 256*64;
  _Float16* WH2 = WL1 + 256*64;                        // 512*128 halves
  _Float16* WL2 = WH2 + 512*128;
  int*    SIDX = (int*)(WL2 + 512*128);                // NB*32
  int*    NIDX = SIDX + NB*32;                         // NB*32*8
  float*  ACC  = (float*)(NIDX + NB*32*8);             // 8
  float*  PS   = ACC + 8;                              // BN
  float*  PT   = PS + BN;                              // BN
  float*  MSEP = PT + BN;                              // 2048
  float*  MAEP = MSEP + 2048;                          // 2048
  float*  Dmulti = MAEP + 2048;                        // optional: nd x NPTS*NPTS

  // how many dedicated D buffers fit? cap at 2 (keeps live D within L3)
  size_t used_floats = (size_t)(Dmulti - ws);
  size_t avail_floats = (ws_size / sizeof(float) > used_floats)
                      ? ws_size / sizeof(float) - used_floats : 0;
  int nd = (int)(avail_floats / ((size_t)NPTS * NPTS));
  if (nd > 2) nd = 2;

  prep_weights<<<2048, 256, 0, stream>>>(wdg1, bdg1, wdg2, wsn1, bsn1, w3,
                                         W2H, W2L, BUV1, BUV2,
                                         W3H, W3L, WH1, WL1, WH2, WL2);

  // ---- both clouds batched: batches 0-3 = src, 4-7 = tgt --------------
  conv12<<<BN2/4, 256, 0, stream>>>(src, tgt, w1, b1, w2, b2,
                                    XT2, XX2, XT2H, XT2L, (float4*)XTP);
  // xyz-space KNN: all 8 batches, one launch
  knn_xyz<<<BN2/8, 512, 0, stream>>>((const float4*)XTP, IDXX);
  // feature-space KNN: triangular dist GEMM + select, nd batches per launch-pair
  if (nd >= 2) {
    for (int g0 = 0; g0 < NBATCH; g0 += 2) {
      dist_gemm_tri<<<dim3(528, 2), 256, 0, stream>>>(XT2, XX2, Dmulti, g0);
      knn_select_feat<<<dim3(NPTS/4, 2), 256, 0, stream>>>(Dmulti, g0, IDXF);
    }
  } else {
    for (int bb = 0; bb < NBATCH; ++bb) {
      dist_gemm_tri<<<dim3(528, 1), 256, 0, stream>>>(XT2, XX2, Dbuf, bb);
      knn_select_feat<<<dim3(NPTS/4, 1), 256, 0, stream>>>(Dbuf, bb, IDXF);
    }
  }
  // UV1 = WEFF1 * XT2 (f16x3 MFMA), both clouds
  mfma_gemm<false,false><<<dim3(BN2/128, 2), 256, 0, stream>>>(
      WH1, WL1, 256, 64, XT2H, XT2L, 64, 0, BUV1, UV1, 256);
  // fused gather + dg2 MFMA -> x1 (cols 0..127) + x2 (cols 128..255)
  dg2_fused<<<BN2/4, 256, 0, stream>>>(W2H, W2L, UV1, IDXF, bdg2, FFH, FFL);
  // UV2 = WEFF2 * x2 (f16x3 MFMA)
  mfma_gemm<false,false><<<dim3(BN2/128, 4), 256, 0, stream>>>(
      WH2, WL2, 512, 128, FFH, FFL, 512, 128, BUV2, UV2, 512);
  sn_gather<<<BN2, 256, 0, stream>>>(UV2, IDXX, FFH, FFL);
  // emb = lrelu(W3 * feat + b3), channel-major; out holds emb_s|emb_t contiguously
  mfma_gemm<true,true><<<dim3(BN2/128, 8), 256, 0, stream>>>(
      W3H, W3L, 1024, 512, FFH, FFL, 512, 0, b3, out, 0);

  float* emb_s = out;
  float* emb_t = out + (size_t)BN*1024;

  hipMemsetAsync(ACC, 0, (8 + 2*BN)*sizeof(float), stream);
  fps_kernel<<<NB, 512, 0, stream>>>(src, SIDX);
  kfn_kernel<<<1, 128, 0, stream>>>(src, SIDX, NIDX);
  trip_kernel<<<NB*32, 256, 0, stream>>>(emb_s, emb_t, SIDX, NIDX, ACC);
  stats_a<<<2048, 256, 0, stream>>>(emb_s, emb_t, PS, PT, MSEP, MAEP);
  stats_b<<<BN/256, 256, 0, stream>>>(PS, PT, ACC);
  stats_c<<<1, 256, 0, stream>>>(MSEP, MAEP, ACC);
  finalize_kernel<<<1, 64, 0, stream>>>(ACC, out + (size_t)2*BN*1024);
}